// Round 10
// baseline (426.350 us; speedup 1.0000x reference)
//
#include <hip/hip_runtime.h>
#include <cstdint>

#define BB    256
#define NNODE 256
#define PP2   64
#define DD    128
#define LLAY  2
#define KNN   9
#define FFND  512
#define BNROWS (BB*NNODE)   // 65536

#define LRELU_(v) ((v) >= 0.f ? (v) : 0.01f*(v))

enum { ACT_NONE = 0, ACT_LRELU = 1 };

constexpr int H2STR  = 136; // h2 LDS stride (shorts)

typedef short  short8_t  __attribute__((ext_vector_type(8)));
typedef float  f32x4     __attribute__((ext_vector_type(4)));
typedef unsigned short us4 __attribute__((ext_vector_type(4)));

__device__ inline unsigned short f2bf(float x) {
    unsigned u = __float_as_uint(x);
    unsigned r = (u + 0x7FFFu + ((u >> 16) & 1u)) >> 16;
    return (unsigned short)r;
}
__device__ inline float bf2f(unsigned short h) {
    return __uint_as_float(((unsigned)h) << 16);
}

// async global->LDS, 16B per lane; LDS dest must be wave-uniform base.
__device__ inline void gload16(const void* src, void* dst) {
    __builtin_amdgcn_global_load_lds(
        (const __attribute__((address_space(1))) void*)src,
        (__attribute__((address_space(3))) void*)dst, 16, 0, 0);
}

// Stage a BK=64 bf16 tile (ROWS x 64 elems, 128B rows) from row-major global
// (element stride Kel, starting col k0) into LINEAR LDS via global_load_lds.
// Source address carries the inverse XOR swizzle; reads apply the same XOR.
template<int ROWS, int WAVES>
__device__ inline void stage64g(const unsigned short* __restrict__ g, size_t rowbase,
                                int Kel, int k0, unsigned short* lds, int w, int lane)
{
    constexpr int PER = (ROWS*128/1024) / WAVES;
    #pragma unroll
    for (int i = 0; i < PER; ++i) {
        const int inst = w + i*WAVES;                 // wave-uniform
        const unsigned o  = (unsigned)inst*1024u + (unsigned)lane*16u;
        const int      r  = (int)(o >> 7);
        const unsigned cb = o & 127u;
        const unsigned cs = cb ^ ((unsigned)(r & 7) << 4);
        gload16((const char*)(g + (rowbase + (size_t)r)*(size_t)Kel + k0) + cs,
                (char*)lds + (size_t)inst*1024u);
    }
}

// swizzled fragment read from a linear BK=64 tile
__device__ inline short8_t frag64(const unsigned short* lds, int r, int cb) {
    return *reinterpret_cast<const short8_t*>(
        (const char*)lds + (size_t)r*128 + (unsigned)(cb ^ ((r & 7) << 4)));
}

// 16-lane-group min (per DPP row); result in ALL lanes of each 16-group.
__device__ inline unsigned grp16_min_u32(unsigned v) {
    unsigned t;
    t = (unsigned)__builtin_amdgcn_update_dpp(-1, (int)v, 0xB1,  0xF, 0xF, false); v = t < v ? t : v; // quad_perm [1,0,3,2]
    t = (unsigned)__builtin_amdgcn_update_dpp(-1, (int)v, 0x4E,  0xF, 0xF, false); v = t < v ? t : v; // quad_perm [2,3,0,1]
    t = (unsigned)__builtin_amdgcn_update_dpp(-1, (int)v, 0x124, 0xF, 0xF, false); v = t < v ? t : v; // row_ror:4
    t = (unsigned)__builtin_amdgcn_update_dpp(-1, (int)v, 0x128, 0xF, 0xF, false); v = t < v ? t : v; // row_ror:8
    return v;
}

// 16-lane (DPP row) sum; result valid in lane 15 of each 16-lane row.
__device__ inline float dpp_rowsum16(float v) {
    float t;
    t = __uint_as_float((unsigned)__builtin_amdgcn_update_dpp(0, (int)__float_as_uint(v), 0x111, 0xF, 0xF, false)); v += t;
    t = __uint_as_float((unsigned)__builtin_amdgcn_update_dpp(0, (int)__float_as_uint(v), 0x112, 0xF, 0xF, false)); v += t;
    t = __uint_as_float((unsigned)__builtin_amdgcn_update_dpp(0, (int)__float_as_uint(v), 0x114, 0xF, 0xF, false)); v += t;
    t = __uint_as_float((unsigned)__builtin_amdgcn_update_dpp(0, (int)__float_as_uint(v), 0x118, 0xF, 0xF, false)); v += t;
    return v;
}

// ---------------------------------------------------------------------------
// bf16 MFMA GEMM, BK=64, global_load_lds staging.
// ---------------------------------------------------------------------------
template<int ACT, bool RES, bool MASK, bool OUTF, bool OUTB, bool OUTS>
__global__ __launch_bounds__(256)
void bgemm_k(const unsigned short* __restrict__ A,
             const unsigned short* __restrict__ W,
             const float* __restrict__ bias,
             const float* __restrict__ resp,
             const int* __restrict__ mask,
             float* __restrict__ Cf, unsigned short* __restrict__ Cb,
             unsigned short* Ohi, unsigned short* Olo,
             int M, int N, int K)
{
    __shared__ __align__(16) unsigned short As[128*64];
    __shared__ __align__(16) unsigned short Bs[128*64];

    const int tid  = threadIdx.x;
    const int lane = tid & 63;
    const int w    = tid >> 6;
    const int wr   = w >> 1, wc = w & 1;
    const int row0 = blockIdx.x * 128;
    const int col0 = blockIdx.y * 128;
    const int l15  = lane & 15;
    const int ko   = lane >> 4;

    f32x4 acc[4][4];
    #pragma unroll
    for (int m = 0; m < 4; ++m)
        #pragma unroll
        for (int n = 0; n < 4; ++n) acc[m][n] = (f32x4){0.f,0.f,0.f,0.f};

    for (int k0 = 0; k0 < K; k0 += 64) {
        stage64g<128,4>(A, (size_t)row0, K, k0, As, w, lane);
        stage64g<128,4>(W, (size_t)col0, K, k0, Bs, w, lane);
        __syncthreads();
        #pragma unroll
        for (int ks = 0; ks < 2; ++ks) {
            short8_t aF[4], bF[4];
            #pragma unroll
            for (int m = 0; m < 4; ++m)
                aF[m] = frag64(As, wr*64 + m*16 + l15, ks*64 + ko*16);
            #pragma unroll
            for (int n = 0; n < 4; ++n)
                bF[n] = frag64(Bs, wc*64 + n*16 + l15, ks*64 + ko*16);
            #pragma unroll
            for (int m = 0; m < 4; ++m)
                #pragma unroll
                for (int n = 0; n < 4; ++n)
                    acc[m][n] = __builtin_amdgcn_mfma_f32_16x16x32_bf16(aF[m], bF[n], acc[m][n], 0, 0, 0);
        }
        __syncthreads();
    }

    #pragma unroll
    for (int m = 0; m < 4; ++m) {
        const int rbase = row0 + wr*64 + m*16 + ko*4;
        #pragma unroll
        for (int n = 0; n < 4; ++n) {
            const int col = col0 + wc*64 + n*16 + l15;
            const float bv = bias[col];
            #pragma unroll
            for (int r = 0; r < 4; ++r) {
                const int row = rbase + r;
                float v = acc[m][n][r] + bv;
                if constexpr (ACT == ACT_LRELU) v = LRELU_(v);
                if constexpr (RES)  v += resp[(size_t)row*N + col];
                if constexpr (MASK) v *= (mask[row] != 0) ? 1.f : 0.f;
                if constexpr (OUTF) Cf[(size_t)row*N + col] = v;
                if constexpr (OUTB) Cb[(size_t)row*N + col] = f2bf(v);
                if constexpr (OUTS) {
                    unsigned short h = f2bf(v);
                    Ohi[(size_t)row*N + col] = h;
                    Olo[(size_t)row*N + col] = f2bf(v - bf2f(h));
                }
            }
        }
    }
}

// ---------------------------------------------------------------------------
// bf16 MFMA GEMM fused with full-row LayerNorm epilogue (BK=64).
// AF32: A fp32, cast during (reg) staging into the same linear-swz layout.
// ---------------------------------------------------------------------------
template<int WR, int WC, bool DO_LRELU, bool MASKMUL, int MODE, bool AF32>
__global__ __launch_bounds__(WR*WC*64)
void bgemm_ln_k(const void* __restrict__ Ap,
                const unsigned short* __restrict__ W,
                const float* __restrict__ bias,
                const float* __restrict__ gam,
                const float* __restrict__ bet,
                const int* __restrict__ mask,
                void* __restrict__ outv,
                unsigned short* __restrict__ ohi, unsigned short* __restrict__ olo,
                int K)
{
    constexpr int BM = WR*64;
    constexpr int BN = WC*64;
    constexpr int THREADS = WR*WC*64;
    constexpr int WAVES = THREADS/64;
    __shared__ __align__(16) unsigned short As[BM*64];
    __shared__ __align__(16) unsigned short Bs[BN*64];
    __shared__ float red_s[WC][BM];
    __shared__ float red_q[WC][BM];
    __shared__ float mu_l[BM];
    __shared__ float rs_l[BM];

    const int tid  = threadIdx.x;
    const int lane = tid & 63;
    const int w    = tid >> 6;
    const int wr   = w / WC, wc = w % WC;
    const int row0 = blockIdx.x * BM;
    const int l15  = lane & 15;
    const int ko   = lane >> 4;

    f32x4 acc[4][4];
    #pragma unroll
    for (int m = 0; m < 4; ++m)
        #pragma unroll
        for (int n = 0; n < 4; ++n) acc[m][n] = (f32x4){0.f,0.f,0.f,0.f};

    for (int k0 = 0; k0 < K; k0 += 64) {
        if constexpr (AF32) {
            const float* Af = (const float*)Ap;
            constexpr int CH = (BM*8)/THREADS;    // 16B chunks per thread
            #pragma unroll
            for (int i = 0; i < CH; ++i) {
                const int q = i*THREADS + tid;
                const unsigned o  = (unsigned)q*16u;
                const int      r  = (int)(o >> 7);
                const unsigned cb = o & 127u;
                const unsigned cs = cb ^ ((unsigned)(r & 7) << 4);
                const float* src = Af + (size_t)(row0 + r)*K + k0 + (cs >> 1);
                const float4 f0 = *reinterpret_cast<const float4*>(src);
                const float4 f1 = *reinterpret_cast<const float4*>(src + 4);
                short8_t v;
                v[0]=(short)f2bf(f0.x); v[1]=(short)f2bf(f0.y); v[2]=(short)f2bf(f0.z); v[3]=(short)f2bf(f0.w);
                v[4]=(short)f2bf(f1.x); v[5]=(short)f2bf(f1.y); v[6]=(short)f2bf(f1.z); v[7]=(short)f2bf(f1.w);
                *reinterpret_cast<short8_t*>((char*)As + o) = v;
            }
        } else {
            stage64g<BM,WAVES>((const unsigned short*)Ap, (size_t)row0, K, k0, As, w, lane);
        }
        stage64g<BN,WAVES>(W, 0, K, k0, Bs, w, lane);
        __syncthreads();
        #pragma unroll
        for (int ks = 0; ks < 2; ++ks) {
            short8_t aF[4], bF[4];
            #pragma unroll
            for (int m = 0; m < 4; ++m)
                aF[m] = frag64(As, wr*64 + m*16 + l15, ks*64 + ko*16);
            #pragma unroll
            for (int n = 0; n < 4; ++n)
                bF[n] = frag64(Bs, wc*64 + n*16 + l15, ks*64 + ko*16);
            #pragma unroll
            for (int m = 0; m < 4; ++m)
                #pragma unroll
                for (int n = 0; n < 4; ++n)
                    acc[m][n] = __builtin_amdgcn_mfma_f32_16x16x32_bf16(aF[m], bF[n], acc[m][n], 0, 0, 0);
        }
        __syncthreads();
    }

    float bv[4];
    #pragma unroll
    for (int n = 0; n < 4; ++n) bv[n] = bias[wc*64 + n*16 + l15];
    #pragma unroll
    for (int m = 0; m < 4; ++m)
        #pragma unroll
        for (int n = 0; n < 4; ++n)
            #pragma unroll
            for (int r = 0; r < 4; ++r) acc[m][n][r] += bv[n];

    #pragma unroll
    for (int m = 0; m < 4; ++m) {
        #pragma unroll
        for (int r = 0; r < 4; ++r) {
            float s = acc[m][0][r] + acc[m][1][r] + acc[m][2][r] + acc[m][3][r];
            float q = acc[m][0][r]*acc[m][0][r] + acc[m][1][r]*acc[m][1][r]
                    + acc[m][2][r]*acc[m][2][r] + acc[m][3][r]*acc[m][3][r];
            s = dpp_rowsum16(s);
            q = dpp_rowsum16(q);
            if (l15 == 15) {
                int rl = wr*64 + m*16 + ko*4 + r;
                red_s[wc][rl] = s;
                red_q[wc][rl] = q;
            }
        }
    }
    __syncthreads();
    if (tid < BM) {
        float s = 0.f, q = 0.f;
        #pragma unroll
        for (int c2 = 0; c2 < WC; ++c2) { s += red_s[c2][tid]; q += red_q[c2][tid]; }
        float mu  = s * (1.0f/BN);
        float var = q * (1.0f/BN) - mu*mu;
        mu_l[tid] = mu;
        rs_l[tid] = rsqrtf(fmaxf(var, 0.f) + 1e-5f);
    }
    __syncthreads();

    float gm[4], bt[4];
    #pragma unroll
    for (int n = 0; n < 4; ++n) {
        int col = wc*64 + n*16 + l15;
        gm[n] = gam[col]; bt[n] = bet[col];
    }
    #pragma unroll
    for (int m = 0; m < 4; ++m) {
        #pragma unroll
        for (int r = 0; r < 4; ++r) {
            const int rl  = wr*64 + m*16 + ko*4 + r;
            const int row = row0 + rl;
            const float mu = mu_l[rl], rs = rs_l[rl];
            float mf = 1.f;
            if constexpr (MASKMUL) mf = (mask[row] != 0) ? 1.f : 0.f;
            #pragma unroll
            for (int n = 0; n < 4; ++n) {
                const int col = wc*64 + n*16 + l15;
                float y = (acc[m][n][r] - mu) * rs * gm[n] + bt[n];
                if constexpr (DO_LRELU) y = LRELU_(y);
                if constexpr (MASKMUL)  y *= mf;
                if constexpr (MODE == 1) {
                    ((unsigned short*)outv)[(size_t)row*BN + col] = f2bf(y);
                } else {
                    ((float*)outv)[(size_t)row*BN + col] = y;
                    unsigned short h = f2bf(y);
                    ohi[(size_t)row*BN + col] = h;
                    olo[(size_t)row*BN + col] = f2bf(y - bf2f(h));
                }
            }
        }
    }
}

// ---------------------------------------------------------------------------
// fc1 split-bf16 MFMA GEMM, 3 phases, BK=64, in-place OK, fused rowsq(x2).
// ---------------------------------------------------------------------------
__global__ __launch_bounds__(256)
void fc1mm_k(const unsigned short* Ahi, const unsigned short* Alo,
             const unsigned short* __restrict__ Bhi, const unsigned short* __restrict__ Blo,
             const float* __restrict__ bias,
             unsigned short* Ohi, unsigned short* Olo,
             float* __restrict__ x2out)
{
    __shared__ __align__(16) unsigned short As[128*64];
    __shared__ __align__(16) unsigned short Bs[128*64];
    __shared__ float red_q[2][128];

    const int tid  = threadIdx.x;
    const int lane = tid & 63;
    const int w    = tid >> 6;
    const int wr   = w >> 1, wc = w & 1;
    const int row0 = blockIdx.x * 128;
    const int l15  = lane & 15;
    const int ko   = lane >> 4;

    f32x4 acc[4][4];
    #pragma unroll
    for (int m = 0; m < 4; ++m)
        #pragma unroll
        for (int n = 0; n < 4; ++n) acc[m][n] = (f32x4){0.f,0.f,0.f,0.f};

    for (int kk = 0; kk < 384; kk += 64) {
        const int p  = kk >> 7;        // 0,0,1,1,2,2
        const int kl = kk & 127;
        const unsigned short* Ap2 = (p == 1) ? Alo : Ahi;
        const unsigned short* Bp2 = (p == 2) ? Blo : Bhi;
        stage64g<128,4>(Ap2, (size_t)row0, DD, kl, As, w, lane);
        stage64g<128,4>(Bp2, 0, DD, kl, Bs, w, lane);
        __syncthreads();
        #pragma unroll
        for (int ks = 0; ks < 2; ++ks) {
            short8_t aF[4], bF[4];
            #pragma unroll
            for (int m = 0; m < 4; ++m)
                aF[m] = frag64(As, wr*64 + m*16 + l15, ks*64 + ko*16);
            #pragma unroll
            for (int n = 0; n < 4; ++n)
                bF[n] = frag64(Bs, wc*64 + n*16 + l15, ks*64 + ko*16);
            #pragma unroll
            for (int m = 0; m < 4; ++m)
                #pragma unroll
                for (int n = 0; n < 4; ++n)
                    acc[m][n] = __builtin_amdgcn_mfma_f32_16x16x32_bf16(aF[m], bF[n], acc[m][n], 0, 0, 0);
        }
        __syncthreads();
    }

    float qacc[4][4];
    #pragma unroll
    for (int m = 0; m < 4; ++m) {
        const int rbase = row0 + wr*64 + m*16 + ko*4;
        #pragma unroll
        for (int r = 0; r < 4; ++r) qacc[m][r] = 0.f;
        #pragma unroll
        for (int n = 0; n < 4; ++n) {
            const int col = wc*64 + n*16 + l15;
            const float bv = bias[col];
            #pragma unroll
            for (int r = 0; r < 4; ++r) {
                const int row = rbase + r;
                float v = acc[m][n][r] + bv;
                unsigned short h = f2bf(v);
                unsigned short l = f2bf(v - bf2f(h));
                Ohi[(size_t)row*DD + col] = h;
                Olo[(size_t)row*DD + col] = l;
                float vv = bf2f(h) + bf2f(l);
                qacc[m][r] += vv*vv;
            }
        }
    }
    #pragma unroll
    for (int m = 0; m < 4; ++m)
        #pragma unroll
        for (int r = 0; r < 4; ++r) {
            float q = dpp_rowsum16(qacc[m][r]);
            if (l15 == 15) red_q[wc][wr*64 + m*16 + ko*4 + r] = q;
        }
    __syncthreads();
    if (tid < 128) x2out[row0 + tid] = red_q[0][tid] + red_q[1][tid];
}

// ---------------------------------------------------------------------------
// Fused distance + top-9: block = half-batch (128 rows x all 256 cols).
// Packed keys: (sortable_d2 & 0xFFFFFF00) | col.
// ---------------------------------------------------------------------------
__global__ __launch_bounds__(512)
void dist_topk_k(const unsigned short* __restrict__ hhi,
                 const unsigned short* __restrict__ hlo,
                 const int* __restrict__ mask,
                 const float* __restrict__ x2,
                 unsigned char* __restrict__ idx)
{
    __shared__ __align__(16) unsigned short BsH[NNODE*64];
    __shared__ __align__(16) unsigned short BsL[NNODE*64];

    const int b    = blockIdx.x >> 1;
    const int half = blockIdx.x & 1;
    const int tid  = threadIdx.x;
    const int lane = tid & 63;
    const int w    = tid >> 6;          // 0..7
    const int l15  = lane & 15;
    const int g    = lane >> 4;         // 0..3

    const unsigned short* Hhi = hhi + (size_t)b*NNODE*DD;
    const unsigned short* Hlo = hlo + (size_t)b*NNODE*DD;
    const float* x2b = x2 + b*NNODE;
    const int*   mkb = mask + b*NNODE;
    unsigned char* idxb = idx + (size_t)(b*NNODE + half*128)*KNN;

    const int arow = half*128 + w*16 + l15;

    f32x4 acc[16];
    #pragma unroll
    for (int n = 0; n < 16; ++n) acc[n] = (f32x4){0.f,0.f,0.f,0.f};

    for (int kl = 0; kl < DD; kl += 64) {
        stage64g<NNODE,8>(Hhi, 0, DD, kl, BsH, w, lane);
        stage64g<NNODE,8>(Hlo, 0, DD, kl, BsL, w, lane);
        __syncthreads();
        #pragma unroll
        for (int ks = 0; ks < 2; ++ks) {
            short8_t aH = frag64(BsH, arow, ks*64 + g*16);
            short8_t aL = frag64(BsL, arow, ks*64 + g*16);
            #pragma unroll
            for (int n = 0; n < 16; ++n) {
                int brow = n*16 + l15;
                short8_t bH = frag64(BsH, brow, ks*64 + g*16);
                short8_t bL = frag64(BsL, brow, ks*64 + g*16);
                acc[n] = __builtin_amdgcn_mfma_f32_16x16x32_bf16(aH, bH, acc[n], 0, 0, 0); // hi.hi
                acc[n] = __builtin_amdgcn_mfma_f32_16x16x32_bf16(aL, bH, acc[n], 0, 0, 0); // lo.hi
                acc[n] = __builtin_amdgcn_mfma_f32_16x16x32_bf16(aH, bL, acc[n], 0, 0, 0); // hi.lo
            }
        }
        __syncthreads();
    }

    float x2c[16]; unsigned mk[16];
    #pragma unroll
    for (int n = 0; n < 16; ++n) {
        int col = n*16 + l15;
        x2c[n] = x2b[col];
        mk[n]  = (mkb[col] != 0) ? 1u : 0u;
    }

    #pragma unroll
    for (int r = 0; r < 4; ++r) {
        const int lrow = w*16 + g*4 + r;
        const float x2r = x2b[half*128 + lrow];
        unsigned key[16];
        #pragma unroll
        for (int n = 0; n < 16; ++n) {
            float v = x2r + x2c[n] - 2.0f*acc[n][r];
            if (!mk[n]) v = 1e10f;
            unsigned u = __float_as_uint(v);
            u = (u & 0x80000000u) ? ~u : (u | 0x80000000u);
            key[n] = (u & 0xFFFFFF00u) | (unsigned)(n*16 + l15);
        }
        for (int it = 0; it < KNN; ++it) {
            unsigned a0 = key[0]  < key[1]  ? key[0]  : key[1];
            unsigned a1 = key[2]  < key[3]  ? key[2]  : key[3];
            unsigned a2 = key[4]  < key[5]  ? key[4]  : key[5];
            unsigned a3 = key[6]  < key[7]  ? key[6]  : key[7];
            unsigned a4 = key[8]  < key[9]  ? key[8]  : key[9];
            unsigned a5 = key[10] < key[11] ? key[10] : key[11];
            unsigned a6 = key[12] < key[13] ? key[12] : key[13];
            unsigned a7 = key[14] < key[15] ? key[14] : key[15];
            unsigned b0 = a0 < a1 ? a0 : a1;
            unsigned b1 = a2 < a3 ? a2 : a3;
            unsigned b2 = a4 < a5 ? a4 : a5;
            unsigned b3 = a6 < a7 ? a6 : a7;
            unsigned c0 = b0 < b1 ? b0 : b1;
            unsigned c1 = b2 < b3 ? b2 : b3;
            unsigned lmin = c0 < c1 ? c0 : c1;
            unsigned gmin = grp16_min_u32(lmin);
            if (l15 == 0) idxb[lrow*KNN + it] = (unsigned char)(gmin & 0xFFu);
            #pragma unroll
            for (int n = 0; n < 16; ++n)
                if (key[n] == gmin) key[n] = 0xFFFFFFFFu;
        }
    }
}

// ---------------------------------------------------------------------------
// Fused conv + fc2:  x += (lrelu(cat@Wc^T + cb)) @ W2^T + fb;  xhi = bf16(x)
// ---------------------------------------------------------------------------
__global__ __launch_bounds__(256)
void conv_fc2_k(const unsigned short* __restrict__ cat,
                const unsigned short* __restrict__ Wc,
                const float* __restrict__ cb,
                const unsigned short* __restrict__ W2,
                const float* __restrict__ fb,
                float* __restrict__ x,
                unsigned short* __restrict__ xhi)
{
    __shared__ __align__(16) unsigned short As[128*64];
    __shared__ __align__(16) unsigned short Bs[128*64];
    __shared__ __align__(16) unsigned short h2s[128*H2STR];

    const int tid  = threadIdx.x;
    const int lane = tid & 63;
    const int w    = tid >> 6;
    const int wr   = w >> 1, wc = w & 1;
    const int row0 = blockIdx.x * 128;
    const int l15  = lane & 15;
    const int ko   = lane >> 4;

    f32x4 acc[4][4];
    #pragma unroll
    for (int m = 0; m < 4; ++m)
        #pragma unroll
        for (int n = 0; n < 4; ++n) acc[m][n] = (f32x4){0.f,0.f,0.f,0.f};

    // stage 1: h2 = lrelu(cat @ Wc^T + cb), K=256
    for (int k0 = 0; k0 < 256; k0 += 64) {
        stage64g<128,4>(cat, (size_t)row0, 256, k0, As, w, lane);
        stage64g<128,4>(Wc, 0, 256, k0, Bs, w, lane);
        __syncthreads();
        #pragma unroll
        for (int ks = 0; ks < 2; ++ks) {
            short8_t aF[4], bF[4];
            #pragma unroll
            for (int m = 0; m < 4; ++m)
                aF[m] = frag64(As, wr*64 + m*16 + l15, ks*64 + ko*16);
            #pragma unroll
            for (int n = 0; n < 4; ++n)
                bF[n] = frag64(Bs, wc*64 + n*16 + l15, ks*64 + ko*16);
            #pragma unroll
            for (int m = 0; m < 4; ++m)
                #pragma unroll
                for (int n = 0; n < 4; ++n)
                    acc[m][n] = __builtin_amdgcn_mfma_f32_16x16x32_bf16(aF[m], bF[n], acc[m][n], 0, 0, 0);
        }
        __syncthreads();
    }

    #pragma unroll
    for (int n = 0; n < 4; ++n) {
        const int col = wc*64 + n*16 + l15;
        const float bv = cb[col];
        #pragma unroll
        for (int m = 0; m < 4; ++m) {
            const int rbase = wr*64 + m*16 + ko*4;
            #pragma unroll
            for (int r = 0; r < 4; ++r) {
                float v = acc[m][n][r] + bv;
                v = LRELU_(v);
                h2s[(rbase + r)*H2STR + col] = f2bf(v);
            }
        }
    }
    __syncthreads();

    // stage 2: out = h2 @ W2^T, K=128
    f32x4 acc2[4][4];
    #pragma unroll
    for (int m = 0; m < 4; ++m)
        #pragma unroll
        for (int n = 0; n < 4; ++n) acc2[m][n] = (f32x4){0.f,0.f,0.f,0.f};

    for (int k0 = 0; k0 < 128; k0 += 64) {
        stage64g<128,4>(W2, 0, 128, k0, Bs, w, lane);
        __syncthreads();
        #pragma unroll
        for (int ks = 0; ks < 2; ++ks) {
            short8_t aF[4], bF[4];
            #pragma unroll
            for (int m = 0; m < 4; ++m) {
                int r = wr*64 + m*16 + l15;
                aF[m] = *reinterpret_cast<const short8_t*>(&h2s[r*H2STR + k0 + ks*32 + ko*8]);
            }
            #pragma unroll
            for (int n = 0; n < 4; ++n)
                bF[n] = frag64(Bs, wc*64 + n*16 + l15, ks*64 + ko*16);
            #pragma unroll
            for (int m = 0; m < 4; ++m)
                #pragma unroll
                for (int n = 0; n < 4; ++n)
                    acc2[m][n] = __builtin_amdgcn_mfma_f32_16x16x32_bf16(aF[m], bF[n], acc2[m][n], 0, 0, 0);
        }
        __syncthreads();
    }

    #pragma unroll
    for (int m = 0; m < 4; ++m) {
        const int rbase = row0 + wr*64 + m*16 + ko*4;
        #pragma unroll
        for (int n = 0; n < 4; ++n) {
            const int col = wc*64 + n*16 + l15;
            const float bv = fb[col];
            #pragma unroll
            for (int r = 0; r < 4; ++r) {
                const int row = rbase + r;
                float v = acc2[m][n][r] + bv + x[(size_t)row*DD + col];
                x[(size_t)row*DD + col] = v;
                xhi[(size_t)row*DD + col] = f2bf(v);
            }
        }
    }
}

// ---------------------------------------------------------------------------
// Batch-resident gather + max-relative (one block per batch, h in LDS).
// Staging via global_load_lds (linear, no swizzle needed).
// ---------------------------------------------------------------------------
__global__ __launch_bounds__(512)
void gatherb_k(const unsigned short* __restrict__ hhi, const unsigned short* __restrict__ hlo,
               const unsigned char* __restrict__ idx, const int* __restrict__ mask,
               unsigned short* __restrict__ cat)
{
    __shared__ __align__(16) unsigned short hi_s[NNODE*DD];
    __shared__ __align__(16) unsigned short lo_s[NNODE*DD];
    __shared__ unsigned char  idx_s[NNODE*KNN];
    __shared__ unsigned char  msk_s[NNODE];

    const int b = blockIdx.x;
    const int t = threadIdx.x;
    const int w = t >> 6, lane = t & 63;
    const size_t hbase = (size_t)b*NNODE*DD;
    const unsigned char* idxg = idx + (size_t)b*NNODE*KNN;

    #pragma unroll
    for (int i = 0; i < 8; ++i) {
        const int inst = w + i*8;               // 64 x 1KB instrs per 128KB pair
        const size_t o = (size_t)inst*1024 + (size_t)lane*16;
        gload16((const char*)(hhi + hbase) + o, (char*)hi_s + (size_t)inst*1024);
        gload16((const char*)(hlo + hbase) + o, (char*)lo_s + (size_t)inst*1024);
    }
    for (int o = t; o < NNODE*KNN; o += 512) idx_s[o] = idxg[o];
    if (t < NNODE) msk_s[t] = (mask[b*NNODE + t] != 0) ? 1 : 0;
    __syncthreads();

    const int c4 = (t & 31) * 4;
    #pragma unroll 4
    for (int pass = 0; pass < 16; ++pass) {
        const int r = (t >> 5) + pass*16;
        us4 h4 = *reinterpret_cast<const us4*>(&hi_s[r*DD + c4]);
        us4 l4 = *reinterpret_cast<const us4*>(&lo_s[r*DD + c4]);
        float hi[4], m[4];
        #pragma unroll
        for (int d = 0; d < 4; ++d) { hi[d] = bf2f(h4[d]) + bf2f(l4[d]); m[d] = -1e9f; }
        bool any = false;
        #pragma unroll
        for (int q = 0; q < KNN; ++q) {
            int j = idx_s[r*KNN + q];
            if (msk_s[j]) {
                any = true;
                us4 a = *reinterpret_cast<const us4*>(&hi_s[j*DD + c4]);
                us4 o = *reinterpret_cast<const us4*>(&lo_s[j*DD + c4]);
                #pragma unroll
                for (int d = 0; d < 4; ++d)
                    m[d] = fmaxf(m[d], bf2f(a[d]) + bf2f(o[d]) - hi[d]);
            }
        }
        us4 o1, o2;
        #pragma unroll
        for (int d = 0; d < 4; ++d) {
            o1[d] = f2bf(hi[d]);
            o2[d] = any ? f2bf(m[d]) : (unsigned short)0;
        }
        const size_t rowbase = (size_t)(b*NNODE + r)*(2*DD);
        *reinterpret_cast<us4*>(&cat[rowbase + c4])      = o1;
        *reinterpret_cast<us4*>(&cat[rowbase + DD + c4]) = o2;
    }
}

__global__ __launch_bounds__(128)
void pool_k(const float* __restrict__ x, const int* __restrict__ mask,
            float* __restrict__ g, unsigned short* __restrict__ gbf)
{
    const int b = blockIdx.x, c = threadIdx.x;
    float s = 0.f; int cnt = 0;
    for (int n = 0; n < NNODE; ++n) {
        s += x[((size_t)b*NNODE + n)*DD + c];
        cnt += (mask[b*NNODE + n] != 0) ? 1 : 0;
    }
    float v = s / fmaxf((float)cnt, 1.0f);
    g[b*DD + c] = v;
    gbf[b*DD + c] = f2bf(v);
}

// ---------------------------------------------------------------------------
// All weight transpose-casts in ONE kernel (compile-time job table).
// ---------------------------------------------------------------------------
__global__ __launch_bounds__(256)
void prep_all_k(const float* __restrict__ emb_w1, const float* __restrict__ emb_w2,
                const float* __restrict__ conv_w, const float* __restrict__ fc2_w,
                const float* __restrict__ f1_w,   const float* __restrict__ f2_w,
                const float* __restrict__ fc1_w,  const float* __restrict__ ow1,
                const float* __restrict__ ow2,
                unsigned short* __restrict__ emb_w1t, unsigned short* __restrict__ emb_w2t,
                unsigned short* __restrict__ conv_wt, unsigned short* __restrict__ fc2_wt,
                unsigned short* __restrict__ ffn1_wt, unsigned short* __restrict__ ffn2_wt,
                unsigned short* __restrict__ fc1_wthi, unsigned short* __restrict__ fc1_wtlo,
                unsigned short* __restrict__ ow1t, unsigned short* __restrict__ ow2t)
{
    __shared__ float tile[32][33];
    const int tx = threadIdx.x & 31, ty = threadIdx.x >> 5;

    int bid = blockIdx.x;
    const float* src = nullptr; unsigned short* dst = nullptr; unsigned short* dlo = nullptr;
    int K = 0, N = 0;
    do {
        if (bid < 16)  { src = emb_w1; dst = emb_w1t; K = 64;  N = 256; break; }  bid -= 16;
        if (bid < 32)  { src = emb_w2; dst = emb_w2t; K = 256; N = 128; break; }  bid -= 32;
        if (bid < 64)  { int l = bid >> 5; bid &= 31;
                         src = conv_w + (size_t)l*256*128; dst = conv_wt + (size_t)l*128*256;
                         K = 256; N = 128; break; }                               bid -= 64;
        if (bid < 32)  { int l = bid >> 4; bid &= 15;
                         src = fc2_w + (size_t)l*128*128; dst = fc2_wt + (size_t)l*128*128;
                         K = 128; N = 128; break; }                               bid -= 32;
        if (bid < 128) { int l = bid >> 6; bid &= 63;
                         src = f1_w + (size_t)l*128*512; dst = ffn1_wt + (size_t)l*512*128;
                         K = 128; N = 512; break; }                               bid -= 128;
        if (bid < 128) { int l = bid >> 6; bid &= 63;
                         src = f2_w + (size_t)l*512*128; dst = ffn2_wt + (size_t)l*128*512;
                         K = 512; N = 128; break; }                               bid -= 128;
        if (bid < 32)  { int l = bid >> 4; bid &= 15;
                         src = fc1_w + (size_t)l*128*128;
                         dst = fc1_wthi + (size_t)l*128*128; dlo = fc1_wtlo + (size_t)l*128*128;
                         K = 128; N = 128; break; }                               bid -= 32;
        if (bid < 64)  { src = ow1; dst = ow1t; K = 128; N = 512; break; }        bid -= 64;
        { src = ow2; dst = ow2t; K = 512; N = 2048; }
    } while (0);

    const int nbx = N / 32;
    const int bx = bid % nbx, by = bid / nbx;
    const int k0 = by*32, n0 = bx*32;

    #pragma unroll
    for (int i = ty; i < 32; i += 8)
        tile[i][tx] = src[(size_t)(k0+i)*N + n0+tx];
    __syncthreads();
    #pragma unroll
    for (int i = ty; i < 32; i += 8) {
        float v = tile[tx][i];
        unsigned short h = f2bf(v);
        dst[(size_t)(n0+i)*K + k0+tx] = h;
        if (dlo) dlo[(size_t)(n0+i)*K + k0+tx] = f2bf(v - bf2f(h));
    }
}

// ---------------------------------------------------------------------------
extern "C" void kernel_launch(void* const* d_in, const int* in_sizes, int n_in,
                              void* d_out, int out_size, void* d_ws, size_t ws_size,
                              hipStream_t stream)
{
    const float* nodes  = (const float*)d_in[0];
    const int*   maskp  = (const int*)  d_in[1];
    const float* emb_w1 = (const float*)d_in[2];
    const float* emb_b1 = (const float*)d_in[3];
    const float* ln1_g  = (const float*)d_in[4];
    const float* ln1_b  = (const float*)d_in[5];
    const float* emb_w2 = (const float*)d_in[6];
    const float* emb_b2 = (const float*)d_in[7];
    const float* ln2_g  = (const float*)d_in[8];
    const float* ln2_b  = (const float*)d_in[9];
    const float* fc1_w  = (const float*)d_in[10];
    const float* fc1_b  = (const float*)d_in[11];
    const float* conv_w = (const float*)d_in[12];
    const float* conv_b = (const float*)d_in[13];
    const float* fc2_w  = (const float*)d_in[14];
    const float* fc2_b  = (const float*)d_in[15];
    const float* f1_w   = (const float*)d_in[16];
    const float* f1_b   = (const float*)d_in[17];
    const float* f2_w   = (const float*)d_in[18];
    const float* f2_b   = (const float*)d_in[19];
    const float* ow1    = (const float*)d_in[20];
    const float* ob1    = (const float*)d_in[21];
    const float* ow2    = (const float*)d_in[22];
    const float* ob2    = (const float*)d_in[23];
    float* out = (float*)d_out;

    // ---- workspace layout ----
    char* base = (char*)d_ws;
    float* x   = (float*)base;                          // 33.55 MB
    char*  H   = base + (size_t)BNROWS*DD*4;            // 33.55 MB (x_hi/x_lo <-> h_hi/h_lo)
    char*  BIG = H + (size_t)BNROWS*DD*4;               // 67.11 MB (t256 / cat / ffn hidden)
    float*          x2    = (float*)(BIG + (size_t)BNROWS*2*DD*4);
    unsigned char*  idx   = (unsigned char*)(x2 + BNROWS);
    float*          g     = (float*)(idx + (size_t)BNROWS*KNN);
    unsigned short* g_bf  = (unsigned short*)(g + BB*DD);
    unsigned short* hid2_bf = g_bf + BB*DD;
    unsigned short* wbuf  = hid2_bf + BB*FFND;

    unsigned short* x_hi   = (unsigned short*)H;
    unsigned short* x_lo   = x_hi + (size_t)BNROWS*DD;
    unsigned short* t256_bf= (unsigned short*)BIG;
    unsigned short* cat_bf = (unsigned short*)(BIG);    // reused regions
    unsigned short* hid_bf = (unsigned short*)BIG;

    unsigned short* emb_w1t  = wbuf;
    unsigned short* emb_w2t  = emb_w1t + 256*64;
    unsigned short* conv_wt  = emb_w2t + 128*256;
    unsigned short* fc2_wt   = conv_wt + 2*128*256;
    unsigned short* ffn1_wt  = fc2_wt  + 2*128*128;
    unsigned short* ffn2_wt  = ffn1_wt + 2*512*128;
    unsigned short* fc1_wthi = ffn2_wt + 2*128*512;
    unsigned short* fc1_wtlo = fc1_wthi + 2*128*128;
    unsigned short* ow1t     = fc1_wtlo + 2*128*128;
    unsigned short* ow2t     = ow1t + 512*128;

    const dim3 blk(256);

    // ---- all weight transpose-casts (one launch) ----
    prep_all_k<<<1520, blk, 0, stream>>>(
        emb_w1, emb_w2, conv_w, fc2_w, f1_w, f2_w, fc1_w, ow1, ow2,
        emb_w1t, emb_w2t, conv_wt, fc2_wt, ffn1_wt, ffn2_wt,
        fc1_wthi, fc1_wtlo, ow1t, ow2t);

    // ---- Embedding (GEMM + fused LN) ----
    bgemm_ln_k<2,4,true,false,1,true>
        <<<dim3(BNROWS/128), dim3(512), 0, stream>>>
        (nodes, emb_w1t, emb_b1, ln1_g, ln1_b, nullptr, t256_bf, nullptr, nullptr, PP2);
    bgemm_ln_k<2,2,false,true,2,false>
        <<<dim3(BNROWS/128), dim3(256), 0, stream>>>
        (t256_bf, emb_w2t, emb_b2, ln2_g, ln2_b, maskp, x, x_hi, x_lo, 2*DD);

    // ---- ViG blocks ----
    for (int l = 0; l < LLAY; ++l) {
        const float* fc1b = fc1_b + (size_t)l*DD;
        const float* cb   = conv_b + (size_t)l*DD;
        const float* fc2b = fc2_b + (size_t)l*DD;
        const float* b1   = f1_b + (size_t)l*FFND;
        const float* b2   = f2_b + (size_t)l*DD;

        fc1mm_k<<<dim3(BNROWS/128), blk, 0, stream>>>
            (x_hi, x_lo, fc1_wthi + (size_t)l*DD*DD, fc1_wtlo + (size_t)l*DD*DD,
             fc1b, x_hi, x_lo, x2);
        dist_topk_k<<<dim3(2*BB), dim3(512), 0, stream>>>
            (x_hi, x_lo, maskp, x2, idx);
        gatherb_k<<<BB, 512, 0, stream>>>(x_hi, x_lo, idx, maskp, cat_bf);
        conv_fc2_k<<<dim3(BNROWS/128), blk, 0, stream>>>
            (cat_bf, conv_wt + (size_t)l*DD*2*DD, cb,
             fc2_wt + (size_t)l*DD*DD, fc2b, x, x_hi);
        bgemm_k<ACT_LRELU,false,false,false,true,false>
            <<<dim3(BNROWS/128, FFND/128), blk, 0, stream>>>
            (x_hi, ffn1_wt + (size_t)l*FFND*DD, b1,
             nullptr, nullptr, nullptr, hid_bf, nullptr, nullptr, BNROWS, FFND, DD);
        bgemm_k<ACT_NONE,true,true,true,false,true>
            <<<dim3(BNROWS/128, 1), blk, 0, stream>>>
            (hid_bf, ffn2_wt + (size_t)l*DD*FFND, b2,
             x, maskp, x, nullptr, x_hi, x_lo, BNROWS, DD, FFND);
    }

    // ---- Pool + head (bf16 MFMA) ----
    pool_k<<<BB, 128, 0, stream>>>(x, maskp, g, g_bf);
    bgemm_k<ACT_LRELU,false,false,false,true,false>
        <<<dim3(BB/128, 512/128), blk, 0, stream>>>
        (g_bf, ow1t, ob1, nullptr, nullptr, nullptr, hid2_bf, nullptr, nullptr, BB, 512, DD);
    bgemm_k<ACT_NONE,false,false,true,false,false>
        <<<dim3(BB/128, 2048/128), blk, 0, stream>>>
        (hid2_bf, ow2t, ob2, nullptr, nullptr, out, nullptr, nullptr, nullptr, BB, 2048, 512);
}

// Round 11
// 402.137 us; speedup vs baseline: 1.0602x; 1.0602x over previous
//
#include <hip/hip_runtime.h>
#include <cstdint>

#define BB    256
#define NNODE 256
#define PP2   64
#define DD    128
#define LLAY  2
#define KNN   9
#define FFND  512
#define BNROWS (BB*NNODE)   // 65536

#define LRELU_(v) ((v) >= 0.f ? (v) : 0.01f*(v))

enum { ACT_NONE = 0, ACT_LRELU = 1 };

typedef short  short8_t  __attribute__((ext_vector_type(8)));
typedef float  f32x4     __attribute__((ext_vector_type(4)));
typedef unsigned short us4 __attribute__((ext_vector_type(4)));

__device__ inline unsigned short f2bf(float x) {
    unsigned u = __float_as_uint(x);
    unsigned r = (u + 0x7FFFu + ((u >> 16) & 1u)) >> 16;
    return (unsigned short)r;
}
__device__ inline float bf2f(unsigned short h) {
    return __uint_as_float(((unsigned)h) << 16);
}

// async global->LDS, 16B per lane; LDS dest must be wave-uniform base.
__device__ inline void gload16(const void* src, void* dst) {
    __builtin_amdgcn_global_load_lds(
        (const __attribute__((address_space(1))) void*)src,
        (__attribute__((address_space(3))) void*)dst, 16, 0, 0);
}

// Stage a BK=64 bf16 tile (ROWS x 64 elems, 128B rows) from row-major global
// (element stride Kel, starting col k0) into LINEAR LDS via global_load_lds.
// Source address carries the inverse XOR swizzle; reads apply the same XOR.
template<int ROWS, int WAVES>
__device__ inline void stage64g(const unsigned short* __restrict__ g, size_t rowbase,
                                int Kel, int k0, unsigned short* lds, int w, int lane)
{
    constexpr int PER = (ROWS*128/1024) / WAVES;
    #pragma unroll
    for (int i = 0; i < PER; ++i) {
        const int inst = w + i*WAVES;                 // wave-uniform
        const unsigned o  = (unsigned)inst*1024u + (unsigned)lane*16u;
        const int      r  = (int)(o >> 7);
        const unsigned cb = o & 127u;
        const unsigned cs = cb ^ ((unsigned)(r & 7) << 4);
        gload16((const char*)(g + (rowbase + (size_t)r)*(size_t)Kel + k0) + cs,
                (char*)lds + (size_t)inst*1024u);
    }
}

// swizzled fragment read from a linear BK=64 tile
__device__ inline short8_t frag64(const unsigned short* lds, int r, int cb) {
    return *reinterpret_cast<const short8_t*>(
        (const char*)lds + (size_t)r*128 + (unsigned)(cb ^ ((r & 7) << 4)));
}

// 16-lane-group min (per DPP row); result in ALL lanes of each 16-group.
__device__ inline unsigned grp16_min_u32(unsigned v) {
    unsigned t;
    t = (unsigned)__builtin_amdgcn_update_dpp(-1, (int)v, 0xB1,  0xF, 0xF, false); v = t < v ? t : v; // quad_perm [1,0,3,2]
    t = (unsigned)__builtin_amdgcn_update_dpp(-1, (int)v, 0x4E,  0xF, 0xF, false); v = t < v ? t : v; // quad_perm [2,3,0,1]
    t = (unsigned)__builtin_amdgcn_update_dpp(-1, (int)v, 0x124, 0xF, 0xF, false); v = t < v ? t : v; // row_ror:4
    t = (unsigned)__builtin_amdgcn_update_dpp(-1, (int)v, 0x128, 0xF, 0xF, false); v = t < v ? t : v; // row_ror:8
    return v;
}

// 16-lane (DPP row) sum; result valid in lane 15 of each 16-lane row.
__device__ inline float dpp_rowsum16(float v) {
    float t;
    t = __uint_as_float((unsigned)__builtin_amdgcn_update_dpp(0, (int)__float_as_uint(v), 0x111, 0xF, 0xF, false)); v += t;
    t = __uint_as_float((unsigned)__builtin_amdgcn_update_dpp(0, (int)__float_as_uint(v), 0x112, 0xF, 0xF, false)); v += t;
    t = __uint_as_float((unsigned)__builtin_amdgcn_update_dpp(0, (int)__float_as_uint(v), 0x114, 0xF, 0xF, false)); v += t;
    t = __uint_as_float((unsigned)__builtin_amdgcn_update_dpp(0, (int)__float_as_uint(v), 0x118, 0xF, 0xF, false)); v += t;
    return v;
}

// ---------------------------------------------------------------------------
// bf16 MFMA GEMM, BK=64, global_load_lds staging.
// ---------------------------------------------------------------------------
template<int ACT, bool RES, bool MASK, bool OUTF, bool OUTB, bool OUTS>
__global__ __launch_bounds__(256)
void bgemm_k(const unsigned short* __restrict__ A,
             const unsigned short* __restrict__ W,
             const float* __restrict__ bias,
             const float* __restrict__ resp,
             const int* __restrict__ mask,
             float* __restrict__ Cf, unsigned short* __restrict__ Cb,
             unsigned short* Ohi, unsigned short* Olo,
             int M, int N, int K)
{
    __shared__ __align__(16) unsigned short As[128*64];
    __shared__ __align__(16) unsigned short Bs[128*64];

    const int tid  = threadIdx.x;
    const int lane = tid & 63;
    const int w    = tid >> 6;
    const int wr   = w >> 1, wc = w & 1;
    const int row0 = blockIdx.x * 128;
    const int col0 = blockIdx.y * 128;
    const int l15  = lane & 15;
    const int ko   = lane >> 4;

    f32x4 acc[4][4];
    #pragma unroll
    for (int m = 0; m < 4; ++m)
        #pragma unroll
        for (int n = 0; n < 4; ++n) acc[m][n] = (f32x4){0.f,0.f,0.f,0.f};

    for (int k0 = 0; k0 < K; k0 += 64) {
        stage64g<128,4>(A, (size_t)row0, K, k0, As, w, lane);
        stage64g<128,4>(W, (size_t)col0, K, k0, Bs, w, lane);
        __syncthreads();
        #pragma unroll
        for (int ks = 0; ks < 2; ++ks) {
            short8_t aF[4], bF[4];
            #pragma unroll
            for (int m = 0; m < 4; ++m)
                aF[m] = frag64(As, wr*64 + m*16 + l15, ks*64 + ko*16);
            #pragma unroll
            for (int n = 0; n < 4; ++n)
                bF[n] = frag64(Bs, wc*64 + n*16 + l15, ks*64 + ko*16);
            #pragma unroll
            for (int m = 0; m < 4; ++m)
                #pragma unroll
                for (int n = 0; n < 4; ++n)
                    acc[m][n] = __builtin_amdgcn_mfma_f32_16x16x32_bf16(aF[m], bF[n], acc[m][n], 0, 0, 0);
        }
        __syncthreads();
    }

    #pragma unroll
    for (int m = 0; m < 4; ++m) {
        const int rbase = row0 + wr*64 + m*16 + ko*4;
        #pragma unroll
        for (int n = 0; n < 4; ++n) {
            const int col = col0 + wc*64 + n*16 + l15;
            const float bv = bias[col];
            #pragma unroll
            for (int r = 0; r < 4; ++r) {
                const int row = rbase + r;
                float v = acc[m][n][r] + bv;
                if constexpr (ACT == ACT_LRELU) v = LRELU_(v);
                if constexpr (RES)  v += resp[(size_t)row*N + col];
                if constexpr (MASK) v *= (mask[row] != 0) ? 1.f : 0.f;
                if constexpr (OUTF) Cf[(size_t)row*N + col] = v;
                if constexpr (OUTB) Cb[(size_t)row*N + col] = f2bf(v);
                if constexpr (OUTS) {
                    unsigned short h = f2bf(v);
                    Ohi[(size_t)row*N + col] = h;
                    Olo[(size_t)row*N + col] = f2bf(v - bf2f(h));
                }
            }
        }
    }
}

// ---------------------------------------------------------------------------
// bf16 MFMA GEMM fused with full-row LayerNorm epilogue (BK=64).
// AF32: A fp32, cast during (reg) staging into the same linear-swz layout.
// ---------------------------------------------------------------------------
template<int WR, int WC, bool DO_LRELU, bool MASKMUL, int MODE, bool AF32>
__global__ __launch_bounds__(WR*WC*64)
void bgemm_ln_k(const void* __restrict__ Ap,
                const unsigned short* __restrict__ W,
                const float* __restrict__ bias,
                const float* __restrict__ gam,
                const float* __restrict__ bet,
                const int* __restrict__ mask,
                void* __restrict__ outv,
                unsigned short* __restrict__ ohi, unsigned short* __restrict__ olo,
                int K)
{
    constexpr int BM = WR*64;
    constexpr int BN = WC*64;
    constexpr int THREADS = WR*WC*64;
    constexpr int WAVES = THREADS/64;
    __shared__ __align__(16) unsigned short As[BM*64];
    __shared__ __align__(16) unsigned short Bs[BN*64];
    __shared__ float red_s[WC][BM];
    __shared__ float red_q[WC][BM];
    __shared__ float mu_l[BM];
    __shared__ float rs_l[BM];

    const int tid  = threadIdx.x;
    const int lane = tid & 63;
    const int w    = tid >> 6;
    const int wr   = w / WC, wc = w % WC;
    const int row0 = blockIdx.x * BM;
    const int l15  = lane & 15;
    const int ko   = lane >> 4;

    f32x4 acc[4][4];
    #pragma unroll
    for (int m = 0; m < 4; ++m)
        #pragma unroll
        for (int n = 0; n < 4; ++n) acc[m][n] = (f32x4){0.f,0.f,0.f,0.f};

    for (int k0 = 0; k0 < K; k0 += 64) {
        if constexpr (AF32) {
            const float* Af = (const float*)Ap;
            constexpr int CH = (BM*8)/THREADS;    // 16B chunks per thread
            #pragma unroll
            for (int i = 0; i < CH; ++i) {
                const int q = i*THREADS + tid;
                const unsigned o  = (unsigned)q*16u;
                const int      r  = (int)(o >> 7);
                const unsigned cb = o & 127u;
                const unsigned cs = cb ^ ((unsigned)(r & 7) << 4);
                const float* src = Af + (size_t)(row0 + r)*K + k0 + (cs >> 1);
                const float4 f0 = *reinterpret_cast<const float4*>(src);
                const float4 f1 = *reinterpret_cast<const float4*>(src + 4);
                short8_t v;
                v[0]=(short)f2bf(f0.x); v[1]=(short)f2bf(f0.y); v[2]=(short)f2bf(f0.z); v[3]=(short)f2bf(f0.w);
                v[4]=(short)f2bf(f1.x); v[5]=(short)f2bf(f1.y); v[6]=(short)f2bf(f1.z); v[7]=(short)f2bf(f1.w);
                *reinterpret_cast<short8_t*>((char*)As + o) = v;
            }
        } else {
            stage64g<BM,WAVES>((const unsigned short*)Ap, (size_t)row0, K, k0, As, w, lane);
        }
        stage64g<BN,WAVES>(W, 0, K, k0, Bs, w, lane);
        __syncthreads();
        #pragma unroll
        for (int ks = 0; ks < 2; ++ks) {
            short8_t aF[4], bF[4];
            #pragma unroll
            for (int m = 0; m < 4; ++m)
                aF[m] = frag64(As, wr*64 + m*16 + l15, ks*64 + ko*16);
            #pragma unroll
            for (int n = 0; n < 4; ++n)
                bF[n] = frag64(Bs, wc*64 + n*16 + l15, ks*64 + ko*16);
            #pragma unroll
            for (int m = 0; m < 4; ++m)
                #pragma unroll
                for (int n = 0; n < 4; ++n)
                    acc[m][n] = __builtin_amdgcn_mfma_f32_16x16x32_bf16(aF[m], bF[n], acc[m][n], 0, 0, 0);
        }
        __syncthreads();
    }

    float bv[4];
    #pragma unroll
    for (int n = 0; n < 4; ++n) bv[n] = bias[wc*64 + n*16 + l15];
    #pragma unroll
    for (int m = 0; m < 4; ++m)
        #pragma unroll
        for (int n = 0; n < 4; ++n)
            #pragma unroll
            for (int r = 0; r < 4; ++r) acc[m][n][r] += bv[n];

    #pragma unroll
    for (int m = 0; m < 4; ++m) {
        #pragma unroll
        for (int r = 0; r < 4; ++r) {
            float s = acc[m][0][r] + acc[m][1][r] + acc[m][2][r] + acc[m][3][r];
            float q = acc[m][0][r]*acc[m][0][r] + acc[m][1][r]*acc[m][1][r]
                    + acc[m][2][r]*acc[m][2][r] + acc[m][3][r]*acc[m][3][r];
            s = dpp_rowsum16(s);
            q = dpp_rowsum16(q);
            if (l15 == 15) {
                int rl = wr*64 + m*16 + ko*4 + r;
                red_s[wc][rl] = s;
                red_q[wc][rl] = q;
            }
        }
    }
    __syncthreads();
    if (tid < BM) {
        float s = 0.f, q = 0.f;
        #pragma unroll
        for (int c2 = 0; c2 < WC; ++c2) { s += red_s[c2][tid]; q += red_q[c2][tid]; }
        float mu  = s * (1.0f/BN);
        float var = q * (1.0f/BN) - mu*mu;
        mu_l[tid] = mu;
        rs_l[tid] = rsqrtf(fmaxf(var, 0.f) + 1e-5f);
    }
    __syncthreads();

    float gm[4], bt[4];
    #pragma unroll
    for (int n = 0; n < 4; ++n) {
        int col = wc*64 + n*16 + l15;
        gm[n] = gam[col]; bt[n] = bet[col];
    }
    #pragma unroll
    for (int m = 0; m < 4; ++m) {
        #pragma unroll
        for (int r = 0; r < 4; ++r) {
            const int rl  = wr*64 + m*16 + ko*4 + r;
            const int row = row0 + rl;
            const float mu = mu_l[rl], rs = rs_l[rl];
            float mf = 1.f;
            if constexpr (MASKMUL) mf = (mask[row] != 0) ? 1.f : 0.f;
            #pragma unroll
            for (int n = 0; n < 4; ++n) {
                const int col = wc*64 + n*16 + l15;
                float y = (acc[m][n][r] - mu) * rs * gm[n] + bt[n];
                if constexpr (DO_LRELU) y = LRELU_(y);
                if constexpr (MASKMUL)  y *= mf;
                if constexpr (MODE == 1) {
                    ((unsigned short*)outv)[(size_t)row*BN + col] = f2bf(y);
                } else {
                    ((float*)outv)[(size_t)row*BN + col] = y;
                    unsigned short h = f2bf(y);
                    ohi[(size_t)row*BN + col] = h;
                    olo[(size_t)row*BN + col] = f2bf(y - bf2f(h));
                }
            }
        }
    }
}

// ---------------------------------------------------------------------------
// fc1 split-bf16 MFMA GEMM, 3 phases, BK=64, in-place OK, fused rowsq(x2).
// ---------------------------------------------------------------------------
__global__ __launch_bounds__(256)
void fc1mm_k(const unsigned short* Ahi, const unsigned short* Alo,
             const unsigned short* __restrict__ Bhi, const unsigned short* __restrict__ Blo,
             const float* __restrict__ bias,
             unsigned short* Ohi, unsigned short* Olo,
             float* __restrict__ x2out)
{
    __shared__ __align__(16) unsigned short As[128*64];
    __shared__ __align__(16) unsigned short Bs[128*64];
    __shared__ float red_q[2][128];

    const int tid  = threadIdx.x;
    const int lane = tid & 63;
    const int w    = tid >> 6;
    const int wr   = w >> 1, wc = w & 1;
    const int row0 = blockIdx.x * 128;
    const int l15  = lane & 15;
    const int ko   = lane >> 4;

    f32x4 acc[4][4];
    #pragma unroll
    for (int m = 0; m < 4; ++m)
        #pragma unroll
        for (int n = 0; n < 4; ++n) acc[m][n] = (f32x4){0.f,0.f,0.f,0.f};

    for (int kk = 0; kk < 384; kk += 64) {
        const int p  = kk >> 7;        // 0,0,1,1,2,2
        const int kl = kk & 127;
        const unsigned short* Ap2 = (p == 1) ? Alo : Ahi;
        const unsigned short* Bp2 = (p == 2) ? Blo : Bhi;
        stage64g<128,4>(Ap2, (size_t)row0, DD, kl, As, w, lane);
        stage64g<128,4>(Bp2, 0, DD, kl, Bs, w, lane);
        __syncthreads();
        #pragma unroll
        for (int ks = 0; ks < 2; ++ks) {
            short8_t aF[4], bF[4];
            #pragma unroll
            for (int m = 0; m < 4; ++m)
                aF[m] = frag64(As, wr*64 + m*16 + l15, ks*64 + ko*16);
            #pragma unroll
            for (int n = 0; n < 4; ++n)
                bF[n] = frag64(Bs, wc*64 + n*16 + l15, ks*64 + ko*16);
            #pragma unroll
            for (int m = 0; m < 4; ++m)
                #pragma unroll
                for (int n = 0; n < 4; ++n)
                    acc[m][n] = __builtin_amdgcn_mfma_f32_16x16x32_bf16(aF[m], bF[n], acc[m][n], 0, 0, 0);
        }
        __syncthreads();
    }

    float qacc[4][4];
    #pragma unroll
    for (int m = 0; m < 4; ++m) {
        const int rbase = row0 + wr*64 + m*16 + ko*4;
        #pragma unroll
        for (int r = 0; r < 4; ++r) qacc[m][r] = 0.f;
        #pragma unroll
        for (int n = 0; n < 4; ++n) {
            const int col = wc*64 + n*16 + l15;
            const float bv = bias[col];
            #pragma unroll
            for (int r = 0; r < 4; ++r) {
                const int row = rbase + r;
                float v = acc[m][n][r] + bv;
                unsigned short h = f2bf(v);
                unsigned short l = f2bf(v - bf2f(h));
                Ohi[(size_t)row*DD + col] = h;
                Olo[(size_t)row*DD + col] = l;
                float vv = bf2f(h) + bf2f(l);
                qacc[m][r] += vv*vv;
            }
        }
    }
    #pragma unroll
    for (int m = 0; m < 4; ++m)
        #pragma unroll
        for (int r = 0; r < 4; ++r) {
            float q = dpp_rowsum16(qacc[m][r]);
            if (l15 == 15) red_q[wc][wr*64 + m*16 + ko*4 + r] = q;
        }
    __syncthreads();
    if (tid < 128) x2out[row0 + tid] = red_q[0][tid] + red_q[1][tid];
}

// ---------------------------------------------------------------------------
// Fused distance + top-9: block = half-batch (128 rows x all 256 cols).
// Packed keys: (sortable_d2 & 0xFFFFFF00) | col.
// ---------------------------------------------------------------------------
__global__ __launch_bounds__(512)
void dist_topk_k(const unsigned short* __restrict__ hhi,
                 const unsigned short* __restrict__ hlo,
                 const int* __restrict__ mask,
                 const float* __restrict__ x2,
                 unsigned char* __restrict__ idx)
{
    __shared__ __align__(16) unsigned short BsH[NNODE*64];
    __shared__ __align__(16) unsigned short BsL[NNODE*64];

    const int b    = blockIdx.x >> 1;
    const int half = blockIdx.x & 1;
    const int tid  = threadIdx.x;
    const int lane = tid & 63;
    const int w    = tid >> 6;          // 0..7
    const int l15  = lane & 15;
    const int g    = lane >> 4;         // 0..3

    const unsigned short* Hhi = hhi + (size_t)b*NNODE*DD;
    const unsigned short* Hlo = hlo + (size_t)b*NNODE*DD;
    const float* x2b = x2 + b*NNODE;
    const int*   mkb = mask + b*NNODE;
    unsigned char* idxb = idx + (size_t)(b*NNODE + half*128)*KNN;

    const int arow = half*128 + w*16 + l15;

    f32x4 acc[16];
    #pragma unroll
    for (int n = 0; n < 16; ++n) acc[n] = (f32x4){0.f,0.f,0.f,0.f};

    for (int kl = 0; kl < DD; kl += 64) {
        stage64g<NNODE,8>(Hhi, 0, DD, kl, BsH, w, lane);
        stage64g<NNODE,8>(Hlo, 0, DD, kl, BsL, w, lane);
        __syncthreads();
        #pragma unroll
        for (int ks = 0; ks < 2; ++ks) {
            short8_t aH = frag64(BsH, arow, ks*64 + g*16);
            short8_t aL = frag64(BsL, arow, ks*64 + g*16);
            #pragma unroll
            for (int n = 0; n < 16; ++n) {
                int brow = n*16 + l15;
                short8_t bH = frag64(BsH, brow, ks*64 + g*16);
                short8_t bL = frag64(BsL, brow, ks*64 + g*16);
                acc[n] = __builtin_amdgcn_mfma_f32_16x16x32_bf16(aH, bH, acc[n], 0, 0, 0); // hi.hi
                acc[n] = __builtin_amdgcn_mfma_f32_16x16x32_bf16(aL, bH, acc[n], 0, 0, 0); // lo.hi
                acc[n] = __builtin_amdgcn_mfma_f32_16x16x32_bf16(aH, bL, acc[n], 0, 0, 0); // hi.lo
            }
        }
        __syncthreads();
    }

    float x2c[16]; unsigned mk[16];
    #pragma unroll
    for (int n = 0; n < 16; ++n) {
        int col = n*16 + l15;
        x2c[n] = x2b[col];
        mk[n]  = (mkb[col] != 0) ? 1u : 0u;
    }

    #pragma unroll
    for (int r = 0; r < 4; ++r) {
        const int lrow = w*16 + g*4 + r;
        const float x2r = x2b[half*128 + lrow];
        unsigned key[16];
        #pragma unroll
        for (int n = 0; n < 16; ++n) {
            float v = x2r + x2c[n] - 2.0f*acc[n][r];
            if (!mk[n]) v = 1e10f;
            unsigned u = __float_as_uint(v);
            u = (u & 0x80000000u) ? ~u : (u | 0x80000000u);
            key[n] = (u & 0xFFFFFF00u) | (unsigned)(n*16 + l15);
        }
        for (int it = 0; it < KNN; ++it) {
            unsigned a0 = key[0]  < key[1]  ? key[0]  : key[1];
            unsigned a1 = key[2]  < key[3]  ? key[2]  : key[3];
            unsigned a2 = key[4]  < key[5]  ? key[4]  : key[5];
            unsigned a3 = key[6]  < key[7]  ? key[6]  : key[7];
            unsigned a4 = key[8]  < key[9]  ? key[8]  : key[9];
            unsigned a5 = key[10] < key[11] ? key[10] : key[11];
            unsigned a6 = key[12] < key[13] ? key[12] : key[13];
            unsigned a7 = key[14] < key[15] ? key[14] : key[15];
            unsigned b0 = a0 < a1 ? a0 : a1;
            unsigned b1 = a2 < a3 ? a2 : a3;
            unsigned b2 = a4 < a5 ? a4 : a5;
            unsigned b3 = a6 < a7 ? a6 : a7;
            unsigned c0 = b0 < b1 ? b0 : b1;
            unsigned c1 = b2 < b3 ? b2 : b3;
            unsigned lmin = c0 < c1 ? c0 : c1;
            unsigned gmin = grp16_min_u32(lmin);
            if (l15 == 0) idxb[lrow*KNN + it] = (unsigned char)(gmin & 0xFFu);
            #pragma unroll
            for (int n = 0; n < 16; ++n)
                if (key[n] == gmin) key[n] = 0xFFFFFFFFu;
        }
    }
}

// ---------------------------------------------------------------------------
// Fused conv + fc2, occupancy-optimized: BM=64 (1024 blocks), 40KB LDS
// (As 8K + Bs 16K + h2s 2x8K) -> 4 blocks/CU. 4 waves, wave = 64x32 out.
// x += (lrelu(cat@Wc^T + cb)) @ W2^T + fb;  xhi = bf16(x)
// ---------------------------------------------------------------------------
__global__ __launch_bounds__(256)
void conv_fc2_k(const unsigned short* __restrict__ cat,
                const unsigned short* __restrict__ Wc,
                const float* __restrict__ cb,
                const unsigned short* __restrict__ W2,
                const float* __restrict__ fb,
                float* __restrict__ x,
                unsigned short* __restrict__ xhi)
{
    __shared__ __align__(16) unsigned short As[64*64];       // 8KB
    __shared__ __align__(16) unsigned short Bs[128*64];      // 16KB
    __shared__ __align__(16) unsigned short h2s[2][64*64];   // 2x8KB (k-halves)

    const int tid  = threadIdx.x;
    const int lane = tid & 63;
    const int w    = tid >> 6;      // 0..3: wave col group (cols w*32..w*32+31)
    const int row0 = blockIdx.x * 64;
    const int l15  = lane & 15;
    const int ko   = lane >> 4;

    // ---- stage 1: h2 = lrelu(cat @ Wc^T + cb), K=256 ----
    f32x4 acc[4][2];
    #pragma unroll
    for (int m = 0; m < 4; ++m)
        #pragma unroll
        for (int n = 0; n < 2; ++n) acc[m][n] = (f32x4){0.f,0.f,0.f,0.f};

    for (int k0 = 0; k0 < 256; k0 += 64) {
        stage64g<64,4>(cat, (size_t)row0, 256, k0, As, w, lane);
        stage64g<128,4>(Wc, 0, 256, k0, Bs, w, lane);
        __syncthreads();
        #pragma unroll
        for (int ks = 0; ks < 2; ++ks) {
            short8_t aF[4], bF[2];
            #pragma unroll
            for (int m = 0; m < 4; ++m)
                aF[m] = frag64(As, m*16 + l15, ks*64 + ko*16);
            #pragma unroll
            for (int n = 0; n < 2; ++n)
                bF[n] = frag64(Bs, w*32 + n*16 + l15, ks*64 + ko*16);
            #pragma unroll
            for (int m = 0; m < 4; ++m)
                #pragma unroll
                for (int n = 0; n < 2; ++n)
                    acc[m][n] = __builtin_amdgcn_mfma_f32_16x16x32_bf16(aF[m], bF[n], acc[m][n], 0, 0, 0);
        }
        __syncthreads();
    }

    // h2 -> swizzled LDS k-half tiles (kt = col/64 = w>>1)
    {
        const int kt = w >> 1;
        #pragma unroll
        for (int n = 0; n < 2; ++n) {
            const int col = w*32 + n*16 + l15;
            const float bv = cb[col];
            const unsigned bc = (unsigned)(((w & 1)*32 + n*16 + l15) * 2);
            #pragma unroll
            for (int m = 0; m < 4; ++m) {
                #pragma unroll
                for (int r = 0; r < 4; ++r) {
                    const int row = m*16 + ko*4 + r;
                    float v = LRELU_(acc[m][n][r] + bv);
                    *(unsigned short*)((char*)&h2s[kt][0] + row*128
                        + (bc ^ ((unsigned)(row & 7) << 4))) = f2bf(v);
                }
            }
        }
    }

    // ---- stage 2: out = h2 @ W2^T, K=128 (2 k-tiles, restage Bs) ----
    f32x4 acc2[4][2];
    #pragma unroll
    for (int m = 0; m < 4; ++m)
        #pragma unroll
        for (int n = 0; n < 2; ++n) acc2[m][n] = (f32x4){0.f,0.f,0.f,0.f};

    #pragma unroll
    for (int kt = 0; kt < 2; ++kt) {
        stage64g<128,4>(W2, 0, 128, kt*64, Bs, w, lane);
        __syncthreads();   // drains W2 gload + (first iter) h2s ds_writes
        #pragma unroll
        for (int ks = 0; ks < 2; ++ks) {
            short8_t aF[4], bF[2];
            #pragma unroll
            for (int m = 0; m < 4; ++m)
                aF[m] = frag64(&h2s[kt][0], m*16 + l15, ks*64 + ko*16);
            #pragma unroll
            for (int n = 0; n < 2; ++n)
                bF[n] = frag64(Bs, w*32 + n*16 + l15, ks*64 + ko*16);
            #pragma unroll
            for (int m = 0; m < 4; ++m)
                #pragma unroll
                for (int n = 0; n < 2; ++n)
                    acc2[m][n] = __builtin_amdgcn_mfma_f32_16x16x32_bf16(aF[m], bF[n], acc2[m][n], 0, 0, 0);
        }
        __syncthreads();
    }

    #pragma unroll
    for (int m = 0; m < 4; ++m) {
        const int rbase = row0 + m*16 + ko*4;
        #pragma unroll
        for (int n = 0; n < 2; ++n) {
            const int col = w*32 + n*16 + l15;
            const float bv = fb[col];
            #pragma unroll
            for (int r = 0; r < 4; ++r) {
                const int row = rbase + r;
                float v = acc2[m][n][r] + bv + x[(size_t)row*DD + col];
                x[(size_t)row*DD + col] = v;
                xhi[(size_t)row*DD + col] = f2bf(v);
            }
        }
    }
}

// ---------------------------------------------------------------------------
// Batch-resident gather + max-relative (one block per batch, h in LDS).
// ---------------------------------------------------------------------------
__global__ __launch_bounds__(512)
void gatherb_k(const unsigned short* __restrict__ hhi, const unsigned short* __restrict__ hlo,
               const unsigned char* __restrict__ idx, const int* __restrict__ mask,
               unsigned short* __restrict__ cat)
{
    __shared__ __align__(16) unsigned short hi_s[NNODE*DD];
    __shared__ __align__(16) unsigned short lo_s[NNODE*DD];
    __shared__ unsigned char  idx_s[NNODE*KNN];
    __shared__ unsigned char  msk_s[NNODE];

    const int b = blockIdx.x;
    const int t = threadIdx.x;
    const int w = t >> 6, lane = t & 63;
    const size_t hbase = (size_t)b*NNODE*DD;
    const unsigned char* idxg = idx + (size_t)b*NNODE*KNN;

    #pragma unroll
    for (int i = 0; i < 8; ++i) {
        const int inst = w + i*8;
        const size_t o = (size_t)inst*1024 + (size_t)lane*16;
        gload16((const char*)(hhi + hbase) + o, (char*)hi_s + (size_t)inst*1024);
        gload16((const char*)(hlo + hbase) + o, (char*)lo_s + (size_t)inst*1024);
    }
    for (int o = t; o < NNODE*KNN; o += 512) idx_s[o] = idxg[o];
    if (t < NNODE) msk_s[t] = (mask[b*NNODE + t] != 0) ? 1 : 0;
    __syncthreads();

    const int c4 = (t & 31) * 4;
    #pragma unroll 4
    for (int pass = 0; pass < 16; ++pass) {
        const int r = (t >> 5) + pass*16;
        us4 h4 = *reinterpret_cast<const us4*>(&hi_s[r*DD + c4]);
        us4 l4 = *reinterpret_cast<const us4*>(&lo_s[r*DD + c4]);
        float hi[4], m[4];
        #pragma unroll
        for (int d = 0; d < 4; ++d) { hi[d] = bf2f(h4[d]) + bf2f(l4[d]); m[d] = -1e9f; }
        bool any = false;
        #pragma unroll
        for (int q = 0; q < KNN; ++q) {
            int j = idx_s[r*KNN + q];
            if (msk_s[j]) {
                any = true;
                us4 a = *reinterpret_cast<const us4*>(&hi_s[j*DD + c4]);
                us4 o = *reinterpret_cast<const us4*>(&lo_s[j*DD + c4]);
                #pragma unroll
                for (int d = 0; d < 4; ++d)
                    m[d] = fmaxf(m[d], bf2f(a[d]) + bf2f(o[d]) - hi[d]);
            }
        }
        us4 o1, o2;
        #pragma unroll
        for (int d = 0; d < 4; ++d) {
            o1[d] = f2bf(hi[d]);
            o2[d] = any ? f2bf(m[d]) : (unsigned short)0;
        }
        const size_t rowbase = (size_t)(b*NNODE + r)*(2*DD);
        *reinterpret_cast<us4*>(&cat[rowbase + c4])      = o1;
        *reinterpret_cast<us4*>(&cat[rowbase + DD + c4]) = o2;
    }
}

__global__ __launch_bounds__(128)
void pool_k(const float* __restrict__ x, const int* __restrict__ mask,
            float* __restrict__ g, unsigned short* __restrict__ gbf)
{
    const int b = blockIdx.x, c = threadIdx.x;
    float s = 0.f; int cnt = 0;
    for (int n = 0; n < NNODE; ++n) {
        s += x[((size_t)b*NNODE + n)*DD + c];
        cnt += (mask[b*NNODE + n] != 0) ? 1 : 0;
    }
    float v = s / fmaxf((float)cnt, 1.0f);
    g[b*DD + c] = v;
    gbf[b*DD + c] = f2bf(v);
}

// ---------------------------------------------------------------------------
// All weight transpose-casts in ONE kernel (compile-time job table).
// ---------------------------------------------------------------------------
__global__ __launch_bounds__(256)
void prep_all_k(const float* __restrict__ emb_w1, const float* __restrict__ emb_w2,
                const float* __restrict__ conv_w, const float* __restrict__ fc2_w,
                const float* __restrict__ f1_w,   const float* __restrict__ f2_w,
                const float* __restrict__ fc1_w,  const float* __restrict__ ow1,
                const float* __restrict__ ow2,
                unsigned short* __restrict__ emb_w1t, unsigned short* __restrict__ emb_w2t,
                unsigned short* __restrict__ conv_wt, unsigned short* __restrict__ fc2_wt,
                unsigned short* __restrict__ ffn1_wt, unsigned short* __restrict__ ffn2_wt,
                unsigned short* __restrict__ fc1_wthi, unsigned short* __restrict__ fc1_wtlo,
                unsigned short* __restrict__ ow1t, unsigned short* __restrict__ ow2t)
{
    __shared__ float tile[32][33];
    const int tx = threadIdx.x & 31, ty = threadIdx.x >> 5;

    int bid = blockIdx.x;
    const float* src = nullptr; unsigned short* dst = nullptr; unsigned short* dlo = nullptr;
    int K = 0, N = 0;
    do {
        if (bid < 16)  { src = emb_w1; dst = emb_w1t; K = 64;  N = 256; break; }  bid -= 16;
        if (bid < 32)  { src = emb_w2; dst = emb_w2t; K = 256; N = 128; break; }  bid -= 32;
        if (bid < 64)  { int l = bid >> 5; bid &= 31;
                         src = conv_w + (size_t)l*256*128; dst = conv_wt + (size_t)l*128*256;
                         K = 256; N = 128; break; }                               bid -= 64;
        if (bid < 32)  { int l = bid >> 4; bid &= 15;
                         src = fc2_w + (size_t)l*128*128; dst = fc2_wt + (size_t)l*128*128;
                         K = 128; N = 128; break; }                               bid -= 32;
        if (bid < 128) { int l = bid >> 6; bid &= 63;
                         src = f1_w + (size_t)l*128*512; dst = ffn1_wt + (size_t)l*512*128;
                         K = 128; N = 512; break; }                               bid -= 128;
        if (bid < 128) { int l = bid >> 6; bid &= 63;
                         src = f2_w + (size_t)l*512*128; dst = ffn2_wt + (size_t)l*128*512;
                         K = 512; N = 128; break; }                               bid -= 128;
        if (bid < 32)  { int l = bid >> 4; bid &= 15;
                         src = fc1_w + (size_t)l*128*128;
                         dst = fc1_wthi + (size_t)l*128*128; dlo = fc1_wtlo + (size_t)l*128*128;
                         K = 128; N = 128; break; }                               bid -= 32;
        if (bid < 64)  { src = ow1; dst = ow1t; K = 128; N = 512; break; }        bid -= 64;
        { src = ow2; dst = ow2t; K = 512; N = 2048; }
    } while (0);

    const int nbx = N / 32;
    const int bx = bid % nbx, by = bid / nbx;
    const int k0 = by*32, n0 = bx*32;

    #pragma unroll
    for (int i = ty; i < 32; i += 8)
        tile[i][tx] = src[(size_t)(k0+i)*N + n0+tx];
    __syncthreads();
    #pragma unroll
    for (int i = ty; i < 32; i += 8) {
        float v = tile[tx][i];
        unsigned short h = f2bf(v);
        dst[(size_t)(n0+i)*K + k0+tx] = h;
        if (dlo) dlo[(size_t)(n0+i)*K + k0+tx] = f2bf(v - bf2f(h));
    }
}

// ---------------------------------------------------------------------------
extern "C" void kernel_launch(void* const* d_in, const int* in_sizes, int n_in,
                              void* d_out, int out_size, void* d_ws, size_t ws_size,
                              hipStream_t stream)
{
    const float* nodes  = (const float*)d_in[0];
    const int*   maskp  = (const int*)  d_in[1];
    const float* emb_w1 = (const float*)d_in[2];
    const float* emb_b1 = (const float*)d_in[3];
    const float* ln1_g  = (const float*)d_in[4];
    const float* ln1_b  = (const float*)d_in[5];
    const float* emb_w2 = (const float*)d_in[6];
    const float* emb_b2 = (const float*)d_in[7];
    const float* ln2_g  = (const float*)d_in[8];
    const float* ln2_b  = (const float*)d_in[9];
    const float* fc1_w  = (const float*)d_in[10];
    const float* fc1_b  = (const float*)d_in[11];
    const float* conv_w = (const float*)d_in[12];
    const float* conv_b = (const float*)d_in[13];
    const float* fc2_w  = (const float*)d_in[14];
    const float* fc2_b  = (const float*)d_in[15];
    const float* f1_w   = (const float*)d_in[16];
    const float* f1_b   = (const float*)d_in[17];
    const float* f2_w   = (const float*)d_in[18];
    const float* f2_b   = (const float*)d_in[19];
    const float* ow1    = (const float*)d_in[20];
    const float* ob1    = (const float*)d_in[21];
    const float* ow2    = (const float*)d_in[22];
    const float* ob2    = (const float*)d_in[23];
    float* out = (float*)d_out;

    // ---- workspace layout ----
    char* base = (char*)d_ws;
    float* x   = (float*)base;                          // 33.55 MB
    char*  H   = base + (size_t)BNROWS*DD*4;            // 33.55 MB (x_hi/x_lo <-> h_hi/h_lo)
    char*  BIG = H + (size_t)BNROWS*DD*4;               // 67.11 MB (t256 / cat / ffn hidden)
    float*          x2    = (float*)(BIG + (size_t)BNROWS*2*DD*4);
    unsigned char*  idx   = (unsigned char*)(x2 + BNROWS);
    float*          g     = (float*)(idx + (size_t)BNROWS*KNN);
    unsigned short* g_bf  = (unsigned short*)(g + BB*DD);
    unsigned short* hid2_bf = g_bf + BB*DD;
    unsigned short* wbuf  = hid2_bf + BB*FFND;

    unsigned short* x_hi   = (unsigned short*)H;
    unsigned short* x_lo   = x_hi + (size_t)BNROWS*DD;
    unsigned short* t256_bf= (unsigned short*)BIG;
    unsigned short* cat_bf = (unsigned short*)(BIG);    // reused regions
    unsigned short* hid_bf = (unsigned short*)BIG;

    unsigned short* emb_w1t  = wbuf;
    unsigned short* emb_w2t  = emb_w1t + 256*64;
    unsigned short* conv_wt  = emb_w2t + 128*256;
    unsigned short* fc2_wt   = conv_wt + 2*128*256;
    unsigned short* ffn1_wt  = fc2_wt  + 2*128*128;
    unsigned short* ffn2_wt  = ffn1_wt + 2*512*128;
    unsigned short* fc1_wthi = ffn2_wt + 2*128*512;
    unsigned short* fc1_wtlo = fc1_wthi + 2*128*128;
    unsigned short* ow1t     = fc1_wtlo + 2*128*128;
    unsigned short* ow2t     = ow1t + 512*128;

    const dim3 blk(256);

    // ---- all weight transpose-casts (one launch) ----
    prep_all_k<<<1520, blk, 0, stream>>>(
        emb_w1, emb_w2, conv_w, fc2_w, f1_w, f2_w, fc1_w, ow1, ow2,
        emb_w1t, emb_w2t, conv_wt, fc2_wt, ffn1_wt, ffn2_wt,
        fc1_wthi, fc1_wtlo, ow1t, ow2t);

    // ---- Embedding (GEMM + fused LN) ----
    bgemm_ln_k<2,4,true,false,1,true>
        <<<dim3(BNROWS/128), dim3(512), 0, stream>>>
        (nodes, emb_w1t, emb_b1, ln1_g, ln1_b, nullptr, t256_bf, nullptr, nullptr, PP2);
    bgemm_ln_k<2,2,false,true,2,false>
        <<<dim3(BNROWS/128), dim3(256), 0, stream>>>
        (t256_bf, emb_w2t, emb_b2, ln2_g, ln2_b, maskp, x, x_hi, x_lo, 2*DD);

    // ---- ViG blocks ----
    for (int l = 0; l < LLAY; ++l) {
        const float* fc1b = fc1_b + (size_t)l*DD;
        const float* cb   = conv_b + (size_t)l*DD;
        const float* fc2b = fc2_b + (size_t)l*DD;
        const float* b1   = f1_b + (size_t)l*FFND;
        const float* b2   = f2_b + (size_t)l*DD;

        fc1mm_k<<<dim3(BNROWS/128), blk, 0, stream>>>
            (x_hi, x_lo, fc1_wthi + (size_t)l*DD*DD, fc1_wtlo + (size_t)l*DD*DD,
             fc1b, x_hi, x_lo, x2);
        dist_topk_k<<<dim3(2*BB), dim3(512), 0, stream>>>
            (x_hi, x_lo, maskp, x2, idx);
        gatherb_k<<<BB, 512, 0, stream>>>(x_hi, x_lo, idx, maskp, cat_bf);
        conv_fc2_k<<<dim3(BNROWS/64), blk, 0, stream>>>
            (cat_bf, conv_wt + (size_t)l*DD*2*DD, cb,
             fc2_wt + (size_t)l*DD*DD, fc2b, x, x_hi);
        bgemm_k<ACT_LRELU,false,false,false,true,false>
            <<<dim3(BNROWS/128, FFND/128), blk, 0, stream>>>
            (x_hi, ffn1_wt + (size_t)l*FFND*DD, b1,
             nullptr, nullptr, nullptr, hid_bf, nullptr, nullptr, BNROWS, FFND, DD);
        bgemm_k<ACT_NONE,true,true,true,false,true>
            <<<dim3(BNROWS/128, 1), blk, 0, stream>>>
            (hid_bf, ffn2_wt + (size_t)l*DD*FFND, b2,
             x, maskp, x, nullptr, x_hi, x_lo, BNROWS, DD, FFND);
    }

    // ---- Pool + head (bf16 MFMA) ----
    pool_k<<<BB, 128, 0, stream>>>(x, maskp, g, g_bf);
    bgemm_k<ACT_LRELU,false,false,false,true,false>
        <<<dim3(BB/128, 512/128), blk, 0, stream>>>
        (g_bf, ow1t, ob1, nullptr, nullptr, nullptr, hid2_bf, nullptr, nullptr, BB, 512, DD);
    bgemm_k<ACT_NONE,false,false,true,false,false>
        <<<dim3(BB/128, 2048/128), blk, 0, stream>>>
        (hid2_bf, ow2t, ob2, nullptr, nullptr, out, nullptr, nullptr, nullptr, BB, 2048, 512);
}

// Round 12
// 392.003 us; speedup vs baseline: 1.0876x; 1.0258x over previous
//
#include <hip/hip_runtime.h>
#include <cstdint>

#define BB    256
#define NNODE 256
#define PP2   64
#define DD    128
#define LLAY  2
#define KNN   9
#define FFND  512
#define BNROWS (BB*NNODE)   // 65536

#define LRELU_(v) ((v) >= 0.f ? (v) : 0.01f*(v))

enum { ACT_NONE = 0, ACT_LRELU = 1 };

typedef short  short8_t  __attribute__((ext_vector_type(8)));
typedef float  f32x4     __attribute__((ext_vector_type(4)));
typedef unsigned short us4 __attribute__((ext_vector_type(4)));

__device__ inline unsigned short f2bf(float x) {
    unsigned u = __float_as_uint(x);
    unsigned r = (u + 0x7FFFu + ((u >> 16) & 1u)) >> 16;
    return (unsigned short)r;
}
__device__ inline float bf2f(unsigned short h) {
    return __uint_as_float(((unsigned)h) << 16);
}

// async global->LDS, 16B per lane; LDS dest must be wave-uniform base.
__device__ inline void gload16(const void* src, void* dst) {
    __builtin_amdgcn_global_load_lds(
        (const __attribute__((address_space(1))) void*)src,
        (__attribute__((address_space(3))) void*)dst, 16, 0, 0);
}

// Stage a BK=64 bf16 tile (ROWS x 64 elems, 128B rows) from row-major global
// (element stride Kel, starting col k0) into LINEAR LDS via global_load_lds.
// Source address carries the inverse XOR swizzle; reads apply the same XOR.
template<int ROWS, int WAVES>
__device__ inline void stage64g(const unsigned short* __restrict__ g, size_t rowbase,
                                int Kel, int k0, unsigned short* lds, int w, int lane)
{
    constexpr int PER = (ROWS*128/1024) / WAVES;
    #pragma unroll
    for (int i = 0; i < PER; ++i) {
        const int inst = w + i*WAVES;                 // wave-uniform
        const unsigned o  = (unsigned)inst*1024u + (unsigned)lane*16u;
        const int      r  = (int)(o >> 7);
        const unsigned cb = o & 127u;
        const unsigned cs = cb ^ ((unsigned)(r & 7) << 4);
        gload16((const char*)(g + (rowbase + (size_t)r)*(size_t)Kel + k0) + cs,
                (char*)lds + (size_t)inst*1024u);
    }
}

// swizzled fragment read from a linear BK=64 tile
__device__ inline short8_t frag64(const unsigned short* lds, int r, int cb) {
    return *reinterpret_cast<const short8_t*>(
        (const char*)lds + (size_t)r*128 + (unsigned)(cb ^ ((r & 7) << 4)));
}

// swizzled 8B (4 cols) read from a BK=64 tile at column-byte cb (mult of 8)
__device__ inline us4 read4sw(const unsigned short* lds, int r, unsigned cb) {
    return *reinterpret_cast<const us4*>(
        (const char*)lds + (size_t)r*128 + (cb ^ ((unsigned)(r & 7) << 4)));
}

// 16-lane-group min (per DPP row); result in ALL lanes of each 16-group.
__device__ inline unsigned grp16_min_u32(unsigned v) {
    unsigned t;
    t = (unsigned)__builtin_amdgcn_update_dpp(-1, (int)v, 0xB1,  0xF, 0xF, false); v = t < v ? t : v; // quad_perm [1,0,3,2]
    t = (unsigned)__builtin_amdgcn_update_dpp(-1, (int)v, 0x4E,  0xF, 0xF, false); v = t < v ? t : v; // quad_perm [2,3,0,1]
    t = (unsigned)__builtin_amdgcn_update_dpp(-1, (int)v, 0x124, 0xF, 0xF, false); v = t < v ? t : v; // row_ror:4
    t = (unsigned)__builtin_amdgcn_update_dpp(-1, (int)v, 0x128, 0xF, 0xF, false); v = t < v ? t : v; // row_ror:8
    return v;
}

// 16-lane (DPP row) sum; result valid in lane 15 of each 16-lane row.
__device__ inline float dpp_rowsum16(float v) {
    float t;
    t = __uint_as_float((unsigned)__builtin_amdgcn_update_dpp(0, (int)__float_as_uint(v), 0x111, 0xF, 0xF, false)); v += t;
    t = __uint_as_float((unsigned)__builtin_amdgcn_update_dpp(0, (int)__float_as_uint(v), 0x112, 0xF, 0xF, false)); v += t;
    t = __uint_as_float((unsigned)__builtin_amdgcn_update_dpp(0, (int)__float_as_uint(v), 0x114, 0xF, 0xF, false)); v += t;
    t = __uint_as_float((unsigned)__builtin_amdgcn_update_dpp(0, (int)__float_as_uint(v), 0x118, 0xF, 0xF, false)); v += t;
    return v;
}

// ---------------------------------------------------------------------------
// bf16 MFMA GEMM, BK=64, global_load_lds staging.
// ---------------------------------------------------------------------------
template<int ACT, bool RES, bool MASK, bool OUTF, bool OUTB, bool OUTS>
__global__ __launch_bounds__(256)
void bgemm_k(const unsigned short* __restrict__ A,
             const unsigned short* __restrict__ W,
             const float* __restrict__ bias,
             const float* __restrict__ resp,
             const int* __restrict__ mask,
             float* __restrict__ Cf, unsigned short* __restrict__ Cb,
             unsigned short* Ohi, unsigned short* Olo,
             int M, int N, int K)
{
    __shared__ __align__(16) unsigned short As[128*64];
    __shared__ __align__(16) unsigned short Bs[128*64];

    const int tid  = threadIdx.x;
    const int lane = tid & 63;
    const int w    = tid >> 6;
    const int wr   = w >> 1, wc = w & 1;
    const int row0 = blockIdx.x * 128;
    const int col0 = blockIdx.y * 128;
    const int l15  = lane & 15;
    const int ko   = lane >> 4;

    f32x4 acc[4][4];
    #pragma unroll
    for (int m = 0; m < 4; ++m)
        #pragma unroll
        for (int n = 0; n < 4; ++n) acc[m][n] = (f32x4){0.f,0.f,0.f,0.f};

    for (int k0 = 0; k0 < K; k0 += 64) {
        stage64g<128,4>(A, (size_t)row0, K, k0, As, w, lane);
        stage64g<128,4>(W, (size_t)col0, K, k0, Bs, w, lane);
        __syncthreads();
        #pragma unroll
        for (int ks = 0; ks < 2; ++ks) {
            short8_t aF[4], bF[4];
            #pragma unroll
            for (int m = 0; m < 4; ++m)
                aF[m] = frag64(As, wr*64 + m*16 + l15, ks*64 + ko*16);
            #pragma unroll
            for (int n = 0; n < 4; ++n)
                bF[n] = frag64(Bs, wc*64 + n*16 + l15, ks*64 + ko*16);
            #pragma unroll
            for (int m = 0; m < 4; ++m)
                #pragma unroll
                for (int n = 0; n < 4; ++n)
                    acc[m][n] = __builtin_amdgcn_mfma_f32_16x16x32_bf16(aF[m], bF[n], acc[m][n], 0, 0, 0);
        }
        __syncthreads();
    }

    #pragma unroll
    for (int m = 0; m < 4; ++m) {
        const int rbase = row0 + wr*64 + m*16 + ko*4;
        #pragma unroll
        for (int n = 0; n < 4; ++n) {
            const int col = col0 + wc*64 + n*16 + l15;
            const float bv = bias[col];
            #pragma unroll
            for (int r = 0; r < 4; ++r) {
                const int row = rbase + r;
                float v = acc[m][n][r] + bv;
                if constexpr (ACT == ACT_LRELU) v = LRELU_(v);
                if constexpr (RES)  v += resp[(size_t)row*N + col];
                if constexpr (MASK) v *= (mask[row] != 0) ? 1.f : 0.f;
                if constexpr (OUTF) Cf[(size_t)row*N + col] = v;
                if constexpr (OUTB) Cb[(size_t)row*N + col] = f2bf(v);
                if constexpr (OUTS) {
                    unsigned short h = f2bf(v);
                    Ohi[(size_t)row*N + col] = h;
                    Olo[(size_t)row*N + col] = f2bf(v - bf2f(h));
                }
            }
        }
    }
}

// ---------------------------------------------------------------------------
// bf16 MFMA GEMM fused with full-row LayerNorm epilogue (BK=64).
// AF32: A fp32, cast during (reg) staging into the same linear-swz layout.
// ---------------------------------------------------------------------------
template<int WR, int WC, bool DO_LRELU, bool MASKMUL, int MODE, bool AF32>
__global__ __launch_bounds__(WR*WC*64)
void bgemm_ln_k(const void* __restrict__ Ap,
                const unsigned short* __restrict__ W,
                const float* __restrict__ bias,
                const float* __restrict__ gam,
                const float* __restrict__ bet,
                const int* __restrict__ mask,
                void* __restrict__ outv,
                unsigned short* __restrict__ ohi, unsigned short* __restrict__ olo,
                int K)
{
    constexpr int BM = WR*64;
    constexpr int BN = WC*64;
    constexpr int THREADS = WR*WC*64;
    constexpr int WAVES = THREADS/64;
    __shared__ __align__(16) unsigned short As[BM*64];
    __shared__ __align__(16) unsigned short Bs[BN*64];
    __shared__ float red_s[WC][BM];
    __shared__ float red_q[WC][BM];
    __shared__ float mu_l[BM];
    __shared__ float rs_l[BM];

    const int tid  = threadIdx.x;
    const int lane = tid & 63;
    const int w    = tid >> 6;
    const int wr   = w / WC, wc = w % WC;
    const int row0 = blockIdx.x * BM;
    const int l15  = lane & 15;
    const int ko   = lane >> 4;

    f32x4 acc[4][4];
    #pragma unroll
    for (int m = 0; m < 4; ++m)
        #pragma unroll
        for (int n = 0; n < 4; ++n) acc[m][n] = (f32x4){0.f,0.f,0.f,0.f};

    for (int k0 = 0; k0 < K; k0 += 64) {
        if constexpr (AF32) {
            const float* Af = (const float*)Ap;
            constexpr int CH = (BM*8)/THREADS;    // 16B chunks per thread
            #pragma unroll
            for (int i = 0; i < CH; ++i) {
                const int q = i*THREADS + tid;
                const unsigned o  = (unsigned)q*16u;
                const int      r  = (int)(o >> 7);
                const unsigned cb = o & 127u;
                const unsigned cs = cb ^ ((unsigned)(r & 7) << 4);
                const float* src = Af + (size_t)(row0 + r)*K + k0 + (cs >> 1);
                const float4 f0 = *reinterpret_cast<const float4*>(src);
                const float4 f1 = *reinterpret_cast<const float4*>(src + 4);
                short8_t v;
                v[0]=(short)f2bf(f0.x); v[1]=(short)f2bf(f0.y); v[2]=(short)f2bf(f0.z); v[3]=(short)f2bf(f0.w);
                v[4]=(short)f2bf(f1.x); v[5]=(short)f2bf(f1.y); v[6]=(short)f2bf(f1.z); v[7]=(short)f2bf(f1.w);
                *reinterpret_cast<short8_t*>((char*)As + o) = v;
            }
        } else {
            stage64g<BM,WAVES>((const unsigned short*)Ap, (size_t)row0, K, k0, As, w, lane);
        }
        stage64g<BN,WAVES>(W, 0, K, k0, Bs, w, lane);
        __syncthreads();
        #pragma unroll
        for (int ks = 0; ks < 2; ++ks) {
            short8_t aF[4], bF[4];
            #pragma unroll
            for (int m = 0; m < 4; ++m)
                aF[m] = frag64(As, wr*64 + m*16 + l15, ks*64 + ko*16);
            #pragma unroll
            for (int n = 0; n < 4; ++n)
                bF[n] = frag64(Bs, wc*64 + n*16 + l15, ks*64 + ko*16);
            #pragma unroll
            for (int m = 0; m < 4; ++m)
                #pragma unroll
                for (int n = 0; n < 4; ++n)
                    acc[m][n] = __builtin_amdgcn_mfma_f32_16x16x32_bf16(aF[m], bF[n], acc[m][n], 0, 0, 0);
        }
        __syncthreads();
    }

    float bv[4];
    #pragma unroll
    for (int n = 0; n < 4; ++n) bv[n] = bias[wc*64 + n*16 + l15];
    #pragma unroll
    for (int m = 0; m < 4; ++m)
        #pragma unroll
        for (int n = 0; n < 4; ++n)
            #pragma unroll
            for (int r = 0; r < 4; ++r) acc[m][n][r] += bv[n];

    #pragma unroll
    for (int m = 0; m < 4; ++m) {
        #pragma unroll
        for (int r = 0; r < 4; ++r) {
            float s = acc[m][0][r] + acc[m][1][r] + acc[m][2][r] + acc[m][3][r];
            float q = acc[m][0][r]*acc[m][0][r] + acc[m][1][r]*acc[m][1][r]
                    + acc[m][2][r]*acc[m][2][r] + acc[m][3][r]*acc[m][3][r];
            s = dpp_rowsum16(s);
            q = dpp_rowsum16(q);
            if (l15 == 15) {
                int rl = wr*64 + m*16 + ko*4 + r;
                red_s[wc][rl] = s;
                red_q[wc][rl] = q;
            }
        }
    }
    __syncthreads();
    if (tid < BM) {
        float s = 0.f, q = 0.f;
        #pragma unroll
        for (int c2 = 0; c2 < WC; ++c2) { s += red_s[c2][tid]; q += red_q[c2][tid]; }
        float mu  = s * (1.0f/BN);
        float var = q * (1.0f/BN) - mu*mu;
        mu_l[tid] = mu;
        rs_l[tid] = rsqrtf(fmaxf(var, 0.f) + 1e-5f);
    }
    __syncthreads();

    float gm[4], bt[4];
    #pragma unroll
    for (int n = 0; n < 4; ++n) {
        int col = wc*64 + n*16 + l15;
        gm[n] = gam[col]; bt[n] = bet[col];
    }
    #pragma unroll
    for (int m = 0; m < 4; ++m) {
        #pragma unroll
        for (int r = 0; r < 4; ++r) {
            const int rl  = wr*64 + m*16 + ko*4 + r;
            const int row = row0 + rl;
            const float mu = mu_l[rl], rs = rs_l[rl];
            float mf = 1.f;
            if constexpr (MASKMUL) mf = (mask[row] != 0) ? 1.f : 0.f;
            #pragma unroll
            for (int n = 0; n < 4; ++n) {
                const int col = wc*64 + n*16 + l15;
                float y = (acc[m][n][r] - mu) * rs * gm[n] + bt[n];
                if constexpr (DO_LRELU) y = LRELU_(y);
                if constexpr (MASKMUL)  y *= mf;
                if constexpr (MODE == 1) {
                    ((unsigned short*)outv)[(size_t)row*BN + col] = f2bf(y);
                } else {
                    ((float*)outv)[(size_t)row*BN + col] = y;
                    unsigned short h = f2bf(y);
                    ohi[(size_t)row*BN + col] = h;
                    olo[(size_t)row*BN + col] = f2bf(y - bf2f(h));
                }
            }
        }
    }
}

// ---------------------------------------------------------------------------
// fc1 split-bf16 MFMA GEMM, 3 phases, BK=64, in-place OK, fused rowsq(x2).
// ---------------------------------------------------------------------------
__global__ __launch_bounds__(256)
void fc1mm_k(const unsigned short* Ahi, const unsigned short* Alo,
             const unsigned short* __restrict__ Bhi, const unsigned short* __restrict__ Blo,
             const float* __restrict__ bias,
             unsigned short* Ohi, unsigned short* Olo,
             float* __restrict__ x2out)
{
    __shared__ __align__(16) unsigned short As[128*64];
    __shared__ __align__(16) unsigned short Bs[128*64];
    __shared__ float red_q[2][128];

    const int tid  = threadIdx.x;
    const int lane = tid & 63;
    const int w    = tid >> 6;
    const int wr   = w >> 1, wc = w & 1;
    const int row0 = blockIdx.x * 128;
    const int l15  = lane & 15;
    const int ko   = lane >> 4;

    f32x4 acc[4][4];
    #pragma unroll
    for (int m = 0; m < 4; ++m)
        #pragma unroll
        for (int n = 0; n < 4; ++n) acc[m][n] = (f32x4){0.f,0.f,0.f,0.f};

    for (int kk = 0; kk < 384; kk += 64) {
        const int p  = kk >> 7;        // 0,0,1,1,2,2
        const int kl = kk & 127;
        const unsigned short* Ap2 = (p == 1) ? Alo : Ahi;
        const unsigned short* Bp2 = (p == 2) ? Blo : Bhi;
        stage64g<128,4>(Ap2, (size_t)row0, DD, kl, As, w, lane);
        stage64g<128,4>(Bp2, 0, DD, kl, Bs, w, lane);
        __syncthreads();
        #pragma unroll
        for (int ks = 0; ks < 2; ++ks) {
            short8_t aF[4], bF[4];
            #pragma unroll
            for (int m = 0; m < 4; ++m)
                aF[m] = frag64(As, wr*64 + m*16 + l15, ks*64 + ko*16);
            #pragma unroll
            for (int n = 0; n < 4; ++n)
                bF[n] = frag64(Bs, wc*64 + n*16 + l15, ks*64 + ko*16);
            #pragma unroll
            for (int m = 0; m < 4; ++m)
                #pragma unroll
                for (int n = 0; n < 4; ++n)
                    acc[m][n] = __builtin_amdgcn_mfma_f32_16x16x32_bf16(aF[m], bF[n], acc[m][n], 0, 0, 0);
        }
        __syncthreads();
    }

    float qacc[4][4];
    #pragma unroll
    for (int m = 0; m < 4; ++m) {
        const int rbase = row0 + wr*64 + m*16 + ko*4;
        #pragma unroll
        for (int r = 0; r < 4; ++r) qacc[m][r] = 0.f;
        #pragma unroll
        for (int n = 0; n < 4; ++n) {
            const int col = wc*64 + n*16 + l15;
            const float bv = bias[col];
            #pragma unroll
            for (int r = 0; r < 4; ++r) {
                const int row = rbase + r;
                float v = acc[m][n][r] + bv;
                unsigned short h = f2bf(v);
                unsigned short l = f2bf(v - bf2f(h));
                Ohi[(size_t)row*DD + col] = h;
                Olo[(size_t)row*DD + col] = l;
                float vv = bf2f(h) + bf2f(l);
                qacc[m][r] += vv*vv;
            }
        }
    }
    #pragma unroll
    for (int m = 0; m < 4; ++m)
        #pragma unroll
        for (int r = 0; r < 4; ++r) {
            float q = dpp_rowsum16(qacc[m][r]);
            if (l15 == 15) red_q[wc][wr*64 + m*16 + ko*4 + r] = q;
        }
    __syncthreads();
    if (tid < 128) x2out[row0 + tid] = red_q[0][tid] + red_q[1][tid];
}

// ---------------------------------------------------------------------------
// Fused distance + top-9 + GATHER: block = half-batch rows x all 256 cols.
// Both k-tiles of the full batch h (hi+lo) stay resident in LDS (128KB), so
// after top-9 (idx kept in LDS) the max-relative gather runs from LDS and
// writes cat directly. No h re-read, no idx global round-trip.
// ---------------------------------------------------------------------------
__global__ __launch_bounds__(512)
void dist_topk_gather_k(const unsigned short* __restrict__ hhi,
                        const unsigned short* __restrict__ hlo,
                        const int* __restrict__ mask,
                        const float* __restrict__ x2,
                        unsigned short* __restrict__ cat)
{
    __shared__ __align__(16) unsigned short BsH[2][NNODE*64];   // 64KB
    __shared__ __align__(16) unsigned short BsL[2][NNODE*64];   // 64KB
    __shared__ unsigned char idx_s[128*KNN];
    __shared__ unsigned char msk_s[NNODE];

    const int b    = blockIdx.x >> 1;
    const int half = blockIdx.x & 1;
    const int tid  = threadIdx.x;
    const int lane = tid & 63;
    const int w    = tid >> 6;          // 0..7
    const int l15  = lane & 15;
    const int g    = lane >> 4;         // 0..3

    const unsigned short* Hhi = hhi + (size_t)b*NNODE*DD;
    const unsigned short* Hlo = hlo + (size_t)b*NNODE*DD;
    const float* x2b = x2 + b*NNODE;
    const int*   mkb = mask + b*NNODE;

    // stage BOTH k-tiles of hi and lo (full batch h resident)
    stage64g<NNODE,8>(Hhi, 0, DD, 0,  &BsH[0][0], w, lane);
    stage64g<NNODE,8>(Hhi, 0, DD, 64, &BsH[1][0], w, lane);
    stage64g<NNODE,8>(Hlo, 0, DD, 0,  &BsL[0][0], w, lane);
    stage64g<NNODE,8>(Hlo, 0, DD, 64, &BsL[1][0], w, lane);
    if (tid < NNODE) msk_s[tid] = (mkb[tid] != 0) ? 1 : 0;
    __syncthreads();

    const int arow = half*128 + w*16 + l15;

    f32x4 acc[16];
    #pragma unroll
    for (int n = 0; n < 16; ++n) acc[n] = (f32x4){0.f,0.f,0.f,0.f};

    #pragma unroll
    for (int kt = 0; kt < 2; ++kt) {
        #pragma unroll
        for (int ks = 0; ks < 2; ++ks) {
            short8_t aH = frag64(&BsH[kt][0], arow, ks*64 + g*16);
            short8_t aL = frag64(&BsL[kt][0], arow, ks*64 + g*16);
            #pragma unroll
            for (int n = 0; n < 16; ++n) {
                int brow = n*16 + l15;
                short8_t bH = frag64(&BsH[kt][0], brow, ks*64 + g*16);
                short8_t bL = frag64(&BsL[kt][0], brow, ks*64 + g*16);
                acc[n] = __builtin_amdgcn_mfma_f32_16x16x32_bf16(aH, bH, acc[n], 0, 0, 0); // hi.hi
                acc[n] = __builtin_amdgcn_mfma_f32_16x16x32_bf16(aL, bH, acc[n], 0, 0, 0); // lo.hi
                acc[n] = __builtin_amdgcn_mfma_f32_16x16x32_bf16(aH, bL, acc[n], 0, 0, 0); // hi.lo
            }
        }
    }

    float x2c[16]; unsigned mk[16];
    #pragma unroll
    for (int n = 0; n < 16; ++n) {
        int col = n*16 + l15;
        x2c[n] = x2b[col];
        mk[n]  = (unsigned)msk_s[col];
    }

    #pragma unroll
    for (int r = 0; r < 4; ++r) {
        const int lrow = w*16 + g*4 + r;          // row within half (0..127)
        const float x2r = x2b[half*128 + lrow];
        unsigned key[16];
        #pragma unroll
        for (int n = 0; n < 16; ++n) {
            float v = x2r + x2c[n] - 2.0f*acc[n][r];
            if (!mk[n]) v = 1e10f;
            unsigned u = __float_as_uint(v);
            u = (u & 0x80000000u) ? ~u : (u | 0x80000000u);
            key[n] = (u & 0xFFFFFF00u) | (unsigned)(n*16 + l15);
        }
        for (int it = 0; it < KNN; ++it) {
            unsigned a0 = key[0]  < key[1]  ? key[0]  : key[1];
            unsigned a1 = key[2]  < key[3]  ? key[2]  : key[3];
            unsigned a2 = key[4]  < key[5]  ? key[4]  : key[5];
            unsigned a3 = key[6]  < key[7]  ? key[6]  : key[7];
            unsigned a4 = key[8]  < key[9]  ? key[8]  : key[9];
            unsigned a5 = key[10] < key[11] ? key[10] : key[11];
            unsigned a6 = key[12] < key[13] ? key[12] : key[13];
            unsigned a7 = key[14] < key[15] ? key[14] : key[15];
            unsigned b0 = a0 < a1 ? a0 : a1;
            unsigned b1 = a2 < a3 ? a2 : a3;
            unsigned b2 = a4 < a5 ? a4 : a5;
            unsigned b3 = a6 < a7 ? a6 : a7;
            unsigned c0 = b0 < b1 ? b0 : b1;
            unsigned c1 = b2 < b3 ? b2 : b3;
            unsigned lmin = c0 < c1 ? c0 : c1;
            unsigned gmin = grp16_min_u32(lmin);
            if (l15 == 0) idx_s[lrow*KNN + it] = (unsigned char)(gmin & 0xFFu);
            #pragma unroll
            for (int n = 0; n < 16; ++n)
                if (key[n] == gmin) key[n] = 0xFFFFFFFFu;
        }
    }
    __syncthreads();

    // ---- gather + max-relative from LDS-resident h ----
    const int c4 = (tid & 31) * 4;                 // col 0..124
    const int kt = c4 >> 6;
    const unsigned cb = (unsigned)((c4 & 63) * 2); // byte col within tile
    #pragma unroll 2
    for (int pass = 0; pass < 8; ++pass) {
        const int rl   = (tid >> 5) + pass*16;     // row within half (0..127)
        const int grow = half*128 + rl;            // row within batch
        us4 h4 = read4sw(&BsH[kt][0], grow, cb);
        us4 l4 = read4sw(&BsL[kt][0], grow, cb);
        float hi[4], m[4];
        #pragma unroll
        for (int d = 0; d < 4; ++d) { hi[d] = bf2f(h4[d]) + bf2f(l4[d]); m[d] = -1e9f; }
        bool any = false;
        #pragma unroll
        for (int q = 0; q < KNN; ++q) {
            int j = idx_s[rl*KNN + q];
            if (msk_s[j]) {
                any = true;
                us4 a = read4sw(&BsH[kt][0], j, cb);
                us4 o = read4sw(&BsL[kt][0], j, cb);
                #pragma unroll
                for (int d = 0; d < 4; ++d)
                    m[d] = fmaxf(m[d], bf2f(a[d]) + bf2f(o[d]) - hi[d]);
            }
        }
        us4 o1, o2;
        #pragma unroll
        for (int d = 0; d < 4; ++d) {
            o1[d] = f2bf(hi[d]);
            o2[d] = any ? f2bf(m[d]) : (unsigned short)0;
        }
        const size_t rowbase = (size_t)(b*NNODE + grow)*(2*DD);
        *reinterpret_cast<us4*>(&cat[rowbase + c4])      = o1;
        *reinterpret_cast<us4*>(&cat[rowbase + DD + c4]) = o2;
    }
}

// ---------------------------------------------------------------------------
// Fused conv + fc2, occupancy-optimized: BM=64 (1024 blocks), 40KB LDS.
// x += (lrelu(cat@Wc^T + cb)) @ W2^T + fb;  xhi = bf16(x)
// ---------------------------------------------------------------------------
__global__ __launch_bounds__(256)
void conv_fc2_k(const unsigned short* __restrict__ cat,
                const unsigned short* __restrict__ Wc,
                const float* __restrict__ cb,
                const unsigned short* __restrict__ W2,
                const float* __restrict__ fb,
                float* __restrict__ x,
                unsigned short* __restrict__ xhi)
{
    __shared__ __align__(16) unsigned short As[64*64];       // 8KB
    __shared__ __align__(16) unsigned short Bs[128*64];      // 16KB
    __shared__ __align__(16) unsigned short h2s[2][64*64];   // 2x8KB (k-halves)

    const int tid  = threadIdx.x;
    const int lane = tid & 63;
    const int w    = tid >> 6;      // 0..3: wave col group (cols w*32..w*32+31)
    const int row0 = blockIdx.x * 64;
    const int l15  = lane & 15;
    const int ko   = lane >> 4;

    f32x4 acc[4][2];
    #pragma unroll
    for (int m = 0; m < 4; ++m)
        #pragma unroll
        for (int n = 0; n < 2; ++n) acc[m][n] = (f32x4){0.f,0.f,0.f,0.f};

    for (int k0 = 0; k0 < 256; k0 += 64) {
        stage64g<64,4>(cat, (size_t)row0, 256, k0, As, w, lane);
        stage64g<128,4>(Wc, 0, 256, k0, Bs, w, lane);
        __syncthreads();
        #pragma unroll
        for (int ks = 0; ks < 2; ++ks) {
            short8_t aF[4], bF[2];
            #pragma unroll
            for (int m = 0; m < 4; ++m)
                aF[m] = frag64(As, m*16 + l15, ks*64 + ko*16);
            #pragma unroll
            for (int n = 0; n < 2; ++n)
                bF[n] = frag64(Bs, w*32 + n*16 + l15, ks*64 + ko*16);
            #pragma unroll
            for (int m = 0; m < 4; ++m)
                #pragma unroll
                for (int n = 0; n < 2; ++n)
                    acc[m][n] = __builtin_amdgcn_mfma_f32_16x16x32_bf16(aF[m], bF[n], acc[m][n], 0, 0, 0);
        }
        __syncthreads();
    }

    {
        const int kt = w >> 1;
        #pragma unroll
        for (int n = 0; n < 2; ++n) {
            const int col = w*32 + n*16 + l15;
            const float bv = cb[col];
            const unsigned bc = (unsigned)(((w & 1)*32 + n*16 + l15) * 2);
            #pragma unroll
            for (int m = 0; m < 4; ++m) {
                #pragma unroll
                for (int r = 0; r < 4; ++r) {
                    const int row = m*16 + ko*4 + r;
                    float v = LRELU_(acc[m][n][r] + bv);
                    *(unsigned short*)((char*)&h2s[kt][0] + row*128
                        + (bc ^ ((unsigned)(row & 7) << 4))) = f2bf(v);
                }
            }
        }
    }

    f32x4 acc2[4][2];
    #pragma unroll
    for (int m = 0; m < 4; ++m)
        #pragma unroll
        for (int n = 0; n < 2; ++n) acc2[m][n] = (f32x4){0.f,0.f,0.f,0.f};

    #pragma unroll
    for (int kt = 0; kt < 2; ++kt) {
        stage64g<128,4>(W2, 0, 128, kt*64, Bs, w, lane);
        __syncthreads();
        #pragma unroll
        for (int ks = 0; ks < 2; ++ks) {
            short8_t aF[4], bF[2];
            #pragma unroll
            for (int m = 0; m < 4; ++m)
                aF[m] = frag64(&h2s[kt][0], m*16 + l15, ks*64 + ko*16);
            #pragma unroll
            for (int n = 0; n < 2; ++n)
                bF[n] = frag64(Bs, w*32 + n*16 + l15, ks*64 + ko*16);
            #pragma unroll
            for (int m = 0; m < 4; ++m)
                #pragma unroll
                for (int n = 0; n < 2; ++n)
                    acc2[m][n] = __builtin_amdgcn_mfma_f32_16x16x32_bf16(aF[m], bF[n], acc2[m][n], 0, 0, 0);
        }
        __syncthreads();
    }

    #pragma unroll
    for (int m = 0; m < 4; ++m) {
        const int rbase = row0 + m*16 + ko*4;
        #pragma unroll
        for (int n = 0; n < 2; ++n) {
            const int col = w*32 + n*16 + l15;
            const float bv = fb[col];
            #pragma unroll
            for (int r = 0; r < 4; ++r) {
                const int row = rbase + r;
                float v = acc2[m][n][r] + bv + x[(size_t)row*DD + col];
                x[(size_t)row*DD + col] = v;
                xhi[(size_t)row*DD + col] = f2bf(v);
            }
        }
    }
}

__global__ __launch_bounds__(128)
void pool_k(const float* __restrict__ x, const int* __restrict__ mask,
            float* __restrict__ g, unsigned short* __restrict__ gbf)
{
    const int b = blockIdx.x, c = threadIdx.x;
    float s = 0.f; int cnt = 0;
    for (int n = 0; n < NNODE; ++n) {
        s += x[((size_t)b*NNODE + n)*DD + c];
        cnt += (mask[b*NNODE + n] != 0) ? 1 : 0;
    }
    float v = s / fmaxf((float)cnt, 1.0f);
    g[b*DD + c] = v;
    gbf[b*DD + c] = f2bf(v);
}

// ---------------------------------------------------------------------------
// All weight transpose-casts in ONE kernel (compile-time job table).
// ---------------------------------------------------------------------------
__global__ __launch_bounds__(256)
void prep_all_k(const float* __restrict__ emb_w1, const float* __restrict__ emb_w2,
                const float* __restrict__ conv_w, const float* __restrict__ fc2_w,
                const float* __restrict__ f1_w,   const float* __restrict__ f2_w,
                const float* __restrict__ fc1_w,  const float* __restrict__ ow1,
                const float* __restrict__ ow2,
                unsigned short* __restrict__ emb_w1t, unsigned short* __restrict__ emb_w2t,
                unsigned short* __restrict__ conv_wt, unsigned short* __restrict__ fc2_wt,
                unsigned short* __restrict__ ffn1_wt, unsigned short* __restrict__ ffn2_wt,
                unsigned short* __restrict__ fc1_wthi, unsigned short* __restrict__ fc1_wtlo,
                unsigned short* __restrict__ ow1t, unsigned short* __restrict__ ow2t)
{
    __shared__ float tile[32][33];
    const int tx = threadIdx.x & 31, ty = threadIdx.x >> 5;

    int bid = blockIdx.x;
    const float* src = nullptr; unsigned short* dst = nullptr; unsigned short* dlo = nullptr;
    int K = 0, N = 0;
    do {
        if (bid < 16)  { src = emb_w1; dst = emb_w1t; K = 64;  N = 256; break; }  bid -= 16;
        if (bid < 32)  { src = emb_w2; dst = emb_w2t; K = 256; N = 128; break; }  bid -= 32;
        if (bid < 64)  { int l = bid >> 5; bid &= 31;
                         src = conv_w + (size_t)l*256*128; dst = conv_wt + (size_t)l*128*256;
                         K = 256; N = 128; break; }                               bid -= 64;
        if (bid < 32)  { int l = bid >> 4; bid &= 15;
                         src = fc2_w + (size_t)l*128*128; dst = fc2_wt + (size_t)l*128*128;
                         K = 128; N = 128; break; }                               bid -= 32;
        if (bid < 128) { int l = bid >> 6; bid &= 63;
                         src = f1_w + (size_t)l*128*512; dst = ffn1_wt + (size_t)l*512*128;
                         K = 128; N = 512; break; }                               bid -= 128;
        if (bid < 128) { int l = bid >> 6; bid &= 63;
                         src = f2_w + (size_t)l*512*128; dst = ffn2_wt + (size_t)l*128*512;
                         K = 512; N = 128; break; }                               bid -= 128;
        if (bid < 32)  { int l = bid >> 4; bid &= 15;
                         src = fc1_w + (size_t)l*128*128;
                         dst = fc1_wthi + (size_t)l*128*128; dlo = fc1_wtlo + (size_t)l*128*128;
                         K = 128; N = 128; break; }                               bid -= 32;
        if (bid < 64)  { src = ow1; dst = ow1t; K = 128; N = 512; break; }        bid -= 64;
        { src = ow2; dst = ow2t; K = 512; N = 2048; }
    } while (0);

    const int nbx = N / 32;
    const int bx = bid % nbx, by = bid / nbx;
    const int k0 = by*32, n0 = bx*32;

    #pragma unroll
    for (int i = ty; i < 32; i += 8)
        tile[i][tx] = src[(size_t)(k0+i)*N + n0+tx];
    __syncthreads();
    #pragma unroll
    for (int i = ty; i < 32; i += 8) {
        float v = tile[tx][i];
        unsigned short h = f2bf(v);
        dst[(size_t)(n0+i)*K + k0+tx] = h;
        if (dlo) dlo[(size_t)(n0+i)*K + k0+tx] = f2bf(v - bf2f(h));
    }
}

// ---------------------------------------------------------------------------
extern "C" void kernel_launch(void* const* d_in, const int* in_sizes, int n_in,
                              void* d_out, int out_size, void* d_ws, size_t ws_size,
                              hipStream_t stream)
{
    const float* nodes  = (const float*)d_in[0];
    const int*   maskp  = (const int*)  d_in[1];
    const float* emb_w1 = (const float*)d_in[2];
    const float* emb_b1 = (const float*)d_in[3];
    const float* ln1_g  = (const float*)d_in[4];
    const float* ln1_b  = (const float*)d_in[5];
    const float* emb_w2 = (const float*)d_in[6];
    const float* emb_b2 = (const float*)d_in[7];
    const float* ln2_g  = (const float*)d_in[8];
    const float* ln2_b  = (const float*)d_in[9];
    const float* fc1_w  = (const float*)d_in[10];
    const float* fc1_b  = (const float*)d_in[11];
    const float* conv_w = (const float*)d_in[12];
    const float* conv_b = (const float*)d_in[13];
    const float* fc2_w  = (const float*)d_in[14];
    const float* fc2_b  = (const float*)d_in[15];
    const float* f1_w   = (const float*)d_in[16];
    const float* f1_b   = (const float*)d_in[17];
    const float* f2_w   = (const float*)d_in[18];
    const float* f2_b   = (const float*)d_in[19];
    const float* ow1    = (const float*)d_in[20];
    const float* ob1    = (const float*)d_in[21];
    const float* ow2    = (const float*)d_in[22];
    const float* ob2    = (const float*)d_in[23];
    float* out = (float*)d_out;

    // ---- workspace layout ----
    char* base = (char*)d_ws;
    float* x   = (float*)base;                          // 33.55 MB
    char*  H   = base + (size_t)BNROWS*DD*4;            // 33.55 MB (x_hi/x_lo <-> h_hi/h_lo)
    char*  BIG = H + (size_t)BNROWS*DD*4;               // 67.11 MB (t256 / cat / ffn hidden)
    float*          x2    = (float*)(BIG + (size_t)BNROWS*2*DD*4);
    float*          g     = (float*)(x2 + BNROWS);
    unsigned short* g_bf  = (unsigned short*)(g + BB*DD);
    unsigned short* hid2_bf = g_bf + BB*DD;
    unsigned short* wbuf  = hid2_bf + BB*FFND;

    unsigned short* x_hi   = (unsigned short*)H;
    unsigned short* x_lo   = x_hi + (size_t)BNROWS*DD;
    unsigned short* t256_bf= (unsigned short*)BIG;
    unsigned short* cat_bf = (unsigned short*)(BIG);    // reused regions
    unsigned short* hid_bf = (unsigned short*)BIG;

    unsigned short* emb_w1t  = wbuf;
    unsigned short* emb_w2t  = emb_w1t + 256*64;
    unsigned short* conv_wt  = emb_w2t + 128*256;
    unsigned short* fc2_wt   = conv_wt + 2*128*256;
    unsigned short* ffn1_wt  = fc2_wt  + 2*128*128;
    unsigned short* ffn2_wt  = ffn1_wt + 2*512*128;
    unsigned short* fc1_wthi = ffn2_wt + 2*128*512;
    unsigned short* fc1_wtlo = fc1_wthi + 2*128*128;
    unsigned short* ow1t     = fc1_wtlo + 2*128*128;
    unsigned short* ow2t     = ow1t + 512*128;

    const dim3 blk(256);

    // ---- all weight transpose-casts (one launch) ----
    prep_all_k<<<1520, blk, 0, stream>>>(
        emb_w1, emb_w2, conv_w, fc2_w, f1_w, f2_w, fc1_w, ow1, ow2,
        emb_w1t, emb_w2t, conv_wt, fc2_wt, ffn1_wt, ffn2_wt,
        fc1_wthi, fc1_wtlo, ow1t, ow2t);

    // ---- Embedding (GEMM + fused LN) ----
    bgemm_ln_k<2,4,true,false,1,true>
        <<<dim3(BNROWS/128), dim3(512), 0, stream>>>
        (nodes, emb_w1t, emb_b1, ln1_g, ln1_b, nullptr, t256_bf, nullptr, nullptr, PP2);
    bgemm_ln_k<2,2,false,true,2,false>
        <<<dim3(BNROWS/128), dim3(256), 0, stream>>>
        (t256_bf, emb_w2t, emb_b2, ln2_g, ln2_b, maskp, x, x_hi, x_lo, 2*DD);

    // ---- ViG blocks ----
    for (int l = 0; l < LLAY; ++l) {
        const float* fc1b = fc1_b + (size_t)l*DD;
        const float* cb   = conv_b + (size_t)l*DD;
        const float* fc2b = fc2_b + (size_t)l*DD;
        const float* b1   = f1_b + (size_t)l*FFND;
        const float* b2   = f2_b + (size_t)l*DD;

        fc1mm_k<<<dim3(BNROWS/128), blk, 0, stream>>>
            (x_hi, x_lo, fc1_wthi + (size_t)l*DD*DD, fc1_wtlo + (size_t)l*DD*DD,
             fc1b, x_hi, x_lo, x2);
        dist_topk_gather_k<<<dim3(2*BB), dim3(512), 0, stream>>>
            (x_hi, x_lo, maskp, x2, cat_bf);
        conv_fc2_k<<<dim3(BNROWS/64), blk, 0, stream>>>
            (cat_bf, conv_wt + (size_t)l*DD*2*DD, cb,
             fc2_wt + (size_t)l*DD*DD, fc2b, x, x_hi);
        bgemm_k<ACT_LRELU,false,false,false,true,false>
            <<<dim3(BNROWS/128, FFND/128), blk, 0, stream>>>
            (x_hi, ffn1_wt + (size_t)l*FFND*DD, b1,
             nullptr, nullptr, nullptr, hid_bf, nullptr, nullptr, BNROWS, FFND, DD);
        bgemm_k<ACT_NONE,true,true,true,false,true>
            <<<dim3(BNROWS/128, 1), blk, 0, stream>>>
            (hid_bf, ffn2_wt + (size_t)l*DD*FFND, b2,
             x, maskp, x, nullptr, x_hi, x_lo, BNROWS, DD, FFND);
    }

    // ---- Pool + head (bf16 MFMA) ----
    pool_k<<<BB, 128, 0, stream>>>(x, maskp, g, g_bf);
    bgemm_k<ACT_LRELU,false,false,false,true,false>
        <<<dim3(BB/128, 512/128), blk, 0, stream>>>
        (g_bf, ow1t, ob1, nullptr, nullptr, nullptr, hid2_bf, nullptr, nullptr, BB, 512, DD);
    bgemm_k<ACT_NONE,false,false,true,false,false>
        <<<dim3(BB/128, 2048/128), blk, 0, stream>>>
        (hid2_bf, ow2t, ob2, nullptr, nullptr, out, nullptr, nullptr, nullptr, BB, 2048, 512);
}

// Round 13
// 361.484 us; speedup vs baseline: 1.1794x; 1.0844x over previous
//
#include <hip/hip_runtime.h>
#include <cstdint>

#define BB    256
#define NNODE 256
#define PP2   64
#define DD    128
#define LLAY  2
#define KNN   9
#define FFND  512
#define BNROWS (BB*NNODE)   // 65536

#define LRELU_(v) ((v) >= 0.f ? (v) : 0.01f*(v))

enum { ACT_NONE = 0, ACT_LRELU = 1 };

typedef short  short8_t  __attribute__((ext_vector_type(8)));
typedef float  f32x4     __attribute__((ext_vector_type(4)));
typedef unsigned short us4 __attribute__((ext_vector_type(4)));

__device__ inline unsigned short f2bf(float x) {
    unsigned u = __float_as_uint(x);
    unsigned r = (u + 0x7FFFu + ((u >> 16) & 1u)) >> 16;
    return (unsigned short)r;
}
__device__ inline float bf2f(unsigned short h) {
    return __uint_as_float(((unsigned)h) << 16);
}

// async global->LDS, 16B per lane; LDS dest must be wave-uniform base.
__device__ inline void gload16(const void* src, void* dst) {
    __builtin_amdgcn_global_load_lds(
        (const __attribute__((address_space(1))) void*)src,
        (__attribute__((address_space(3))) void*)dst, 16, 0, 0);
}

// Stage a BK=64 bf16 tile (ROWS x 64 elems, 128B rows) from row-major global
// (element stride Kel, starting col k0) into LINEAR LDS via global_load_lds.
// Source address carries the inverse XOR swizzle; reads apply the same XOR.
template<int ROWS, int WAVES>
__device__ inline void stage64g(const unsigned short* __restrict__ g, size_t rowbase,
                                int Kel, int k0, unsigned short* lds, int w, int lane)
{
    constexpr int PER = (ROWS*128/1024) / WAVES;
    #pragma unroll
    for (int i = 0; i < PER; ++i) {
        const int inst = w + i*WAVES;                 // wave-uniform
        const unsigned o  = (unsigned)inst*1024u + (unsigned)lane*16u;
        const int      r  = (int)(o >> 7);
        const unsigned cb = o & 127u;
        const unsigned cs = cb ^ ((unsigned)(r & 7) << 4);
        gload16((const char*)(g + (rowbase + (size_t)r)*(size_t)Kel + k0) + cs,
                (char*)lds + (size_t)inst*1024u);
    }
}

// swizzled fragment read from a linear BK=64 tile
__device__ inline short8_t frag64(const unsigned short* lds, int r, int cb) {
    return *reinterpret_cast<const short8_t*>(
        (const char*)lds + (size_t)r*128 + (unsigned)(cb ^ ((r & 7) << 4)));
}

// swizzled 8B (4 cols) read from a BK=64 tile at column-byte cb (mult of 8)
__device__ inline us4 read4sw(const unsigned short* lds, int r, unsigned cb) {
    return *reinterpret_cast<const us4*>(
        (const char*)lds + (size_t)r*128 + (cb ^ ((unsigned)(r & 7) << 4)));
}

// 16-lane-group min (per DPP row); result in ALL lanes of each 16-group.
__device__ inline unsigned grp16_min_u32(unsigned v) {
    unsigned t;
    t = (unsigned)__builtin_amdgcn_update_dpp(-1, (int)v, 0xB1,  0xF, 0xF, false); v = t < v ? t : v; // quad_perm [1,0,3,2]
    t = (unsigned)__builtin_amdgcn_update_dpp(-1, (int)v, 0x4E,  0xF, 0xF, false); v = t < v ? t : v; // quad_perm [2,3,0,1]
    t = (unsigned)__builtin_amdgcn_update_dpp(-1, (int)v, 0x124, 0xF, 0xF, false); v = t < v ? t : v; // row_ror:4
    t = (unsigned)__builtin_amdgcn_update_dpp(-1, (int)v, 0x128, 0xF, 0xF, false); v = t < v ? t : v; // row_ror:8
    return v;
}

// 16-lane (DPP row) sum; result valid in lane 15 of each 16-lane row.
__device__ inline float dpp_rowsum16(float v) {
    float t;
    t = __uint_as_float((unsigned)__builtin_amdgcn_update_dpp(0, (int)__float_as_uint(v), 0x111, 0xF, 0xF, false)); v += t;
    t = __uint_as_float((unsigned)__builtin_amdgcn_update_dpp(0, (int)__float_as_uint(v), 0x112, 0xF, 0xF, false)); v += t;
    t = __uint_as_float((unsigned)__builtin_amdgcn_update_dpp(0, (int)__float_as_uint(v), 0x114, 0xF, 0xF, false)); v += t;
    t = __uint_as_float((unsigned)__builtin_amdgcn_update_dpp(0, (int)__float_as_uint(v), 0x118, 0xF, 0xF, false)); v += t;
    return v;
}

// ---------------------------------------------------------------------------
// bf16 MFMA GEMM, BK=64, global_load_lds staging.
// ---------------------------------------------------------------------------
template<int ACT, bool RES, bool MASK, bool OUTF, bool OUTB, bool OUTS>
__global__ __launch_bounds__(256)
void bgemm_k(const unsigned short* __restrict__ A,
             const unsigned short* __restrict__ W,
             const float* __restrict__ bias,
             const float* __restrict__ resp,
             const int* __restrict__ mask,
             float* __restrict__ Cf, unsigned short* __restrict__ Cb,
             unsigned short* Ohi, unsigned short* Olo,
             int M, int N, int K)
{
    __shared__ __align__(16) unsigned short As[128*64];
    __shared__ __align__(16) unsigned short Bs[128*64];

    const int tid  = threadIdx.x;
    const int lane = tid & 63;
    const int w    = tid >> 6;
    const int wr   = w >> 1, wc = w & 1;
    const int row0 = blockIdx.x * 128;
    const int col0 = blockIdx.y * 128;
    const int l15  = lane & 15;
    const int ko   = lane >> 4;

    f32x4 acc[4][4];
    #pragma unroll
    for (int m = 0; m < 4; ++m)
        #pragma unroll
        for (int n = 0; n < 4; ++n) acc[m][n] = (f32x4){0.f,0.f,0.f,0.f};

    for (int k0 = 0; k0 < K; k0 += 64) {
        stage64g<128,4>(A, (size_t)row0, K, k0, As, w, lane);
        stage64g<128,4>(W, (size_t)col0, K, k0, Bs, w, lane);
        __syncthreads();
        #pragma unroll
        for (int ks = 0; ks < 2; ++ks) {
            short8_t aF[4], bF[4];
            #pragma unroll
            for (int m = 0; m < 4; ++m)
                aF[m] = frag64(As, wr*64 + m*16 + l15, ks*64 + ko*16);
            #pragma unroll
            for (int n = 0; n < 4; ++n)
                bF[n] = frag64(Bs, wc*64 + n*16 + l15, ks*64 + ko*16);
            #pragma unroll
            for (int m = 0; m < 4; ++m)
                #pragma unroll
                for (int n = 0; n < 4; ++n)
                    acc[m][n] = __builtin_amdgcn_mfma_f32_16x16x32_bf16(aF[m], bF[n], acc[m][n], 0, 0, 0);
        }
        __syncthreads();
    }

    #pragma unroll
    for (int m = 0; m < 4; ++m) {
        const int rbase = row0 + wr*64 + m*16 + ko*4;
        #pragma unroll
        for (int n = 0; n < 4; ++n) {
            const int col = col0 + wc*64 + n*16 + l15;
            const float bv = bias[col];
            #pragma unroll
            for (int r = 0; r < 4; ++r) {
                const int row = rbase + r;
                float v = acc[m][n][r] + bv;
                if constexpr (ACT == ACT_LRELU) v = LRELU_(v);
                if constexpr (RES)  v += resp[(size_t)row*N + col];
                if constexpr (MASK) v *= (mask[row] != 0) ? 1.f : 0.f;
                if constexpr (OUTF) Cf[(size_t)row*N + col] = v;
                if constexpr (OUTB) Cb[(size_t)row*N + col] = f2bf(v);
                if constexpr (OUTS) {
                    unsigned short h = f2bf(v);
                    Ohi[(size_t)row*N + col] = h;
                    Olo[(size_t)row*N + col] = f2bf(v - bf2f(h));
                }
            }
        }
    }
}

// ---------------------------------------------------------------------------
// bf16 MFMA GEMM fused with full-row LayerNorm epilogue (BK=64).
// AF32: A fp32, cast during (reg) staging into the same linear-swz layout.
// ---------------------------------------------------------------------------
template<int WR, int WC, bool DO_LRELU, bool MASKMUL, int MODE, bool AF32>
__global__ __launch_bounds__(WR*WC*64)
void bgemm_ln_k(const void* __restrict__ Ap,
                const unsigned short* __restrict__ W,
                const float* __restrict__ bias,
                const float* __restrict__ gam,
                const float* __restrict__ bet,
                const int* __restrict__ mask,
                void* __restrict__ outv,
                unsigned short* __restrict__ ohi, unsigned short* __restrict__ olo,
                int K)
{
    constexpr int BM = WR*64;
    constexpr int BN = WC*64;
    constexpr int THREADS = WR*WC*64;
    constexpr int WAVES = THREADS/64;
    __shared__ __align__(16) unsigned short As[BM*64];
    __shared__ __align__(16) unsigned short Bs[BN*64];
    __shared__ float red_s[WC][BM];
    __shared__ float red_q[WC][BM];
    __shared__ float mu_l[BM];
    __shared__ float rs_l[BM];

    const int tid  = threadIdx.x;
    const int lane = tid & 63;
    const int w    = tid >> 6;
    const int wr   = w / WC, wc = w % WC;
    const int row0 = blockIdx.x * BM;
    const int l15  = lane & 15;
    const int ko   = lane >> 4;

    f32x4 acc[4][4];
    #pragma unroll
    for (int m = 0; m < 4; ++m)
        #pragma unroll
        for (int n = 0; n < 4; ++n) acc[m][n] = (f32x4){0.f,0.f,0.f,0.f};

    for (int k0 = 0; k0 < K; k0 += 64) {
        if constexpr (AF32) {
            const float* Af = (const float*)Ap;
            constexpr int CH = (BM*8)/THREADS;    // 16B chunks per thread
            #pragma unroll
            for (int i = 0; i < CH; ++i) {
                const int q = i*THREADS + tid;
                const unsigned o  = (unsigned)q*16u;
                const int      r  = (int)(o >> 7);
                const unsigned cb = o & 127u;
                const unsigned cs = cb ^ ((unsigned)(r & 7) << 4);
                const float* src = Af + (size_t)(row0 + r)*K + k0 + (cs >> 1);
                const float4 f0 = *reinterpret_cast<const float4*>(src);
                const float4 f1 = *reinterpret_cast<const float4*>(src + 4);
                short8_t v;
                v[0]=(short)f2bf(f0.x); v[1]=(short)f2bf(f0.y); v[2]=(short)f2bf(f0.z); v[3]=(short)f2bf(f0.w);
                v[4]=(short)f2bf(f1.x); v[5]=(short)f2bf(f1.y); v[6]=(short)f2bf(f1.z); v[7]=(short)f2bf(f1.w);
                *reinterpret_cast<short8_t*>((char*)As + o) = v;
            }
        } else {
            stage64g<BM,WAVES>((const unsigned short*)Ap, (size_t)row0, K, k0, As, w, lane);
        }
        stage64g<BN,WAVES>(W, 0, K, k0, Bs, w, lane);
        __syncthreads();
        #pragma unroll
        for (int ks = 0; ks < 2; ++ks) {
            short8_t aF[4], bF[4];
            #pragma unroll
            for (int m = 0; m < 4; ++m)
                aF[m] = frag64(As, wr*64 + m*16 + l15, ks*64 + ko*16);
            #pragma unroll
            for (int n = 0; n < 4; ++n)
                bF[n] = frag64(Bs, wc*64 + n*16 + l15, ks*64 + ko*16);
            #pragma unroll
            for (int m = 0; m < 4; ++m)
                #pragma unroll
                for (int n = 0; n < 4; ++n)
                    acc[m][n] = __builtin_amdgcn_mfma_f32_16x16x32_bf16(aF[m], bF[n], acc[m][n], 0, 0, 0);
        }
        __syncthreads();
    }

    float bv[4];
    #pragma unroll
    for (int n = 0; n < 4; ++n) bv[n] = bias[wc*64 + n*16 + l15];
    #pragma unroll
    for (int m = 0; m < 4; ++m)
        #pragma unroll
        for (int n = 0; n < 4; ++n)
            #pragma unroll
            for (int r = 0; r < 4; ++r) acc[m][n][r] += bv[n];

    #pragma unroll
    for (int m = 0; m < 4; ++m) {
        #pragma unroll
        for (int r = 0; r < 4; ++r) {
            float s = acc[m][0][r] + acc[m][1][r] + acc[m][2][r] + acc[m][3][r];
            float q = acc[m][0][r]*acc[m][0][r] + acc[m][1][r]*acc[m][1][r]
                    + acc[m][2][r]*acc[m][2][r] + acc[m][3][r]*acc[m][3][r];
            s = dpp_rowsum16(s);
            q = dpp_rowsum16(q);
            if (l15 == 15) {
                int rl = wr*64 + m*16 + ko*4 + r;
                red_s[wc][rl] = s;
                red_q[wc][rl] = q;
            }
        }
    }
    __syncthreads();
    if (tid < BM) {
        float s = 0.f, q = 0.f;
        #pragma unroll
        for (int c2 = 0; c2 < WC; ++c2) { s += red_s[c2][tid]; q += red_q[c2][tid]; }
        float mu  = s * (1.0f/BN);
        float var = q * (1.0f/BN) - mu*mu;
        mu_l[tid] = mu;
        rs_l[tid] = rsqrtf(fmaxf(var, 0.f) + 1e-5f);
    }
    __syncthreads();

    float gm[4], bt[4];
    #pragma unroll
    for (int n = 0; n < 4; ++n) {
        int col = wc*64 + n*16 + l15;
        gm[n] = gam[col]; bt[n] = bet[col];
    }
    #pragma unroll
    for (int m = 0; m < 4; ++m) {
        #pragma unroll
        for (int r = 0; r < 4; ++r) {
            const int rl  = wr*64 + m*16 + ko*4 + r;
            const int row = row0 + rl;
            const float mu = mu_l[rl], rs = rs_l[rl];
            float mf = 1.f;
            if constexpr (MASKMUL) mf = (mask[row] != 0) ? 1.f : 0.f;
            #pragma unroll
            for (int n = 0; n < 4; ++n) {
                const int col = wc*64 + n*16 + l15;
                float y = (acc[m][n][r] - mu) * rs * gm[n] + bt[n];
                if constexpr (DO_LRELU) y = LRELU_(y);
                if constexpr (MASKMUL)  y *= mf;
                if constexpr (MODE == 1) {
                    ((unsigned short*)outv)[(size_t)row*BN + col] = f2bf(y);
                } else {
                    ((float*)outv)[(size_t)row*BN + col] = y;
                    unsigned short h = f2bf(y);
                    ohi[(size_t)row*BN + col] = h;
                    olo[(size_t)row*BN + col] = f2bf(y - bf2f(h));
                }
            }
        }
    }
}

// ---------------------------------------------------------------------------
// fc1 split-bf16 MFMA GEMM, 3 phases, BK=64, in-place OK, fused rowsq(x2).
// ---------------------------------------------------------------------------
__global__ __launch_bounds__(256)
void fc1mm_k(const unsigned short* Ahi, const unsigned short* Alo,
             const unsigned short* __restrict__ Bhi, const unsigned short* __restrict__ Blo,
             const float* __restrict__ bias,
             unsigned short* Ohi, unsigned short* Olo,
             float* __restrict__ x2out)
{
    __shared__ __align__(16) unsigned short As[128*64];
    __shared__ __align__(16) unsigned short Bs[128*64];
    __shared__ float red_q[2][128];

    const int tid  = threadIdx.x;
    const int lane = tid & 63;
    const int w    = tid >> 6;
    const int wr   = w >> 1, wc = w & 1;
    const int row0 = blockIdx.x * 128;
    const int l15  = lane & 15;
    const int ko   = lane >> 4;

    f32x4 acc[4][4];
    #pragma unroll
    for (int m = 0; m < 4; ++m)
        #pragma unroll
        for (int n = 0; n < 4; ++n) acc[m][n] = (f32x4){0.f,0.f,0.f,0.f};

    for (int kk = 0; kk < 384; kk += 64) {
        const int p  = kk >> 7;        // 0,0,1,1,2,2
        const int kl = kk & 127;
        const unsigned short* Ap2 = (p == 1) ? Alo : Ahi;
        const unsigned short* Bp2 = (p == 2) ? Blo : Bhi;
        stage64g<128,4>(Ap2, (size_t)row0, DD, kl, As, w, lane);
        stage64g<128,4>(Bp2, 0, DD, kl, Bs, w, lane);
        __syncthreads();
        #pragma unroll
        for (int ks = 0; ks < 2; ++ks) {
            short8_t aF[4], bF[4];
            #pragma unroll
            for (int m = 0; m < 4; ++m)
                aF[m] = frag64(As, wr*64 + m*16 + l15, ks*64 + ko*16);
            #pragma unroll
            for (int n = 0; n < 4; ++n)
                bF[n] = frag64(Bs, wc*64 + n*16 + l15, ks*64 + ko*16);
            #pragma unroll
            for (int m = 0; m < 4; ++m)
                #pragma unroll
                for (int n = 0; n < 4; ++n)
                    acc[m][n] = __builtin_amdgcn_mfma_f32_16x16x32_bf16(aF[m], bF[n], acc[m][n], 0, 0, 0);
        }
        __syncthreads();
    }

    float qacc[4][4];
    #pragma unroll
    for (int m = 0; m < 4; ++m) {
        const int rbase = row0 + wr*64 + m*16 + ko*4;
        #pragma unroll
        for (int r = 0; r < 4; ++r) qacc[m][r] = 0.f;
        #pragma unroll
        for (int n = 0; n < 4; ++n) {
            const int col = wc*64 + n*16 + l15;
            const float bv = bias[col];
            #pragma unroll
            for (int r = 0; r < 4; ++r) {
                const int row = rbase + r;
                float v = acc[m][n][r] + bv;
                unsigned short h = f2bf(v);
                unsigned short l = f2bf(v - bf2f(h));
                Ohi[(size_t)row*DD + col] = h;
                Olo[(size_t)row*DD + col] = l;
                float vv = bf2f(h) + bf2f(l);
                qacc[m][r] += vv*vv;
            }
        }
    }
    #pragma unroll
    for (int m = 0; m < 4; ++m)
        #pragma unroll
        for (int r = 0; r < 4; ++r) {
            float q = dpp_rowsum16(qacc[m][r]);
            if (l15 == 15) red_q[wc][wr*64 + m*16 + ko*4 + r] = q;
        }
    __syncthreads();
    if (tid < 128) x2out[row0 + tid] = red_q[0][tid] + red_q[1][tid];
}

// ---------------------------------------------------------------------------
// Fused distance + top-9 + gather: ONE block per batch (1024 thr, 16 waves).
// Full batch h (hi+lo, both k-tiles) resident in LDS; staged ONCE.
// Wave w owns A-rows w*16..w*16+15. idx stays in LDS; gather writes cat.
// ---------------------------------------------------------------------------
__global__ __launch_bounds__(1024)
void dist_topk_gather_k(const unsigned short* __restrict__ hhi,
                        const unsigned short* __restrict__ hlo,
                        const int* __restrict__ mask,
                        const float* __restrict__ x2,
                        unsigned short* __restrict__ cat)
{
    __shared__ __align__(16) unsigned short BsH[2][NNODE*64];   // 64KB
    __shared__ __align__(16) unsigned short BsL[2][NNODE*64];   // 64KB
    __shared__ unsigned char idx_s[NNODE*KNN];
    __shared__ unsigned char msk_s[NNODE];

    const int b    = blockIdx.x;
    const int tid  = threadIdx.x;
    const int lane = tid & 63;
    const int w    = tid >> 6;          // 0..15
    const int l15  = lane & 15;
    const int g    = lane >> 4;         // 0..3

    const unsigned short* Hhi = hhi + (size_t)b*NNODE*DD;
    const unsigned short* Hlo = hlo + (size_t)b*NNODE*DD;
    const float* x2b = x2 + b*NNODE;
    const int*   mkb = mask + b*NNODE;

    // stage both k-tiles of hi and lo once (full batch h resident)
    stage64g<NNODE,16>(Hhi, 0, DD, 0,  &BsH[0][0], w, lane);
    stage64g<NNODE,16>(Hhi, 0, DD, 64, &BsH[1][0], w, lane);
    stage64g<NNODE,16>(Hlo, 0, DD, 0,  &BsL[0][0], w, lane);
    stage64g<NNODE,16>(Hlo, 0, DD, 64, &BsL[1][0], w, lane);
    if (tid < NNODE) msk_s[tid] = (mkb[tid] != 0) ? 1 : 0;
    __syncthreads();

    const int arow = w*16 + l15;        // 0..255

    f32x4 acc[16];
    #pragma unroll
    for (int n = 0; n < 16; ++n) acc[n] = (f32x4){0.f,0.f,0.f,0.f};

    #pragma unroll
    for (int kt = 0; kt < 2; ++kt) {
        #pragma unroll
        for (int ks = 0; ks < 2; ++ks) {
            short8_t aH = frag64(&BsH[kt][0], arow, ks*64 + g*16);
            short8_t aL = frag64(&BsL[kt][0], arow, ks*64 + g*16);
            #pragma unroll
            for (int n = 0; n < 16; ++n) {
                int brow = n*16 + l15;
                short8_t bH = frag64(&BsH[kt][0], brow, ks*64 + g*16);
                short8_t bL = frag64(&BsL[kt][0], brow, ks*64 + g*16);
                acc[n] = __builtin_amdgcn_mfma_f32_16x16x32_bf16(aH, bH, acc[n], 0, 0, 0); // hi.hi
                acc[n] = __builtin_amdgcn_mfma_f32_16x16x32_bf16(aL, bH, acc[n], 0, 0, 0); // lo.hi
                acc[n] = __builtin_amdgcn_mfma_f32_16x16x32_bf16(aH, bL, acc[n], 0, 0, 0); // hi.lo
            }
        }
    }

    float x2c[16]; unsigned mk[16];
    #pragma unroll
    for (int n = 0; n < 16; ++n) {
        int col = n*16 + l15;
        x2c[n] = x2b[col];
        mk[n]  = (unsigned)msk_s[col];
    }

    #pragma unroll
    for (int r = 0; r < 4; ++r) {
        const int lrow = w*16 + g*4 + r;          // 0..255
        const float x2r = x2b[lrow];
        unsigned key[16];
        #pragma unroll
        for (int n = 0; n < 16; ++n) {
            float v = x2r + x2c[n] - 2.0f*acc[n][r];
            if (!mk[n]) v = 1e10f;
            unsigned u = __float_as_uint(v);
            u = (u & 0x80000000u) ? ~u : (u | 0x80000000u);
            key[n] = (u & 0xFFFFFF00u) | (unsigned)(n*16 + l15);
        }
        for (int it = 0; it < KNN; ++it) {
            unsigned a0 = key[0]  < key[1]  ? key[0]  : key[1];
            unsigned a1 = key[2]  < key[3]  ? key[2]  : key[3];
            unsigned a2 = key[4]  < key[5]  ? key[4]  : key[5];
            unsigned a3 = key[6]  < key[7]  ? key[6]  : key[7];
            unsigned a4 = key[8]  < key[9]  ? key[8]  : key[9];
            unsigned a5 = key[10] < key[11] ? key[10] : key[11];
            unsigned a6 = key[12] < key[13] ? key[12] : key[13];
            unsigned a7 = key[14] < key[15] ? key[14] : key[15];
            unsigned b0 = a0 < a1 ? a0 : a1;
            unsigned b1 = a2 < a3 ? a2 : a3;
            unsigned b2 = a4 < a5 ? a4 : a5;
            unsigned b3 = a6 < a7 ? a6 : a7;
            unsigned c0 = b0 < b1 ? b0 : b1;
            unsigned c1 = b2 < b3 ? b2 : b3;
            unsigned lmin = c0 < c1 ? c0 : c1;
            unsigned gmin = grp16_min_u32(lmin);
            if (l15 == 0) idx_s[lrow*KNN + it] = (unsigned char)(gmin & 0xFFu);
            #pragma unroll
            for (int n = 0; n < 16; ++n)
                if (key[n] == gmin) key[n] = 0xFFFFFFFFu;
        }
    }
    __syncthreads();

    // ---- gather + max-relative from LDS-resident h ----
    const int c4 = (tid & 31) * 4;                 // col 0..124
    const int kt = c4 >> 6;
    const unsigned cb = (unsigned)((c4 & 63) * 2); // byte col within tile
    #pragma unroll 2
    for (int pass = 0; pass < 8; ++pass) {
        const int rl = (tid >> 5) + pass*32;       // 0..255
        us4 h4 = read4sw(&BsH[kt][0], rl, cb);
        us4 l4 = read4sw(&BsL[kt][0], rl, cb);
        float hi[4], m[4];
        #pragma unroll
        for (int d = 0; d < 4; ++d) { hi[d] = bf2f(h4[d]) + bf2f(l4[d]); m[d] = -1e9f; }
        bool any = false;
        #pragma unroll
        for (int q = 0; q < KNN; ++q) {
            int j = idx_s[rl*KNN + q];
            if (msk_s[j]) {
                any = true;
                us4 a = read4sw(&BsH[kt][0], j, cb);
                us4 o = read4sw(&BsL[kt][0], j, cb);
                #pragma unroll
                for (int d = 0; d < 4; ++d)
                    m[d] = fmaxf(m[d], bf2f(a[d]) + bf2f(o[d]) - hi[d]);
            }
        }
        us4 o1, o2;
        #pragma unroll
        for (int d = 0; d < 4; ++d) {
            o1[d] = f2bf(hi[d]);
            o2[d] = any ? f2bf(m[d]) : (unsigned short)0;
        }
        const size_t rowbase = (size_t)(b*NNODE + rl)*(2*DD);
        *reinterpret_cast<us4*>(&cat[rowbase + c4])      = o1;
        *reinterpret_cast<us4*>(&cat[rowbase + DD + c4]) = o2;
    }
}

// ---------------------------------------------------------------------------
// Fused conv + fc2, occupancy-optimized: BM=64 (1024 blocks), 40KB LDS.
// x += (lrelu(cat@Wc^T + cb)) @ W2^T + fb;  xhi = bf16(x)
// ---------------------------------------------------------------------------
__global__ __launch_bounds__(256)
void conv_fc2_k(const unsigned short* __restrict__ cat,
                const unsigned short* __restrict__ Wc,
                const float* __restrict__ cb,
                const unsigned short* __restrict__ W2,
                const float* __restrict__ fb,
                float* __restrict__ x,
                unsigned short* __restrict__ xhi)
{
    __shared__ __align__(16) unsigned short As[64*64];       // 8KB
    __shared__ __align__(16) unsigned short Bs[128*64];      // 16KB
    __shared__ __align__(16) unsigned short h2s[2][64*64];   // 2x8KB (k-halves)

    const int tid  = threadIdx.x;
    const int lane = tid & 63;
    const int w    = tid >> 6;      // 0..3: wave col group (cols w*32..w*32+31)
    const int row0 = blockIdx.x * 64;
    const int l15  = lane & 15;
    const int ko   = lane >> 4;

    f32x4 acc[4][2];
    #pragma unroll
    for (int m = 0; m < 4; ++m)
        #pragma unroll
        for (int n = 0; n < 2; ++n) acc[m][n] = (f32x4){0.f,0.f,0.f,0.f};

    for (int k0 = 0; k0 < 256; k0 += 64) {
        stage64g<64,4>(cat, (size_t)row0, 256, k0, As, w, lane);
        stage64g<128,4>(Wc, 0, 256, k0, Bs, w, lane);
        __syncthreads();
        #pragma unroll
        for (int ks = 0; ks < 2; ++ks) {
            short8_t aF[4], bF[2];
            #pragma unroll
            for (int m = 0; m < 4; ++m)
                aF[m] = frag64(As, m*16 + l15, ks*64 + ko*16);
            #pragma unroll
            for (int n = 0; n < 2; ++n)
                bF[n] = frag64(Bs, w*32 + n*16 + l15, ks*64 + ko*16);
            #pragma unroll
            for (int m = 0; m < 4; ++m)
                #pragma unroll
                for (int n = 0; n < 2; ++n)
                    acc[m][n] = __builtin_amdgcn_mfma_f32_16x16x32_bf16(aF[m], bF[n], acc[m][n], 0, 0, 0);
        }
        __syncthreads();
    }

    {
        const int kt = w >> 1;
        #pragma unroll
        for (int n = 0; n < 2; ++n) {
            const int col = w*32 + n*16 + l15;
            const float bv = cb[col];
            const unsigned bc = (unsigned)(((w & 1)*32 + n*16 + l15) * 2);
            #pragma unroll
            for (int m = 0; m < 4; ++m) {
                #pragma unroll
                for (int r = 0; r < 4; ++r) {
                    const int row = m*16 + ko*4 + r;
                    float v = LRELU_(acc[m][n][r] + bv);
                    *(unsigned short*)((char*)&h2s[kt][0] + row*128
                        + (bc ^ ((unsigned)(row & 7) << 4))) = f2bf(v);
                }
            }
        }
    }

    f32x4 acc2[4][2];
    #pragma unroll
    for (int m = 0; m < 4; ++m)
        #pragma unroll
        for (int n = 0; n < 2; ++n) acc2[m][n] = (f32x4){0.f,0.f,0.f,0.f};

    #pragma unroll
    for (int kt = 0; kt < 2; ++kt) {
        stage64g<128,4>(W2, 0, 128, kt*64, Bs, w, lane);
        __syncthreads();
        #pragma unroll
        for (int ks = 0; ks < 2; ++ks) {
            short8_t aF[4], bF[2];
            #pragma unroll
            for (int m = 0; m < 4; ++m)
                aF[m] = frag64(&h2s[kt][0], m*16 + l15, ks*64 + ko*16);
            #pragma unroll
            for (int n = 0; n < 2; ++n)
                bF[n] = frag64(Bs, w*32 + n*16 + l15, ks*64 + ko*16);
            #pragma unroll
            for (int m = 0; m < 4; ++m)
                #pragma unroll
                for (int n = 0; n < 2; ++n)
                    acc2[m][n] = __builtin_amdgcn_mfma_f32_16x16x32_bf16(aF[m], bF[n], acc2[m][n], 0, 0, 0);
        }
        __syncthreads();
    }

    #pragma unroll
    for (int m = 0; m < 4; ++m) {
        const int rbase = row0 + m*16 + ko*4;
        #pragma unroll
        for (int n = 0; n < 2; ++n) {
            const int col = w*32 + n*16 + l15;
            const float bv = fb[col];
            #pragma unroll
            for (int r = 0; r < 4; ++r) {
                const int row = rbase + r;
                float v = acc2[m][n][r] + bv + x[(size_t)row*DD + col];
                x[(size_t)row*DD + col] = v;
                xhi[(size_t)row*DD + col] = f2bf(v);
            }
        }
    }
}

__global__ __launch_bounds__(128)
void pool_k(const float* __restrict__ x, const int* __restrict__ mask,
            float* __restrict__ g, unsigned short* __restrict__ gbf)
{
    const int b = blockIdx.x, c = threadIdx.x;
    float s = 0.f; int cnt = 0;
    for (int n = 0; n < NNODE; ++n) {
        s += x[((size_t)b*NNODE + n)*DD + c];
        cnt += (mask[b*NNODE + n] != 0) ? 1 : 0;
    }
    float v = s / fmaxf((float)cnt, 1.0f);
    g[b*DD + c] = v;
    gbf[b*DD + c] = f2bf(v);
}

// ---------------------------------------------------------------------------
// All weight transpose-casts in ONE kernel (compile-time job table).
// ---------------------------------------------------------------------------
__global__ __launch_bounds__(256)
void prep_all_k(const float* __restrict__ emb_w1, const float* __restrict__ emb_w2,
                const float* __restrict__ conv_w, const float* __restrict__ fc2_w,
                const float* __restrict__ f1_w,   const float* __restrict__ f2_w,
                const float* __restrict__ fc1_w,  const float* __restrict__ ow1,
                const float* __restrict__ ow2,
                unsigned short* __restrict__ emb_w1t, unsigned short* __restrict__ emb_w2t,
                unsigned short* __restrict__ conv_wt, unsigned short* __restrict__ fc2_wt,
                unsigned short* __restrict__ ffn1_wt, unsigned short* __restrict__ ffn2_wt,
                unsigned short* __restrict__ fc1_wthi, unsigned short* __restrict__ fc1_wtlo,
                unsigned short* __restrict__ ow1t, unsigned short* __restrict__ ow2t)
{
    __shared__ float tile[32][33];
    const int tx = threadIdx.x & 31, ty = threadIdx.x >> 5;

    int bid = blockIdx.x;
    const float* src = nullptr; unsigned short* dst = nullptr; unsigned short* dlo = nullptr;
    int K = 0, N = 0;
    do {
        if (bid < 16)  { src = emb_w1; dst = emb_w1t; K = 64;  N = 256; break; }  bid -= 16;
        if (bid < 32)  { src = emb_w2; dst = emb_w2t; K = 256; N = 128; break; }  bid -= 32;
        if (bid < 64)  { int l = bid >> 5; bid &= 31;
                         src = conv_w + (size_t)l*256*128; dst = conv_wt + (size_t)l*128*256;
                         K = 256; N = 128; break; }                               bid -= 64;
        if (bid < 32)  { int l = bid >> 4; bid &= 15;
                         src = fc2_w + (size_t)l*128*128; dst = fc2_wt + (size_t)l*128*128;
                         K = 128; N = 128; break; }                               bid -= 32;
        if (bid < 128) { int l = bid >> 6; bid &= 63;
                         src = f1_w + (size_t)l*128*512; dst = ffn1_wt + (size_t)l*512*128;
                         K = 128; N = 512; break; }                               bid -= 128;
        if (bid < 128) { int l = bid >> 6; bid &= 63;
                         src = f2_w + (size_t)l*512*128; dst = ffn2_wt + (size_t)l*128*512;
                         K = 512; N = 128; break; }                               bid -= 128;
        if (bid < 32)  { int l = bid >> 4; bid &= 15;
                         src = fc1_w + (size_t)l*128*128;
                         dst = fc1_wthi + (size_t)l*128*128; dlo = fc1_wtlo + (size_t)l*128*128;
                         K = 128; N = 128; break; }                               bid -= 32;
        if (bid < 64)  { src = ow1; dst = ow1t; K = 128; N = 512; break; }        bid -= 64;
        { src = ow2; dst = ow2t; K = 512; N = 2048; }
    } while (0);

    const int nbx = N / 32;
    const int bx = bid % nbx, by = bid / nbx;
    const int k0 = by*32, n0 = bx*32;

    #pragma unroll
    for (int i = ty; i < 32; i += 8)
        tile[i][tx] = src[(size_t)(k0+i)*N + n0+tx];
    __syncthreads();
    #pragma unroll
    for (int i = ty; i < 32; i += 8) {
        float v = tile[tx][i];
        unsigned short h = f2bf(v);
        dst[(size_t)(n0+i)*K + k0+tx] = h;
        if (dlo) dlo[(size_t)(n0+i)*K + k0+tx] = f2bf(v - bf2f(h));
    }
}

// ---------------------------------------------------------------------------
extern "C" void kernel_launch(void* const* d_in, const int* in_sizes, int n_in,
                              void* d_out, int out_size, void* d_ws, size_t ws_size,
                              hipStream_t stream)
{
    const float* nodes  = (const float*)d_in[0];
    const int*   maskp  = (const int*)  d_in[1];
    const float* emb_w1 = (const float*)d_in[2];
    const float* emb_b1 = (const float*)d_in[3];
    const float* ln1_g  = (const float*)d_in[4];
    const float* ln1_b  = (const float*)d_in[5];
    const float* emb_w2 = (const float*)d_in[6];
    const float* emb_b2 = (const float*)d_in[7];
    const float* ln2_g  = (const float*)d_in[8];
    const float* ln2_b  = (const float*)d_in[9];
    const float* fc1_w  = (const float*)d_in[10];
    const float* fc1_b  = (const float*)d_in[11];
    const float* conv_w = (const float*)d_in[12];
    const float* conv_b = (const float*)d_in[13];
    const float* fc2_w  = (const float*)d_in[14];
    const float* fc2_b  = (const float*)d_in[15];
    const float* f1_w   = (const float*)d_in[16];
    const float* f1_b   = (const float*)d_in[17];
    const float* f2_w   = (const float*)d_in[18];
    const float* f2_b   = (const float*)d_in[19];
    const float* ow1    = (const float*)d_in[20];
    const float* ob1    = (const float*)d_in[21];
    const float* ow2    = (const float*)d_in[22];
    const float* ob2    = (const float*)d_in[23];
    float* out = (float*)d_out;

    // ---- workspace layout ----
    char* base = (char*)d_ws;
    float* x   = (float*)base;                          // 33.55 MB
    char*  H   = base + (size_t)BNROWS*DD*4;            // 33.55 MB (x_hi/x_lo <-> h_hi/h_lo)
    char*  BIG = H + (size_t)BNROWS*DD*4;               // 67.11 MB (t256 / cat / ffn hidden)
    float*          x2    = (float*)(BIG + (size_t)BNROWS*2*DD*4);
    float*          g     = (float*)(x2 + BNROWS);
    unsigned short* g_bf  = (unsigned short*)(g + BB*DD);
    unsigned short* hid2_bf = g_bf + BB*DD;
    unsigned short* wbuf  = hid2_bf + BB*FFND;

    unsigned short* x_hi   = (unsigned short*)H;
    unsigned short* x_lo   = x_hi + (size_t)BNROWS*DD;
    unsigned short* t256_bf= (unsigned short*)BIG;
    unsigned short* cat_bf = (unsigned short*)(BIG);    // reused regions
    unsigned short* hid_bf = (unsigned short*)BIG;

    unsigned short* emb_w1t  = wbuf;
    unsigned short* emb_w2t  = emb_w1t + 256*64;
    unsigned short* conv_wt  = emb_w2t + 128*256;
    unsigned short* fc2_wt   = conv_wt + 2*128*256;
    unsigned short* ffn1_wt  = fc2_wt  + 2*128*128;
    unsigned short* ffn2_wt  = ffn1_wt + 2*512*128;
    unsigned short* fc1_wthi = ffn2_wt + 2*128*512;
    unsigned short* fc1_wtlo = fc1_wthi + 2*128*128;
    unsigned short* ow1t     = fc1_wtlo + 2*128*128;
    unsigned short* ow2t     = ow1t + 512*128;

    const dim3 blk(256);

    // ---- all weight transpose-casts (one launch) ----
    prep_all_k<<<1520, blk, 0, stream>>>(
        emb_w1, emb_w2, conv_w, fc2_w, f1_w, f2_w, fc1_w, ow1, ow2,
        emb_w1t, emb_w2t, conv_wt, fc2_wt, ffn1_wt, ffn2_wt,
        fc1_wthi, fc1_wtlo, ow1t, ow2t);

    // ---- Embedding (GEMM + fused LN) ----
    bgemm_ln_k<2,4,true,false,1,true>
        <<<dim3(BNROWS/128), dim3(512), 0, stream>>>
        (nodes, emb_w1t, emb_b1, ln1_g, ln1_b, nullptr, t256_bf, nullptr, nullptr, PP2);
    bgemm_ln_k<2,2,false,true,2,false>
        <<<dim3(BNROWS/128), dim3(256), 0, stream>>>
        (t256_bf, emb_w2t, emb_b2, ln2_g, ln2_b, maskp, x, x_hi, x_lo, 2*DD);

    // ---- ViG blocks ----
    for (int l = 0; l < LLAY; ++l) {
        const float* fc1b = fc1_b + (size_t)l*DD;
        const float* cb   = conv_b + (size_t)l*DD;
        const float* fc2b = fc2_b + (size_t)l*DD;
        const float* b1   = f1_b + (size_t)l*FFND;
        const float* b2   = f2_b + (size_t)l*DD;

        fc1mm_k<<<dim3(BNROWS/128), blk, 0, stream>>>
            (x_hi, x_lo, fc1_wthi + (size_t)l*DD*DD, fc1_wtlo + (size_t)l*DD*DD,
             fc1b, x_hi, x_lo, x2);
        dist_topk_gather_k<<<dim3(BB), dim3(1024), 0, stream>>>
            (x_hi, x_lo, maskp, x2, cat_bf);
        conv_fc2_k<<<dim3(BNROWS/64), blk, 0, stream>>>
            (cat_bf, conv_wt + (size_t)l*DD*2*DD, cb,
             fc2_wt + (size_t)l*DD*DD, fc2b, x, x_hi);
        bgemm_k<ACT_LRELU,false,false,false,true,false>
            <<<dim3(BNROWS/128, FFND/128), blk, 0, stream>>>
            (x_hi, ffn1_wt + (size_t)l*FFND*DD, b1,
             nullptr, nullptr, nullptr, hid_bf, nullptr, nullptr, BNROWS, FFND, DD);
        bgemm_k<ACT_NONE,true,true,true,false,true>
            <<<dim3(BNROWS/128, 1), blk, 0, stream>>>
            (hid_bf, ffn2_wt + (size_t)l*DD*FFND, b2,
             x, maskp, x, nullptr, x_hi, x_lo, BNROWS, DD, FFND);
    }

    // ---- Pool + head (bf16 MFMA) ----
    pool_k<<<BB, 128, 0, stream>>>(x, maskp, g, g_bf);
    bgemm_k<ACT_LRELU,false,false,false,true,false>
        <<<dim3(BB/128, 512/128), blk, 0, stream>>>
        (g_bf, ow1t, ob1, nullptr, nullptr, nullptr, hid2_bf, nullptr, nullptr, BB, 512, DD);
    bgemm_k<ACT_NONE,false,false,true,false,false>
        <<<dim3(BB/128, 2048/128), blk, 0, stream>>>
        (hid2_bf, ow2t, ob2, nullptr, nullptr, out, nullptr, nullptr, nullptr, BB, 2048, 512);
}

// Round 14
// 354.226 us; speedup vs baseline: 1.2036x; 1.0205x over previous
//
#include <hip/hip_runtime.h>
#include <cstdint>

#define BB    256
#define NNODE 256
#define PP2   64
#define DD    128
#define LLAY  2
#define KNN   9
#define FFND  512
#define BNROWS (BB*NNODE)   // 65536

#define LRELU_(v) ((v) >= 0.f ? (v) : 0.01f*(v))

enum { ACT_NONE = 0, ACT_LRELU = 1 };

typedef short  short8_t  __attribute__((ext_vector_type(8)));
typedef float  f32x4     __attribute__((ext_vector_type(4)));
typedef unsigned short us4 __attribute__((ext_vector_type(4)));

__device__ inline unsigned short f2bf(float x) {
    unsigned u = __float_as_uint(x);
    unsigned r = (u + 0x7FFFu + ((u >> 16) & 1u)) >> 16;
    return (unsigned short)r;
}
__device__ inline float bf2f(unsigned short h) {
    return __uint_as_float(((unsigned)h) << 16);
}

// async global->LDS, 16B per lane; LDS dest must be wave-uniform base.
__device__ inline void gload16(const void* src, void* dst) {
    __builtin_amdgcn_global_load_lds(
        (const __attribute__((address_space(1))) void*)src,
        (__attribute__((address_space(3))) void*)dst, 16, 0, 0);
}

// Stage a BK=64 bf16 tile (ROWS x 64 elems, 128B rows) from row-major global
// (element stride Kel, starting col k0) into LINEAR LDS via global_load_lds.
// Source address carries the inverse XOR swizzle; reads apply the same XOR.
template<int ROWS, int WAVES>
__device__ inline void stage64g(const unsigned short* __restrict__ g, size_t rowbase,
                                int Kel, int k0, unsigned short* lds, int w, int lane)
{
    constexpr int PER = (ROWS*128/1024) / WAVES;
    #pragma unroll
    for (int i = 0; i < PER; ++i) {
        const int inst = w + i*WAVES;                 // wave-uniform
        const unsigned o  = (unsigned)inst*1024u + (unsigned)lane*16u;
        const int      r  = (int)(o >> 7);
        const unsigned cb = o & 127u;
        const unsigned cs = cb ^ ((unsigned)(r & 7) << 4);
        gload16((const char*)(g + (rowbase + (size_t)r)*(size_t)Kel + k0) + cs,
                (char*)lds + (size_t)inst*1024u);
    }
}

// swizzled fragment read from a linear BK=64 tile
__device__ inline short8_t frag64(const unsigned short* lds, int r, int cb) {
    return *reinterpret_cast<const short8_t*>(
        (const char*)lds + (size_t)r*128 + (unsigned)(cb ^ ((r & 7) << 4)));
}

// swizzled 8B (4 cols) read from a BK=64 tile at column-byte cb (mult of 8)
__device__ inline us4 read4sw(const unsigned short* lds, int r, unsigned cb) {
    return *reinterpret_cast<const us4*>(
        (const char*)lds + (size_t)r*128 + (cb ^ ((unsigned)(r & 7) << 4)));
}

// 16-lane-group min (per DPP row); result in ALL lanes of each 16-group.
__device__ inline unsigned grp16_min_u32(unsigned v) {
    unsigned t;
    t = (unsigned)__builtin_amdgcn_update_dpp(-1, (int)v, 0xB1,  0xF, 0xF, false); v = t < v ? t : v; // quad_perm [1,0,3,2]
    t = (unsigned)__builtin_amdgcn_update_dpp(-1, (int)v, 0x4E,  0xF, 0xF, false); v = t < v ? t : v; // quad_perm [2,3,0,1]
    t = (unsigned)__builtin_amdgcn_update_dpp(-1, (int)v, 0x124, 0xF, 0xF, false); v = t < v ? t : v; // row_ror:4
    t = (unsigned)__builtin_amdgcn_update_dpp(-1, (int)v, 0x128, 0xF, 0xF, false); v = t < v ? t : v; // row_ror:8
    return v;
}

// 16-lane (DPP row) sum; result valid in lane 15 of each 16-lane row.
__device__ inline float dpp_rowsum16(float v) {
    float t;
    t = __uint_as_float((unsigned)__builtin_amdgcn_update_dpp(0, (int)__float_as_uint(v), 0x111, 0xF, 0xF, false)); v += t;
    t = __uint_as_float((unsigned)__builtin_amdgcn_update_dpp(0, (int)__float_as_uint(v), 0x112, 0xF, 0xF, false)); v += t;
    t = __uint_as_float((unsigned)__builtin_amdgcn_update_dpp(0, (int)__float_as_uint(v), 0x114, 0xF, 0xF, false)); v += t;
    t = __uint_as_float((unsigned)__builtin_amdgcn_update_dpp(0, (int)__float_as_uint(v), 0x118, 0xF, 0xF, false)); v += t;
    return v;
}

// ---------------------------------------------------------------------------
// bf16 MFMA GEMM, BK=64, global_load_lds staging.
// ---------------------------------------------------------------------------
template<int ACT, bool RES, bool MASK, bool OUTF, bool OUTB, bool OUTS>
__global__ __launch_bounds__(256)
void bgemm_k(const unsigned short* __restrict__ A,
             const unsigned short* __restrict__ W,
             const float* __restrict__ bias,
             const float* __restrict__ resp,
             const int* __restrict__ mask,
             float* __restrict__ Cf, unsigned short* __restrict__ Cb,
             unsigned short* Ohi, unsigned short* Olo,
             int M, int N, int K)
{
    __shared__ __align__(16) unsigned short As[128*64];
    __shared__ __align__(16) unsigned short Bs[128*64];

    const int tid  = threadIdx.x;
    const int lane = tid & 63;
    const int w    = tid >> 6;
    const int wr   = w >> 1, wc = w & 1;
    const int row0 = blockIdx.x * 128;
    const int col0 = blockIdx.y * 128;
    const int l15  = lane & 15;
    const int ko   = lane >> 4;

    f32x4 acc[4][4];
    #pragma unroll
    for (int m = 0; m < 4; ++m)
        #pragma unroll
        for (int n = 0; n < 4; ++n) acc[m][n] = (f32x4){0.f,0.f,0.f,0.f};

    for (int k0 = 0; k0 < K; k0 += 64) {
        stage64g<128,4>(A, (size_t)row0, K, k0, As, w, lane);
        stage64g<128,4>(W, (size_t)col0, K, k0, Bs, w, lane);
        __syncthreads();
        #pragma unroll
        for (int ks = 0; ks < 2; ++ks) {
            short8_t aF[4], bF[4];
            #pragma unroll
            for (int m = 0; m < 4; ++m)
                aF[m] = frag64(As, wr*64 + m*16 + l15, ks*64 + ko*16);
            #pragma unroll
            for (int n = 0; n < 4; ++n)
                bF[n] = frag64(Bs, wc*64 + n*16 + l15, ks*64 + ko*16);
            #pragma unroll
            for (int m = 0; m < 4; ++m)
                #pragma unroll
                for (int n = 0; n < 4; ++n)
                    acc[m][n] = __builtin_amdgcn_mfma_f32_16x16x32_bf16(aF[m], bF[n], acc[m][n], 0, 0, 0);
        }
        __syncthreads();
    }

    #pragma unroll
    for (int m = 0; m < 4; ++m) {
        const int rbase = row0 + wr*64 + m*16 + ko*4;
        #pragma unroll
        for (int n = 0; n < 4; ++n) {
            const int col = col0 + wc*64 + n*16 + l15;
            const float bv = bias[col];
            #pragma unroll
            for (int r = 0; r < 4; ++r) {
                const int row = rbase + r;
                float v = acc[m][n][r] + bv;
                if constexpr (ACT == ACT_LRELU) v = LRELU_(v);
                if constexpr (RES)  v += resp[(size_t)row*N + col];
                if constexpr (MASK) v *= (mask[row] != 0) ? 1.f : 0.f;
                if constexpr (OUTF) Cf[(size_t)row*N + col] = v;
                if constexpr (OUTB) Cb[(size_t)row*N + col] = f2bf(v);
                if constexpr (OUTS) {
                    unsigned short h = f2bf(v);
                    Ohi[(size_t)row*N + col] = h;
                    Olo[(size_t)row*N + col] = f2bf(v - bf2f(h));
                }
            }
        }
    }
}

// ---------------------------------------------------------------------------
// bf16 MFMA GEMM fused with full-row LayerNorm epilogue (BK=64).
// AF32: A fp32, cast during (reg) staging into the same linear-swz layout.
// ---------------------------------------------------------------------------
template<int WR, int WC, bool DO_LRELU, bool MASKMUL, int MODE, bool AF32>
__global__ __launch_bounds__(WR*WC*64)
void bgemm_ln_k(const void* __restrict__ Ap,
                const unsigned short* __restrict__ W,
                const float* __restrict__ bias,
                const float* __restrict__ gam,
                const float* __restrict__ bet,
                const int* __restrict__ mask,
                void* __restrict__ outv,
                unsigned short* __restrict__ ohi, unsigned short* __restrict__ olo,
                int K)
{
    constexpr int BM = WR*64;
    constexpr int BN = WC*64;
    constexpr int THREADS = WR*WC*64;
    constexpr int WAVES = THREADS/64;
    __shared__ __align__(16) unsigned short As[BM*64];
    __shared__ __align__(16) unsigned short Bs[BN*64];
    __shared__ float red_s[WC][BM];
    __shared__ float red_q[WC][BM];
    __shared__ float mu_l[BM];
    __shared__ float rs_l[BM];

    const int tid  = threadIdx.x;
    const int lane = tid & 63;
    const int w    = tid >> 6;
    const int wr   = w / WC, wc = w % WC;
    const int row0 = blockIdx.x * BM;
    const int l15  = lane & 15;
    const int ko   = lane >> 4;

    f32x4 acc[4][4];
    #pragma unroll
    for (int m = 0; m < 4; ++m)
        #pragma unroll
        for (int n = 0; n < 4; ++n) acc[m][n] = (f32x4){0.f,0.f,0.f,0.f};

    for (int k0 = 0; k0 < K; k0 += 64) {
        if constexpr (AF32) {
            const float* Af = (const float*)Ap;
            constexpr int CH = (BM*8)/THREADS;    // 16B chunks per thread
            #pragma unroll
            for (int i = 0; i < CH; ++i) {
                const int q = i*THREADS + tid;
                const unsigned o  = (unsigned)q*16u;
                const int      r  = (int)(o >> 7);
                const unsigned cb = o & 127u;
                const unsigned cs = cb ^ ((unsigned)(r & 7) << 4);
                const float* src = Af + (size_t)(row0 + r)*K + k0 + (cs >> 1);
                const float4 f0 = *reinterpret_cast<const float4*>(src);
                const float4 f1 = *reinterpret_cast<const float4*>(src + 4);
                short8_t v;
                v[0]=(short)f2bf(f0.x); v[1]=(short)f2bf(f0.y); v[2]=(short)f2bf(f0.z); v[3]=(short)f2bf(f0.w);
                v[4]=(short)f2bf(f1.x); v[5]=(short)f2bf(f1.y); v[6]=(short)f2bf(f1.z); v[7]=(short)f2bf(f1.w);
                *reinterpret_cast<short8_t*>((char*)As + o) = v;
            }
        } else {
            stage64g<BM,WAVES>((const unsigned short*)Ap, (size_t)row0, K, k0, As, w, lane);
        }
        stage64g<BN,WAVES>(W, 0, K, k0, Bs, w, lane);
        __syncthreads();
        #pragma unroll
        for (int ks = 0; ks < 2; ++ks) {
            short8_t aF[4], bF[4];
            #pragma unroll
            for (int m = 0; m < 4; ++m)
                aF[m] = frag64(As, wr*64 + m*16 + l15, ks*64 + ko*16);
            #pragma unroll
            for (int n = 0; n < 4; ++n)
                bF[n] = frag64(Bs, wc*64 + n*16 + l15, ks*64 + ko*16);
            #pragma unroll
            for (int m = 0; m < 4; ++m)
                #pragma unroll
                for (int n = 0; n < 4; ++n)
                    acc[m][n] = __builtin_amdgcn_mfma_f32_16x16x32_bf16(aF[m], bF[n], acc[m][n], 0, 0, 0);
        }
        __syncthreads();
    }

    float bv[4];
    #pragma unroll
    for (int n = 0; n < 4; ++n) bv[n] = bias[wc*64 + n*16 + l15];
    #pragma unroll
    for (int m = 0; m < 4; ++m)
        #pragma unroll
        for (int n = 0; n < 4; ++n)
            #pragma unroll
            for (int r = 0; r < 4; ++r) acc[m][n][r] += bv[n];

    #pragma unroll
    for (int m = 0; m < 4; ++m) {
        #pragma unroll
        for (int r = 0; r < 4; ++r) {
            float s = acc[m][0][r] + acc[m][1][r] + acc[m][2][r] + acc[m][3][r];
            float q = acc[m][0][r]*acc[m][0][r] + acc[m][1][r]*acc[m][1][r]
                    + acc[m][2][r]*acc[m][2][r] + acc[m][3][r]*acc[m][3][r];
            s = dpp_rowsum16(s);
            q = dpp_rowsum16(q);
            if (l15 == 15) {
                int rl = wr*64 + m*16 + ko*4 + r;
                red_s[wc][rl] = s;
                red_q[wc][rl] = q;
            }
        }
    }
    __syncthreads();
    if (tid < BM) {
        float s = 0.f, q = 0.f;
        #pragma unroll
        for (int c2 = 0; c2 < WC; ++c2) { s += red_s[c2][tid]; q += red_q[c2][tid]; }
        float mu  = s * (1.0f/BN);
        float var = q * (1.0f/BN) - mu*mu;
        mu_l[tid] = mu;
        rs_l[tid] = rsqrtf(fmaxf(var, 0.f) + 1e-5f);
    }
    __syncthreads();

    float gm[4], bt[4];
    #pragma unroll
    for (int n = 0; n < 4; ++n) {
        int col = wc*64 + n*16 + l15;
        gm[n] = gam[col]; bt[n] = bet[col];
    }
    #pragma unroll
    for (int m = 0; m < 4; ++m) {
        #pragma unroll
        for (int r = 0; r < 4; ++r) {
            const int rl  = wr*64 + m*16 + ko*4 + r;
            const int row = row0 + rl;
            const float mu = mu_l[rl], rs = rs_l[rl];
            float mf = 1.f;
            if constexpr (MASKMUL) mf = (mask[row] != 0) ? 1.f : 0.f;
            #pragma unroll
            for (int n = 0; n < 4; ++n) {
                const int col = wc*64 + n*16 + l15;
                float y = (acc[m][n][r] - mu) * rs * gm[n] + bt[n];
                if constexpr (DO_LRELU) y = LRELU_(y);
                if constexpr (MASKMUL)  y *= mf;
                if constexpr (MODE == 1) {
                    ((unsigned short*)outv)[(size_t)row*BN + col] = f2bf(y);
                } else {
                    ((float*)outv)[(size_t)row*BN + col] = y;
                    unsigned short h = f2bf(y);
                    ohi[(size_t)row*BN + col] = h;
                    olo[(size_t)row*BN + col] = f2bf(y - bf2f(h));
                }
            }
        }
    }
}

// ---------------------------------------------------------------------------
// fc1 split-bf16 MFMA GEMM, 3 phases, BK=64, in-place OK, fused rowsq(x2).
// ---------------------------------------------------------------------------
__global__ __launch_bounds__(256)
void fc1mm_k(const unsigned short* Ahi, const unsigned short* Alo,
             const unsigned short* __restrict__ Bhi, const unsigned short* __restrict__ Blo,
             const float* __restrict__ bias,
             unsigned short* Ohi, unsigned short* Olo,
             float* __restrict__ x2out)
{
    __shared__ __align__(16) unsigned short As[128*64];
    __shared__ __align__(16) unsigned short Bs[128*64];
    __shared__ float red_q[2][128];

    const int tid  = threadIdx.x;
    const int lane = tid & 63;
    const int w    = tid >> 6;
    const int wr   = w >> 1, wc = w & 1;
    const int row0 = blockIdx.x * 128;
    const int l15  = lane & 15;
    const int ko   = lane >> 4;

    f32x4 acc[4][4];
    #pragma unroll
    for (int m = 0; m < 4; ++m)
        #pragma unroll
        for (int n = 0; n < 4; ++n) acc[m][n] = (f32x4){0.f,0.f,0.f,0.f};

    for (int kk = 0; kk < 384; kk += 64) {
        const int p  = kk >> 7;        // 0,0,1,1,2,2
        const int kl = kk & 127;
        const unsigned short* Ap2 = (p == 1) ? Alo : Ahi;
        const unsigned short* Bp2 = (p == 2) ? Blo : Bhi;
        stage64g<128,4>(Ap2, (size_t)row0, DD, kl, As, w, lane);
        stage64g<128,4>(Bp2, 0, DD, kl, Bs, w, lane);
        __syncthreads();
        #pragma unroll
        for (int ks = 0; ks < 2; ++ks) {
            short8_t aF[4], bF[4];
            #pragma unroll
            for (int m = 0; m < 4; ++m)
                aF[m] = frag64(As, wr*64 + m*16 + l15, ks*64 + ko*16);
            #pragma unroll
            for (int n = 0; n < 4; ++n)
                bF[n] = frag64(Bs, wc*64 + n*16 + l15, ks*64 + ko*16);
            #pragma unroll
            for (int m = 0; m < 4; ++m)
                #pragma unroll
                for (int n = 0; n < 4; ++n)
                    acc[m][n] = __builtin_amdgcn_mfma_f32_16x16x32_bf16(aF[m], bF[n], acc[m][n], 0, 0, 0);
        }
        __syncthreads();
    }

    float qacc[4][4];
    #pragma unroll
    for (int m = 0; m < 4; ++m) {
        const int rbase = row0 + wr*64 + m*16 + ko*4;
        #pragma unroll
        for (int r = 0; r < 4; ++r) qacc[m][r] = 0.f;
        #pragma unroll
        for (int n = 0; n < 4; ++n) {
            const int col = wc*64 + n*16 + l15;
            const float bv = bias[col];
            #pragma unroll
            for (int r = 0; r < 4; ++r) {
                const int row = rbase + r;
                float v = acc[m][n][r] + bv;
                unsigned short h = f2bf(v);
                unsigned short l = f2bf(v - bf2f(h));
                Ohi[(size_t)row*DD + col] = h;
                Olo[(size_t)row*DD + col] = l;
                float vv = bf2f(h) + bf2f(l);
                qacc[m][r] += vv*vv;
            }
        }
    }
    #pragma unroll
    for (int m = 0; m < 4; ++m)
        #pragma unroll
        for (int r = 0; r < 4; ++r) {
            float q = dpp_rowsum16(qacc[m][r]);
            if (l15 == 15) red_q[wc][wr*64 + m*16 + ko*4 + r] = q;
        }
    __syncthreads();
    if (tid < 128) x2out[row0 + tid] = red_q[0][tid] + red_q[1][tid];
}

// ---------------------------------------------------------------------------
// Fused distance + top-9 + gather: ONE block per batch (1024 thr, 16 waves).
// Full batch h resident in LDS. After the stage barrier, each wave runs
// MFMA -> top-9 -> gather for ITS OWN 16 rows with no further barriers
// (idx_s written and read by the same wave; same-wave DS ops are in-order),
// so VALU-heavy top-k overlaps other waves' LDS/HBM gather traffic.
// ---------------------------------------------------------------------------
__global__ __launch_bounds__(1024)
void dist_topk_gather_k(const unsigned short* __restrict__ hhi,
                        const unsigned short* __restrict__ hlo,
                        const int* __restrict__ mask,
                        const float* __restrict__ x2,
                        unsigned short* __restrict__ cat)
{
    __shared__ __align__(16) unsigned short BsH[2][NNODE*64];   // 64KB
    __shared__ __align__(16) unsigned short BsL[2][NNODE*64];   // 64KB
    __shared__ unsigned char idx_s[NNODE*KNN];
    __shared__ unsigned char msk_s[NNODE];

    const int b    = blockIdx.x;
    const int tid  = threadIdx.x;
    const int lane = tid & 63;
    const int w    = tid >> 6;          // 0..15
    const int l15  = lane & 15;
    const int g    = lane >> 4;         // 0..3

    const unsigned short* Hhi = hhi + (size_t)b*NNODE*DD;
    const unsigned short* Hlo = hlo + (size_t)b*NNODE*DD;
    const float* x2b = x2 + b*NNODE;
    const int*   mkb = mask + b*NNODE;

    // stage both k-tiles of hi and lo once (full batch h resident)
    stage64g<NNODE,16>(Hhi, 0, DD, 0,  &BsH[0][0], w, lane);
    stage64g<NNODE,16>(Hhi, 0, DD, 64, &BsH[1][0], w, lane);
    stage64g<NNODE,16>(Hlo, 0, DD, 0,  &BsL[0][0], w, lane);
    stage64g<NNODE,16>(Hlo, 0, DD, 64, &BsL[1][0], w, lane);
    if (tid < NNODE) msk_s[tid] = (mkb[tid] != 0) ? 1 : 0;
    __syncthreads();

    const int arow = w*16 + l15;        // 0..255

    f32x4 acc[16];
    #pragma unroll
    for (int n = 0; n < 16; ++n) acc[n] = (f32x4){0.f,0.f,0.f,0.f};

    #pragma unroll
    for (int kt = 0; kt < 2; ++kt) {
        #pragma unroll
        for (int ks = 0; ks < 2; ++ks) {
            short8_t aH = frag64(&BsH[kt][0], arow, ks*64 + g*16);
            short8_t aL = frag64(&BsL[kt][0], arow, ks*64 + g*16);
            #pragma unroll
            for (int n = 0; n < 16; ++n) {
                int brow = n*16 + l15;
                short8_t bH = frag64(&BsH[kt][0], brow, ks*64 + g*16);
                short8_t bL = frag64(&BsL[kt][0], brow, ks*64 + g*16);
                acc[n] = __builtin_amdgcn_mfma_f32_16x16x32_bf16(aH, bH, acc[n], 0, 0, 0); // hi.hi
                acc[n] = __builtin_amdgcn_mfma_f32_16x16x32_bf16(aL, bH, acc[n], 0, 0, 0); // lo.hi
                acc[n] = __builtin_amdgcn_mfma_f32_16x16x32_bf16(aH, bL, acc[n], 0, 0, 0); // hi.lo
            }
        }
    }

    float x2c[16]; unsigned mk[16];
    #pragma unroll
    for (int n = 0; n < 16; ++n) {
        int col = n*16 + l15;
        x2c[n] = x2b[col];
        mk[n]  = (unsigned)msk_s[col];
    }

    #pragma unroll
    for (int r = 0; r < 4; ++r) {
        const int lrow = w*16 + g*4 + r;          // this wave's rows only
        const float x2r = x2b[lrow];
        unsigned key[16];
        #pragma unroll
        for (int n = 0; n < 16; ++n) {
            float v = x2r + x2c[n] - 2.0f*acc[n][r];
            if (!mk[n]) v = 1e10f;
            unsigned u = __float_as_uint(v);
            u = (u & 0x80000000u) ? ~u : (u | 0x80000000u);
            key[n] = (u & 0xFFFFFF00u) | (unsigned)(n*16 + l15);
        }
        for (int it = 0; it < KNN; ++it) {
            unsigned a0 = key[0]  < key[1]  ? key[0]  : key[1];
            unsigned a1 = key[2]  < key[3]  ? key[2]  : key[3];
            unsigned a2 = key[4]  < key[5]  ? key[4]  : key[5];
            unsigned a3 = key[6]  < key[7]  ? key[6]  : key[7];
            unsigned a4 = key[8]  < key[9]  ? key[8]  : key[9];
            unsigned a5 = key[10] < key[11] ? key[10] : key[11];
            unsigned a6 = key[12] < key[13] ? key[12] : key[13];
            unsigned a7 = key[14] < key[15] ? key[14] : key[15];
            unsigned b0 = a0 < a1 ? a0 : a1;
            unsigned b1 = a2 < a3 ? a2 : a3;
            unsigned b2 = a4 < a5 ? a4 : a5;
            unsigned b3 = a6 < a7 ? a6 : a7;
            unsigned c0 = b0 < b1 ? b0 : b1;
            unsigned c1 = b2 < b3 ? b2 : b3;
            unsigned lmin = c0 < c1 ? c0 : c1;
            unsigned gmin = grp16_min_u32(lmin);
            if (l15 == 0) idx_s[lrow*KNN + it] = (unsigned char)(gmin & 0xFFu);
            #pragma unroll
            for (int n = 0; n < 16; ++n)
                if (key[n] == gmin) key[n] = 0xFFFFFFFFu;
        }
    }
    // NO block barrier: gather below touches only this wave's rows, whose
    // idx_s entries were written by this wave (same-wave DS ops in order).

    // ---- gather + max-relative from LDS-resident h (per-wave rows) ----
    const int rl = w*16 + (lane >> 2);             // this wave's row
    const int cbase = (lane & 3) * 4;
    #pragma unroll 2
    for (int pass = 0; pass < 8; ++pass) {
        const int c4 = cbase + pass*16;            // col 0..124
        const int kt = c4 >> 6;
        const unsigned cb = (unsigned)((c4 & 63) * 2);
        us4 h4 = read4sw(&BsH[kt][0], rl, cb);
        us4 l4 = read4sw(&BsL[kt][0], rl, cb);
        float hi[4], m[4];
        #pragma unroll
        for (int d = 0; d < 4; ++d) { hi[d] = bf2f(h4[d]) + bf2f(l4[d]); m[d] = -1e9f; }
        bool any = false;
        #pragma unroll
        for (int q = 0; q < KNN; ++q) {
            int j = idx_s[rl*KNN + q];
            if (msk_s[j]) {
                any = true;
                us4 a = read4sw(&BsH[kt][0], j, cb);
                us4 o = read4sw(&BsL[kt][0], j, cb);
                #pragma unroll
                for (int d = 0; d < 4; ++d)
                    m[d] = fmaxf(m[d], bf2f(a[d]) + bf2f(o[d]) - hi[d]);
            }
        }
        us4 o1, o2;
        #pragma unroll
        for (int d = 0; d < 4; ++d) {
            o1[d] = f2bf(hi[d]);
            o2[d] = any ? f2bf(m[d]) : (unsigned short)0;
        }
        const size_t rowbase = (size_t)(b*NNODE + rl)*(2*DD);
        *reinterpret_cast<us4*>(&cat[rowbase + c4])      = o1;
        *reinterpret_cast<us4*>(&cat[rowbase + DD + c4]) = o2;
    }
}

// ---------------------------------------------------------------------------
// Fused conv + fc2, occupancy-optimized: BM=64 (1024 blocks), 40KB LDS.
// x += (lrelu(cat@Wc^T + cb)) @ W2^T + fb;  xhi = bf16(x)
// ---------------------------------------------------------------------------
__global__ __launch_bounds__(256)
void conv_fc2_k(const unsigned short* __restrict__ cat,
                const unsigned short* __restrict__ Wc,
                const float* __restrict__ cb,
                const unsigned short* __restrict__ W2,
                const float* __restrict__ fb,
                float* __restrict__ x,
                unsigned short* __restrict__ xhi)
{
    __shared__ __align__(16) unsigned short As[64*64];       // 8KB
    __shared__ __align__(16) unsigned short Bs[128*64];      // 16KB
    __shared__ __align__(16) unsigned short h2s[2][64*64];   // 2x8KB (k-halves)

    const int tid  = threadIdx.x;
    const int lane = tid & 63;
    const int w    = tid >> 6;      // 0..3: wave col group (cols w*32..w*32+31)
    const int row0 = blockIdx.x * 64;
    const int l15  = lane & 15;
    const int ko   = lane >> 4;

    f32x4 acc[4][2];
    #pragma unroll
    for (int m = 0; m < 4; ++m)
        #pragma unroll
        for (int n = 0; n < 2; ++n) acc[m][n] = (f32x4){0.f,0.f,0.f,0.f};

    for (int k0 = 0; k0 < 256; k0 += 64) {
        stage64g<64,4>(cat, (size_t)row0, 256, k0, As, w, lane);
        stage64g<128,4>(Wc, 0, 256, k0, Bs, w, lane);
        __syncthreads();
        #pragma unroll
        for (int ks = 0; ks < 2; ++ks) {
            short8_t aF[4], bF[2];
            #pragma unroll
            for (int m = 0; m < 4; ++m)
                aF[m] = frag64(As, m*16 + l15, ks*64 + ko*16);
            #pragma unroll
            for (int n = 0; n < 2; ++n)
                bF[n] = frag64(Bs, w*32 + n*16 + l15, ks*64 + ko*16);
            #pragma unroll
            for (int m = 0; m < 4; ++m)
                #pragma unroll
                for (int n = 0; n < 2; ++n)
                    acc[m][n] = __builtin_amdgcn_mfma_f32_16x16x32_bf16(aF[m], bF[n], acc[m][n], 0, 0, 0);
        }
        __syncthreads();
    }

    {
        const int kt = w >> 1;
        #pragma unroll
        for (int n = 0; n < 2; ++n) {
            const int col = w*32 + n*16 + l15;
            const float bv = cb[col];
            const unsigned bc = (unsigned)(((w & 1)*32 + n*16 + l15) * 2);
            #pragma unroll
            for (int m = 0; m < 4; ++m) {
                #pragma unroll
                for (int r = 0; r < 4; ++r) {
                    const int row = m*16 + ko*4 + r;
                    float v = LRELU_(acc[m][n][r] + bv);
                    *(unsigned short*)((char*)&h2s[kt][0] + row*128
                        + (bc ^ ((unsigned)(row & 7) << 4))) = f2bf(v);
                }
            }
        }
    }

    f32x4 acc2[4][2];
    #pragma unroll
    for (int m = 0; m < 4; ++m)
        #pragma unroll
        for (int n = 0; n < 2; ++n) acc2[m][n] = (f32x4){0.f,0.f,0.f,0.f};

    #pragma unroll
    for (int kt = 0; kt < 2; ++kt) {
        stage64g<128,4>(W2, 0, 128, kt*64, Bs, w, lane);
        __syncthreads();
        #pragma unroll
        for (int ks = 0; ks < 2; ++ks) {
            short8_t aF[4], bF[2];
            #pragma unroll
            for (int m = 0; m < 4; ++m)
                aF[m] = frag64(&h2s[kt][0], m*16 + l15, ks*64 + ko*16);
            #pragma unroll
            for (int n = 0; n < 2; ++n)
                bF[n] = frag64(Bs, w*32 + n*16 + l15, ks*64 + ko*16);
            #pragma unroll
            for (int m = 0; m < 4; ++m)
                #pragma unroll
                for (int n = 0; n < 2; ++n)
                    acc2[m][n] = __builtin_amdgcn_mfma_f32_16x16x32_bf16(aF[m], bF[n], acc2[m][n], 0, 0, 0);
        }
        __syncthreads();
    }

    #pragma unroll
    for (int m = 0; m < 4; ++m) {
        const int rbase = row0 + m*16 + ko*4;
        #pragma unroll
        for (int n = 0; n < 2; ++n) {
            const int col = w*32 + n*16 + l15;
            const float bv = fb[col];
            #pragma unroll
            for (int r = 0; r < 4; ++r) {
                const int row = rbase + r;
                float v = acc2[m][n][r] + bv + x[(size_t)row*DD + col];
                x[(size_t)row*DD + col] = v;
                xhi[(size_t)row*DD + col] = f2bf(v);
            }
        }
    }
}

__global__ __launch_bounds__(128)
void pool_k(const float* __restrict__ x, const int* __restrict__ mask,
            float* __restrict__ g, unsigned short* __restrict__ gbf)
{
    const int b = blockIdx.x, c = threadIdx.x;
    float s = 0.f; int cnt = 0;
    for (int n = 0; n < NNODE; ++n) {
        s += x[((size_t)b*NNODE + n)*DD + c];
        cnt += (mask[b*NNODE + n] != 0) ? 1 : 0;
    }
    float v = s / fmaxf((float)cnt, 1.0f);
    g[b*DD + c] = v;
    gbf[b*DD + c] = f2bf(v);
}

// ---------------------------------------------------------------------------
// All weight transpose-casts in ONE kernel (compile-time job table).
// ---------------------------------------------------------------------------
__global__ __launch_bounds__(256)
void prep_all_k(const float* __restrict__ emb_w1, const float* __restrict__ emb_w2,
                const float* __restrict__ conv_w, const float* __restrict__ fc2_w,
                const float* __restrict__ f1_w,   const float* __restrict__ f2_w,
                const float* __restrict__ fc1_w,  const float* __restrict__ ow1,
                const float* __restrict__ ow2,
                unsigned short* __restrict__ emb_w1t, unsigned short* __restrict__ emb_w2t,
                unsigned short* __restrict__ conv_wt, unsigned short* __restrict__ fc2_wt,
                unsigned short* __restrict__ ffn1_wt, unsigned short* __restrict__ ffn2_wt,
                unsigned short* __restrict__ fc1_wthi, unsigned short* __restrict__ fc1_wtlo,
                unsigned short* __restrict__ ow1t, unsigned short* __restrict__ ow2t)
{
    __shared__ float tile[32][33];
    const int tx = threadIdx.x & 31, ty = threadIdx.x >> 5;

    int bid = blockIdx.x;
    const float* src = nullptr; unsigned short* dst = nullptr; unsigned short* dlo = nullptr;
    int K = 0, N = 0;
    do {
        if (bid < 16)  { src = emb_w1; dst = emb_w1t; K = 64;  N = 256; break; }  bid -= 16;
        if (bid < 32)  { src = emb_w2; dst = emb_w2t; K = 256; N = 128; break; }  bid -= 32;
        if (bid < 64)  { int l = bid >> 5; bid &= 31;
                         src = conv_w + (size_t)l*256*128; dst = conv_wt + (size_t)l*128*256;
                         K = 256; N = 128; break; }                               bid -= 64;
        if (bid < 32)  { int l = bid >> 4; bid &= 15;
                         src = fc2_w + (size_t)l*128*128; dst = fc2_wt + (size_t)l*128*128;
                         K = 128; N = 128; break; }                               bid -= 32;
        if (bid < 128) { int l = bid >> 6; bid &= 63;
                         src = f1_w + (size_t)l*128*512; dst = ffn1_wt + (size_t)l*512*128;
                         K = 128; N = 512; break; }                               bid -= 128;
        if (bid < 128) { int l = bid >> 6; bid &= 63;
                         src = f2_w + (size_t)l*512*128; dst = ffn2_wt + (size_t)l*128*512;
                         K = 512; N = 128; break; }                               bid -= 128;
        if (bid < 32)  { int l = bid >> 4; bid &= 15;
                         src = fc1_w + (size_t)l*128*128;
                         dst = fc1_wthi + (size_t)l*128*128; dlo = fc1_wtlo + (size_t)l*128*128;
                         K = 128; N = 128; break; }                               bid -= 32;
        if (bid < 64)  { src = ow1; dst = ow1t; K = 128; N = 512; break; }        bid -= 64;
        { src = ow2; dst = ow2t; K = 512; N = 2048; }
    } while (0);

    const int nbx = N / 32;
    const int bx = bid % nbx, by = bid / nbx;
    const int k0 = by*32, n0 = bx*32;

    #pragma unroll
    for (int i = ty; i < 32; i += 8)
        tile[i][tx] = src[(size_t)(k0+i)*N + n0+tx];
    __syncthreads();
    #pragma unroll
    for (int i = ty; i < 32; i += 8) {
        float v = tile[tx][i];
        unsigned short h = f2bf(v);
        dst[(size_t)(n0+i)*K + k0+tx] = h;
        if (dlo) dlo[(size_t)(n0+i)*K + k0+tx] = f2bf(v - bf2f(h));
    }
}

// ---------------------------------------------------------------------------
extern "C" void kernel_launch(void* const* d_in, const int* in_sizes, int n_in,
                              void* d_out, int out_size, void* d_ws, size_t ws_size,
                              hipStream_t stream)
{
    const float* nodes  = (const float*)d_in[0];
    const int*   maskp  = (const int*)  d_in[1];
    const float* emb_w1 = (const float*)d_in[2];
    const float* emb_b1 = (const float*)d_in[3];
    const float* ln1_g  = (const float*)d_in[4];
    const float* ln1_b  = (const float*)d_in[5];
    const float* emb_w2 = (const float*)d_in[6];
    const float* emb_b2 = (const float*)d_in[7];
    const float* ln2_g  = (const float*)d_in[8];
    const float* ln2_b  = (const float*)d_in[9];
    const float* fc1_w  = (const float*)d_in[10];
    const float* fc1_b  = (const float*)d_in[11];
    const float* conv_w = (const float*)d_in[12];
    const float* conv_b = (const float*)d_in[13];
    const float* fc2_w  = (const float*)d_in[14];
    const float* fc2_b  = (const float*)d_in[15];
    const float* f1_w   = (const float*)d_in[16];
    const float* f1_b   = (const float*)d_in[17];
    const float* f2_w   = (const float*)d_in[18];
    const float* f2_b   = (const float*)d_in[19];
    const float* ow1    = (const float*)d_in[20];
    const float* ob1    = (const float*)d_in[21];
    const float* ow2    = (const float*)d_in[22];
    const float* ob2    = (const float*)d_in[23];
    float* out = (float*)d_out;

    // ---- workspace layout ----
    char* base = (char*)d_ws;
    float* x   = (float*)base;                          // 33.55 MB
    char*  H   = base + (size_t)BNROWS*DD*4;            // 33.55 MB (x_hi/x_lo <-> h_hi/h_lo)
    char*  BIG = H + (size_t)BNROWS*DD*4;               // 67.11 MB (t256 / cat / ffn hidden)
    float*          x2    = (float*)(BIG + (size_t)BNROWS*2*DD*4);
    float*          g     = (float*)(x2 + BNROWS);
    unsigned short* g_bf  = (unsigned short*)(g + BB*DD);
    unsigned short* hid2_bf = g_bf + BB*DD;
    unsigned short* wbuf  = hid2_bf + BB*FFND;

    unsigned short* x_hi   = (unsigned short*)H;
    unsigned short* x_lo   = x_hi + (size_t)BNROWS*DD;
    unsigned short* t256_bf= (unsigned short*)BIG;
    unsigned short* cat_bf = (unsigned short*)(BIG);    // reused regions
    unsigned short* hid_bf = (unsigned short*)BIG;

    unsigned short* emb_w1t  = wbuf;
    unsigned short* emb_w2t  = emb_w1t + 256*64;
    unsigned short* conv_wt  = emb_w2t + 128*256;
    unsigned short* fc2_wt   = conv_wt + 2*128*256;
    unsigned short* ffn1_wt  = fc2_wt  + 2*128*128;
    unsigned short* ffn2_wt  = ffn1_wt + 2*512*128;
    unsigned short* fc1_wthi = ffn2_wt + 2*128*512;
    unsigned short* fc1_wtlo = fc1_wthi + 2*128*128;
    unsigned short* ow1t     = fc1_wtlo + 2*128*128;
    unsigned short* ow2t     = ow1t + 512*128;

    const dim3 blk(256);

    // ---- all weight transpose-casts (one launch) ----
    prep_all_k<<<1520, blk, 0, stream>>>(
        emb_w1, emb_w2, conv_w, fc2_w, f1_w, f2_w, fc1_w, ow1, ow2,
        emb_w1t, emb_w2t, conv_wt, fc2_wt, ffn1_wt, ffn2_wt,
        fc1_wthi, fc1_wtlo, ow1t, ow2t);

    // ---- Embedding (GEMM + fused LN) ----
    bgemm_ln_k<2,4,true,false,1,true>
        <<<dim3(BNROWS/128), dim3(512), 0, stream>>>
        (nodes, emb_w1t, emb_b1, ln1_g, ln1_b, nullptr, t256_bf, nullptr, nullptr, PP2);
    bgemm_ln_k<2,2,false,true,2,false>
        <<<dim3(BNROWS/128), dim3(256), 0, stream>>>
        (t256_bf, emb_w2t, emb_b2, ln2_g, ln2_b, maskp, x, x_hi, x_lo, 2*DD);

    // ---- ViG blocks ----
    for (int l = 0; l < LLAY; ++l) {
        const float* fc1b = fc1_b + (size_t)l*DD;
        const float* cb   = conv_b + (size_t)l*DD;
        const float* fc2b = fc2_b + (size_t)l*DD;
        const float* b1   = f1_b + (size_t)l*FFND;
        const float* b2   = f2_b + (size_t)l*DD;

        fc1mm_k<<<dim3(BNROWS/128), blk, 0, stream>>>
            (x_hi, x_lo, fc1_wthi + (size_t)l*DD*DD, fc1_wtlo + (size_t)l*DD*DD,
             fc1b, x_hi, x_lo, x2);
        dist_topk_gather_k<<<dim3(BB), dim3(1024), 0, stream>>>
            (x_hi, x_lo, maskp, x2, cat_bf);
        conv_fc2_k<<<dim3(BNROWS/64), blk, 0, stream>>>
            (cat_bf, conv_wt + (size_t)l*DD*2*DD, cb,
             fc2_wt + (size_t)l*DD*DD, fc2b, x, x_hi);
        bgemm_k<ACT_LRELU,false,false,false,true,false>
            <<<dim3(BNROWS/128, FFND/128), blk, 0, stream>>>
            (x_hi, ffn1_wt + (size_t)l*FFND*DD, b1,
             nullptr, nullptr, nullptr, hid_bf, nullptr, nullptr, BNROWS, FFND, DD);
        bgemm_k<ACT_NONE,true,true,true,false,true>
            <<<dim3(BNROWS/128, 1), blk, 0, stream>>>
            (hid_bf, ffn2_wt + (size_t)l*DD*FFND, b2,
             x, maskp, x, nullptr, x_hi, x_lo, BNROWS, DD, FFND);
    }

    // ---- Pool + head (bf16 MFMA) ----
    pool_k<<<BB, 128, 0, stream>>>(x, maskp, g, g_bf);
    bgemm_k<ACT_LRELU,false,false,false,true,false>
        <<<dim3(BB/128, 512/128), blk, 0, stream>>>
        (g_bf, ow1t, ob1, nullptr, nullptr, nullptr, hid2_bf, nullptr, nullptr, BB, 512, DD);
    bgemm_k<ACT_NONE,false,false,true,false,false>
        <<<dim3(BB/128, 2048/128), blk, 0, stream>>>
        (hid2_bf, ow2t, ob2, nullptr, nullptr, out, nullptr, nullptr, nullptr, BB, 2048, 512);
}

// Round 15
// 339.895 us; speedup vs baseline: 1.2544x; 1.0422x over previous
//
#include <hip/hip_runtime.h>
#include <cstdint>

#define BB    256
#define NNODE 256
#define PP2   64
#define DD    128
#define LLAY  2
#define KNN   9
#define FFND  512
#define BNROWS (BB*NNODE)   // 65536

#define LRELU_(v) ((v) >= 0.f ? (v) : 0.01f*(v))

enum { ACT_NONE = 0, ACT_LRELU = 1 };

typedef short  short8_t  __attribute__((ext_vector_type(8)));
typedef float  f32x4     __attribute__((ext_vector_type(4)));
typedef unsigned short us4 __attribute__((ext_vector_type(4)));
typedef unsigned short us8 __attribute__((ext_vector_type(8)));

__device__ inline unsigned short f2bf(float x) {
    unsigned u = __float_as_uint(x);
    unsigned r = (u + 0x7FFFu + ((u >> 16) & 1u)) >> 16;
    return (unsigned short)r;
}
__device__ inline float bf2f(unsigned short h) {
    return __uint_as_float(((unsigned)h) << 16);
}

// async global->LDS, 16B per lane; LDS dest must be wave-uniform base.
__device__ inline void gload16(const void* src, void* dst) {
    __builtin_amdgcn_global_load_lds(
        (const __attribute__((address_space(1))) void*)src,
        (__attribute__((address_space(3))) void*)dst, 16, 0, 0);
}

// Stage a BK=64 bf16 tile (ROWS x 64 elems, 128B rows) from row-major global
// (element stride Kel, starting col k0) into LINEAR LDS via global_load_lds.
// Source address carries the inverse XOR swizzle; reads apply the same XOR.
template<int ROWS, int WAVES>
__device__ inline void stage64g(const unsigned short* __restrict__ g, size_t rowbase,
                                int Kel, int k0, unsigned short* lds, int w, int lane)
{
    constexpr int PER = (ROWS*128/1024) / WAVES;
    #pragma unroll
    for (int i = 0; i < PER; ++i) {
        const int inst = w + i*WAVES;                 // wave-uniform
        const unsigned o  = (unsigned)inst*1024u + (unsigned)lane*16u;
        const int      r  = (int)(o >> 7);
        const unsigned cb = o & 127u;
        const unsigned cs = cb ^ ((unsigned)(r & 7) << 4);
        gload16((const char*)(g + (rowbase + (size_t)r)*(size_t)Kel + k0) + cs,
                (char*)lds + (size_t)inst*1024u);
    }
}

// swizzled fragment read from a linear BK=64 tile
__device__ inline short8_t frag64(const unsigned short* lds, int r, int cb) {
    return *reinterpret_cast<const short8_t*>(
        (const char*)lds + (size_t)r*128 + (unsigned)(cb ^ ((r & 7) << 4)));
}

// swizzled 16B (8 cols) read from a BK=64 tile at column-byte cb (mult of 16)
__device__ inline us8 read8sw(const unsigned short* lds, int r, unsigned cb) {
    return *reinterpret_cast<const us8*>(
        (const char*)lds + (size_t)r*128 + (cb ^ ((unsigned)(r & 7) << 4)));
}

// 16-lane-group min (per DPP row); result in ALL lanes of each 16-group.
__device__ inline unsigned grp16_min_u32(unsigned v) {
    unsigned t;
    t = (unsigned)__builtin_amdgcn_update_dpp(-1, (int)v, 0xB1,  0xF, 0xF, false); v = t < v ? t : v; // quad_perm [1,0,3,2]
    t = (unsigned)__builtin_amdgcn_update_dpp(-1, (int)v, 0x4E,  0xF, 0xF, false); v = t < v ? t : v; // quad_perm [2,3,0,1]
    t = (unsigned)__builtin_amdgcn_update_dpp(-1, (int)v, 0x124, 0xF, 0xF, false); v = t < v ? t : v; // row_ror:4
    t = (unsigned)__builtin_amdgcn_update_dpp(-1, (int)v, 0x128, 0xF, 0xF, false); v = t < v ? t : v; // row_ror:8
    return v;
}

// 16-lane (DPP row) sum; result valid in lane 15 of each 16-lane row.
__device__ inline float dpp_rowsum16(float v) {
    float t;
    t = __uint_as_float((unsigned)__builtin_amdgcn_update_dpp(0, (int)__float_as_uint(v), 0x111, 0xF, 0xF, false)); v += t;
    t = __uint_as_float((unsigned)__builtin_amdgcn_update_dpp(0, (int)__float_as_uint(v), 0x112, 0xF, 0xF, false)); v += t;
    t = __uint_as_float((unsigned)__builtin_amdgcn_update_dpp(0, (int)__float_as_uint(v), 0x114, 0xF, 0xF, false)); v += t;
    t = __uint_as_float((unsigned)__builtin_amdgcn_update_dpp(0, (int)__float_as_uint(v), 0x118, 0xF, 0xF, false)); v += t;
    return v;
}

// ---------------------------------------------------------------------------
// bf16 MFMA GEMM, BK=64, global_load_lds staging.
// ---------------------------------------------------------------------------
template<int ACT, bool RES, bool MASK, bool OUTF, bool OUTB, bool OUTS>
__global__ __launch_bounds__(256)
void bgemm_k(const unsigned short* __restrict__ A,
             const unsigned short* __restrict__ W,
             const float* __restrict__ bias,
             const float* __restrict__ resp,
             const int* __restrict__ mask,
             float* __restrict__ Cf, unsigned short* __restrict__ Cb,
             unsigned short* Ohi, unsigned short* Olo,
             int M, int N, int K)
{
    __shared__ __align__(16) unsigned short As[128*64];
    __shared__ __align__(16) unsigned short Bs[128*64];

    const int tid  = threadIdx.x;
    const int lane = tid & 63;
    const int w    = tid >> 6;
    const int wr   = w >> 1, wc = w & 1;
    const int row0 = blockIdx.x * 128;
    const int col0 = blockIdx.y * 128;
    const int l15  = lane & 15;
    const int ko   = lane >> 4;

    f32x4 acc[4][4];
    #pragma unroll
    for (int m = 0; m < 4; ++m)
        #pragma unroll
        for (int n = 0; n < 4; ++n) acc[m][n] = (f32x4){0.f,0.f,0.f,0.f};

    for (int k0 = 0; k0 < K; k0 += 64) {
        stage64g<128,4>(A, (size_t)row0, K, k0, As, w, lane);
        stage64g<128,4>(W, (size_t)col0, K, k0, Bs, w, lane);
        __syncthreads();
        #pragma unroll
        for (int ks = 0; ks < 2; ++ks) {
            short8_t aF[4], bF[4];
            #pragma unroll
            for (int m = 0; m < 4; ++m)
                aF[m] = frag64(As, wr*64 + m*16 + l15, ks*64 + ko*16);
            #pragma unroll
            for (int n = 0; n < 4; ++n)
                bF[n] = frag64(Bs, wc*64 + n*16 + l15, ks*64 + ko*16);
            #pragma unroll
            for (int m = 0; m < 4; ++m)
                #pragma unroll
                for (int n = 0; n < 4; ++n)
                    acc[m][n] = __builtin_amdgcn_mfma_f32_16x16x32_bf16(aF[m], bF[n], acc[m][n], 0, 0, 0);
        }
        __syncthreads();
    }

    #pragma unroll
    for (int m = 0; m < 4; ++m) {
        const int rbase = row0 + wr*64 + m*16 + ko*4;
        #pragma unroll
        for (int n = 0; n < 4; ++n) {
            const int col = col0 + wc*64 + n*16 + l15;
            const float bv = bias[col];
            #pragma unroll
            for (int r = 0; r < 4; ++r) {
                const int row = rbase + r;
                float v = acc[m][n][r] + bv;
                if constexpr (ACT == ACT_LRELU) v = LRELU_(v);
                if constexpr (RES)  v += resp[(size_t)row*N + col];
                if constexpr (MASK) v *= (mask[row] != 0) ? 1.f : 0.f;
                if constexpr (OUTF) Cf[(size_t)row*N + col] = v;
                if constexpr (OUTB) Cb[(size_t)row*N + col] = f2bf(v);
                if constexpr (OUTS) {
                    unsigned short h = f2bf(v);
                    Ohi[(size_t)row*N + col] = h;
                    Olo[(size_t)row*N + col] = f2bf(v - bf2f(h));
                }
            }
        }
    }
}

// ---------------------------------------------------------------------------
// bf16 MFMA GEMM fused with full-row LayerNorm epilogue (BK=64).
// AF32: A fp32, cast during (reg) staging into the same linear-swz layout.
// ---------------------------------------------------------------------------
template<int WR, int WC, bool DO_LRELU, bool MASKMUL, int MODE, bool AF32>
__global__ __launch_bounds__(WR*WC*64)
void bgemm_ln_k(const void* __restrict__ Ap,
                const unsigned short* __restrict__ W,
                const float* __restrict__ bias,
                const float* __restrict__ gam,
                const float* __restrict__ bet,
                const int* __restrict__ mask,
                void* __restrict__ outv,
                unsigned short* __restrict__ ohi, unsigned short* __restrict__ olo,
                int K)
{
    constexpr int BM = WR*64;
    constexpr int BN = WC*64;
    constexpr int THREADS = WR*WC*64;
    constexpr int WAVES = THREADS/64;
    __shared__ __align__(16) unsigned short As[BM*64];
    __shared__ __align__(16) unsigned short Bs[BN*64];
    __shared__ float red_s[WC][BM];
    __shared__ float red_q[WC][BM];
    __shared__ float mu_l[BM];
    __shared__ float rs_l[BM];

    const int tid  = threadIdx.x;
    const int lane = tid & 63;
    const int w    = tid >> 6;
    const int wr   = w / WC, wc = w % WC;
    const int row0 = blockIdx.x * BM;
    const int l15  = lane & 15;
    const int ko   = lane >> 4;

    f32x4 acc[4][4];
    #pragma unroll
    for (int m = 0; m < 4; ++m)
        #pragma unroll
        for (int n = 0; n < 4; ++n) acc[m][n] = (f32x4){0.f,0.f,0.f,0.f};

    for (int k0 = 0; k0 < K; k0 += 64) {
        if constexpr (AF32) {
            const float* Af = (const float*)Ap;
            constexpr int CH = (BM*8)/THREADS;    // 16B chunks per thread
            #pragma unroll
            for (int i = 0; i < CH; ++i) {
                const int q = i*THREADS + tid;
                const unsigned o  = (unsigned)q*16u;
                const int      r  = (int)(o >> 7);
                const unsigned cb = o & 127u;
                const unsigned cs = cb ^ ((unsigned)(r & 7) << 4);
                const float* src = Af + (size_t)(row0 + r)*K + k0 + (cs >> 1);
                const float4 f0 = *reinterpret_cast<const float4*>(src);
                const float4 f1 = *reinterpret_cast<const float4*>(src + 4);
                short8_t v;
                v[0]=(short)f2bf(f0.x); v[1]=(short)f2bf(f0.y); v[2]=(short)f2bf(f0.z); v[3]=(short)f2bf(f0.w);
                v[4]=(short)f2bf(f1.x); v[5]=(short)f2bf(f1.y); v[6]=(short)f2bf(f1.z); v[7]=(short)f2bf(f1.w);
                *reinterpret_cast<short8_t*>((char*)As + o) = v;
            }
        } else {
            stage64g<BM,WAVES>((const unsigned short*)Ap, (size_t)row0, K, k0, As, w, lane);
        }
        stage64g<BN,WAVES>(W, 0, K, k0, Bs, w, lane);
        __syncthreads();
        #pragma unroll
        for (int ks = 0; ks < 2; ++ks) {
            short8_t aF[4], bF[4];
            #pragma unroll
            for (int m = 0; m < 4; ++m)
                aF[m] = frag64(As, wr*64 + m*16 + l15, ks*64 + ko*16);
            #pragma unroll
            for (int n = 0; n < 4; ++n)
                bF[n] = frag64(Bs, wc*64 + n*16 + l15, ks*64 + ko*16);
            #pragma unroll
            for (int m = 0; m < 4; ++m)
                #pragma unroll
                for (int n = 0; n < 4; ++n)
                    acc[m][n] = __builtin_amdgcn_mfma_f32_16x16x32_bf16(aF[m], bF[n], acc[m][n], 0, 0, 0);
        }
        __syncthreads();
    }

    float bv[4];
    #pragma unroll
    for (int n = 0; n < 4; ++n) bv[n] = bias[wc*64 + n*16 + l15];
    #pragma unroll
    for (int m = 0; m < 4; ++m)
        #pragma unroll
        for (int n = 0; n < 4; ++n)
            #pragma unroll
            for (int r = 0; r < 4; ++r) acc[m][n][r] += bv[n];

    #pragma unroll
    for (int m = 0; m < 4; ++m) {
        #pragma unroll
        for (int r = 0; r < 4; ++r) {
            float s = acc[m][0][r] + acc[m][1][r] + acc[m][2][r] + acc[m][3][r];
            float q = acc[m][0][r]*acc[m][0][r] + acc[m][1][r]*acc[m][1][r]
                    + acc[m][2][r]*acc[m][2][r] + acc[m][3][r]*acc[m][3][r];
            s = dpp_rowsum16(s);
            q = dpp_rowsum16(q);
            if (l15 == 15) {
                int rl = wr*64 + m*16 + ko*4 + r;
                red_s[wc][rl] = s;
                red_q[wc][rl] = q;
            }
        }
    }
    __syncthreads();
    if (tid < BM) {
        float s = 0.f, q = 0.f;
        #pragma unroll
        for (int c2 = 0; c2 < WC; ++c2) { s += red_s[c2][tid]; q += red_q[c2][tid]; }
        float mu  = s * (1.0f/BN);
        float var = q * (1.0f/BN) - mu*mu;
        mu_l[tid] = mu;
        rs_l[tid] = rsqrtf(fmaxf(var, 0.f) + 1e-5f);
    }
    __syncthreads();

    float gm[4], bt[4];
    #pragma unroll
    for (int n = 0; n < 4; ++n) {
        int col = wc*64 + n*16 + l15;
        gm[n] = gam[col]; bt[n] = bet[col];
    }
    #pragma unroll
    for (int m = 0; m < 4; ++m) {
        #pragma unroll
        for (int r = 0; r < 4; ++r) {
            const int rl  = wr*64 + m*16 + ko*4 + r;
            const int row = row0 + rl;
            const float mu = mu_l[rl], rs = rs_l[rl];
            float mf = 1.f;
            if constexpr (MASKMUL) mf = (mask[row] != 0) ? 1.f : 0.f;
            #pragma unroll
            for (int n = 0; n < 4; ++n) {
                const int col = wc*64 + n*16 + l15;
                float y = (acc[m][n][r] - mu) * rs * gm[n] + bt[n];
                if constexpr (DO_LRELU) y = LRELU_(y);
                if constexpr (MASKMUL)  y *= mf;
                if constexpr (MODE == 1) {
                    ((unsigned short*)outv)[(size_t)row*BN + col] = f2bf(y);
                } else {
                    ((float*)outv)[(size_t)row*BN + col] = y;
                    unsigned short h = f2bf(y);
                    ohi[(size_t)row*BN + col] = h;
                    olo[(size_t)row*BN + col] = f2bf(y - bf2f(h));
                }
            }
        }
    }
}

// ---------------------------------------------------------------------------
// fc1 split-bf16 MFMA GEMM, 3 phases, BK=64, in-place OK, fused rowsq(x2).
// ---------------------------------------------------------------------------
__global__ __launch_bounds__(256)
void fc1mm_k(const unsigned short* Ahi, const unsigned short* Alo,
             const unsigned short* __restrict__ Bhi, const unsigned short* __restrict__ Blo,
             const float* __restrict__ bias,
             unsigned short* Ohi, unsigned short* Olo,
             float* __restrict__ x2out)
{
    __shared__ __align__(16) unsigned short As[128*64];
    __shared__ __align__(16) unsigned short Bs[128*64];
    __shared__ float red_q[2][128];

    const int tid  = threadIdx.x;
    const int lane = tid & 63;
    const int w    = tid >> 6;
    const int wr   = w >> 1, wc = w & 1;
    const int row0 = blockIdx.x * 128;
    const int l15  = lane & 15;
    const int ko   = lane >> 4;

    f32x4 acc[4][4];
    #pragma unroll
    for (int m = 0; m < 4; ++m)
        #pragma unroll
        for (int n = 0; n < 4; ++n) acc[m][n] = (f32x4){0.f,0.f,0.f,0.f};

    for (int kk = 0; kk < 384; kk += 64) {
        const int p  = kk >> 7;        // 0,0,1,1,2,2
        const int kl = kk & 127;
        const unsigned short* Ap2 = (p == 1) ? Alo : Ahi;
        const unsigned short* Bp2 = (p == 2) ? Blo : Bhi;
        stage64g<128,4>(Ap2, (size_t)row0, DD, kl, As, w, lane);
        stage64g<128,4>(Bp2, 0, DD, kl, Bs, w, lane);
        __syncthreads();
        #pragma unroll
        for (int ks = 0; ks < 2; ++ks) {
            short8_t aF[4], bF[4];
            #pragma unroll
            for (int m = 0; m < 4; ++m)
                aF[m] = frag64(As, wr*64 + m*16 + l15, ks*64 + ko*16);
            #pragma unroll
            for (int n = 0; n < 4; ++n)
                bF[n] = frag64(Bs, wc*64 + n*16 + l15, ks*64 + ko*16);
            #pragma unroll
            for (int m = 0; m < 4; ++m)
                #pragma unroll
                for (int n = 0; n < 4; ++n)
                    acc[m][n] = __builtin_amdgcn_mfma_f32_16x16x32_bf16(aF[m], bF[n], acc[m][n], 0, 0, 0);
        }
        __syncthreads();
    }

    float qacc[4][4];
    #pragma unroll
    for (int m = 0; m < 4; ++m) {
        const int rbase = row0 + wr*64 + m*16 + ko*4;
        #pragma unroll
        for (int r = 0; r < 4; ++r) qacc[m][r] = 0.f;
        #pragma unroll
        for (int n = 0; n < 4; ++n) {
            const int col = wc*64 + n*16 + l15;
            const float bv = bias[col];
            #pragma unroll
            for (int r = 0; r < 4; ++r) {
                const int row = rbase + r;
                float v = acc[m][n][r] + bv;
                unsigned short h = f2bf(v);
                unsigned short l = f2bf(v - bf2f(h));
                Ohi[(size_t)row*DD + col] = h;
                Olo[(size_t)row*DD + col] = l;
                float vv = bf2f(h) + bf2f(l);
                qacc[m][r] += vv*vv;
            }
        }
    }
    #pragma unroll
    for (int m = 0; m < 4; ++m)
        #pragma unroll
        for (int r = 0; r < 4; ++r) {
            float q = dpp_rowsum16(qacc[m][r]);
            if (l15 == 15) red_q[wc][wr*64 + m*16 + ko*4 + r] = q;
        }
    __syncthreads();
    if (tid < 128) x2out[row0 + tid] = red_q[0][tid] + red_q[1][tid];
}

// ---------------------------------------------------------------------------
// Fused distance + top-9 + gather: ONE block per batch (1024 thr, 16 waves).
// Per-wave pipeline after the stage barrier (no further barriers). Gather
// uses 16B/lane swizzled reads (conflict-free: 8 lanes cover a full row).
// ---------------------------------------------------------------------------
__global__ __launch_bounds__(1024)
void dist_topk_gather_k(const unsigned short* __restrict__ hhi,
                        const unsigned short* __restrict__ hlo,
                        const int* __restrict__ mask,
                        const float* __restrict__ x2,
                        unsigned short* __restrict__ cat)
{
    __shared__ __align__(16) unsigned short BsH[2][NNODE*64];   // 64KB
    __shared__ __align__(16) unsigned short BsL[2][NNODE*64];   // 64KB
    __shared__ unsigned char idx_s[NNODE*KNN];
    __shared__ unsigned char msk_s[NNODE];

    const int b    = blockIdx.x;
    const int tid  = threadIdx.x;
    const int lane = tid & 63;
    const int w    = tid >> 6;          // 0..15
    const int l15  = lane & 15;
    const int g    = lane >> 4;         // 0..3

    const unsigned short* Hhi = hhi + (size_t)b*NNODE*DD;
    const unsigned short* Hlo = hlo + (size_t)b*NNODE*DD;
    const float* x2b = x2 + b*NNODE;
    const int*   mkb = mask + b*NNODE;

    stage64g<NNODE,16>(Hhi, 0, DD, 0,  &BsH[0][0], w, lane);
    stage64g<NNODE,16>(Hhi, 0, DD, 64, &BsH[1][0], w, lane);
    stage64g<NNODE,16>(Hlo, 0, DD, 0,  &BsL[0][0], w, lane);
    stage64g<NNODE,16>(Hlo, 0, DD, 64, &BsL[1][0], w, lane);
    if (tid < NNODE) msk_s[tid] = (mkb[tid] != 0) ? 1 : 0;
    __syncthreads();

    const int arow = w*16 + l15;        // 0..255

    f32x4 acc[16];
    #pragma unroll
    for (int n = 0; n < 16; ++n) acc[n] = (f32x4){0.f,0.f,0.f,0.f};

    #pragma unroll
    for (int kt = 0; kt < 2; ++kt) {
        #pragma unroll
        for (int ks = 0; ks < 2; ++ks) {
            short8_t aH = frag64(&BsH[kt][0], arow, ks*64 + g*16);
            short8_t aL = frag64(&BsL[kt][0], arow, ks*64 + g*16);
            #pragma unroll
            for (int n = 0; n < 16; ++n) {
                int brow = n*16 + l15;
                short8_t bH = frag64(&BsH[kt][0], brow, ks*64 + g*16);
                short8_t bL = frag64(&BsL[kt][0], brow, ks*64 + g*16);
                acc[n] = __builtin_amdgcn_mfma_f32_16x16x32_bf16(aH, bH, acc[n], 0, 0, 0); // hi.hi
                acc[n] = __builtin_amdgcn_mfma_f32_16x16x32_bf16(aL, bH, acc[n], 0, 0, 0); // lo.hi
                acc[n] = __builtin_amdgcn_mfma_f32_16x16x32_bf16(aH, bL, acc[n], 0, 0, 0); // hi.lo
            }
        }
    }

    float x2c[16]; unsigned mk[16];
    #pragma unroll
    for (int n = 0; n < 16; ++n) {
        int col = n*16 + l15;
        x2c[n] = x2b[col];
        mk[n]  = (unsigned)msk_s[col];
    }

    #pragma unroll
    for (int r = 0; r < 4; ++r) {
        const int lrow = w*16 + g*4 + r;          // this wave's rows only
        const float x2r = x2b[lrow];
        unsigned key[16];
        #pragma unroll
        for (int n = 0; n < 16; ++n) {
            float v = x2r + x2c[n] - 2.0f*acc[n][r];
            if (!mk[n]) v = 1e10f;
            unsigned u = __float_as_uint(v);
            u = (u & 0x80000000u) ? ~u : (u | 0x80000000u);
            key[n] = (u & 0xFFFFFF00u) | (unsigned)(n*16 + l15);
        }
        for (int it = 0; it < KNN; ++it) {
            unsigned a0 = key[0]  < key[1]  ? key[0]  : key[1];
            unsigned a1 = key[2]  < key[3]  ? key[2]  : key[3];
            unsigned a2 = key[4]  < key[5]  ? key[4]  : key[5];
            unsigned a3 = key[6]  < key[7]  ? key[6]  : key[7];
            unsigned a4 = key[8]  < key[9]  ? key[8]  : key[9];
            unsigned a5 = key[10] < key[11] ? key[10] : key[11];
            unsigned a6 = key[12] < key[13] ? key[12] : key[13];
            unsigned a7 = key[14] < key[15] ? key[14] : key[15];
            unsigned b0 = a0 < a1 ? a0 : a1;
            unsigned b1 = a2 < a3 ? a2 : a3;
            unsigned b2 = a4 < a5 ? a4 : a5;
            unsigned b3 = a6 < a7 ? a6 : a7;
            unsigned c0 = b0 < b1 ? b0 : b1;
            unsigned c1 = b2 < b3 ? b2 : b3;
            unsigned lmin = c0 < c1 ? c0 : c1;
            unsigned gmin = grp16_min_u32(lmin);
            if (l15 == 0) idx_s[lrow*KNN + it] = (unsigned char)(gmin & 0xFFu);
            #pragma unroll
            for (int n = 0; n < 16; ++n)
                if (key[n] == gmin) key[n] = 0xFFFFFFFFu;
        }
    }
    // NO block barrier: gather touches only this wave's rows (same-wave DS order).

    // ---- gather + max-relative: 16B/lane, 8 lanes cover one full tile-row ----
    const int gi = lane & 7;                       // granule 0..7 (8 cols)
    const unsigned cb = (unsigned)(gi * 16);       // byte col within tile
    #pragma unroll
    for (int kt = 0; kt < 2; ++kt) {
        #pragma unroll
        for (int p = 0; p < 2; ++p) {
            const int rl = w*16 + p*8 + (lane >> 3);   // this wave's row
            us8 h8 = read8sw(&BsH[kt][0], rl, cb);
            us8 l8 = read8sw(&BsL[kt][0], rl, cb);
            float hi[8], m[8];
            #pragma unroll
            for (int d = 0; d < 8; ++d) { hi[d] = bf2f(h8[d]) + bf2f(l8[d]); m[d] = -1e9f; }
            bool any = false;
            #pragma unroll
            for (int q = 0; q < KNN; ++q) {
                int j = idx_s[rl*KNN + q];
                if (msk_s[j]) {
                    any = true;
                    us8 a = read8sw(&BsH[kt][0], j, cb);
                    us8 o = read8sw(&BsL[kt][0], j, cb);
                    #pragma unroll
                    for (int d = 0; d < 8; ++d)
                        m[d] = fmaxf(m[d], bf2f(a[d]) + bf2f(o[d]) - hi[d]);
                }
            }
            us8 o1, o2;
            #pragma unroll
            for (int d = 0; d < 8; ++d) {
                o1[d] = f2bf(hi[d]);
                o2[d] = any ? f2bf(m[d]) : (unsigned short)0;
            }
            const size_t rowbase = (size_t)(b*NNODE + rl)*(2*DD);
            const int c0 = kt*64 + gi*8;
            *reinterpret_cast<us8*>(&cat[rowbase + c0])      = o1;
            *reinterpret_cast<us8*>(&cat[rowbase + DD + c0]) = o2;
        }
    }
}

// ---------------------------------------------------------------------------
// Fused conv + fc2: BM=64 (1024 blocks), 40KB LDS.
// x += (lrelu(cat@Wc^T + cb)) @ W2^T + fb;  xhi = bf16(x)
// ---------------------------------------------------------------------------
__global__ __launch_bounds__(256)
void conv_fc2_k(const unsigned short* __restrict__ cat,
                const unsigned short* __restrict__ Wc,
                const float* __restrict__ cb,
                const unsigned short* __restrict__ W2,
                const float* __restrict__ fb,
                float* __restrict__ x,
                unsigned short* __restrict__ xhi)
{
    __shared__ __align__(16) unsigned short As[64*64];       // 8KB
    __shared__ __align__(16) unsigned short Bs[128*64];      // 16KB
    __shared__ __align__(16) unsigned short h2s[2][64*64];   // 2x8KB (k-halves)

    const int tid  = threadIdx.x;
    const int lane = tid & 63;
    const int w    = tid >> 6;      // 0..3: wave col group (cols w*32..w*32+31)
    const int row0 = blockIdx.x * 64;
    const int l15  = lane & 15;
    const int ko   = lane >> 4;

    f32x4 acc[4][2];
    #pragma unroll
    for (int m = 0; m < 4; ++m)
        #pragma unroll
        for (int n = 0; n < 2; ++n) acc[m][n] = (f32x4){0.f,0.f,0.f,0.f};

    for (int k0 = 0; k0 < 256; k0 += 64) {
        stage64g<64,4>(cat, (size_t)row0, 256, k0, As, w, lane);
        stage64g<128,4>(Wc, 0, 256, k0, Bs, w, lane);
        __syncthreads();
        #pragma unroll
        for (int ks = 0; ks < 2; ++ks) {
            short8_t aF[4], bF[2];
            #pragma unroll
            for (int m = 0; m < 4; ++m)
                aF[m] = frag64(As, m*16 + l15, ks*64 + ko*16);
            #pragma unroll
            for (int n = 0; n < 2; ++n)
                bF[n] = frag64(Bs, w*32 + n*16 + l15, ks*64 + ko*16);
            #pragma unroll
            for (int m = 0; m < 4; ++m)
                #pragma unroll
                for (int n = 0; n < 2; ++n)
                    acc[m][n] = __builtin_amdgcn_mfma_f32_16x16x32_bf16(aF[m], bF[n], acc[m][n], 0, 0, 0);
        }
        __syncthreads();
    }

    {
        const int kt = w >> 1;
        #pragma unroll
        for (int n = 0; n < 2; ++n) {
            const int col = w*32 + n*16 + l15;
            const float bv = cb[col];
            const unsigned bc = (unsigned)(((w & 1)*32 + n*16 + l15) * 2);
            #pragma unroll
            for (int m = 0; m < 4; ++m) {
                #pragma unroll
                for (int r = 0; r < 4; ++r) {
                    const int row = m*16 + ko*4 + r;
                    float v = LRELU_(acc[m][n][r] + bv);
                    *(unsigned short*)((char*)&h2s[kt][0] + row*128
                        + (bc ^ ((unsigned)(row & 7) << 4))) = f2bf(v);
                }
            }
        }
    }

    f32x4 acc2[4][2];
    #pragma unroll
    for (int m = 0; m < 4; ++m)
        #pragma unroll
        for (int n = 0; n < 2; ++n) acc2[m][n] = (f32x4){0.f,0.f,0.f,0.f};

    #pragma unroll
    for (int kt = 0; kt < 2; ++kt) {
        stage64g<128,4>(W2, 0, 128, kt*64, Bs, w, lane);
        __syncthreads();
        #pragma unroll
        for (int ks = 0; ks < 2; ++ks) {
            short8_t aF[4], bF[2];
            #pragma unroll
            for (int m = 0; m < 4; ++m)
                aF[m] = frag64(&h2s[kt][0], m*16 + l15, ks*64 + ko*16);
            #pragma unroll
            for (int n = 0; n < 2; ++n)
                bF[n] = frag64(Bs, w*32 + n*16 + l15, ks*64 + ko*16);
            #pragma unroll
            for (int m = 0; m < 4; ++m)
                #pragma unroll
                for (int n = 0; n < 2; ++n)
                    acc2[m][n] = __builtin_amdgcn_mfma_f32_16x16x32_bf16(aF[m], bF[n], acc2[m][n], 0, 0, 0);
        }
        __syncthreads();
    }

    #pragma unroll
    for (int m = 0; m < 4; ++m) {
        const int rbase = row0 + m*16 + ko*4;
        #pragma unroll
        for (int n = 0; n < 2; ++n) {
            const int col = w*32 + n*16 + l15;
            const float bv = fb[col];
            #pragma unroll
            for (int r = 0; r < 4; ++r) {
                const int row = rbase + r;
                float v = acc2[m][n][r] + bv + x[(size_t)row*DD + col];
                x[(size_t)row*DD + col] = v;
                xhi[(size_t)row*DD + col] = f2bf(v);
            }
        }
    }
}

// ---------------------------------------------------------------------------
// Fused FFN: x = lrelu(x@W1^T+b1)@W2^T + b2 + x, masked; hidden NEVER hits
// HBM. BM=64, 4 hidden chunks of 128. LDS 48KB -> 3 blocks/CU.
// Epilogue also writes split x_hi/x_lo (for next fc1 / pool input).
// ---------------------------------------------------------------------------
__global__ __launch_bounds__(256)
void ffn_k(const unsigned short* __restrict__ xhi_in,
           const unsigned short* __restrict__ W1,     // [512][128]
           const float* __restrict__ b1,
           const unsigned short* __restrict__ W2,     // [128][512]
           const float* __restrict__ b2,
           const int* __restrict__ mask,
           float* __restrict__ x,
           unsigned short* __restrict__ xhi_out,
           unsigned short* __restrict__ xlo_out)
{
    __shared__ __align__(16) unsigned short Xs[2][64*64];    // 16KB (x tile resident)
    __shared__ __align__(16) unsigned short Bs[128*64];      // 16KB (weight tiles)
    __shared__ __align__(16) unsigned short h2s[2][64*64];   // 16KB (hidden chunk)

    const int tid  = threadIdx.x;
    const int lane = tid & 63;
    const int w    = tid >> 6;      // 0..3
    const int row0 = blockIdx.x * 64;
    const int l15  = lane & 15;
    const int ko   = lane >> 4;

    stage64g<64,4>(xhi_in, (size_t)row0, DD, 0,  &Xs[0][0], w, lane);
    stage64g<64,4>(xhi_in, (size_t)row0, DD, 64, &Xs[1][0], w, lane);

    f32x4 acc2[4][2];
    #pragma unroll
    for (int m = 0; m < 4; ++m)
        #pragma unroll
        for (int n = 0; n < 2; ++n) acc2[m][n] = (f32x4){0.f,0.f,0.f,0.f};

    for (int c = 0; c < 4; ++c) {
        // ---- h = lrelu(x @ W1[c]^T + b1[c]) ----
        f32x4 acc1[4][2];
        #pragma unroll
        for (int m = 0; m < 4; ++m)
            #pragma unroll
            for (int n = 0; n < 2; ++n) acc1[m][n] = (f32x4){0.f,0.f,0.f,0.f};

        #pragma unroll
        for (int kt = 0; kt < 2; ++kt) {
            stage64g<128,4>(W1, (size_t)(c*128), DD, kt*64, Bs, w, lane);
            __syncthreads();   // drains Bs stage (+ Xs stage on first iter)
            #pragma unroll
            for (int ks = 0; ks < 2; ++ks) {
                short8_t aF[4], bF[2];
                #pragma unroll
                for (int m = 0; m < 4; ++m)
                    aF[m] = frag64(&Xs[kt][0], m*16 + l15, ks*64 + ko*16);
                #pragma unroll
                for (int n = 0; n < 2; ++n)
                    bF[n] = frag64(Bs, w*32 + n*16 + l15, ks*64 + ko*16);
                #pragma unroll
                for (int m = 0; m < 4; ++m)
                    #pragma unroll
                    for (int n = 0; n < 2; ++n)
                        acc1[m][n] = __builtin_amdgcn_mfma_f32_16x16x32_bf16(aF[m], bF[n], acc1[m][n], 0, 0, 0);
            }
            __syncthreads();
        }

        // hidden chunk -> swizzled LDS k-half tiles
        {
            const int kt = w >> 1;
            #pragma unroll
            for (int n = 0; n < 2; ++n) {
                const int col = w*32 + n*16 + l15;            // 0..127 within chunk
                const float bv = b1[c*128 + col];
                const unsigned bc = (unsigned)(((w & 1)*32 + n*16 + l15) * 2);
                #pragma unroll
                for (int m = 0; m < 4; ++m) {
                    #pragma unroll
                    for (int r = 0; r < 4; ++r) {
                        const int row = m*16 + ko*4 + r;
                        float v = LRELU_(acc1[m][n][r] + bv);
                        *(unsigned short*)((char*)&h2s[kt][0] + row*128
                            + (bc ^ ((unsigned)(row & 7) << 4))) = f2bf(v);
                    }
                }
            }
        }

        // ---- acc2 += h @ W2[:, c*128 .. +128]^T ----
        #pragma unroll
        for (int kt2 = 0; kt2 < 2; ++kt2) {
            stage64g<128,4>(W2, 0, FFND, c*128 + kt2*64, Bs, w, lane);
            __syncthreads();   // drains h2 ds_writes (kt2==0) + Bs stage
            #pragma unroll
            for (int ks = 0; ks < 2; ++ks) {
                short8_t aF[4], bF[2];
                #pragma unroll
                for (int m = 0; m < 4; ++m)
                    aF[m] = frag64(&h2s[kt2][0], m*16 + l15, ks*64 + ko*16);
                #pragma unroll
                for (int n = 0; n < 2; ++n)
                    bF[n] = frag64(Bs, w*32 + n*16 + l15, ks*64 + ko*16);
                #pragma unroll
                for (int m = 0; m < 4; ++m)
                    #pragma unroll
                    for (int n = 0; n < 2; ++n)
                        acc2[m][n] = __builtin_amdgcn_mfma_f32_16x16x32_bf16(aF[m], bF[n], acc2[m][n], 0, 0, 0);
            }
            __syncthreads();
        }
    }

    #pragma unroll
    for (int m = 0; m < 4; ++m) {
        const int rbase = row0 + m*16 + ko*4;
        #pragma unroll
        for (int n = 0; n < 2; ++n) {
            const int col = w*32 + n*16 + l15;
            const float bv = b2[col];
            #pragma unroll
            for (int r = 0; r < 4; ++r) {
                const int row = rbase + r;
                float v = acc2[m][n][r] + bv + x[(size_t)row*DD + col];
                v *= (mask[row] != 0) ? 1.f : 0.f;
                x[(size_t)row*DD + col] = v;
                unsigned short h = f2bf(v);
                xhi_out[(size_t)row*DD + col] = h;
                xlo_out[(size_t)row*DD + col] = f2bf(v - bf2f(h));
            }
        }
    }
}

__global__ __launch_bounds__(128)
void pool_k(const float* __restrict__ x, const int* __restrict__ mask,
            float* __restrict__ g, unsigned short* __restrict__ gbf)
{
    const int b = blockIdx.x, c = threadIdx.x;
    float s = 0.f; int cnt = 0;
    for (int n = 0; n < NNODE; ++n) {
        s += x[((size_t)b*NNODE + n)*DD + c];
        cnt += (mask[b*NNODE + n] != 0) ? 1 : 0;
    }
    float v = s / fmaxf((float)cnt, 1.0f);
    g[b*DD + c] = v;
    gbf[b*DD + c] = f2bf(v);
}

// ---------------------------------------------------------------------------
// All weight transpose-casts in ONE kernel (compile-time job table).
// ---------------------------------------------------------------------------
__global__ __launch_bounds__(256)
void prep_all_k(const float* __restrict__ emb_w1, const float* __restrict__ emb_w2,
                const float* __restrict__ conv_w, const float* __restrict__ fc2_w,
                const float* __restrict__ f1_w,   const float* __restrict__ f2_w,
                const float* __restrict__ fc1_w,  const float* __restrict__ ow1,
                const float* __restrict__ ow2,
                unsigned short* __restrict__ emb_w1t, unsigned short* __restrict__ emb_w2t,
                unsigned short* __restrict__ conv_wt, unsigned short* __restrict__ fc2_wt,
                unsigned short* __restrict__ ffn1_wt, unsigned short* __restrict__ ffn2_wt,
                unsigned short* __restrict__ fc1_wthi, unsigned short* __restrict__ fc1_wtlo,
                unsigned short* __restrict__ ow1t, unsigned short* __restrict__ ow2t)
{
    __shared__ float tile[32][33];
    const int tx = threadIdx.x & 31, ty = threadIdx.x >> 5;

    int bid = blockIdx.x;
    const float* src = nullptr; unsigned short* dst = nullptr; unsigned short* dlo = nullptr;
    int K = 0, N = 0;
    do {
        if (bid < 16)  { src = emb_w1; dst = emb_w1t; K = 64;  N = 256; break; }  bid -= 16;
        if (bid < 32)  { src = emb_w2; dst = emb_w2t; K = 256; N = 128; break; }  bid -= 32;
        if (bid < 64)  { int l = bid >> 5; bid &= 31;
                         src = conv_w + (size_t)l*256*128; dst = conv_wt + (size_t)l*128*256;
                         K = 256; N = 128; break; }                               bid -= 64;
        if (bid < 32)  { int l = bid >> 4; bid &= 15;
                         src = fc2_w + (size_t)l*128*128; dst = fc2_wt + (size_t)l*128*128;
                         K = 128; N = 128; break; }                               bid -= 32;
        if (bid < 128) { int l = bid >> 6; bid &= 63;
                         src = f1_w + (size_t)l*128*512; dst = ffn1_wt + (size_t)l*512*128;
                         K = 128; N = 512; break; }                               bid -= 128;
        if (bid < 128) { int l = bid >> 6; bid &= 63;
                         src = f2_w + (size_t)l*512*128; dst = ffn2_wt + (size_t)l*128*512;
                         K = 512; N = 128; break; }                               bid -= 128;
        if (bid < 32)  { int l = bid >> 4; bid &= 15;
                         src = fc1_w + (size_t)l*128*128;
                         dst = fc1_wthi + (size_t)l*128*128; dlo = fc1_wtlo + (size_t)l*128*128;
                         K = 128; N = 128; break; }                               bid -= 32;
        if (bid < 64)  { src = ow1; dst = ow1t; K = 128; N = 512; break; }        bid -= 64;
        { src = ow2; dst = ow2t; K = 512; N = 2048; }
    } while (0);

    const int nbx = N / 32;
    const int bx = bid % nbx, by = bid / nbx;
    const int k0 = by*32, n0 = bx*32;

    #pragma unroll
    for (int i = ty; i < 32; i += 8)
        tile[i][tx] = src[(size_t)(k0+i)*N + n0+tx];
    __syncthreads();
    #pragma unroll
    for (int i = ty; i < 32; i += 8) {
        float v = tile[tx][i];
        unsigned short h = f2bf(v);
        dst[(size_t)(n0+i)*K + k0+tx] = h;
        if (dlo) dlo[(size_t)(n0+i)*K + k0+tx] = f2bf(v - bf2f(h));
    }
}

// ---------------------------------------------------------------------------
extern "C" void kernel_launch(void* const* d_in, const int* in_sizes, int n_in,
                              void* d_out, int out_size, void* d_ws, size_t ws_size,
                              hipStream_t stream)
{
    const float* nodes  = (const float*)d_in[0];
    const int*   maskp  = (const int*)  d_in[1];
    const float* emb_w1 = (const float*)d_in[2];
    const float* emb_b1 = (const float*)d_in[3];
    const float* ln1_g  = (const float*)d_in[4];
    const float* ln1_b  = (const float*)d_in[5];
    const float* emb_w2 = (const float*)d_in[6];
    const float* emb_b2 = (const float*)d_in[7];
    const float* ln2_g  = (const float*)d_in[8];
    const float* ln2_b  = (const float*)d_in[9];
    const float* fc1_w  = (const float*)d_in[10];
    const float* fc1_b  = (const float*)d_in[11];
    const float* conv_w = (const float*)d_in[12];
    const float* conv_b = (const float*)d_in[13];
    const float* fc2_w  = (const float*)d_in[14];
    const float* fc2_b  = (const float*)d_in[15];
    const float* f1_w   = (const float*)d_in[16];
    const float* f1_b   = (const float*)d_in[17];
    const float* f2_w   = (const float*)d_in[18];
    const float* f2_b   = (const float*)d_in[19];
    const float* ow1    = (const float*)d_in[20];
    const float* ob1    = (const float*)d_in[21];
    const float* ow2    = (const float*)d_in[22];
    const float* ob2    = (const float*)d_in[23];
    float* out = (float*)d_out;

    // ---- workspace layout ----
    char* base = (char*)d_ws;
    float* x   = (float*)base;                          // 33.55 MB
    char*  H   = base + (size_t)BNROWS*DD*4;            // 33.55 MB (x_hi/x_lo <-> h_hi/h_lo)
    char*  BIG = H + (size_t)BNROWS*DD*4;               // 67.11 MB (t256 / cat)
    float*          x2    = (float*)(BIG + (size_t)BNROWS*2*DD*4);
    float*          g     = (float*)(x2 + BNROWS);
    unsigned short* g_bf  = (unsigned short*)(g + BB*DD);
    unsigned short* hid2_bf = g_bf + BB*DD;
    unsigned short* wbuf  = hid2_bf + BB*FFND;

    unsigned short* x_hi   = (unsigned short*)H;
    unsigned short* x_lo   = x_hi + (size_t)BNROWS*DD;
    unsigned short* t256_bf= (unsigned short*)BIG;
    unsigned short* cat_bf = (unsigned short*)BIG;

    unsigned short* emb_w1t  = wbuf;
    unsigned short* emb_w2t  = emb_w1t + 256*64;
    unsigned short* conv_wt  = emb_w2t + 128*256;
    unsigned short* fc2_wt   = conv_wt + 2*128*256;
    unsigned short* ffn1_wt  = fc2_wt  + 2*128*128;
    unsigned short* ffn2_wt  = ffn1_wt + 2*512*128;
    unsigned short* fc1_wthi = ffn2_wt + 2*128*512;
    unsigned short* fc1_wtlo = fc1_wthi + 2*128*128;
    unsigned short* ow1t     = fc1_wtlo + 2*128*128;
    unsigned short* ow2t     = ow1t + 512*128;

    const dim3 blk(256);

    // ---- all weight transpose-casts (one launch) ----
    prep_all_k<<<1520, blk, 0, stream>>>(
        emb_w1, emb_w2, conv_w, fc2_w, f1_w, f2_w, fc1_w, ow1, ow2,
        emb_w1t, emb_w2t, conv_wt, fc2_wt, ffn1_wt, ffn2_wt,
        fc1_wthi, fc1_wtlo, ow1t, ow2t);

    // ---- Embedding (GEMM + fused LN) ----
    bgemm_ln_k<2,4,true,false,1,true>
        <<<dim3(BNROWS/128), dim3(512), 0, stream>>>
        (nodes, emb_w1t, emb_b1, ln1_g, ln1_b, nullptr, t256_bf, nullptr, nullptr, PP2);
    bgemm_ln_k<2,2,false,true,2,false>
        <<<dim3(BNROWS/128), dim3(256), 0, stream>>>
        (t256_bf, emb_w2t, emb_b2, ln2_g, ln2_b, maskp, x, x_hi, x_lo, 2*DD);

    // ---- ViG blocks ----
    for (int l = 0; l < LLAY; ++l) {
        const float* fc1b = fc1_b + (size_t)l*DD;
        const float* cb   = conv_b + (size_t)l*DD;
        const float* fc2b = fc2_b + (size_t)l*DD;
        const float* b1   = f1_b + (size_t)l*FFND;
        const float* b2   = f2_b + (size_t)l*DD;

        fc1mm_k<<<dim3(BNROWS/128), blk, 0, stream>>>
            (x_hi, x_lo, fc1_wthi + (size_t)l*DD*DD, fc1_wtlo + (size_t)l*DD*DD,
             fc1b, x_hi, x_lo, x2);
        dist_topk_gather_k<<<dim3(BB), dim3(1024), 0, stream>>>
            (x_hi, x_lo, maskp, x2, cat_bf);
        conv_fc2_k<<<dim3(BNROWS/64), blk, 0, stream>>>
            (cat_bf, conv_wt + (size_t)l*DD*2*DD, cb,
             fc2_wt + (size_t)l*DD*DD, fc2b, x, x_hi);
        ffn_k<<<dim3(BNROWS/64), blk, 0, stream>>>
            (x_hi, ffn1_wt + (size_t)l*FFND*DD, b1,
             ffn2_wt + (size_t)l*DD*FFND, b2, maskp, x, x_hi, x_lo);
    }

    // ---- Pool + head (bf16 MFMA) ----
    pool_k<<<BB, 128, 0, stream>>>(x, maskp, g, g_bf);
    bgemm_k<ACT_LRELU,false,false,false,true,false>
        <<<dim3(BB/128, 512/128), blk, 0, stream>>>
        (g_bf, ow1t, ob1, nullptr, nullptr, nullptr, hid2_bf, nullptr, nullptr, BB, 512, DD);
    bgemm_k<ACT_NONE,false,false,true,false,false>
        <<<dim3(BB/128, 2048/128), blk, 0, stream>>>
        (hid2_bf, ow2t, ob2, nullptr, nullptr, out, nullptr, nullptr, nullptr, BB, 2048, 512);
}

// Round 16
// 335.276 us; speedup vs baseline: 1.2716x; 1.0138x over previous
//
#include <hip/hip_runtime.h>
#include <cstdint>

#define BB    256
#define NNODE 256
#define PP2   64
#define DD    128
#define LLAY  2
#define KNN   9
#define FFND  512
#define BNROWS (BB*NNODE)   // 65536

#define LRELU_(v) ((v) >= 0.f ? (v) : 0.01f*(v))

enum { ACT_NONE = 0, ACT_LRELU = 1 };

typedef short  short8_t  __attribute__((ext_vector_type(8)));
typedef float  f32x4     __attribute__((ext_vector_type(4)));
typedef unsigned short us4 __attribute__((ext_vector_type(4)));
typedef unsigned short us8 __attribute__((ext_vector_type(8)));

__device__ inline unsigned short f2bf(float x) {
    unsigned u = __float_as_uint(x);
    unsigned r = (u + 0x7FFFu + ((u >> 16) & 1u)) >> 16;
    return (unsigned short)r;
}
__device__ inline float bf2f(unsigned short h) {
    return __uint_as_float(((unsigned)h) << 16);
}

// async global->LDS, 16B per lane; LDS dest must be wave-uniform base.
__device__ inline void gload16(const void* src, void* dst) {
    __builtin_amdgcn_global_load_lds(
        (const __attribute__((address_space(1))) void*)src,
        (__attribute__((address_space(3))) void*)dst, 16, 0, 0);
}

// Stage a BK=64 bf16 tile (ROWS x 64 elems, 128B rows) from row-major global
// (element stride Kel, starting col k0) into LINEAR LDS via global_load_lds.
// Source address carries the inverse XOR swizzle; reads apply the same XOR.
template<int ROWS, int WAVES>
__device__ inline void stage64g(const unsigned short* __restrict__ g, size_t rowbase,
                                int Kel, int k0, unsigned short* lds, int w, int lane)
{
    constexpr int PER = (ROWS*128/1024) / WAVES;
    #pragma unroll
    for (int i = 0; i < PER; ++i) {
        const int inst = w + i*WAVES;                 // wave-uniform
        const unsigned o  = (unsigned)inst*1024u + (unsigned)lane*16u;
        const int      r  = (int)(o >> 7);
        const unsigned cb = o & 127u;
        const unsigned cs = cb ^ ((unsigned)(r & 7) << 4);
        gload16((const char*)(g + (rowbase + (size_t)r)*(size_t)Kel + k0) + cs,
                (char*)lds + (size_t)inst*1024u);
    }
}

// swizzled fragment read from a linear BK=64 tile
__device__ inline short8_t frag64(const unsigned short* lds, int r, int cb) {
    return *reinterpret_cast<const short8_t*>(
        (const char*)lds + (size_t)r*128 + (unsigned)(cb ^ ((r & 7) << 4)));
}

// swizzled 16B (8 cols) read from a BK=64 tile at column-byte cb (mult of 16)
__device__ inline us8 read8sw(const unsigned short* lds, int r, unsigned cb) {
    return *reinterpret_cast<const us8*>(
        (const char*)lds + (size_t)r*128 + (cb ^ ((unsigned)(r & 7) << 4)));
}

// 16-lane-group min (per DPP row); result in ALL lanes of each 16-group.
__device__ inline unsigned grp16_min_u32(unsigned v) {
    unsigned t;
    t = (unsigned)__builtin_amdgcn_update_dpp(-1, (int)v, 0xB1,  0xF, 0xF, false); v = t < v ? t : v; // quad_perm [1,0,3,2]
    t = (unsigned)__builtin_amdgcn_update_dpp(-1, (int)v, 0x4E,  0xF, 0xF, false); v = t < v ? t : v; // quad_perm [2,3,0,1]
    t = (unsigned)__builtin_amdgcn_update_dpp(-1, (int)v, 0x124, 0xF, 0xF, false); v = t < v ? t : v; // row_ror:4
    t = (unsigned)__builtin_amdgcn_update_dpp(-1, (int)v, 0x128, 0xF, 0xF, false); v = t < v ? t : v; // row_ror:8
    return v;
}

// 16-lane (DPP row) sum; result valid in lane 15 of each 16-lane row.
__device__ inline float dpp_rowsum16(float v) {
    float t;
    t = __uint_as_float((unsigned)__builtin_amdgcn_update_dpp(0, (int)__float_as_uint(v), 0x111, 0xF, 0xF, false)); v += t;
    t = __uint_as_float((unsigned)__builtin_amdgcn_update_dpp(0, (int)__float_as_uint(v), 0x112, 0xF, 0xF, false)); v += t;
    t = __uint_as_float((unsigned)__builtin_amdgcn_update_dpp(0, (int)__float_as_uint(v), 0x114, 0xF, 0xF, false)); v += t;
    t = __uint_as_float((unsigned)__builtin_amdgcn_update_dpp(0, (int)__float_as_uint(v), 0x118, 0xF, 0xF, false)); v += t;
    return v;
}

// ---------------------------------------------------------------------------
// bf16 MFMA GEMM, BK=64, global_load_lds staging.
// ---------------------------------------------------------------------------
template<int ACT, bool RES, bool MASK, bool OUTF, bool OUTB, bool OUTS>
__global__ __launch_bounds__(256)
void bgemm_k(const unsigned short* __restrict__ A,
             const unsigned short* __restrict__ W,
             const float* __restrict__ bias,
             const float* __restrict__ resp,
             const int* __restrict__ mask,
             float* __restrict__ Cf, unsigned short* __restrict__ Cb,
             unsigned short* Ohi, unsigned short* Olo,
             int M, int N, int K)
{
    __shared__ __align__(16) unsigned short As[128*64];
    __shared__ __align__(16) unsigned short Bs[128*64];

    const int tid  = threadIdx.x;
    const int lane = tid & 63;
    const int w    = tid >> 6;
    const int wr   = w >> 1, wc = w & 1;
    const int row0 = blockIdx.x * 128;
    const int col0 = blockIdx.y * 128;
    const int l15  = lane & 15;
    const int ko   = lane >> 4;

    f32x4 acc[4][4];
    #pragma unroll
    for (int m = 0; m < 4; ++m)
        #pragma unroll
        for (int n = 0; n < 4; ++n) acc[m][n] = (f32x4){0.f,0.f,0.f,0.f};

    for (int k0 = 0; k0 < K; k0 += 64) {
        stage64g<128,4>(A, (size_t)row0, K, k0, As, w, lane);
        stage64g<128,4>(W, (size_t)col0, K, k0, Bs, w, lane);
        __syncthreads();
        #pragma unroll
        for (int ks = 0; ks < 2; ++ks) {
            short8_t aF[4], bF[4];
            #pragma unroll
            for (int m = 0; m < 4; ++m)
                aF[m] = frag64(As, wr*64 + m*16 + l15, ks*64 + ko*16);
            #pragma unroll
            for (int n = 0; n < 4; ++n)
                bF[n] = frag64(Bs, wc*64 + n*16 + l15, ks*64 + ko*16);
            #pragma unroll
            for (int m = 0; m < 4; ++m)
                #pragma unroll
                for (int n = 0; n < 4; ++n)
                    acc[m][n] = __builtin_amdgcn_mfma_f32_16x16x32_bf16(aF[m], bF[n], acc[m][n], 0, 0, 0);
        }
        __syncthreads();
    }

    #pragma unroll
    for (int m = 0; m < 4; ++m) {
        const int rbase = row0 + wr*64 + m*16 + ko*4;
        #pragma unroll
        for (int n = 0; n < 4; ++n) {
            const int col = col0 + wc*64 + n*16 + l15;
            const float bv = bias[col];
            #pragma unroll
            for (int r = 0; r < 4; ++r) {
                const int row = rbase + r;
                float v = acc[m][n][r] + bv;
                if constexpr (ACT == ACT_LRELU) v = LRELU_(v);
                if constexpr (RES)  v += resp[(size_t)row*N + col];
                if constexpr (MASK) v *= (mask[row] != 0) ? 1.f : 0.f;
                if constexpr (OUTF) Cf[(size_t)row*N + col] = v;
                if constexpr (OUTB) Cb[(size_t)row*N + col] = f2bf(v);
                if constexpr (OUTS) {
                    unsigned short h = f2bf(v);
                    Ohi[(size_t)row*N + col] = h;
                    Olo[(size_t)row*N + col] = f2bf(v - bf2f(h));
                }
            }
        }
    }
}

// ---------------------------------------------------------------------------
// bf16 MFMA GEMM fused with full-row LayerNorm epilogue (BK=64).
// AF32: A fp32, cast during (reg) staging into the same linear-swz layout.
// ---------------------------------------------------------------------------
template<int WR, int WC, bool DO_LRELU, bool MASKMUL, int MODE, bool AF32>
__global__ __launch_bounds__(WR*WC*64)
void bgemm_ln_k(const void* __restrict__ Ap,
                const unsigned short* __restrict__ W,
                const float* __restrict__ bias,
                const float* __restrict__ gam,
                const float* __restrict__ bet,
                const int* __restrict__ mask,
                void* __restrict__ outv,
                unsigned short* __restrict__ ohi, unsigned short* __restrict__ olo,
                int K)
{
    constexpr int BM = WR*64;
    constexpr int BN = WC*64;
    constexpr int THREADS = WR*WC*64;
    constexpr int WAVES = THREADS/64;
    __shared__ __align__(16) unsigned short As[BM*64];
    __shared__ __align__(16) unsigned short Bs[BN*64];
    __shared__ float red_s[WC][BM];
    __shared__ float red_q[WC][BM];
    __shared__ float mu_l[BM];
    __shared__ float rs_l[BM];

    const int tid  = threadIdx.x;
    const int lane = tid & 63;
    const int w    = tid >> 6;
    const int wr   = w / WC, wc = w % WC;
    const int row0 = blockIdx.x * BM;
    const int l15  = lane & 15;
    const int ko   = lane >> 4;

    f32x4 acc[4][4];
    #pragma unroll
    for (int m = 0; m < 4; ++m)
        #pragma unroll
        for (int n = 0; n < 4; ++n) acc[m][n] = (f32x4){0.f,0.f,0.f,0.f};

    for (int k0 = 0; k0 < K; k0 += 64) {
        if constexpr (AF32) {
            const float* Af = (const float*)Ap;
            constexpr int CH = (BM*8)/THREADS;    // 16B chunks per thread
            #pragma unroll
            for (int i = 0; i < CH; ++i) {
                const int q = i*THREADS + tid;
                const unsigned o  = (unsigned)q*16u;
                const int      r  = (int)(o >> 7);
                const unsigned cb = o & 127u;
                const unsigned cs = cb ^ ((unsigned)(r & 7) << 4);
                const float* src = Af + (size_t)(row0 + r)*K + k0 + (cs >> 1);
                const float4 f0 = *reinterpret_cast<const float4*>(src);
                const float4 f1 = *reinterpret_cast<const float4*>(src + 4);
                short8_t v;
                v[0]=(short)f2bf(f0.x); v[1]=(short)f2bf(f0.y); v[2]=(short)f2bf(f0.z); v[3]=(short)f2bf(f0.w);
                v[4]=(short)f2bf(f1.x); v[5]=(short)f2bf(f1.y); v[6]=(short)f2bf(f1.z); v[7]=(short)f2bf(f1.w);
                *reinterpret_cast<short8_t*>((char*)As + o) = v;
            }
        } else {
            stage64g<BM,WAVES>((const unsigned short*)Ap, (size_t)row0, K, k0, As, w, lane);
        }
        stage64g<BN,WAVES>(W, 0, K, k0, Bs, w, lane);
        __syncthreads();
        #pragma unroll
        for (int ks = 0; ks < 2; ++ks) {
            short8_t aF[4], bF[4];
            #pragma unroll
            for (int m = 0; m < 4; ++m)
                aF[m] = frag64(As, wr*64 + m*16 + l15, ks*64 + ko*16);
            #pragma unroll
            for (int n = 0; n < 4; ++n)
                bF[n] = frag64(Bs, wc*64 + n*16 + l15, ks*64 + ko*16);
            #pragma unroll
            for (int m = 0; m < 4; ++m)
                #pragma unroll
                for (int n = 0; n < 4; ++n)
                    acc[m][n] = __builtin_amdgcn_mfma_f32_16x16x32_bf16(aF[m], bF[n], acc[m][n], 0, 0, 0);
        }
        __syncthreads();
    }

    float bv[4];
    #pragma unroll
    for (int n = 0; n < 4; ++n) bv[n] = bias[wc*64 + n*16 + l15];
    #pragma unroll
    for (int m = 0; m < 4; ++m)
        #pragma unroll
        for (int n = 0; n < 4; ++n)
            #pragma unroll
            for (int r = 0; r < 4; ++r) acc[m][n][r] += bv[n];

    #pragma unroll
    for (int m = 0; m < 4; ++m) {
        #pragma unroll
        for (int r = 0; r < 4; ++r) {
            float s = acc[m][0][r] + acc[m][1][r] + acc[m][2][r] + acc[m][3][r];
            float q = acc[m][0][r]*acc[m][0][r] + acc[m][1][r]*acc[m][1][r]
                    + acc[m][2][r]*acc[m][2][r] + acc[m][3][r]*acc[m][3][r];
            s = dpp_rowsum16(s);
            q = dpp_rowsum16(q);
            if (l15 == 15) {
                int rl = wr*64 + m*16 + ko*4 + r;
                red_s[wc][rl] = s;
                red_q[wc][rl] = q;
            }
        }
    }
    __syncthreads();
    if (tid < BM) {
        float s = 0.f, q = 0.f;
        #pragma unroll
        for (int c2 = 0; c2 < WC; ++c2) { s += red_s[c2][tid]; q += red_q[c2][tid]; }
        float mu  = s * (1.0f/BN);
        float var = q * (1.0f/BN) - mu*mu;
        mu_l[tid] = mu;
        rs_l[tid] = rsqrtf(fmaxf(var, 0.f) + 1e-5f);
    }
    __syncthreads();

    float gm[4], bt[4];
    #pragma unroll
    for (int n = 0; n < 4; ++n) {
        int col = wc*64 + n*16 + l15;
        gm[n] = gam[col]; bt[n] = bet[col];
    }
    #pragma unroll
    for (int m = 0; m < 4; ++m) {
        #pragma unroll
        for (int r = 0; r < 4; ++r) {
            const int rl  = wr*64 + m*16 + ko*4 + r;
            const int row = row0 + rl;
            const float mu = mu_l[rl], rs = rs_l[rl];
            float mf = 1.f;
            if constexpr (MASKMUL) mf = (mask[row] != 0) ? 1.f : 0.f;
            #pragma unroll
            for (int n = 0; n < 4; ++n) {
                const int col = wc*64 + n*16 + l15;
                float y = (acc[m][n][r] - mu) * rs * gm[n] + bt[n];
                if constexpr (DO_LRELU) y = LRELU_(y);
                if constexpr (MASKMUL)  y *= mf;
                if constexpr (MODE == 1) {
                    ((unsigned short*)outv)[(size_t)row*BN + col] = f2bf(y);
                } else {
                    ((float*)outv)[(size_t)row*BN + col] = y;
                    unsigned short h = f2bf(y);
                    ohi[(size_t)row*BN + col] = h;
                    olo[(size_t)row*BN + col] = f2bf(y - bf2f(h));
                }
            }
        }
    }
}

// ---------------------------------------------------------------------------
// fc1 split-bf16 MFMA GEMM, 3 phases, BK=64, in-place OK, fused rowsq(x2).
// ---------------------------------------------------------------------------
__global__ __launch_bounds__(256)
void fc1mm_k(const unsigned short* Ahi, const unsigned short* Alo,
             const unsigned short* __restrict__ Bhi, const unsigned short* __restrict__ Blo,
             const float* __restrict__ bias,
             unsigned short* Ohi, unsigned short* Olo,
             float* __restrict__ x2out)
{
    __shared__ __align__(16) unsigned short As[128*64];
    __shared__ __align__(16) unsigned short Bs[128*64];
    __shared__ float red_q[2][128];

    const int tid  = threadIdx.x;
    const int lane = tid & 63;
    const int w    = tid >> 6;
    const int wr   = w >> 1, wc = w & 1;
    const int row0 = blockIdx.x * 128;
    const int l15  = lane & 15;
    const int ko   = lane >> 4;

    f32x4 acc[4][4];
    #pragma unroll
    for (int m = 0; m < 4; ++m)
        #pragma unroll
        for (int n = 0; n < 4; ++n) acc[m][n] = (f32x4){0.f,0.f,0.f,0.f};

    for (int kk = 0; kk < 384; kk += 64) {
        const int p  = kk >> 7;        // 0,0,1,1,2,2
        const int kl = kk & 127;
        const unsigned short* Ap2 = (p == 1) ? Alo : Ahi;
        const unsigned short* Bp2 = (p == 2) ? Blo : Bhi;
        stage64g<128,4>(Ap2, (size_t)row0, DD, kl, As, w, lane);
        stage64g<128,4>(Bp2, 0, DD, kl, Bs, w, lane);
        __syncthreads();
        #pragma unroll
        for (int ks = 0; ks < 2; ++ks) {
            short8_t aF[4], bF[4];
            #pragma unroll
            for (int m = 0; m < 4; ++m)
                aF[m] = frag64(As, wr*64 + m*16 + l15, ks*64 + ko*16);
            #pragma unroll
            for (int n = 0; n < 4; ++n)
                bF[n] = frag64(Bs, wc*64 + n*16 + l15, ks*64 + ko*16);
            #pragma unroll
            for (int m = 0; m < 4; ++m)
                #pragma unroll
                for (int n = 0; n < 4; ++n)
                    acc[m][n] = __builtin_amdgcn_mfma_f32_16x16x32_bf16(aF[m], bF[n], acc[m][n], 0, 0, 0);
        }
        __syncthreads();
    }

    float qacc[4][4];
    #pragma unroll
    for (int m = 0; m < 4; ++m) {
        const int rbase = row0 + wr*64 + m*16 + ko*4;
        #pragma unroll
        for (int r = 0; r < 4; ++r) qacc[m][r] = 0.f;
        #pragma unroll
        for (int n = 0; n < 4; ++n) {
            const int col = wc*64 + n*16 + l15;
            const float bv = bias[col];
            #pragma unroll
            for (int r = 0; r < 4; ++r) {
                const int row = rbase + r;
                float v = acc[m][n][r] + bv;
                unsigned short h = f2bf(v);
                unsigned short l = f2bf(v - bf2f(h));
                Ohi[(size_t)row*DD + col] = h;
                Olo[(size_t)row*DD + col] = l;
                float vv = bf2f(h) + bf2f(l);
                qacc[m][r] += vv*vv;
            }
        }
    }
    #pragma unroll
    for (int m = 0; m < 4; ++m)
        #pragma unroll
        for (int r = 0; r < 4; ++r) {
            float q = dpp_rowsum16(qacc[m][r]);
            if (l15 == 15) red_q[wc][wr*64 + m*16 + ko*4 + r] = q;
        }
    __syncthreads();
    if (tid < 128) x2out[row0 + tid] = red_q[0][tid] + red_q[1][tid];
}

// ---------------------------------------------------------------------------
// Fused distance + top-9 + gather: ONE block per batch (1024 thr, 16 waves).
// Per-wave pipeline after the stage barrier (no further barriers). Gather
// uses 16B/lane swizzled reads (conflict-free: 8 lanes cover a full row).
// ---------------------------------------------------------------------------
__global__ __launch_bounds__(1024)
void dist_topk_gather_k(const unsigned short* __restrict__ hhi,
                        const unsigned short* __restrict__ hlo,
                        const int* __restrict__ mask,
                        const float* __restrict__ x2,
                        unsigned short* __restrict__ cat)
{
    __shared__ __align__(16) unsigned short BsH[2][NNODE*64];   // 64KB
    __shared__ __align__(16) unsigned short BsL[2][NNODE*64];   // 64KB
    __shared__ unsigned char idx_s[NNODE*KNN];
    __shared__ unsigned char msk_s[NNODE];

    const int b    = blockIdx.x;
    const int tid  = threadIdx.x;
    const int lane = tid & 63;
    const int w    = tid >> 6;          // 0..15
    const int l15  = lane & 15;
    const int g    = lane >> 4;         // 0..3

    const unsigned short* Hhi = hhi + (size_t)b*NNODE*DD;
    const unsigned short* Hlo = hlo + (size_t)b*NNODE*DD;
    const float* x2b = x2 + b*NNODE;
    const int*   mkb = mask + b*NNODE;

    stage64g<NNODE,16>(Hhi, 0, DD, 0,  &BsH[0][0], w, lane);
    stage64g<NNODE,16>(Hhi, 0, DD, 64, &BsH[1][0], w, lane);
    stage64g<NNODE,16>(Hlo, 0, DD, 0,  &BsL[0][0], w, lane);
    stage64g<NNODE,16>(Hlo, 0, DD, 64, &BsL[1][0], w, lane);
    if (tid < NNODE) msk_s[tid] = (mkb[tid] != 0) ? 1 : 0;
    __syncthreads();

    const int arow = w*16 + l15;        // 0..255

    f32x4 acc[16];
    #pragma unroll
    for (int n = 0; n < 16; ++n) acc[n] = (f32x4){0.f,0.f,0.f,0.f};

    #pragma unroll
    for (int kt = 0; kt < 2; ++kt) {
        #pragma unroll
        for (int ks = 0; ks < 2; ++ks) {
            short8_t aH = frag64(&BsH[kt][0], arow, ks*64 + g*16);
            short8_t aL = frag64(&BsL[kt][0], arow, ks*64 + g*16);
            #pragma unroll
            for (int n = 0; n < 16; ++n) {
                int brow = n*16 + l15;
                short8_t bH = frag64(&BsH[kt][0], brow, ks*64 + g*16);
                short8_t bL = frag64(&BsL[kt][0], brow, ks*64 + g*16);
                acc[n] = __builtin_amdgcn_mfma_f32_16x16x32_bf16(aH, bH, acc[n], 0, 0, 0); // hi.hi
                acc[n] = __builtin_amdgcn_mfma_f32_16x16x32_bf16(aL, bH, acc[n], 0, 0, 0); // lo.hi
                acc[n] = __builtin_amdgcn_mfma_f32_16x16x32_bf16(aH, bL, acc[n], 0, 0, 0); // hi.lo
            }
        }
    }

    float x2c[16]; unsigned mk[16];
    #pragma unroll
    for (int n = 0; n < 16; ++n) {
        int col = n*16 + l15;
        x2c[n] = x2b[col];
        mk[n]  = (unsigned)msk_s[col];
    }

    #pragma unroll
    for (int r = 0; r < 4; ++r) {
        const int lrow = w*16 + g*4 + r;          // this wave's rows only
        const float x2r = x2b[lrow];
        unsigned key[16];
        #pragma unroll
        for (int n = 0; n < 16; ++n) {
            float v = x2r + x2c[n] - 2.0f*acc[n][r];
            if (!mk[n]) v = 1e10f;
            unsigned u = __float_as_uint(v);
            u = (u & 0x80000000u) ? ~u : (u | 0x80000000u);
            key[n] = (u & 0xFFFFFF00u) | (unsigned)(n*16 + l15);
        }
        for (int it = 0; it < KNN; ++it) {
            unsigned a0 = key[0]  < key[1]  ? key[0]  : key[1];
            unsigned a1 = key[2]  < key[3]  ? key[2]  : key[3];
            unsigned a2 = key[4]  < key[5]  ? key[4]  : key[5];
            unsigned a3 = key[6]  < key[7]  ? key[6]  : key[7];
            unsigned a4 = key[8]  < key[9]  ? key[8]  : key[9];
            unsigned a5 = key[10] < key[11] ? key[10] : key[11];
            unsigned a6 = key[12] < key[13] ? key[12] : key[13];
            unsigned a7 = key[14] < key[15] ? key[14] : key[15];
            unsigned b0 = a0 < a1 ? a0 : a1;
            unsigned b1 = a2 < a3 ? a2 : a3;
            unsigned b2 = a4 < a5 ? a4 : a5;
            unsigned b3 = a6 < a7 ? a6 : a7;
            unsigned c0 = b0 < b1 ? b0 : b1;
            unsigned c1 = b2 < b3 ? b2 : b3;
            unsigned lmin = c0 < c1 ? c0 : c1;
            unsigned gmin = grp16_min_u32(lmin);
            if (l15 == 0) idx_s[lrow*KNN + it] = (unsigned char)(gmin & 0xFFu);
            #pragma unroll
            for (int n = 0; n < 16; ++n)
                if (key[n] == gmin) key[n] = 0xFFFFFFFFu;
        }
    }
    // NO block barrier: gather touches only this wave's rows (same-wave DS order).

    // ---- gather + max-relative: 16B/lane, 8 lanes cover one full tile-row ----
    const int gi = lane & 7;                       // granule 0..7 (8 cols)
    const unsigned cb = (unsigned)(gi * 16);       // byte col within tile
    #pragma unroll
    for (int kt = 0; kt < 2; ++kt) {
        #pragma unroll
        for (int p = 0; p < 2; ++p) {
            const int rl = w*16 + p*8 + (lane >> 3);   // this wave's row
            us8 h8 = read8sw(&BsH[kt][0], rl, cb);
            us8 l8 = read8sw(&BsL[kt][0], rl, cb);
            float hi[8], m[8];
            #pragma unroll
            for (int d = 0; d < 8; ++d) { hi[d] = bf2f(h8[d]) + bf2f(l8[d]); m[d] = -1e9f; }
            bool any = false;
            #pragma unroll
            for (int q = 0; q < KNN; ++q) {
                int j = idx_s[rl*KNN + q];
                if (msk_s[j]) {
                    any = true;
                    us8 a = read8sw(&BsH[kt][0], j, cb);
                    us8 o = read8sw(&BsL[kt][0], j, cb);
                    #pragma unroll
                    for (int d = 0; d < 8; ++d)
                        m[d] = fmaxf(m[d], bf2f(a[d]) + bf2f(o[d]) - hi[d]);
                }
            }
            us8 o1, o2;
            #pragma unroll
            for (int d = 0; d < 8; ++d) {
                o1[d] = f2bf(hi[d]);
                o2[d] = any ? f2bf(m[d]) : (unsigned short)0;
            }
            const size_t rowbase = (size_t)(b*NNODE + rl)*(2*DD);
            const int c0 = kt*64 + gi*8;
            *reinterpret_cast<us8*>(&cat[rowbase + c0])      = o1;
            *reinterpret_cast<us8*>(&cat[rowbase + DD + c0]) = o2;
        }
    }
}

// ---------------------------------------------------------------------------
// Fused conv + fc2: BM=64 (1024 blocks), 40KB LDS.
// x += (lrelu(cat@Wc^T + cb)) @ W2^T + fb;  xhi = bf16(x)
// ---------------------------------------------------------------------------
__global__ __launch_bounds__(256)
void conv_fc2_k(const unsigned short* __restrict__ cat,
                const unsigned short* __restrict__ Wc,
                const float* __restrict__ cb,
                const unsigned short* __restrict__ W2,
                const float* __restrict__ fb,
                float* __restrict__ x,
                unsigned short* __restrict__ xhi)
{
    __shared__ __align__(16) unsigned short As[64*64];       // 8KB
    __shared__ __align__(16) unsigned short Bs[128*64];      // 16KB
    __shared__ __align__(16) unsigned short h2s[2][64*64];   // 2x8KB (k-halves)

    const int tid  = threadIdx.x;
    const int lane = tid & 63;
    const int w    = tid >> 6;      // 0..3: wave col group (cols w*32..w*32+31)
    const int row0 = blockIdx.x * 64;
    const int l15  = lane & 15;
    const int ko   = lane >> 4;

    f32x4 acc[4][2];
    #pragma unroll
    for (int m = 0; m < 4; ++m)
        #pragma unroll
        for (int n = 0; n < 2; ++n) acc[m][n] = (f32x4){0.f,0.f,0.f,0.f};

    for (int k0 = 0; k0 < 256; k0 += 64) {
        stage64g<64,4>(cat, (size_t)row0, 256, k0, As, w, lane);
        stage64g<128,4>(Wc, 0, 256, k0, Bs, w, lane);
        __syncthreads();
        #pragma unroll
        for (int ks = 0; ks < 2; ++ks) {
            short8_t aF[4], bF[2];
            #pragma unroll
            for (int m = 0; m < 4; ++m)
                aF[m] = frag64(As, m*16 + l15, ks*64 + ko*16);
            #pragma unroll
            for (int n = 0; n < 2; ++n)
                bF[n] = frag64(Bs, w*32 + n*16 + l15, ks*64 + ko*16);
            #pragma unroll
            for (int m = 0; m < 4; ++m)
                #pragma unroll
                for (int n = 0; n < 2; ++n)
                    acc[m][n] = __builtin_amdgcn_mfma_f32_16x16x32_bf16(aF[m], bF[n], acc[m][n], 0, 0, 0);
        }
        __syncthreads();
    }

    {
        const int kt = w >> 1;
        #pragma unroll
        for (int n = 0; n < 2; ++n) {
            const int col = w*32 + n*16 + l15;
            const float bv = cb[col];
            const unsigned bc = (unsigned)(((w & 1)*32 + n*16 + l15) * 2);
            #pragma unroll
            for (int m = 0; m < 4; ++m) {
                #pragma unroll
                for (int r = 0; r < 4; ++r) {
                    const int row = m*16 + ko*4 + r;
                    float v = LRELU_(acc[m][n][r] + bv);
                    *(unsigned short*)((char*)&h2s[kt][0] + row*128
                        + (bc ^ ((unsigned)(row & 7) << 4))) = f2bf(v);
                }
            }
        }
    }

    f32x4 acc2[4][2];
    #pragma unroll
    for (int m = 0; m < 4; ++m)
        #pragma unroll
        for (int n = 0; n < 2; ++n) acc2[m][n] = (f32x4){0.f,0.f,0.f,0.f};

    #pragma unroll
    for (int kt = 0; kt < 2; ++kt) {
        stage64g<128,4>(W2, 0, 128, kt*64, Bs, w, lane);
        __syncthreads();
        #pragma unroll
        for (int ks = 0; ks < 2; ++ks) {
            short8_t aF[4], bF[2];
            #pragma unroll
            for (int m = 0; m < 4; ++m)
                aF[m] = frag64(&h2s[kt][0], m*16 + l15, ks*64 + ko*16);
            #pragma unroll
            for (int n = 0; n < 2; ++n)
                bF[n] = frag64(Bs, w*32 + n*16 + l15, ks*64 + ko*16);
            #pragma unroll
            for (int m = 0; m < 4; ++m)
                #pragma unroll
                for (int n = 0; n < 2; ++n)
                    acc2[m][n] = __builtin_amdgcn_mfma_f32_16x16x32_bf16(aF[m], bF[n], acc2[m][n], 0, 0, 0);
        }
        __syncthreads();
    }

    #pragma unroll
    for (int m = 0; m < 4; ++m) {
        const int rbase = row0 + m*16 + ko*4;
        #pragma unroll
        for (int n = 0; n < 2; ++n) {
            const int col = w*32 + n*16 + l15;
            const float bv = fb[col];
            #pragma unroll
            for (int r = 0; r < 4; ++r) {
                const int row = rbase + r;
                float v = acc2[m][n][r] + bv + x[(size_t)row*DD + col];
                x[(size_t)row*DD + col] = v;
                xhi[(size_t)row*DD + col] = f2bf(v);
            }
        }
    }
}

// ---------------------------------------------------------------------------
// Fused FFN: x = lrelu(x@W1^T+b1)@W2^T + b2 + x, masked; hidden NEVER hits
// HBM. BM=64, 4 hidden chunks of 128. Both k-tiles of each weight chunk are
// staged into a double-wide Bs[2] with ONE barrier, then all 4 MFMA
// sub-phases run barrier-free: 4 barriers/chunk (was 8+). LDS 64KB.
// ---------------------------------------------------------------------------
__global__ __launch_bounds__(256)
void ffn_k(const unsigned short* __restrict__ xhi_in,
           const unsigned short* __restrict__ W1,     // [512][128]
           const float* __restrict__ b1,
           const unsigned short* __restrict__ W2,     // [128][512]
           const float* __restrict__ b2,
           const int* __restrict__ mask,
           float* __restrict__ x,
           unsigned short* __restrict__ xhi_out,
           unsigned short* __restrict__ xlo_out)
{
    __shared__ __align__(16) unsigned short Xs[2][64*64];    // 16KB (x tile resident)
    __shared__ __align__(16) unsigned short Bs[2][128*64];   // 32KB (both weight k-tiles)
    __shared__ __align__(16) unsigned short h2s[2][64*64];   // 16KB (hidden chunk)

    const int tid  = threadIdx.x;
    const int lane = tid & 63;
    const int w    = tid >> 6;      // 0..3
    const int row0 = blockIdx.x * 64;
    const int l15  = lane & 15;
    const int ko   = lane >> 4;

    stage64g<64,4>(xhi_in, (size_t)row0, DD, 0,  &Xs[0][0], w, lane);
    stage64g<64,4>(xhi_in, (size_t)row0, DD, 64, &Xs[1][0], w, lane);

    f32x4 acc2[4][2];
    #pragma unroll
    for (int m = 0; m < 4; ++m)
        #pragma unroll
        for (int n = 0; n < 2; ++n) acc2[m][n] = (f32x4){0.f,0.f,0.f,0.f};

    for (int c = 0; c < 4; ++c) {
        // A: stage BOTH k-tiles of the W1 chunk
        stage64g<128,4>(W1, (size_t)(c*128), DD, 0,  &Bs[0][0], w, lane);
        stage64g<128,4>(W1, (size_t)(c*128), DD, 64, &Bs[1][0], w, lane);
        __syncthreads();   // B: drains W1 (+Xs on first iter); prev chunk's Bs reads done

        // C: stage-1 MFMA, all 4 sub-phases barrier-free
        f32x4 acc1[4][2];
        #pragma unroll
        for (int m = 0; m < 4; ++m)
            #pragma unroll
            for (int n = 0; n < 2; ++n) acc1[m][n] = (f32x4){0.f,0.f,0.f,0.f};
        #pragma unroll
        for (int kt = 0; kt < 2; ++kt) {
            #pragma unroll
            for (int ks = 0; ks < 2; ++ks) {
                short8_t aF[4], bF[2];
                #pragma unroll
                for (int m = 0; m < 4; ++m)
                    aF[m] = frag64(&Xs[kt][0], m*16 + l15, ks*64 + ko*16);
                #pragma unroll
                for (int n = 0; n < 2; ++n)
                    bF[n] = frag64(&Bs[kt][0], w*32 + n*16 + l15, ks*64 + ko*16);
                #pragma unroll
                for (int m = 0; m < 4; ++m)
                    #pragma unroll
                    for (int n = 0; n < 2; ++n)
                        acc1[m][n] = __builtin_amdgcn_mfma_f32_16x16x32_bf16(aF[m], bF[n], acc1[m][n], 0, 0, 0);
            }
        }

        // hidden chunk -> swizzled LDS k-half tiles (register dep only)
        {
            const int kt = w >> 1;
            #pragma unroll
            for (int n = 0; n < 2; ++n) {
                const int col = w*32 + n*16 + l15;            // 0..127 within chunk
                const float bv = b1[c*128 + col];
                const unsigned bc = (unsigned)(((w & 1)*32 + n*16 + l15) * 2);
                #pragma unroll
                for (int m = 0; m < 4; ++m) {
                    #pragma unroll
                    for (int r = 0; r < 4; ++r) {
                        const int row = m*16 + ko*4 + r;
                        float v = LRELU_(acc1[m][n][r] + bv);
                        *(unsigned short*)((char*)&h2s[kt][0] + row*128
                            + (bc ^ ((unsigned)(row & 7) << 4))) = f2bf(v);
                    }
                }
            }
        }
        __syncthreads();   // D: Bs(W1) reads + h2 writes complete

        // E: stage BOTH k-tiles of the W2 chunk
        stage64g<128,4>(W2, 0, FFND, c*128,      &Bs[0][0], w, lane);
        stage64g<128,4>(W2, 0, FFND, c*128 + 64, &Bs[1][0], w, lane);
        __syncthreads();   // F: drains W2 stage

        // G: stage-2 MFMA, all 4 sub-phases barrier-free
        #pragma unroll
        for (int kt2 = 0; kt2 < 2; ++kt2) {
            #pragma unroll
            for (int ks = 0; ks < 2; ++ks) {
                short8_t aF[4], bF[2];
                #pragma unroll
                for (int m = 0; m < 4; ++m)
                    aF[m] = frag64(&h2s[kt2][0], m*16 + l15, ks*64 + ko*16);
                #pragma unroll
                for (int n = 0; n < 2; ++n)
                    bF[n] = frag64(&Bs[kt2][0], w*32 + n*16 + l15, ks*64 + ko*16);
                #pragma unroll
                for (int m = 0; m < 4; ++m)
                    #pragma unroll
                    for (int n = 0; n < 2; ++n)
                        acc2[m][n] = __builtin_amdgcn_mfma_f32_16x16x32_bf16(aF[m], bF[n], acc2[m][n], 0, 0, 0);
            }
        }
        __syncthreads();   // H: Bs(W2) + h2s reads done before next chunk's writes
    }

    #pragma unroll
    for (int m = 0; m < 4; ++m) {
        const int rbase = row0 + m*16 + ko*4;
        #pragma unroll
        for (int n = 0; n < 2; ++n) {
            const int col = w*32 + n*16 + l15;
            const float bv = b2[col];
            #pragma unroll
            for (int r = 0; r < 4; ++r) {
                const int row = rbase + r;
                float v = acc2[m][n][r] + bv + x[(size_t)row*DD + col];
                v *= (mask[row] != 0) ? 1.f : 0.f;
                x[(size_t)row*DD + col] = v;
                unsigned short h = f2bf(v);
                xhi_out[(size_t)row*DD + col] = h;
                xlo_out[(size_t)row*DD + col] = f2bf(v - bf2f(h));
            }
        }
    }
}

__global__ __launch_bounds__(128)
void pool_k(const float* __restrict__ x, const int* __restrict__ mask,
            float* __restrict__ g, unsigned short* __restrict__ gbf)
{
    const int b = blockIdx.x, c = threadIdx.x;
    float s = 0.f; int cnt = 0;
    for (int n = 0; n < NNODE; ++n) {
        s += x[((size_t)b*NNODE + n)*DD + c];
        cnt += (mask[b*NNODE + n] != 0) ? 1 : 0;
    }
    float v = s / fmaxf((float)cnt, 1.0f);
    g[b*DD + c] = v;
    gbf[b*DD + c] = f2bf(v);
}

// ---------------------------------------------------------------------------
// All weight transpose-casts in ONE kernel (compile-time job table).
// ---------------------------------------------------------------------------
__global__ __launch_bounds__(256)
void prep_all_k(const float* __restrict__ emb_w1, const float* __restrict__ emb_w2,
                const float* __restrict__ conv_w, const float* __restrict__ fc2_w,
                const float* __restrict__ f1_w,   const float* __restrict__ f2_w,
                const float* __restrict__ fc1_w,  const float* __restrict__ ow1,
                const float* __restrict__ ow2,
                unsigned short* __restrict__ emb_w1t, unsigned short* __restrict__ emb_w2t,
                unsigned short* __restrict__ conv_wt, unsigned short* __restrict__ fc2_wt,
                unsigned short* __restrict__ ffn1_wt, unsigned short* __restrict__ ffn2_wt,
                unsigned short* __restrict__ fc1_wthi, unsigned short* __restrict__ fc1_wtlo,
                unsigned short* __restrict__ ow1t, unsigned short* __restrict__ ow2t)
{
    __shared__ float tile[32][33];
    const int tx = threadIdx.x & 31, ty = threadIdx.x >> 5;

    int bid = blockIdx.x;
    const float* src = nullptr; unsigned short* dst = nullptr; unsigned short* dlo = nullptr;
    int K = 0, N = 0;
    do {
        if (bid < 16)  { src = emb_w1; dst = emb_w1t; K = 64;  N = 256; break; }  bid -= 16;
        if (bid < 32)  { src = emb_w2; dst = emb_w2t; K = 256; N = 128; break; }  bid -= 32;
        if (bid < 64)  { int l = bid >> 5; bid &= 31;
                         src = conv_w + (size_t)l*256*128; dst = conv_wt + (size_t)l*128*256;
                         K = 256; N = 128; break; }                               bid -= 64;
        if (bid < 32)  { int l = bid >> 4; bid &= 15;
                         src = fc2_w + (size_t)l*128*128; dst = fc2_wt + (size_t)l*128*128;
                         K = 128; N = 128; break; }                               bid -= 32;
        if (bid < 128) { int l = bid >> 6; bid &= 63;
                         src = f1_w + (size_t)l*128*512; dst = ffn1_wt + (size_t)l*512*128;
                         K = 128; N = 512; break; }                               bid -= 128;
        if (bid < 128) { int l = bid >> 6; bid &= 63;
                         src = f2_w + (size_t)l*512*128; dst = ffn2_wt + (size_t)l*128*512;
                         K = 512; N = 128; break; }                               bid -= 128;
        if (bid < 32)  { int l = bid >> 4; bid &= 15;
                         src = fc1_w + (size_t)l*128*128;
                         dst = fc1_wthi + (size_t)l*128*128; dlo = fc1_wtlo + (size_t)l*128*128;
                         K = 128; N = 128; break; }                               bid -= 32;
        if (bid < 64)  { src = ow1; dst = ow1t; K = 128; N = 512; break; }        bid -= 64;
        { src = ow2; dst = ow2t; K = 512; N = 2048; }
    } while (0);

    const int nbx = N / 32;
    const int bx = bid % nbx, by = bid / nbx;
    const int k0 = by*32, n0 = bx*32;

    #pragma unroll
    for (int i = ty; i < 32; i += 8)
        tile[i][tx] = src[(size_t)(k0+i)*N + n0+tx];
    __syncthreads();
    #pragma unroll
    for (int i = ty; i < 32; i += 8) {
        float v = tile[tx][i];
        unsigned short h = f2bf(v);
        dst[(size_t)(n0+i)*K + k0+tx] = h;
        if (dlo) dlo[(size_t)(n0+i)*K + k0+tx] = f2bf(v - bf2f(h));
    }
}

// ---------------------------------------------------------------------------
extern "C" void kernel_launch(void* const* d_in, const int* in_sizes, int n_in,
                              void* d_out, int out_size, void* d_ws, size_t ws_size,
                              hipStream_t stream)
{
    const float* nodes  = (const float*)d_in[0];
    const int*   maskp  = (const int*)  d_in[1];
    const float* emb_w1 = (const float*)d_in[2];
    const float* emb_b1 = (const float*)d_in[3];
    const float* ln1_g  = (const float*)d_in[4];
    const float* ln1_b  = (const float*)d_in[5];
    const float* emb_w2 = (const float*)d_in[6];
    const float* emb_b2 = (const float*)d_in[7];
    const float* ln2_g  = (const float*)d_in[8];
    const float* ln2_b  = (const float*)d_in[9];
    const float* fc1_w  = (const float*)d_in[10];
    const float* fc1_b  = (const float*)d_in[11];
    const float* conv_w = (const float*)d_in[12];
    const float* conv_b = (const float*)d_in[13];
    const float* fc2_w  = (const float*)d_in[14];
    const float* fc2_b  = (const float*)d_in[15];
    const float* f1_w   = (const float*)d_in[16];
    const float* f1_b   = (const float*)d_in[17];
    const float* f2_w   = (const float*)d_in[18];
    const float* f2_b   = (const float*)d_in[19];
    const float* ow1    = (const float*)d_in[20];
    const float* ob1    = (const float*)d_in[21];
    const float* ow2    = (const float*)d_in[22];
    const float* ob2    = (const float*)d_in[23];
    float* out = (float*)d_out;

    // ---- workspace layout ----
    char* base = (char*)d_ws;
    float* x   = (float*)base;                          // 33.55 MB
    char*  H   = base + (size_t)BNROWS*DD*4;            // 33.55 MB (x_hi/x_lo <-> h_hi/h_lo)
    char*  BIG = H + (size_t)BNROWS*DD*4;               // 67.11 MB (t256 / cat)
    float*          x2    = (float*)(BIG + (size_t)BNROWS*2*DD*4);
    float*          g     = (float*)(x2 + BNROWS);
    unsigned short* g_bf  = (unsigned short*)(g + BB*DD);
    unsigned short* hid2_bf = g_bf + BB*DD;
    unsigned short* wbuf  = hid2_bf + BB*FFND;

    unsigned short* x_hi   = (unsigned short*)H;
    unsigned short* x_lo   = x_hi + (size_t)BNROWS*DD;
    unsigned short* t256_bf= (unsigned short*)BIG;
    unsigned short* cat_bf = (unsigned short*)BIG;

    unsigned short* emb_w1t  = wbuf;
    unsigned short* emb_w2t  = emb_w1t + 256*64;
    unsigned short* conv_wt  = emb_w2t + 128*256;
    unsigned short* fc2_wt   = conv_wt + 2*128*256;
    unsigned short* ffn1_wt  = fc2_wt  + 2*128*128;
    unsigned short* ffn2_wt  = ffn1_wt + 2*512*128;
    unsigned short* fc1_wthi = ffn2_wt + 2*128*512;
    unsigned short* fc1_wtlo = fc1_wthi + 2*128*128;
    unsigned short* ow1t     = fc1_wtlo + 2*128*128;
    unsigned short* ow2t     = ow1t + 512*128;

    const dim3 blk(256);

    // ---- all weight transpose-casts (one launch) ----
    prep_all_k<<<1520, blk, 0, stream>>>(
        emb_w1, emb_w2, conv_w, fc2_w, f1_w, f2_w, fc1_w, ow1, ow2,
        emb_w1t, emb_w2t, conv_wt, fc2_wt, ffn1_wt, ffn2_wt,
        fc1_wthi, fc1_wtlo, ow1t, ow2t);

    // ---- Embedding (GEMM + fused LN) ----
    bgemm_ln_k<2,4,true,false,1,true>
        <<<dim3(BNROWS/128), dim3(512), 0, stream>>>
        (nodes, emb_w1t, emb_b1, ln1_g, ln1_b, nullptr, t256_bf, nullptr, nullptr, PP2);
    bgemm_ln_k<2,2,false,true,2,false>
        <<<dim3(BNROWS/128), dim3(256), 0, stream>>>
        (t256_bf, emb_w2t, emb_b2, ln2_g, ln2_b, maskp, x, x_hi, x_lo, 2*DD);

    // ---- ViG blocks ----
    for (int l = 0; l < LLAY; ++l) {
        const float* fc1b = fc1_b + (size_t)l*DD;
        const float* cb   = conv_b + (size_t)l*DD;
        const float* fc2b = fc2_b + (size_t)l*DD;
        const float* b1   = f1_b + (size_t)l*FFND;
        const float* b2   = f2_b + (size_t)l*DD;

        fc1mm_k<<<dim3(BNROWS/128), blk, 0, stream>>>
            (x_hi, x_lo, fc1_wthi + (size_t)l*DD*DD, fc1_wtlo + (size_t)l*DD*DD,
             fc1b, x_hi, x_lo, x2);
        dist_topk_gather_k<<<dim3(BB), dim3(1024), 0, stream>>>
            (x_hi, x_lo, maskp, x2, cat_bf);
        conv_fc2_k<<<dim3(BNROWS/64), blk, 0, stream>>>
            (cat_bf, conv_wt + (size_t)l*DD*2*DD, cb,
             fc2_wt + (size_t)l*DD*DD, fc2b, x, x_hi);
        ffn_k<<<dim3(BNROWS/64), blk, 0, stream>>>
            (x_hi, ffn1_wt + (size_t)l*FFND*DD, b1,
             ffn2_wt + (size_t)l*DD*FFND, b2, maskp, x, x_hi, x_lo);
    }

    // ---- Pool + head (bf16 MFMA) ----
    pool_k<<<BB, 128, 0, stream>>>(x, maskp, g, g_bf);
    bgemm_k<ACT_LRELU,false,false,false,true,false>
        <<<dim3(BB/128, 512/128), blk, 0, stream>>>
        (g_bf, ow1t, ob1, nullptr, nullptr, nullptr, hid2_bf, nullptr, nullptr, BB, 512, DD);
    bgemm_k<ACT_NONE,false,false,true,false,false>
        <<<dim3(BB/128, 2048/128), blk, 0, stream>>>
        (hid2_bf, ow2t, ob2, nullptr, nullptr, out, nullptr, nullptr, nullptr, BB, 2048, 512);
}

// Round 17
// 297.834 us; speedup vs baseline: 1.4315x; 1.1257x over previous
//
#include <hip/hip_runtime.h>
#include <cstdint>

#define BB    256
#define NNODE 256
#define PP2   64
#define DD    128
#define LLAY  2
#define KNN   9
#define FFND  512
#define BNROWS (BB*NNODE)   // 65536

#define LRELU_(v) ((v) >= 0.f ? (v) : 0.01f*(v))

enum { ACT_NONE = 0, ACT_LRELU = 1 };

typedef short  short8_t  __attribute__((ext_vector_type(8)));
typedef float  f32x4     __attribute__((ext_vector_type(4)));
typedef unsigned short us4 __attribute__((ext_vector_type(4)));
typedef unsigned short us8 __attribute__((ext_vector_type(8)));

__device__ inline unsigned short f2bf(float x) {
    unsigned u = __float_as_uint(x);
    unsigned r = (u + 0x7FFFu + ((u >> 16) & 1u)) >> 16;
    return (unsigned short)r;
}
__device__ inline float bf2f(unsigned short h) {
    return __uint_as_float(((unsigned)h) << 16);
}

// async global->LDS, 16B per lane; LDS dest must be wave-uniform base.
__device__ inline void gload16(const void* src, void* dst) {
    __builtin_amdgcn_global_load_lds(
        (const __attribute__((address_space(1))) void*)src,
        (__attribute__((address_space(3))) void*)dst, 16, 0, 0);
}

// Stage a BK=64 bf16 tile (ROWS x 64 elems, 128B rows) from row-major global
// (element stride Kel, starting col k0) into LINEAR LDS via global_load_lds.
// Source address carries the inverse XOR swizzle; reads apply the same XOR.
template<int ROWS, int WAVES>
__device__ inline void stage64g(const unsigned short* __restrict__ g, size_t rowbase,
                                int Kel, int k0, unsigned short* lds, int w, int lane)
{
    constexpr int PER = (ROWS*128/1024) / WAVES;
    #pragma unroll
    for (int i = 0; i < PER; ++i) {
        const int inst = w + i*WAVES;                 // wave-uniform
        const unsigned o  = (unsigned)inst*1024u + (unsigned)lane*16u;
        const int      r  = (int)(o >> 7);
        const unsigned cb = o & 127u;
        const unsigned cs = cb ^ ((unsigned)(r & 7) << 4);
        gload16((const char*)(g + (rowbase + (size_t)r)*(size_t)Kel + k0) + cs,
                (char*)lds + (size_t)inst*1024u);
    }
}

// swizzled fragment read from a linear BK=64 tile
__device__ inline short8_t frag64(const unsigned short* lds, int r, int cb) {
    return *reinterpret_cast<const short8_t*>(
        (const char*)lds + (size_t)r*128 + (unsigned)(cb ^ ((r & 7) << 4)));
}

// swizzled 16B (8 cols) read from a BK=64 tile at column-byte cb (mult of 16)
__device__ inline us8 read8sw(const unsigned short* lds, int r, unsigned cb) {
    return *reinterpret_cast<const us8*>(
        (const char*)lds + (size_t)r*128 + (cb ^ ((unsigned)(r & 7) << 4)));
}

// 16-lane-group min (per DPP row); result in ALL lanes of each 16-group.
__device__ inline unsigned grp16_min_u32(unsigned v) {
    unsigned t;
    t = (unsigned)__builtin_amdgcn_update_dpp(-1, (int)v, 0xB1,  0xF, 0xF, false); v = t < v ? t : v; // quad_perm [1,0,3,2]
    t = (unsigned)__builtin_amdgcn_update_dpp(-1, (int)v, 0x4E,  0xF, 0xF, false); v = t < v ? t : v; // quad_perm [2,3,0,1]
    t = (unsigned)__builtin_amdgcn_update_dpp(-1, (int)v, 0x124, 0xF, 0xF, false); v = t < v ? t : v; // row_ror:4
    t = (unsigned)__builtin_amdgcn_update_dpp(-1, (int)v, 0x128, 0xF, 0xF, false); v = t < v ? t : v; // row_ror:8
    return v;
}

// 16-lane (DPP row) sum; result valid in lane 15 of each 16-lane row.
__device__ inline float dpp_rowsum16(float v) {
    float t;
    t = __uint_as_float((unsigned)__builtin_amdgcn_update_dpp(0, (int)__float_as_uint(v), 0x111, 0xF, 0xF, false)); v += t;
    t = __uint_as_float((unsigned)__builtin_amdgcn_update_dpp(0, (int)__float_as_uint(v), 0x112, 0xF, 0xF, false)); v += t;
    t = __uint_as_float((unsigned)__builtin_amdgcn_update_dpp(0, (int)__float_as_uint(v), 0x114, 0xF, 0xF, false)); v += t;
    t = __uint_as_float((unsigned)__builtin_amdgcn_update_dpp(0, (int)__float_as_uint(v), 0x118, 0xF, 0xF, false)); v += t;
    return v;
}

// ---------------------------------------------------------------------------
// bf16 MFMA GEMM, BK=64, global_load_lds staging.
// ---------------------------------------------------------------------------
template<int ACT, bool RES, bool MASK, bool OUTF, bool OUTB, bool OUTS>
__global__ __launch_bounds__(256)
void bgemm_k(const unsigned short* __restrict__ A,
             const unsigned short* __restrict__ W,
             const float* __restrict__ bias,
             const float* __restrict__ resp,
             const int* __restrict__ mask,
             float* __restrict__ Cf, unsigned short* __restrict__ Cb,
             unsigned short* Ohi, unsigned short* Olo,
             int M, int N, int K)
{
    __shared__ __align__(16) unsigned short As[128*64];
    __shared__ __align__(16) unsigned short Bs[128*64];

    const int tid  = threadIdx.x;
    const int lane = tid & 63;
    const int w    = tid >> 6;
    const int wr   = w >> 1, wc = w & 1;
    const int row0 = blockIdx.x * 128;
    const int col0 = blockIdx.y * 128;
    const int l15  = lane & 15;
    const int ko   = lane >> 4;

    f32x4 acc[4][4];
    #pragma unroll
    for (int m = 0; m < 4; ++m)
        #pragma unroll
        for (int n = 0; n < 4; ++n) acc[m][n] = (f32x4){0.f,0.f,0.f,0.f};

    for (int k0 = 0; k0 < K; k0 += 64) {
        stage64g<128,4>(A, (size_t)row0, K, k0, As, w, lane);
        stage64g<128,4>(W, (size_t)col0, K, k0, Bs, w, lane);
        __syncthreads();
        #pragma unroll
        for (int ks = 0; ks < 2; ++ks) {
            short8_t aF[4], bF[4];
            #pragma unroll
            for (int m = 0; m < 4; ++m)
                aF[m] = frag64(As, wr*64 + m*16 + l15, ks*64 + ko*16);
            #pragma unroll
            for (int n = 0; n < 4; ++n)
                bF[n] = frag64(Bs, wc*64 + n*16 + l15, ks*64 + ko*16);
            #pragma unroll
            for (int m = 0; m < 4; ++m)
                #pragma unroll
                for (int n = 0; n < 4; ++n)
                    acc[m][n] = __builtin_amdgcn_mfma_f32_16x16x32_bf16(aF[m], bF[n], acc[m][n], 0, 0, 0);
        }
        __syncthreads();
    }

    #pragma unroll
    for (int m = 0; m < 4; ++m) {
        const int rbase = row0 + wr*64 + m*16 + ko*4;
        #pragma unroll
        for (int n = 0; n < 4; ++n) {
            const int col = col0 + wc*64 + n*16 + l15;
            const float bv = bias[col];
            #pragma unroll
            for (int r = 0; r < 4; ++r) {
                const int row = rbase + r;
                float v = acc[m][n][r] + bv;
                if constexpr (ACT == ACT_LRELU) v = LRELU_(v);
                if constexpr (RES)  v += resp[(size_t)row*N + col];
                if constexpr (MASK) v *= (mask[row] != 0) ? 1.f : 0.f;
                if constexpr (OUTF) Cf[(size_t)row*N + col] = v;
                if constexpr (OUTB) Cb[(size_t)row*N + col] = f2bf(v);
                if constexpr (OUTS) {
                    unsigned short h = f2bf(v);
                    Ohi[(size_t)row*N + col] = h;
                    Olo[(size_t)row*N + col] = f2bf(v - bf2f(h));
                }
            }
        }
    }
}

// ---------------------------------------------------------------------------
// bf16 MFMA GEMM fused with full-row LayerNorm epilogue (BK=64).
// AF32: A fp32, cast during (reg) staging into the same linear-swz layout.
// ---------------------------------------------------------------------------
template<int WR, int WC, bool DO_LRELU, bool MASKMUL, int MODE, bool AF32>
__global__ __launch_bounds__(WR*WC*64)
void bgemm_ln_k(const void* __restrict__ Ap,
                const unsigned short* __restrict__ W,
                const float* __restrict__ bias,
                const float* __restrict__ gam,
                const float* __restrict__ bet,
                const int* __restrict__ mask,
                void* __restrict__ outv,
                unsigned short* __restrict__ ohi, unsigned short* __restrict__ olo,
                int K)
{
    constexpr int BM = WR*64;
    constexpr int BN = WC*64;
    constexpr int THREADS = WR*WC*64;
    constexpr int WAVES = THREADS/64;
    __shared__ __align__(16) unsigned short As[BM*64];
    __shared__ __align__(16) unsigned short Bs[BN*64];
    __shared__ float red_s[WC][BM];
    __shared__ float red_q[WC][BM];
    __shared__ float mu_l[BM];
    __shared__ float rs_l[BM];

    const int tid  = threadIdx.x;
    const int lane = tid & 63;
    const int w    = tid >> 6;
    const int wr   = w / WC, wc = w % WC;
    const int row0 = blockIdx.x * BM;
    const int l15  = lane & 15;
    const int ko   = lane >> 4;

    f32x4 acc[4][4];
    #pragma unroll
    for (int m = 0; m < 4; ++m)
        #pragma unroll
        for (int n = 0; n < 4; ++n) acc[m][n] = (f32x4){0.f,0.f,0.f,0.f};

    for (int k0 = 0; k0 < K; k0 += 64) {
        if constexpr (AF32) {
            const float* Af = (const float*)Ap;
            constexpr int CH = (BM*8)/THREADS;    // 16B chunks per thread
            #pragma unroll
            for (int i = 0; i < CH; ++i) {
                const int q = i*THREADS + tid;
                const unsigned o  = (unsigned)q*16u;
                const int      r  = (int)(o >> 7);
                const unsigned cb = o & 127u;
                const unsigned cs = cb ^ ((unsigned)(r & 7) << 4);
                const float* src = Af + (size_t)(row0 + r)*K + k0 + (cs >> 1);
                const float4 f0 = *reinterpret_cast<const float4*>(src);
                const float4 f1 = *reinterpret_cast<const float4*>(src + 4);
                short8_t v;
                v[0]=(short)f2bf(f0.x); v[1]=(short)f2bf(f0.y); v[2]=(short)f2bf(f0.z); v[3]=(short)f2bf(f0.w);
                v[4]=(short)f2bf(f1.x); v[5]=(short)f2bf(f1.y); v[6]=(short)f2bf(f1.z); v[7]=(short)f2bf(f1.w);
                *reinterpret_cast<short8_t*>((char*)As + o) = v;
            }
        } else {
            stage64g<BM,WAVES>((const unsigned short*)Ap, (size_t)row0, K, k0, As, w, lane);
        }
        stage64g<BN,WAVES>(W, 0, K, k0, Bs, w, lane);
        __syncthreads();
        #pragma unroll
        for (int ks = 0; ks < 2; ++ks) {
            short8_t aF[4], bF[4];
            #pragma unroll
            for (int m = 0; m < 4; ++m)
                aF[m] = frag64(As, wr*64 + m*16 + l15, ks*64 + ko*16);
            #pragma unroll
            for (int n = 0; n < 4; ++n)
                bF[n] = frag64(Bs, wc*64 + n*16 + l15, ks*64 + ko*16);
            #pragma unroll
            for (int m = 0; m < 4; ++m)
                #pragma unroll
                for (int n = 0; n < 4; ++n)
                    acc[m][n] = __builtin_amdgcn_mfma_f32_16x16x32_bf16(aF[m], bF[n], acc[m][n], 0, 0, 0);
        }
        __syncthreads();
    }

    float bv[4];
    #pragma unroll
    for (int n = 0; n < 4; ++n) bv[n] = bias[wc*64 + n*16 + l15];
    #pragma unroll
    for (int m = 0; m < 4; ++m)
        #pragma unroll
        for (int n = 0; n < 4; ++n)
            #pragma unroll
            for (int r = 0; r < 4; ++r) acc[m][n][r] += bv[n];

    #pragma unroll
    for (int m = 0; m < 4; ++m) {
        #pragma unroll
        for (int r = 0; r < 4; ++r) {
            float s = acc[m][0][r] + acc[m][1][r] + acc[m][2][r] + acc[m][3][r];
            float q = acc[m][0][r]*acc[m][0][r] + acc[m][1][r]*acc[m][1][r]
                    + acc[m][2][r]*acc[m][2][r] + acc[m][3][r]*acc[m][3][r];
            s = dpp_rowsum16(s);
            q = dpp_rowsum16(q);
            if (l15 == 15) {
                int rl = wr*64 + m*16 + ko*4 + r;
                red_s[wc][rl] = s;
                red_q[wc][rl] = q;
            }
        }
    }
    __syncthreads();
    if (tid < BM) {
        float s = 0.f, q = 0.f;
        #pragma unroll
        for (int c2 = 0; c2 < WC; ++c2) { s += red_s[c2][tid]; q += red_q[c2][tid]; }
        float mu  = s * (1.0f/BN);
        float var = q * (1.0f/BN) - mu*mu;
        mu_l[tid] = mu;
        rs_l[tid] = rsqrtf(fmaxf(var, 0.f) + 1e-5f);
    }
    __syncthreads();

    float gm[4], bt[4];
    #pragma unroll
    for (int n = 0; n < 4; ++n) {
        int col = wc*64 + n*16 + l15;
        gm[n] = gam[col]; bt[n] = bet[col];
    }
    #pragma unroll
    for (int m = 0; m < 4; ++m) {
        #pragma unroll
        for (int r = 0; r < 4; ++r) {
            const int rl  = wr*64 + m*16 + ko*4 + r;
            const int row = row0 + rl;
            const float mu = mu_l[rl], rs = rs_l[rl];
            float mf = 1.f;
            if constexpr (MASKMUL) mf = (mask[row] != 0) ? 1.f : 0.f;
            #pragma unroll
            for (int n = 0; n < 4; ++n) {
                const int col = wc*64 + n*16 + l15;
                float y = (acc[m][n][r] - mu) * rs * gm[n] + bt[n];
                if constexpr (DO_LRELU) y = LRELU_(y);
                if constexpr (MASKMUL)  y *= mf;
                if constexpr (MODE == 1) {
                    ((unsigned short*)outv)[(size_t)row*BN + col] = f2bf(y);
                } else {
                    ((float*)outv)[(size_t)row*BN + col] = y;
                    unsigned short h = f2bf(y);
                    ohi[(size_t)row*BN + col] = h;
                    olo[(size_t)row*BN + col] = f2bf(y - bf2f(h));
                }
            }
        }
    }
}

// ---------------------------------------------------------------------------
// fc1 split-bf16 MFMA GEMM, 3 phases, BK=64, in-place OK, fused rowsq(x2).
// ---------------------------------------------------------------------------
__global__ __launch_bounds__(256)
void fc1mm_k(const unsigned short* Ahi, const unsigned short* Alo,
             const unsigned short* __restrict__ Bhi, const unsigned short* __restrict__ Blo,
             const float* __restrict__ bias,
             unsigned short* Ohi, unsigned short* Olo,
             float* __restrict__ x2out)
{
    __shared__ __align__(16) unsigned short As[128*64];
    __shared__ __align__(16) unsigned short Bs[128*64];
    __shared__ float red_q[2][128];

    const int tid  = threadIdx.x;
    const int lane = tid & 63;
    const int w    = tid >> 6;
    const int wr   = w >> 1, wc = w & 1;
    const int row0 = blockIdx.x * 128;
    const int l15  = lane & 15;
    const int ko   = lane >> 4;

    f32x4 acc[4][4];
    #pragma unroll
    for (int m = 0; m < 4; ++m)
        #pragma unroll
        for (int n = 0; n < 4; ++n) acc[m][n] = (f32x4){0.f,0.f,0.f,0.f};

    for (int kk = 0; kk < 384; kk += 64) {
        const int p  = kk >> 7;        // 0,0,1,1,2,2
        const int kl = kk & 127;
        const unsigned short* Ap2 = (p == 1) ? Alo : Ahi;
        const unsigned short* Bp2 = (p == 2) ? Blo : Bhi;
        stage64g<128,4>(Ap2, (size_t)row0, DD, kl, As, w, lane);
        stage64g<128,4>(Bp2, 0, DD, kl, Bs, w, lane);
        __syncthreads();
        #pragma unroll
        for (int ks = 0; ks < 2; ++ks) {
            short8_t aF[4], bF[4];
            #pragma unroll
            for (int m = 0; m < 4; ++m)
                aF[m] = frag64(As, wr*64 + m*16 + l15, ks*64 + ko*16);
            #pragma unroll
            for (int n = 0; n < 4; ++n)
                bF[n] = frag64(Bs, wc*64 + n*16 + l15, ks*64 + ko*16);
            #pragma unroll
            for (int m = 0; m < 4; ++m)
                #pragma unroll
                for (int n = 0; n < 4; ++n)
                    acc[m][n] = __builtin_amdgcn_mfma_f32_16x16x32_bf16(aF[m], bF[n], acc[m][n], 0, 0, 0);
        }
        __syncthreads();
    }

    float qacc[4][4];
    #pragma unroll
    for (int m = 0; m < 4; ++m) {
        const int rbase = row0 + wr*64 + m*16 + ko*4;
        #pragma unroll
        for (int r = 0; r < 4; ++r) qacc[m][r] = 0.f;
        #pragma unroll
        for (int n = 0; n < 4; ++n) {
            const int col = wc*64 + n*16 + l15;
            const float bv = bias[col];
            #pragma unroll
            for (int r = 0; r < 4; ++r) {
                const int row = rbase + r;
                float v = acc[m][n][r] + bv;
                unsigned short h = f2bf(v);
                unsigned short l = f2bf(v - bf2f(h));
                Ohi[(size_t)row*DD + col] = h;
                Olo[(size_t)row*DD + col] = l;
                float vv = bf2f(h) + bf2f(l);
                qacc[m][r] += vv*vv;
            }
        }
    }
    #pragma unroll
    for (int m = 0; m < 4; ++m)
        #pragma unroll
        for (int r = 0; r < 4; ++r) {
            float q = dpp_rowsum16(qacc[m][r]);
            if (l15 == 15) red_q[wc][wr*64 + m*16 + ko*4 + r] = q;
        }
    __syncthreads();
    if (tid < 128) x2out[row0 + tid] = red_q[0][tid] + red_q[1][tid];
}

// ---------------------------------------------------------------------------
// Fused distance + top-9 + gather: ONE block per batch (1024 thr, 16 waves).
// Per-wave pipeline after the stage barrier (no further barriers). Gather
// uses 16B/lane swizzled reads (conflict-free: 8 lanes cover a full row).
// ---------------------------------------------------------------------------
__global__ __launch_bounds__(1024)
void dist_topk_gather_k(const unsigned short* __restrict__ hhi,
                        const unsigned short* __restrict__ hlo,
                        const int* __restrict__ mask,
                        const float* __restrict__ x2,
                        unsigned short* __restrict__ cat)
{
    __shared__ __align__(16) unsigned short BsH[2][NNODE*64];   // 64KB
    __shared__ __align__(16) unsigned short BsL[2][NNODE*64];   // 64KB
    __shared__ unsigned char idx_s[NNODE*KNN];
    __shared__ unsigned char msk_s[NNODE];

    const int b    = blockIdx.x;
    const int tid  = threadIdx.x;
    const int lane = tid & 63;
    const int w    = tid >> 6;          // 0..15
    const int l15  = lane & 15;
    const int g    = lane >> 4;         // 0..3

    const unsigned short* Hhi = hhi + (size_t)b*NNODE*DD;
    const unsigned short* Hlo = hlo + (size_t)b*NNODE*DD;
    const float* x2b = x2 + b*NNODE;
    const int*   mkb = mask + b*NNODE;

    stage64g<NNODE,16>(Hhi, 0, DD, 0,  &BsH[0][0], w, lane);
    stage64g<NNODE,16>(Hhi, 0, DD, 64, &BsH[1][0], w, lane);
    stage64g<NNODE,16>(Hlo, 0, DD, 0,  &BsL[0][0], w, lane);
    stage64g<NNODE,16>(Hlo, 0, DD, 64, &BsL[1][0], w, lane);
    if (tid < NNODE) msk_s[tid] = (mkb[tid] != 0) ? 1 : 0;
    __syncthreads();

    const int arow = w*16 + l15;        // 0..255

    f32x4 acc[16];
    #pragma unroll
    for (int n = 0; n < 16; ++n) acc[n] = (f32x4){0.f,0.f,0.f,0.f};

    #pragma unroll
    for (int kt = 0; kt < 2; ++kt) {
        #pragma unroll
        for (int ks = 0; ks < 2; ++ks) {
            short8_t aH = frag64(&BsH[kt][0], arow, ks*64 + g*16);
            short8_t aL = frag64(&BsL[kt][0], arow, ks*64 + g*16);
            #pragma unroll
            for (int n = 0; n < 16; ++n) {
                int brow = n*16 + l15;
                short8_t bH = frag64(&BsH[kt][0], brow, ks*64 + g*16);
                short8_t bL = frag64(&BsL[kt][0], brow, ks*64 + g*16);
                acc[n] = __builtin_amdgcn_mfma_f32_16x16x32_bf16(aH, bH, acc[n], 0, 0, 0); // hi.hi
                acc[n] = __builtin_amdgcn_mfma_f32_16x16x32_bf16(aL, bH, acc[n], 0, 0, 0); // lo.hi
                acc[n] = __builtin_amdgcn_mfma_f32_16x16x32_bf16(aH, bL, acc[n], 0, 0, 0); // hi.lo
            }
        }
    }

    float x2c[16]; unsigned mk[16];
    #pragma unroll
    for (int n = 0; n < 16; ++n) {
        int col = n*16 + l15;
        x2c[n] = x2b[col];
        mk[n]  = (unsigned)msk_s[col];
    }

    #pragma unroll
    for (int r = 0; r < 4; ++r) {
        const int lrow = w*16 + g*4 + r;          // this wave's rows only
        const float x2r = x2b[lrow];
        unsigned key[16];
        #pragma unroll
        for (int n = 0; n < 16; ++n) {
            float v = x2r + x2c[n] - 2.0f*acc[n][r];
            if (!mk[n]) v = 1e10f;
            unsigned u = __float_as_uint(v);
            u = (u & 0x80000000u) ? ~u : (u | 0x80000000u);
            key[n] = (u & 0xFFFFFF00u) | (unsigned)(n*16 + l15);
        }
        for (int it = 0; it < KNN; ++it) {
            unsigned a0 = key[0]  < key[1]  ? key[0]  : key[1];
            unsigned a1 = key[2]  < key[3]  ? key[2]  : key[3];
            unsigned a2 = key[4]  < key[5]  ? key[4]  : key[5];
            unsigned a3 = key[6]  < key[7]  ? key[6]  : key[7];
            unsigned a4 = key[8]  < key[9]  ? key[8]  : key[9];
            unsigned a5 = key[10] < key[11] ? key[10] : key[11];
            unsigned a6 = key[12] < key[13] ? key[12] : key[13];
            unsigned a7 = key[14] < key[15] ? key[14] : key[15];
            unsigned b0 = a0 < a1 ? a0 : a1;
            unsigned b1 = a2 < a3 ? a2 : a3;
            unsigned b2 = a4 < a5 ? a4 : a5;
            unsigned b3 = a6 < a7 ? a6 : a7;
            unsigned c0 = b0 < b1 ? b0 : b1;
            unsigned c1 = b2 < b3 ? b2 : b3;
            unsigned lmin = c0 < c1 ? c0 : c1;
            unsigned gmin = grp16_min_u32(lmin);
            if (l15 == 0) idx_s[lrow*KNN + it] = (unsigned char)(gmin & 0xFFu);
            #pragma unroll
            for (int n = 0; n < 16; ++n)
                if (key[n] == gmin) key[n] = 0xFFFFFFFFu;
        }
    }
    // NO block barrier: gather touches only this wave's rows (same-wave DS order).

    // ---- gather + max-relative: 16B/lane, 8 lanes cover one full tile-row ----
    const int gi = lane & 7;                       // granule 0..7 (8 cols)
    const unsigned cb = (unsigned)(gi * 16);       // byte col within tile
    #pragma unroll
    for (int kt = 0; kt < 2; ++kt) {
        #pragma unroll
        for (int p = 0; p < 2; ++p) {
            const int rl = w*16 + p*8 + (lane >> 3);   // this wave's row
            us8 h8 = read8sw(&BsH[kt][0], rl, cb);
            us8 l8 = read8sw(&BsL[kt][0], rl, cb);
            float hi[8], m[8];
            #pragma unroll
            for (int d = 0; d < 8; ++d) { hi[d] = bf2f(h8[d]) + bf2f(l8[d]); m[d] = -1e9f; }
            bool any = false;
            #pragma unroll
            for (int q = 0; q < KNN; ++q) {
                int j = idx_s[rl*KNN + q];
                if (msk_s[j]) {
                    any = true;
                    us8 a = read8sw(&BsH[kt][0], j, cb);
                    us8 o = read8sw(&BsL[kt][0], j, cb);
                    #pragma unroll
                    for (int d = 0; d < 8; ++d)
                        m[d] = fmaxf(m[d], bf2f(a[d]) + bf2f(o[d]) - hi[d]);
                }
            }
            us8 o1, o2;
            #pragma unroll
            for (int d = 0; d < 8; ++d) {
                o1[d] = f2bf(hi[d]);
                o2[d] = any ? f2bf(m[d]) : (unsigned short)0;
            }
            const size_t rowbase = (size_t)(b*NNODE + rl)*(2*DD);
            const int c0 = kt*64 + gi*8;
            *reinterpret_cast<us8*>(&cat[rowbase + c0])      = o1;
            *reinterpret_cast<us8*>(&cat[rowbase + DD + c0]) = o2;
        }
    }
}

// ---------------------------------------------------------------------------
// Fused conv + fc2 + FFN: one block = 64 rows, x stays on-chip end to end.
//   h2 = lrelu(cat@Wc^T + cb);  xn = h2@W2c^T + fb + x   (xn in REGISTERS)
//   Xs = bf16(xn) in LDS;  x_out = lrelu(Xs@W1^T+b1)@W2f^T + b2 + xn, masked.
// LDS 72KB -> 2 blocks/CU. Batched double-Bs staging, single barrier each.
// ---------------------------------------------------------------------------
__global__ __launch_bounds__(256)
void conv_ffn_k(const unsigned short* __restrict__ cat,
                const unsigned short* __restrict__ Wc,   // [128][256]
                const float* __restrict__ cb,
                const unsigned short* __restrict__ W2c,  // [128][128] (fc2)
                const float* __restrict__ fb,
                const unsigned short* __restrict__ W1,   // [512][128] (ffn1)
                const float* __restrict__ b1,
                const unsigned short* __restrict__ W2f,  // [128][512] (ffn2)
                const float* __restrict__ b2,
                const int* __restrict__ mask,
                float* __restrict__ x,
                unsigned short* __restrict__ xhi_out,
                unsigned short* __restrict__ xlo_out)
{
    __shared__ __align__(16) unsigned short As[64*64];       // 8KB  (cat k-tile)
    __shared__ __align__(16) unsigned short Bs[2][128*64];   // 32KB (weight k-tiles)
    __shared__ __align__(16) unsigned short h2s[2][64*64];   // 16KB (hidden chunk)
    __shared__ __align__(16) unsigned short Xs[2][64*64];    // 16KB (xn bf16)

    const int tid  = threadIdx.x;
    const int lane = tid & 63;
    const int w    = tid >> 6;      // 0..3: wave col group (cols w*32..w*32+31)
    const int row0 = blockIdx.x * 64;
    const int l15  = lane & 15;
    const int ko   = lane >> 4;

    // ======== conv: accc = cat @ Wc^T ========
    f32x4 accc[4][2];
    #pragma unroll
    for (int m = 0; m < 4; ++m)
        #pragma unroll
        for (int n = 0; n < 2; ++n) accc[m][n] = (f32x4){0.f,0.f,0.f,0.f};

    for (int k0 = 0; k0 < 256; k0 += 64) {
        stage64g<64,4>(cat, (size_t)row0, 256, k0, As, w, lane);
        stage64g<128,4>(Wc, 0, 256, k0, &Bs[0][0], w, lane);
        __syncthreads();
        #pragma unroll
        for (int ks = 0; ks < 2; ++ks) {
            short8_t aF[4], bF[2];
            #pragma unroll
            for (int m = 0; m < 4; ++m)
                aF[m] = frag64(As, m*16 + l15, ks*64 + ko*16);
            #pragma unroll
            for (int n = 0; n < 2; ++n)
                bF[n] = frag64(&Bs[0][0], w*32 + n*16 + l15, ks*64 + ko*16);
            #pragma unroll
            for (int m = 0; m < 4; ++m)
                #pragma unroll
                for (int n = 0; n < 2; ++n)
                    accc[m][n] = __builtin_amdgcn_mfma_f32_16x16x32_bf16(aF[m], bF[n], accc[m][n], 0, 0, 0);
        }
        __syncthreads();
    }

    // h2 = lrelu(accc + cb) -> swizzled LDS
    {
        const int kt = w >> 1;
        #pragma unroll
        for (int n = 0; n < 2; ++n) {
            const int col = w*32 + n*16 + l15;
            const float bv = cb[col];
            const unsigned bc = (unsigned)(((w & 1)*32 + n*16 + l15) * 2);
            #pragma unroll
            for (int m = 0; m < 4; ++m) {
                #pragma unroll
                for (int r = 0; r < 4; ++r) {
                    const int row = m*16 + ko*4 + r;
                    float v = LRELU_(accc[m][n][r] + bv);
                    *(unsigned short*)((char*)&h2s[kt][0] + row*128
                        + (bc ^ ((unsigned)(row & 7) << 4))) = f2bf(v);
                }
            }
        }
    }

    // ======== fc2: xn = h2 @ W2c^T + fb + x  (registers) ========
    stage64g<128,4>(W2c, 0, 128, 0,  &Bs[0][0], w, lane);
    stage64g<128,4>(W2c, 0, 128, 64, &Bs[1][0], w, lane);
    __syncthreads();   // drains W2c stage + h2s writes

    f32x4 accx[4][2];
    #pragma unroll
    for (int m = 0; m < 4; ++m)
        #pragma unroll
        for (int n = 0; n < 2; ++n) accx[m][n] = (f32x4){0.f,0.f,0.f,0.f};
    #pragma unroll
    for (int kt = 0; kt < 2; ++kt) {
        #pragma unroll
        for (int ks = 0; ks < 2; ++ks) {
            short8_t aF[4], bF[2];
            #pragma unroll
            for (int m = 0; m < 4; ++m)
                aF[m] = frag64(&h2s[kt][0], m*16 + l15, ks*64 + ko*16);
            #pragma unroll
            for (int n = 0; n < 2; ++n)
                bF[n] = frag64(&Bs[kt][0], w*32 + n*16 + l15, ks*64 + ko*16);
            #pragma unroll
            for (int m = 0; m < 4; ++m)
                #pragma unroll
                for (int n = 0; n < 2; ++n)
                    accx[m][n] = __builtin_amdgcn_mfma_f32_16x16x32_bf16(aF[m], bF[n], accx[m][n], 0, 0, 0);
        }
    }

    // xn fp32 in regs; bf16 image -> Xs (swizzled)
    float xn[4][2][4];
    {
        const int kt = w >> 1;
        #pragma unroll
        for (int n = 0; n < 2; ++n) {
            const int col = w*32 + n*16 + l15;
            const float bv = fb[col];
            const unsigned bc = (unsigned)(((w & 1)*32 + n*16 + l15) * 2);
            #pragma unroll
            for (int m = 0; m < 4; ++m) {
                #pragma unroll
                for (int r = 0; r < 4; ++r) {
                    const int row = m*16 + ko*4 + r;
                    float v = accx[m][n][r] + bv + x[(size_t)(row0 + row)*DD + col];
                    xn[m][n][r] = v;
                    *(unsigned short*)((char*)&Xs[kt][0] + row*128
                        + (bc ^ ((unsigned)(row & 7) << 4))) = f2bf(v);
                }
            }
        }
    }
    __syncthreads();   // Xs writes visible; Bs(W2c)+h2s reads complete

    // ======== FFN: acc2 = lrelu(Xs@W1^T+b1) @ W2f^T ========
    f32x4 acc2[4][2];
    #pragma unroll
    for (int m = 0; m < 4; ++m)
        #pragma unroll
        for (int n = 0; n < 2; ++n) acc2[m][n] = (f32x4){0.f,0.f,0.f,0.f};

    for (int c = 0; c < 4; ++c) {
        stage64g<128,4>(W1, (size_t)(c*128), DD, 0,  &Bs[0][0], w, lane);
        stage64g<128,4>(W1, (size_t)(c*128), DD, 64, &Bs[1][0], w, lane);
        __syncthreads();

        f32x4 acc1[4][2];
        #pragma unroll
        for (int m = 0; m < 4; ++m)
            #pragma unroll
            for (int n = 0; n < 2; ++n) acc1[m][n] = (f32x4){0.f,0.f,0.f,0.f};
        #pragma unroll
        for (int kt = 0; kt < 2; ++kt) {
            #pragma unroll
            for (int ks = 0; ks < 2; ++ks) {
                short8_t aF[4], bF[2];
                #pragma unroll
                for (int m = 0; m < 4; ++m)
                    aF[m] = frag64(&Xs[kt][0], m*16 + l15, ks*64 + ko*16);
                #pragma unroll
                for (int n = 0; n < 2; ++n)
                    bF[n] = frag64(&Bs[kt][0], w*32 + n*16 + l15, ks*64 + ko*16);
                #pragma unroll
                for (int m = 0; m < 4; ++m)
                    #pragma unroll
                    for (int n = 0; n < 2; ++n)
                        acc1[m][n] = __builtin_amdgcn_mfma_f32_16x16x32_bf16(aF[m], bF[n], acc1[m][n], 0, 0, 0);
            }
        }

        {
            const int kt = w >> 1;
            #pragma unroll
            for (int n = 0; n < 2; ++n) {
                const int col = w*32 + n*16 + l15;            // 0..127 within chunk
                const float bv = b1[c*128 + col];
                const unsigned bc = (unsigned)(((w & 1)*32 + n*16 + l15) * 2);
                #pragma unroll
                for (int m = 0; m < 4; ++m) {
                    #pragma unroll
                    for (int r = 0; r < 4; ++r) {
                        const int row = m*16 + ko*4 + r;
                        float v = LRELU_(acc1[m][n][r] + bv);
                        *(unsigned short*)((char*)&h2s[kt][0] + row*128
                            + (bc ^ ((unsigned)(row & 7) << 4))) = f2bf(v);
                    }
                }
            }
        }
        __syncthreads();   // Bs(W1) reads + h2 writes complete

        stage64g<128,4>(W2f, 0, FFND, c*128,      &Bs[0][0], w, lane);
        stage64g<128,4>(W2f, 0, FFND, c*128 + 64, &Bs[1][0], w, lane);
        __syncthreads();

        #pragma unroll
        for (int kt2 = 0; kt2 < 2; ++kt2) {
            #pragma unroll
            for (int ks = 0; ks < 2; ++ks) {
                short8_t aF[4], bF[2];
                #pragma unroll
                for (int m = 0; m < 4; ++m)
                    aF[m] = frag64(&h2s[kt2][0], m*16 + l15, ks*64 + ko*16);
                #pragma unroll
                for (int n = 0; n < 2; ++n)
                    bF[n] = frag64(&Bs[kt2][0], w*32 + n*16 + l15, ks*64 + ko*16);
                #pragma unroll
                for (int m = 0; m < 4; ++m)
                    #pragma unroll
                    for (int n = 0; n < 2; ++n)
                        acc2[m][n] = __builtin_amdgcn_mfma_f32_16x16x32_bf16(aF[m], bF[n], acc2[m][n], 0, 0, 0);
            }
        }
        __syncthreads();
    }

    // ======== epilogue: x = acc2 + b2 + xn, masked; write x/xhi/xlo ========
    #pragma unroll
    for (int m = 0; m < 4; ++m) {
        const int rbase = row0 + m*16 + ko*4;
        #pragma unroll
        for (int n = 0; n < 2; ++n) {
            const int col = w*32 + n*16 + l15;
            const float bv = b2[col];
            #pragma unroll
            for (int r = 0; r < 4; ++r) {
                const int row = rbase + r;
                float v = acc2[m][n][r] + bv + xn[m][n][r];
                v *= (mask[row] != 0) ? 1.f : 0.f;
                x[(size_t)row*DD + col] = v;
                unsigned short h = f2bf(v);
                xhi_out[(size_t)row*DD + col] = h;
                xlo_out[(size_t)row*DD + col] = f2bf(v - bf2f(h));
            }
        }
    }
}

__global__ __launch_bounds__(128)
void pool_k(const float* __restrict__ x, const int* __restrict__ mask,
            float* __restrict__ g, unsigned short* __restrict__ gbf)
{
    const int b = blockIdx.x, c = threadIdx.x;
    float s = 0.f; int cnt = 0;
    for (int n = 0; n < NNODE; ++n) {
        s += x[((size_t)b*NNODE + n)*DD + c];
        cnt += (mask[b*NNODE + n] != 0) ? 1 : 0;
    }
    float v = s / fmaxf((float)cnt, 1.0f);
    g[b*DD + c] = v;
    gbf[b*DD + c] = f2bf(v);
}

// ---------------------------------------------------------------------------
// All weight transpose-casts in ONE kernel (compile-time job table).
// ---------------------------------------------------------------------------
__global__ __launch_bounds__(256)
void prep_all_k(const float* __restrict__ emb_w1, const float* __restrict__ emb_w2,
                const float* __restrict__ conv_w, const float* __restrict__ fc2_w,
                const float* __restrict__ f1_w,   const float* __restrict__ f2_w,
                const float* __restrict__ fc1_w,  const float* __restrict__ ow1,
                const float* __restrict__ ow2,
                unsigned short* __restrict__ emb_w1t, unsigned short* __restrict__ emb_w2t,
                unsigned short* __restrict__ conv_wt, unsigned short* __restrict__ fc2_wt,
                unsigned short* __restrict__ ffn1_wt, unsigned short* __restrict__ ffn2_wt,
                unsigned short* __restrict__ fc1_wthi, unsigned short* __restrict__ fc1_wtlo,
                unsigned short* __restrict__ ow1t, unsigned short* __restrict__ ow2t)
{
    __shared__ float tile[32][33];
    const int tx = threadIdx.x & 31, ty = threadIdx.x >> 5;

    int bid = blockIdx.x;
    const float* src = nullptr; unsigned short* dst = nullptr; unsigned short* dlo = nullptr;
    int K = 0, N = 0;
    do {
        if (bid < 16)  { src = emb_w1; dst = emb_w1t; K = 64;  N = 256; break; }  bid -= 16;
        if (bid < 32)  { src = emb_w2; dst = emb_w2t; K = 256; N = 128; break; }  bid -= 32;
        if (bid < 64)  { int l = bid >> 5; bid &= 31;
                         src = conv_w + (size_t)l*256*128; dst = conv_wt + (size_t)l*128*256;
                         K = 256; N = 128; break; }                               bid -= 64;
        if (bid < 32)  { int l = bid >> 4; bid &= 15;
                         src = fc2_w + (size_t)l*128*128; dst = fc2_wt + (size_t)l*128*128;
                         K = 128; N = 128; break; }                               bid -= 32;
        if (bid < 128) { int l = bid >> 6; bid &= 63;
                         src = f1_w + (size_t)l*128*512; dst = ffn1_wt + (size_t)l*512*128;
                         K = 128; N = 512; break; }                               bid -= 128;
        if (bid < 128) { int l = bid >> 6; bid &= 63;
                         src = f2_w + (size_t)l*512*128; dst = ffn2_wt + (size_t)l*128*512;
                         K = 512; N = 128; break; }                               bid -= 128;
        if (bid < 32)  { int l = bid >> 4; bid &= 15;
                         src = fc1_w + (size_t)l*128*128;
                         dst = fc1_wthi + (size_t)l*128*128; dlo = fc1_wtlo + (size_t)l*128*128;
                         K = 128; N = 128; break; }                               bid -= 32;
        if (bid < 64)  { src = ow1; dst = ow1t; K = 128; N = 512; break; }        bid -= 64;
        { src = ow2; dst = ow2t; K = 512; N = 2048; }
    } while (0);

    const int nbx = N / 32;
    const int bx = bid % nbx, by = bid / nbx;
    const int k0 = by*32, n0 = bx*32;

    #pragma unroll
    for (int i = ty; i < 32; i += 8)
        tile[i][tx] = src[(size_t)(k0+i)*N + n0+tx];
    __syncthreads();
    #pragma unroll
    for (int i = ty; i < 32; i += 8) {
        float v = tile[tx][i];
        unsigned short h = f2bf(v);
        dst[(size_t)(n0+i)*K + k0+tx] = h;
        if (dlo) dlo[(size_t)(n0+i)*K + k0+tx] = f2bf(v - bf2f(h));
    }
}

// ---------------------------------------------------------------------------
extern "C" void kernel_launch(void* const* d_in, const int* in_sizes, int n_in,
                              void* d_out, int out_size, void* d_ws, size_t ws_size,
                              hipStream_t stream)
{
    const float* nodes  = (const float*)d_in[0];
    const int*   maskp  = (const int*)  d_in[1];
    const float* emb_w1 = (const float*)d_in[2];
    const float* emb_b1 = (const float*)d_in[3];
    const float* ln1_g  = (const float*)d_in[4];
    const float* ln1_b  = (const float*)d_in[5];
    const float* emb_w2 = (const float*)d_in[6];
    const float* emb_b2 = (const float*)d_in[7];
    const float* ln2_g  = (const float*)d_in[8];
    const float* ln2_b  = (const float*)d_in[9];
    const float* fc1_w  = (const float*)d_in[10];
    const float* fc1_b  = (const float*)d_in[11];
    const float* conv_w = (const float*)d_in[12];
    const float* conv_b = (const float*)d_in[13];
    const float* fc2_w  = (const float*)d_in[14];
    const float* fc2_b  = (const float*)d_in[15];
    const float* f1_w   = (const float*)d_in[16];
    const float* f1_b   = (const float*)d_in[17];
    const float* f2_w   = (const float*)d_in[18];
    const float* f2_b   = (const float*)d_in[19];
    const float* ow1    = (const float*)d_in[20];
    const float* ob1    = (const float*)d_in[21];
    const float* ow2    = (const float*)d_in[22];
    const float* ob2    = (const float*)d_in[23];
    float* out = (float*)d_out;

    // ---- workspace layout ----
    char* base = (char*)d_ws;
    float* x   = (float*)base;                          // 33.55 MB
    char*  H   = base + (size_t)BNROWS*DD*4;            // 33.55 MB (x_hi/x_lo <-> h_hi/h_lo)
    char*  BIG = H + (size_t)BNROWS*DD*4;               // 67.11 MB (t256 / cat)
    float*          x2    = (float*)(BIG + (size_t)BNROWS*2*DD*4);
    float*          g     = (float*)(x2 + BNROWS);
    unsigned short* g_bf  = (unsigned short*)(g + BB*DD);
    unsigned short* hid2_bf = g_bf + BB*DD;
    unsigned short* wbuf  = hid2_bf + BB*FFND;

    unsigned short* x_hi   = (unsigned short*)H;
    unsigned short* x_lo   = x_hi + (size_t)BNROWS*DD;
    unsigned short* t256_bf= (unsigned short*)BIG;
    unsigned short* cat_bf = (unsigned short*)BIG;

    unsigned short* emb_w1t  = wbuf;
    unsigned short* emb_w2t  = emb_w1t + 256*64;
    unsigned short* conv_wt  = emb_w2t + 128*256;
    unsigned short* fc2_wt   = conv_wt + 2*128*256;
    unsigned short* ffn1_wt  = fc2_wt  + 2*128*128;
    unsigned short* ffn2_wt  = ffn1_wt + 2*512*128;
    unsigned short* fc1_wthi = ffn2_wt + 2*128*512;
    unsigned short* fc1_wtlo = fc1_wthi + 2*128*128;
    unsigned short* ow1t     = fc1_wtlo + 2*128*128;
    unsigned short* ow2t     = ow1t + 512*128;

    const dim3 blk(256);

    // ---- all weight transpose-casts (one launch) ----
    prep_all_k<<<1520, blk, 0, stream>>>(
        emb_w1, emb_w2, conv_w, fc2_w, f1_w, f2_w, fc1_w, ow1, ow2,
        emb_w1t, emb_w2t, conv_wt, fc2_wt, ffn1_wt, ffn2_wt,
        fc1_wthi, fc1_wtlo, ow1t, ow2t);

    // ---- Embedding (GEMM + fused LN) ----
    bgemm_ln_k<2,4,true,false,1,true>
        <<<dim3(BNROWS/128), dim3(512), 0, stream>>>
        (nodes, emb_w1t, emb_b1, ln1_g, ln1_b, nullptr, t256_bf, nullptr, nullptr, PP2);
    bgemm_ln_k<2,2,false,true,2,false>
        <<<dim3(BNROWS/128), dim3(256), 0, stream>>>
        (t256_bf, emb_w2t, emb_b2, ln2_g, ln2_b, maskp, x, x_hi, x_lo, 2*DD);

    // ---- ViG blocks ----
    for (int l = 0; l < LLAY; ++l) {
        const float* fc1b = fc1_b + (size_t)l*DD;
        const float* cb   = conv_b + (size_t)l*DD;
        const float* fc2b = fc2_b + (size_t)l*DD;
        const float* b1   = f1_b + (size_t)l*FFND;
        const float* b2   = f2_b + (size_t)l*DD;

        fc1mm_k<<<dim3(BNROWS/128), blk, 0, stream>>>
            (x_hi, x_lo, fc1_wthi + (size_t)l*DD*DD, fc1_wtlo + (size_t)l*DD*DD,
             fc1b, x_hi, x_lo, x2);
        dist_topk_gather_k<<<dim3(BB), dim3(1024), 0, stream>>>
            (x_hi, x_lo, maskp, x2, cat_bf);
        conv_ffn_k<<<dim3(BNROWS/64), blk, 0, stream>>>
            (cat_bf, conv_wt + (size_t)l*DD*2*DD, cb,
             fc2_wt + (size_t)l*DD*DD, fc2b,
             ffn1_wt + (size_t)l*FFND*DD, b1,
             ffn2_wt + (size_t)l*DD*FFND, b2, maskp,
             x, x_hi, x_lo);
    }

    // ---- Pool + head (bf16 MFMA) ----
    pool_k<<<BB, 128, 0, stream>>>(x, maskp, g, g_bf);
    bgemm_k<ACT_LRELU,false,false,false,true,false>
        <<<dim3(BB/128, 512/128), blk, 0, stream>>>
        (g_bf, ow1t, ob1, nullptr, nullptr, nullptr, hid2_bf, nullptr, nullptr, BB, 512, DD);
    bgemm_k<ACT_NONE,false,false,true,false,false>
        <<<dim3(BB/128, 2048/128), blk, 0, stream>>>
        (hid2_bf, ow2t, ob2, nullptr, nullptr, out, nullptr, nullptr, nullptr, BB, 2048, 512);
}

// Round 18
// 297.614 us; speedup vs baseline: 1.4326x; 1.0007x over previous
//
#include <hip/hip_runtime.h>
#include <cstdint>

#define BB    256
#define NNODE 256
#define PP2   64
#define DD    128
#define LLAY  2
#define KNN   9
#define FFND  512
#define BNROWS (BB*NNODE)   // 65536

#define LRELU_(v) ((v) >= 0.f ? (v) : 0.01f*(v))

enum { ACT_NONE = 0, ACT_LRELU = 1 };

typedef short  short8_t  __attribute__((ext_vector_type(8)));
typedef float  f32x4     __attribute__((ext_vector_type(4)));
typedef unsigned short us4 __attribute__((ext_vector_type(4)));
typedef unsigned short us8 __attribute__((ext_vector_type(8)));

__device__ inline unsigned short f2bf(float x) {
    unsigned u = __float_as_uint(x);
    unsigned r = (u + 0x7FFFu + ((u >> 16) & 1u)) >> 16;
    return (unsigned short)r;
}
__device__ inline float bf2f(unsigned short h) {
    return __uint_as_float(((unsigned)h) << 16);
}

// async global->LDS, 16B per lane; LDS dest must be wave-uniform base.
__device__ inline void gload16(const void* src, void* dst) {
    __builtin_amdgcn_global_load_lds(
        (const __attribute__((address_space(1))) void*)src,
        (__attribute__((address_space(3))) void*)dst, 16, 0, 0);
}

// Stage a BK=64 bf16 tile (ROWS x 64 elems, 128B rows) from row-major global
// (element stride Kel, starting col k0) into LINEAR LDS via global_load_lds.
// Source address carries the inverse XOR swizzle; reads apply the same XOR.
template<int ROWS, int WAVES>
__device__ inline void stage64g(const unsigned short* __restrict__ g, size_t rowbase,
                                int Kel, int k0, unsigned short* lds, int w, int lane)
{
    constexpr int PER = (ROWS*128/1024) / WAVES;
    #pragma unroll
    for (int i = 0; i < PER; ++i) {
        const int inst = w + i*WAVES;                 // wave-uniform
        const unsigned o  = (unsigned)inst*1024u + (unsigned)lane*16u;
        const int      r  = (int)(o >> 7);
        const unsigned cb = o & 127u;
        const unsigned cs = cb ^ ((unsigned)(r & 7) << 4);
        gload16((const char*)(g + (rowbase + (size_t)r)*(size_t)Kel + k0) + cs,
                (char*)lds + (size_t)inst*1024u);
    }
}

// swizzled fragment read from a linear BK=64 tile
__device__ inline short8_t frag64(const unsigned short* lds, int r, int cb) {
    return *reinterpret_cast<const short8_t*>(
        (const char*)lds + (size_t)r*128 + (unsigned)(cb ^ ((r & 7) << 4)));
}

// swizzled 16B (8 cols) read from a BK=64 tile at column-byte cb (mult of 16)
__device__ inline us8 read8sw(const unsigned short* lds, int r, unsigned cb) {
    return *reinterpret_cast<const us8*>(
        (const char*)lds + (size_t)r*128 + (cb ^ ((unsigned)(r & 7) << 4)));
}

// 16-lane-group min (per DPP row); result in ALL lanes of each 16-group.
__device__ inline unsigned grp16_min_u32(unsigned v) {
    unsigned t;
    t = (unsigned)__builtin_amdgcn_update_dpp(-1, (int)v, 0xB1,  0xF, 0xF, false); v = t < v ? t : v; // quad_perm [1,0,3,2]
    t = (unsigned)__builtin_amdgcn_update_dpp(-1, (int)v, 0x4E,  0xF, 0xF, false); v = t < v ? t : v; // quad_perm [2,3,0,1]
    t = (unsigned)__builtin_amdgcn_update_dpp(-1, (int)v, 0x124, 0xF, 0xF, false); v = t < v ? t : v; // row_ror:4
    t = (unsigned)__builtin_amdgcn_update_dpp(-1, (int)v, 0x128, 0xF, 0xF, false); v = t < v ? t : v; // row_ror:8
    return v;
}

// 16-lane (DPP row) sum; result valid in lane 15 of each 16-lane row.
__device__ inline float dpp_rowsum16(float v) {
    float t;
    t = __uint_as_float((unsigned)__builtin_amdgcn_update_dpp(0, (int)__float_as_uint(v), 0x111, 0xF, 0xF, false)); v += t;
    t = __uint_as_float((unsigned)__builtin_amdgcn_update_dpp(0, (int)__float_as_uint(v), 0x112, 0xF, 0xF, false)); v += t;
    t = __uint_as_float((unsigned)__builtin_amdgcn_update_dpp(0, (int)__float_as_uint(v), 0x114, 0xF, 0xF, false)); v += t;
    t = __uint_as_float((unsigned)__builtin_amdgcn_update_dpp(0, (int)__float_as_uint(v), 0x118, 0xF, 0xF, false)); v += t;
    return v;
}

// ---------------------------------------------------------------------------
// bf16 MFMA GEMM, BK=64, global_load_lds staging. (head only now)
// ---------------------------------------------------------------------------
template<int ACT, bool RES, bool MASK, bool OUTF, bool OUTB, bool OUTS>
__global__ __launch_bounds__(256)
void bgemm_k(const unsigned short* __restrict__ A,
             const unsigned short* __restrict__ W,
             const float* __restrict__ bias,
             const float* __restrict__ resp,
             const int* __restrict__ mask,
             float* __restrict__ Cf, unsigned short* __restrict__ Cb,
             unsigned short* Ohi, unsigned short* Olo,
             int M, int N, int K)
{
    __shared__ __align__(16) unsigned short As[128*64];
    __shared__ __align__(16) unsigned short Bs[128*64];

    const int tid  = threadIdx.x;
    const int lane = tid & 63;
    const int w    = tid >> 6;
    const int wr   = w >> 1, wc = w & 1;
    const int row0 = blockIdx.x * 128;
    const int col0 = blockIdx.y * 128;
    const int l15  = lane & 15;
    const int ko   = lane >> 4;

    f32x4 acc[4][4];
    #pragma unroll
    for (int m = 0; m < 4; ++m)
        #pragma unroll
        for (int n = 0; n < 4; ++n) acc[m][n] = (f32x4){0.f,0.f,0.f,0.f};

    for (int k0 = 0; k0 < K; k0 += 64) {
        stage64g<128,4>(A, (size_t)row0, K, k0, As, w, lane);
        stage64g<128,4>(W, (size_t)col0, K, k0, Bs, w, lane);
        __syncthreads();
        #pragma unroll
        for (int ks = 0; ks < 2; ++ks) {
            short8_t aF[4], bF[4];
            #pragma unroll
            for (int m = 0; m < 4; ++m)
                aF[m] = frag64(As, wr*64 + m*16 + l15, ks*64 + ko*16);
            #pragma unroll
            for (int n = 0; n < 4; ++n)
                bF[n] = frag64(Bs, wc*64 + n*16 + l15, ks*64 + ko*16);
            #pragma unroll
            for (int m = 0; m < 4; ++m)
                #pragma unroll
                for (int n = 0; n < 4; ++n)
                    acc[m][n] = __builtin_amdgcn_mfma_f32_16x16x32_bf16(aF[m], bF[n], acc[m][n], 0, 0, 0);
        }
        __syncthreads();
    }

    #pragma unroll
    for (int m = 0; m < 4; ++m) {
        const int rbase = row0 + wr*64 + m*16 + ko*4;
        #pragma unroll
        for (int n = 0; n < 4; ++n) {
            const int col = col0 + wc*64 + n*16 + l15;
            const float bv = bias[col];
            #pragma unroll
            for (int r = 0; r < 4; ++r) {
                const int row = rbase + r;
                float v = acc[m][n][r] + bv;
                if constexpr (ACT == ACT_LRELU) v = LRELU_(v);
                if constexpr (RES)  v += resp[(size_t)row*N + col];
                if constexpr (MASK) v *= (mask[row] != 0) ? 1.f : 0.f;
                if constexpr (OUTF) Cf[(size_t)row*N + col] = v;
                if constexpr (OUTB) Cb[(size_t)row*N + col] = f2bf(v);
                if constexpr (OUTS) {
                    unsigned short h = f2bf(v);
                    Ohi[(size_t)row*N + col] = h;
                    Olo[(size_t)row*N + col] = f2bf(v - bf2f(h));
                }
            }
        }
    }
}

// ---------------------------------------------------------------------------
// bf16 MFMA GEMM fused with full-row LayerNorm epilogue (BK=64).
// MODE 1: bf16 out. MODE 2: split hi/lo ONLY (no fp32).
// ---------------------------------------------------------------------------
template<int WR, int WC, bool DO_LRELU, bool MASKMUL, int MODE, bool AF32>
__global__ __launch_bounds__(WR*WC*64)
void bgemm_ln_k(const void* __restrict__ Ap,
                const unsigned short* __restrict__ W,
                const float* __restrict__ bias,
                const float* __restrict__ gam,
                const float* __restrict__ bet,
                const int* __restrict__ mask,
                void* __restrict__ outv,
                unsigned short* __restrict__ ohi, unsigned short* __restrict__ olo,
                int K)
{
    constexpr int BM = WR*64;
    constexpr int BN = WC*64;
    constexpr int THREADS = WR*WC*64;
    constexpr int WAVES = THREADS/64;
    __shared__ __align__(16) unsigned short As[BM*64];
    __shared__ __align__(16) unsigned short Bs[BN*64];
    __shared__ float red_s[WC][BM];
    __shared__ float red_q[WC][BM];
    __shared__ float mu_l[BM];
    __shared__ float rs_l[BM];

    const int tid  = threadIdx.x;
    const int lane = tid & 63;
    const int w    = tid >> 6;
    const int wr   = w / WC, wc = w % WC;
    const int row0 = blockIdx.x * BM;
    const int l15  = lane & 15;
    const int ko   = lane >> 4;

    f32x4 acc[4][4];
    #pragma unroll
    for (int m = 0; m < 4; ++m)
        #pragma unroll
        for (int n = 0; n < 4; ++n) acc[m][n] = (f32x4){0.f,0.f,0.f,0.f};

    for (int k0 = 0; k0 < K; k0 += 64) {
        if constexpr (AF32) {
            const float* Af = (const float*)Ap;
            constexpr int CH = (BM*8)/THREADS;    // 16B chunks per thread
            #pragma unroll
            for (int i = 0; i < CH; ++i) {
                const int q = i*THREADS + tid;
                const unsigned o  = (unsigned)q*16u;
                const int      r  = (int)(o >> 7);
                const unsigned cb = o & 127u;
                const unsigned cs = cb ^ ((unsigned)(r & 7) << 4);
                const float* src = Af + (size_t)(row0 + r)*K + k0 + (cs >> 1);
                const float4 f0 = *reinterpret_cast<const float4*>(src);
                const float4 f1 = *reinterpret_cast<const float4*>(src + 4);
                short8_t v;
                v[0]=(short)f2bf(f0.x); v[1]=(short)f2bf(f0.y); v[2]=(short)f2bf(f0.z); v[3]=(short)f2bf(f0.w);
                v[4]=(short)f2bf(f1.x); v[5]=(short)f2bf(f1.y); v[6]=(short)f2bf(f1.z); v[7]=(short)f2bf(f1.w);
                *reinterpret_cast<short8_t*>((char*)As + o) = v;
            }
        } else {
            stage64g<BM,WAVES>((const unsigned short*)Ap, (size_t)row0, K, k0, As, w, lane);
        }
        stage64g<BN,WAVES>(W, 0, K, k0, Bs, w, lane);
        __syncthreads();
        #pragma unroll
        for (int ks = 0; ks < 2; ++ks) {
            short8_t aF[4], bF[4];
            #pragma unroll
            for (int m = 0; m < 4; ++m)
                aF[m] = frag64(As, wr*64 + m*16 + l15, ks*64 + ko*16);
            #pragma unroll
            for (int n = 0; n < 4; ++n)
                bF[n] = frag64(Bs, wc*64 + n*16 + l15, ks*64 + ko*16);
            #pragma unroll
            for (int m = 0; m < 4; ++m)
                #pragma unroll
                for (int n = 0; n < 4; ++n)
                    acc[m][n] = __builtin_amdgcn_mfma_f32_16x16x32_bf16(aF[m], bF[n], acc[m][n], 0, 0, 0);
        }
        __syncthreads();
    }

    float bv[4];
    #pragma unroll
    for (int n = 0; n < 4; ++n) bv[n] = bias[wc*64 + n*16 + l15];
    #pragma unroll
    for (int m = 0; m < 4; ++m)
        #pragma unroll
        for (int n = 0; n < 4; ++n)
            #pragma unroll
            for (int r = 0; r < 4; ++r) acc[m][n][r] += bv[n];

    #pragma unroll
    for (int m = 0; m < 4; ++m) {
        #pragma unroll
        for (int r = 0; r < 4; ++r) {
            float s = acc[m][0][r] + acc[m][1][r] + acc[m][2][r] + acc[m][3][r];
            float q = acc[m][0][r]*acc[m][0][r] + acc[m][1][r]*acc[m][1][r]
                    + acc[m][2][r]*acc[m][2][r] + acc[m][3][r]*acc[m][3][r];
            s = dpp_rowsum16(s);
            q = dpp_rowsum16(q);
            if (l15 == 15) {
                int rl = wr*64 + m*16 + ko*4 + r;
                red_s[wc][rl] = s;
                red_q[wc][rl] = q;
            }
        }
    }
    __syncthreads();
    if (tid < BM) {
        float s = 0.f, q = 0.f;
        #pragma unroll
        for (int c2 = 0; c2 < WC; ++c2) { s += red_s[c2][tid]; q += red_q[c2][tid]; }
        float mu  = s * (1.0f/BN);
        float var = q * (1.0f/BN) - mu*mu;
        mu_l[tid] = mu;
        rs_l[tid] = rsqrtf(fmaxf(var, 0.f) + 1e-5f);
    }
    __syncthreads();

    float gm[4], bt[4];
    #pragma unroll
    for (int n = 0; n < 4; ++n) {
        int col = wc*64 + n*16 + l15;
        gm[n] = gam[col]; bt[n] = bet[col];
    }
    #pragma unroll
    for (int m = 0; m < 4; ++m) {
        #pragma unroll
        for (int r = 0; r < 4; ++r) {
            const int rl  = wr*64 + m*16 + ko*4 + r;
            const int row = row0 + rl;
            const float mu = mu_l[rl], rs = rs_l[rl];
            float mf = 1.f;
            if constexpr (MASKMUL) mf = (mask[row] != 0) ? 1.f : 0.f;
            #pragma unroll
            for (int n = 0; n < 4; ++n) {
                const int col = wc*64 + n*16 + l15;
                float y = (acc[m][n][r] - mu) * rs * gm[n] + bt[n];
                if constexpr (DO_LRELU) y = LRELU_(y);
                if constexpr (MASKMUL)  y *= mf;
                if constexpr (MODE == 1) {
                    ((unsigned short*)outv)[(size_t)row*BN + col] = f2bf(y);
                } else {
                    unsigned short h = f2bf(y);
                    ohi[(size_t)row*BN + col] = h;
                    olo[(size_t)row*BN + col] = f2bf(y - bf2f(h));
                }
            }
        }
    }
}

// ---------------------------------------------------------------------------
// fc1 split-bf16 MFMA GEMM, 3 phases, BK=64, fused rowsq(x2).
// In: x split (preserved). Out: h split (separate buffers).
// ---------------------------------------------------------------------------
__global__ __launch_bounds__(256)
void fc1mm_k(const unsigned short* __restrict__ Ahi, const unsigned short* __restrict__ Alo,
             const unsigned short* __restrict__ Bhi, const unsigned short* __restrict__ Blo,
             const float* __restrict__ bias,
             unsigned short* __restrict__ Ohi, unsigned short* __restrict__ Olo,
             float* __restrict__ x2out)
{
    __shared__ __align__(16) unsigned short As[128*64];
    __shared__ __align__(16) unsigned short Bs[128*64];
    __shared__ float red_q[2][128];

    const int tid  = threadIdx.x;
    const int lane = tid & 63;
    const int w    = tid >> 6;
    const int wr   = w >> 1, wc = w & 1;
    const int row0 = blockIdx.x * 128;
    const int l15  = lane & 15;
    const int ko   = lane >> 4;

    f32x4 acc[4][4];
    #pragma unroll
    for (int m = 0; m < 4; ++m)
        #pragma unroll
        for (int n = 0; n < 4; ++n) acc[m][n] = (f32x4){0.f,0.f,0.f,0.f};

    for (int kk = 0; kk < 384; kk += 64) {
        const int p  = kk >> 7;        // 0,0,1,1,2,2
        const int kl = kk & 127;
        const unsigned short* Ap2 = (p == 1) ? Alo : Ahi;
        const unsigned short* Bp2 = (p == 2) ? Blo : Bhi;
        stage64g<128,4>(Ap2, (size_t)row0, DD, kl, As, w, lane);
        stage64g<128,4>(Bp2, 0, DD, kl, Bs, w, lane);
        __syncthreads();
        #pragma unroll
        for (int ks = 0; ks < 2; ++ks) {
            short8_t aF[4], bF[4];
            #pragma unroll
            for (int m = 0; m < 4; ++m)
                aF[m] = frag64(As, wr*64 + m*16 + l15, ks*64 + ko*16);
            #pragma unroll
            for (int n = 0; n < 4; ++n)
                bF[n] = frag64(Bs, wc*64 + n*16 + l15, ks*64 + ko*16);
            #pragma unroll
            for (int m = 0; m < 4; ++m)
                #pragma unroll
                for (int n = 0; n < 4; ++n)
                    acc[m][n] = __builtin_amdgcn_mfma_f32_16x16x32_bf16(aF[m], bF[n], acc[m][n], 0, 0, 0);
        }
        __syncthreads();
    }

    float qacc[4][4];
    #pragma unroll
    for (int m = 0; m < 4; ++m) {
        const int rbase = row0 + wr*64 + m*16 + ko*4;
        #pragma unroll
        for (int r = 0; r < 4; ++r) qacc[m][r] = 0.f;
        #pragma unroll
        for (int n = 0; n < 4; ++n) {
            const int col = wc*64 + n*16 + l15;
            const float bv = bias[col];
            #pragma unroll
            for (int r = 0; r < 4; ++r) {
                const int row = rbase + r;
                float v = acc[m][n][r] + bv;
                unsigned short h = f2bf(v);
                unsigned short l = f2bf(v - bf2f(h));
                Ohi[(size_t)row*DD + col] = h;
                Olo[(size_t)row*DD + col] = l;
                float vv = bf2f(h) + bf2f(l);
                qacc[m][r] += vv*vv;
            }
        }
    }
    #pragma unroll
    for (int m = 0; m < 4; ++m)
        #pragma unroll
        for (int r = 0; r < 4; ++r) {
            float q = dpp_rowsum16(qacc[m][r]);
            if (l15 == 15) red_q[wc][wr*64 + m*16 + ko*4 + r] = q;
        }
    __syncthreads();
    if (tid < 128) x2out[row0 + tid] = red_q[0][tid] + red_q[1][tid];
}

// ---------------------------------------------------------------------------
// Fused distance + top-9 + gather: ONE block per batch (1024 thr, 16 waves).
// ---------------------------------------------------------------------------
__global__ __launch_bounds__(1024)
void dist_topk_gather_k(const unsigned short* __restrict__ hhi,
                        const unsigned short* __restrict__ hlo,
                        const int* __restrict__ mask,
                        const float* __restrict__ x2,
                        unsigned short* __restrict__ cat)
{
    __shared__ __align__(16) unsigned short BsH[2][NNODE*64];   // 64KB
    __shared__ __align__(16) unsigned short BsL[2][NNODE*64];   // 64KB
    __shared__ unsigned char idx_s[NNODE*KNN];
    __shared__ unsigned char msk_s[NNODE];

    const int b    = blockIdx.x;
    const int tid  = threadIdx.x;
    const int lane = tid & 63;
    const int w    = tid >> 6;          // 0..15
    const int l15  = lane & 15;
    const int g    = lane >> 4;         // 0..3

    const unsigned short* Hhi = hhi + (size_t)b*NNODE*DD;
    const unsigned short* Hlo = hlo + (size_t)b*NNODE*DD;
    const float* x2b = x2 + b*NNODE;
    const int*   mkb = mask + b*NNODE;

    stage64g<NNODE,16>(Hhi, 0, DD, 0,  &BsH[0][0], w, lane);
    stage64g<NNODE,16>(Hhi, 0, DD, 64, &BsH[1][0], w, lane);
    stage64g<NNODE,16>(Hlo, 0, DD, 0,  &BsL[0][0], w, lane);
    stage64g<NNODE,16>(Hlo, 0, DD, 64, &BsL[1][0], w, lane);
    if (tid < NNODE) msk_s[tid] = (mkb[tid] != 0) ? 1 : 0;
    __syncthreads();

    const int arow = w*16 + l15;        // 0..255

    f32x4 acc[16];
    #pragma unroll
    for (int n = 0; n < 16; ++n) acc[n] = (f32x4){0.f,0.f,0.f,0.f};

    #pragma unroll
    for (int kt = 0; kt < 2; ++kt) {
        #pragma unroll
        for (int ks = 0; ks < 2; ++ks) {
            short8_t aH = frag64(&BsH[kt][0], arow, ks*64 + g*16);
            short8_t aL = frag64(&BsL[kt][0], arow, ks*64 + g*16);
            #pragma unroll
            for (int n = 0; n < 16; ++n) {
                int brow = n*16 + l15;
                short8_t bH = frag64(&BsH[kt][0], brow, ks*64 + g*16);
                short8_t bL = frag64(&BsL[kt][0], brow, ks*64 + g*16);
                acc[n] = __builtin_amdgcn_mfma_f32_16x16x32_bf16(aH, bH, acc[n], 0, 0, 0); // hi.hi
                acc[n] = __builtin_amdgcn_mfma_f32_16x16x32_bf16(aL, bH, acc[n], 0, 0, 0); // lo.hi
                acc[n] = __builtin_amdgcn_mfma_f32_16x16x32_bf16(aH, bL, acc[n], 0, 0, 0); // hi.lo
            }
        }
    }

    float x2c[16]; unsigned mk[16];
    #pragma unroll
    for (int n = 0; n < 16; ++n) {
        int col = n*16 + l15;
        x2c[n] = x2b[col];
        mk[n]  = (unsigned)msk_s[col];
    }

    #pragma unroll
    for (int r = 0; r < 4; ++r) {
        const int lrow = w*16 + g*4 + r;          // this wave's rows only
        const float x2r = x2b[lrow];
        unsigned key[16];
        #pragma unroll
        for (int n = 0; n < 16; ++n) {
            float v = x2r + x2c[n] - 2.0f*acc[n][r];
            if (!mk[n]) v = 1e10f;
            unsigned u = __float_as_uint(v);
            u = (u & 0x80000000u) ? ~u : (u | 0x80000000u);
            key[n] = (u & 0xFFFFFF00u) | (unsigned)(n*16 + l15);
        }
        for (int it = 0; it < KNN; ++it) {
            unsigned a0 = key[0]  < key[1]  ? key[0]  : key[1];
            unsigned a1 = key[2]  < key[3]  ? key[2]  : key[3];
            unsigned a2 = key[4]  < key[5]  ? key[4]  : key[5];
            unsigned a3 = key[6]  < key[7]  ? key[6]  : key[7];
            unsigned a4 = key[8]  < key[9]  ? key[8]  : key[9];
            unsigned a5 = key[10] < key[11] ? key[10] : key[11];
            unsigned a6 = key[12] < key[13] ? key[12] : key[13];
            unsigned a7 = key[14] < key[15] ? key[14] : key[15];
            unsigned b0 = a0 < a1 ? a0 : a1;
            unsigned b1 = a2 < a3 ? a2 : a3;
            unsigned b2 = a4 < a5 ? a4 : a5;
            unsigned b3 = a6 < a7 ? a6 : a7;
            unsigned c0 = b0 < b1 ? b0 : b1;
            unsigned c1 = b2 < b3 ? b2 : b3;
            unsigned lmin = c0 < c1 ? c0 : c1;
            unsigned gmin = grp16_min_u32(lmin);
            if (l15 == 0) idx_s[lrow*KNN + it] = (unsigned char)(gmin & 0xFFu);
            #pragma unroll
            for (int n = 0; n < 16; ++n)
                if (key[n] == gmin) key[n] = 0xFFFFFFFFu;
        }
    }
    // NO block barrier: gather touches only this wave's rows (same-wave DS order).

    const int gi = lane & 7;                       // granule 0..7 (8 cols)
    const unsigned cb = (unsigned)(gi * 16);       // byte col within tile
    #pragma unroll
    for (int kt = 0; kt < 2; ++kt) {
        #pragma unroll
        for (int p = 0; p < 2; ++p) {
            const int rl = w*16 + p*8 + (lane >> 3);   // this wave's row
            us8 h8 = read8sw(&BsH[kt][0], rl, cb);
            us8 l8 = read8sw(&BsL[kt][0], rl, cb);
            float hi[8], m[8];
            #pragma unroll
            for (int d = 0; d < 8; ++d) { hi[d] = bf2f(h8[d]) + bf2f(l8[d]); m[d] = -1e9f; }
            bool any = false;
            #pragma unroll
            for (int q = 0; q < KNN; ++q) {
                int j = idx_s[rl*KNN + q];
                if (msk_s[j]) {
                    any = true;
                    us8 a = read8sw(&BsH[kt][0], j, cb);
                    us8 o = read8sw(&BsL[kt][0], j, cb);
                    #pragma unroll
                    for (int d = 0; d < 8; ++d)
                        m[d] = fmaxf(m[d], bf2f(a[d]) + bf2f(o[d]) - hi[d]);
                }
            }
            us8 o1, o2;
            #pragma unroll
            for (int d = 0; d < 8; ++d) {
                o1[d] = f2bf(hi[d]);
                o2[d] = any ? f2bf(m[d]) : (unsigned short)0;
            }
            const size_t rowbase = (size_t)(b*NNODE + rl)*(2*DD);
            const int c0 = kt*64 + gi*8;
            *reinterpret_cast<us8*>(&cat[rowbase + c0])      = o1;
            *reinterpret_cast<us8*>(&cat[rowbase + DD + c0]) = o2;
        }
    }
}

// ---------------------------------------------------------------------------
// Fused conv + fc2 + FFN with ring-3 weight staging (2-phase-early issue).
// Residual from x split (hi+lo); no fp32 x anywhere.
// LDS: Bs[3] 48KB + h2s 16KB + Xs 16KB (conv A-tiles alias Xs) = 80KB.
// 22 phases; each phase issues tile t+2 before its MFMA.
// ---------------------------------------------------------------------------
__global__ __launch_bounds__(256)
void conv_ffn_k(const unsigned short* __restrict__ cat,
                const unsigned short* __restrict__ Wc,   // [128][256]
                const float* __restrict__ cb,
                const unsigned short* __restrict__ W2c,  // [128][128] (fc2)
                const float* __restrict__ fb,
                const unsigned short* __restrict__ W1,   // [512][128] (ffn1)
                const float* __restrict__ b1,
                const unsigned short* __restrict__ W2f,  // [128][512] (ffn2)
                const float* __restrict__ b2,
                const int* __restrict__ mask,
                unsigned short* xhi,                     // in: x residual / out: new x
                unsigned short* xlo)
{
    __shared__ __align__(16) unsigned short Bs[3][128*64];   // 48KB ring
    __shared__ __align__(16) unsigned short h2s[2][64*64];   // 16KB
    __shared__ __align__(16) unsigned short Xs[2][64*64];    // 16KB; conv A-tiles alias

    const int tid  = threadIdx.x;
    const int lane = tid & 63;
    const int w    = tid >> 6;      // 0..3: wave col group
    const int row0 = blockIdx.x * 64;
    const int l15  = lane & 15;
    const int ko   = lane >> 4;

    // tile t -> weight source (t = 0..21)
    auto issueB = [&](int t) {
        unsigned short* buf = &Bs[t % 3][0];
        if (t < 4)      stage64g<128,4>(Wc,  0, 256, t*64, buf, w, lane);
        else if (t < 6) stage64g<128,4>(W2c, 0, 128, (t-4)*64, buf, w, lane);
        else {
            int c = (t-6) >> 2, j = (t-6) & 3;
            if (j < 2) stage64g<128,4>(W1, (size_t)(c*128), DD, j*64, buf, w, lane);
            else       stage64g<128,4>(W2f, 0, FFND, c*128 + (j-2)*64, buf, w, lane);
        }
    };

    // 8-MFMA phase body (A 64x64 tile, B 128x64 tile)
    #define MM8(ATILE, BTILE, ACC)                                              \
        { _Pragma("unroll")                                                     \
          for (int ks = 0; ks < 2; ++ks) {                                      \
            short8_t aF[4], bF[2];                                              \
            _Pragma("unroll")                                                   \
            for (int m = 0; m < 4; ++m) aF[m] = frag64(ATILE, m*16 + l15, ks*64 + ko*16); \
            _Pragma("unroll")                                                   \
            for (int n = 0; n < 2; ++n) bF[n] = frag64(BTILE, w*32 + n*16 + l15, ks*64 + ko*16); \
            _Pragma("unroll")                                                   \
            for (int m = 0; m < 4; ++m)                                         \
              _Pragma("unroll")                                                 \
              for (int n = 0; n < 2; ++n)                                       \
                ACC[m][n] = __builtin_amdgcn_mfma_f32_16x16x32_bf16(aF[m], bF[n], ACC[m][n], 0, 0, 0); } }

    // swizzled bf16 write of acc+bias (lrelu) into a 64x64 k-half tile pair
    #define H2WRITE(ACC, BPTR, DST)                                             \
        { const int kt_ = w >> 1;                                               \
          _Pragma("unroll")                                                     \
          for (int n = 0; n < 2; ++n) {                                         \
            const int col_ = w*32 + n*16 + l15;                                 \
            const float bv_ = (BPTR)[col_];                                     \
            const unsigned bc_ = (unsigned)(((w & 1)*32 + n*16 + l15) * 2);     \
            _Pragma("unroll")                                                   \
            for (int m = 0; m < 4; ++m)                                         \
              _Pragma("unroll")                                                 \
              for (int r = 0; r < 4; ++r) {                                     \
                const int row_ = m*16 + ko*4 + r;                               \
                float v_ = LRELU_(ACC[m][n][r] + bv_);                          \
                *(unsigned short*)((char*)&(DST)[kt_][0] + row_*128             \
                    + (bc_ ^ ((unsigned)(row_ & 7) << 4))) = f2bf(v_); } } }

    // ---- prologue: As0, As1, B0, B1 ----
    stage64g<64,4>(cat, (size_t)row0, 256, 0,  &Xs[0][0], w, lane);
    stage64g<64,4>(cat, (size_t)row0, 256, 64, &Xs[1][0], w, lane);
    issueB(0); issueB(1);
    __syncthreads();

    // ---- conv phases 0..3 ----
    f32x4 accc[4][2];
    #pragma unroll
    for (int m = 0; m < 4; ++m)
        #pragma unroll
        for (int n = 0; n < 2; ++n) accc[m][n] = (f32x4){0.f,0.f,0.f,0.f};

    // phase 0
    issueB(2);
    MM8(&Xs[0][0], &Bs[0][0], accc);
    __syncthreads();
    // phase 1
    stage64g<64,4>(cat, (size_t)row0, 256, 128, &Xs[0][0], w, lane);
    issueB(3);
    MM8(&Xs[1][0], &Bs[1][0], accc);
    __syncthreads();
    // phase 2
    stage64g<64,4>(cat, (size_t)row0, 256, 192, &Xs[1][0], w, lane);
    issueB(4);
    MM8(&Xs[0][0], &Bs[2][0], accc);
    __syncthreads();
    // phase 3
    issueB(5);
    MM8(&Xs[1][0], &Bs[0][0], accc);
    H2WRITE(accc, cb, h2s);
    __syncthreads();

    // ---- fc2 phases 4..5 ----
    f32x4 accx[4][2];
    #pragma unroll
    for (int m = 0; m < 4; ++m)
        #pragma unroll
        for (int n = 0; n < 2; ++n) accx[m][n] = (f32x4){0.f,0.f,0.f,0.f};
    // phase 4
    issueB(6);
    MM8(&h2s[0][0], &Bs[1][0], accx);
    __syncthreads();
    // phase 5
    issueB(7);
    MM8(&h2s[1][0], &Bs[2][0], accx);
    // xn = accx + fb + residual(hi+lo); bf16 image -> Xs (As reads long done)
    float xn[4][2][4];
    {
        const int kt = w >> 1;
        #pragma unroll
        for (int n = 0; n < 2; ++n) {
            const int col = w*32 + n*16 + l15;
            const float bv = fb[col];
            const unsigned bc = (unsigned)(((w & 1)*32 + n*16 + l15) * 2);
            #pragma unroll
            for (int m = 0; m < 4; ++m) {
                #pragma unroll
                for (int r = 0; r < 4; ++r) {
                    const int row = m*16 + ko*4 + r;
                    const size_t gix = (size_t)(row0 + row)*DD + col;
                    float res = bf2f(xhi[gix]) + bf2f(xlo[gix]);
                    float v = accx[m][n][r] + bv + res;
                    xn[m][n][r] = v;
                    *(unsigned short*)((char*)&Xs[kt][0] + row*128
                        + (bc ^ ((unsigned)(row & 7) << 4))) = f2bf(v);
                }
            }
        }
    }
    __syncthreads();

    // ---- FFN chunks, phases 6..21 ----
    f32x4 acc2[4][2];
    #pragma unroll
    for (int m = 0; m < 4; ++m)
        #pragma unroll
        for (int n = 0; n < 2; ++n) acc2[m][n] = (f32x4){0.f,0.f,0.f,0.f};

    #pragma unroll
    for (int c = 0; c < 4; ++c) {
        const int tb = 6 + c*4;
        f32x4 acc1[4][2];
        #pragma unroll
        for (int m = 0; m < 4; ++m)
            #pragma unroll
            for (int n = 0; n < 2; ++n) acc1[m][n] = (f32x4){0.f,0.f,0.f,0.f};
        // j=0: W1 kt0
        if (tb+2 <= 21) issueB(tb+2);
        MM8(&Xs[0][0], &Bs[tb % 3][0], acc1);
        __syncthreads();
        // j=1: W1 kt1 (+ hidden write)
        if (tb+3 <= 21) issueB(tb+3);
        MM8(&Xs[1][0], &Bs[(tb+1) % 3][0], acc1);
        H2WRITE(acc1, b1 + c*128, h2s);
        __syncthreads();
        // j=2: W2f kt0
        if (tb+4 <= 21) issueB(tb+4);
        MM8(&h2s[0][0], &Bs[(tb+2) % 3][0], acc2);
        __syncthreads();
        // j=3: W2f kt1
        if (tb+5 <= 21) issueB(tb+5);
        MM8(&h2s[1][0], &Bs[(tb+3) % 3][0], acc2);
        __syncthreads();
    }

    // ---- epilogue: x = acc2 + b2 + xn, masked; write split ----
    #pragma unroll
    for (int m = 0; m < 4; ++m) {
        const int rbase = row0 + m*16 + ko*4;
        #pragma unroll
        for (int n = 0; n < 2; ++n) {
            const int col = w*32 + n*16 + l15;
            const float bv = b2[col];
            #pragma unroll
            for (int r = 0; r < 4; ++r) {
                const int row = rbase + r;
                float v = acc2[m][n][r] + bv + xn[m][n][r];
                v *= (mask[row] != 0) ? 1.f : 0.f;
                unsigned short h = f2bf(v);
                xhi[(size_t)row*DD + col] = h;
                xlo[(size_t)row*DD + col] = f2bf(v - bf2f(h));
            }
        }
    }
    #undef MM8
    #undef H2WRITE
}

__global__ __launch_bounds__(128)
void pool_k(const unsigned short* __restrict__ xhi, const unsigned short* __restrict__ xlo,
            const int* __restrict__ mask,
            float* __restrict__ g, unsigned short* __restrict__ gbf)
{
    const int b = blockIdx.x, c = threadIdx.x;
    float s = 0.f; int cnt = 0;
    for (int n = 0; n < NNODE; ++n) {
        const size_t ix = ((size_t)b*NNODE + n)*DD + c;
        s += bf2f(xhi[ix]) + bf2f(xlo[ix]);
        cnt += (mask[b*NNODE + n] != 0) ? 1 : 0;
    }
    float v = s / fmaxf((float)cnt, 1.0f);
    g[b*DD + c] = v;
    gbf[b*DD + c] = f2bf(v);
}

// ---------------------------------------------------------------------------
// All weight transpose-casts in ONE kernel (compile-time job table).
// ---------------------------------------------------------------------------
__global__ __launch_bounds__(256)
void prep_all_k(const float* __restrict__ emb_w1, const float* __restrict__ emb_w2,
                const float* __restrict__ conv_w, const float* __restrict__ fc2_w,
                const float* __restrict__ f1_w,   const float* __restrict__ f2_w,
                const float* __restrict__ fc1_w,  const float* __restrict__ ow1,
                const float* __restrict__ ow2,
                unsigned short* __restrict__ emb_w1t, unsigned short* __restrict__ emb_w2t,
                unsigned short* __restrict__ conv_wt, unsigned short* __restrict__ fc2_wt,
                unsigned short* __restrict__ ffn1_wt, unsigned short* __restrict__ ffn2_wt,
                unsigned short* __restrict__ fc1_wthi, unsigned short* __restrict__ fc1_wtlo,
                unsigned short* __restrict__ ow1t, unsigned short* __restrict__ ow2t)
{
    __shared__ float tile[32][33];
    const int tx = threadIdx.x & 31, ty = threadIdx.x >> 5;

    int bid = blockIdx.x;
    const float* src = nullptr; unsigned short* dst = nullptr; unsigned short* dlo = nullptr;
    int K = 0, N = 0;
    do {
        if (bid < 16)  { src = emb_w1; dst = emb_w1t; K = 64;  N = 256; break; }  bid -= 16;
        if (bid < 32)  { src = emb_w2; dst = emb_w2t; K = 256; N = 128; break; }  bid -= 32;
        if (bid < 64)  { int l = bid >> 5; bid &= 31;
                         src = conv_w + (size_t)l*256*128; dst = conv_wt + (size_t)l*128*256;
                         K = 256; N = 128; break; }                               bid -= 64;
        if (bid < 32)  { int l = bid >> 4; bid &= 15;
                         src = fc2_w + (size_t)l*128*128; dst = fc2_wt + (size_t)l*128*128;
                         K = 128; N = 128; break; }                               bid -= 32;
        if (bid < 128) { int l = bid >> 6; bid &= 63;
                         src = f1_w + (size_t)l*128*512; dst = ffn1_wt + (size_t)l*512*128;
                         K = 128; N = 512; break; }                               bid -= 128;
        if (bid < 128) { int l = bid >> 6; bid &= 63;
                         src = f2_w + (size_t)l*512*128; dst = ffn2_wt + (size_t)l*128*512;
                         K = 512; N = 128; break; }                               bid -= 128;
        if (bid < 32)  { int l = bid >> 4; bid &= 15;
                         src = fc1_w + (size_t)l*128*128;
                         dst = fc1_wthi + (size_t)l*128*128; dlo = fc1_wtlo + (size_t)l*128*128;
                         K = 128; N = 128; break; }                               bid -= 32;
        if (bid < 64)  { src = ow1; dst = ow1t; K = 128; N = 512; break; }        bid -= 64;
        { src = ow2; dst = ow2t; K = 512; N = 2048; }
    } while (0);

    const int nbx = N / 32;
    const int bx = bid % nbx, by = bid / nbx;
    const int k0 = by*32, n0 = bx*32;

    #pragma unroll
    for (int i = ty; i < 32; i += 8)
        tile[i][tx] = src[(size_t)(k0+i)*N + n0+tx];
    __syncthreads();
    #pragma unroll
    for (int i = ty; i < 32; i += 8) {
        float v = tile[tx][i];
        unsigned short h = f2bf(v);
        dst[(size_t)(n0+i)*K + k0+tx] = h;
        if (dlo) dlo[(size_t)(n0+i)*K + k0+tx] = f2bf(v - bf2f(h));
    }
}

// ---------------------------------------------------------------------------
extern "C" void kernel_launch(void* const* d_in, const int* in_sizes, int n_in,
                              void* d_out, int out_size, void* d_ws, size_t ws_size,
                              hipStream_t stream)
{
    const float* nodes  = (const float*)d_in[0];
    const int*   maskp  = (const int*)  d_in[1];
    const float* emb_w1 = (const float*)d_in[2];
    const float* emb_b1 = (const float*)d_in[3];
    const float* ln1_g  = (const float*)d_in[4];
    const float* ln1_b  = (const float*)d_in[5];
    const float* emb_w2 = (const float*)d_in[6];
    const float* emb_b2 = (const float*)d_in[7];
    const float* ln2_g  = (const float*)d_in[8];
    const float* ln2_b  = (const float*)d_in[9];
    const float* fc1_w  = (const float*)d_in[10];
    const float* fc1_b  = (const float*)d_in[11];
    const float* conv_w = (const float*)d_in[12];
    const float* conv_b = (const float*)d_in[13];
    const float* fc2_w  = (const float*)d_in[14];
    const float* fc2_b  = (const float*)d_in[15];
    const float* f1_w   = (const float*)d_in[16];
    const float* f1_b   = (const float*)d_in[17];
    const float* f2_w   = (const float*)d_in[18];
    const float* f2_b   = (const float*)d_in[19];
    const float* ow1    = (const float*)d_in[20];
    const float* ob1    = (const float*)d_in[21];
    const float* ow2    = (const float*)d_in[22];
    const float* ob2    = (const float*)d_in[23];
    float* out = (float*)d_out;

    // ---- workspace layout ----
    char* base = (char*)d_ws;
    char*  H   = base + (size_t)BNROWS*DD*4;            // x_hi/x_lo (residual-carrying)
    char*  BIG = H + (size_t)BNROWS*DD*4;               // cat [0:33.5M] + h split [33.5:67.1M]
    float*          x2    = (float*)(BIG + (size_t)BNROWS*2*DD*4);
    float*          g     = (float*)(x2 + BNROWS);
    unsigned short* g_bf  = (unsigned short*)(g + BB*DD);
    unsigned short* hid2_bf = g_bf + BB*DD;
    unsigned short* wbuf  = hid2_bf + BB*FFND;

    unsigned short* x_hi   = (unsigned short*)H;
    unsigned short* x_lo   = x_hi + (size_t)BNROWS*DD;
    unsigned short* t256_bf= (unsigned short*)base;     // embed phase scratch (x region)
    unsigned short* cat_bf = (unsigned short*)BIG;
    unsigned short* h_hi   = (unsigned short*)(BIG + (size_t)BNROWS*DD*2);
    unsigned short* h_lo   = h_hi + (size_t)BNROWS*DD;

    unsigned short* emb_w1t  = wbuf;
    unsigned short* emb_w2t  = emb_w1t + 256*64;
    unsigned short* conv_wt  = emb_w2t + 128*256;
    unsigned short* fc2_wt   = conv_wt + 2*128*256;
    unsigned short* ffn1_wt  = fc2_wt  + 2*128*128;
    unsigned short* ffn2_wt  = ffn1_wt + 2*512*128;
    unsigned short* fc1_wthi = ffn2_wt + 2*128*512;
    unsigned short* fc1_wtlo = fc1_wthi + 2*128*128;
    unsigned short* ow1t     = fc1_wtlo + 2*128*128;
    unsigned short* ow2t     = ow1t + 512*128;

    const dim3 blk(256);

    // ---- all weight transpose-casts (one launch) ----
    prep_all_k<<<1520, blk, 0, stream>>>(
        emb_w1, emb_w2, conv_w, fc2_w, f1_w, f2_w, fc1_w, ow1, ow2,
        emb_w1t, emb_w2t, conv_wt, fc2_wt, ffn1_wt, ffn2_wt,
        fc1_wthi, fc1_wtlo, ow1t, ow2t);

    // ---- Embedding (GEMM + fused LN) ----
    bgemm_ln_k<2,4,true,false,1,true>
        <<<dim3(BNROWS/128), dim3(512), 0, stream>>>
        (nodes, emb_w1t, emb_b1, ln1_g, ln1_b, nullptr, t256_bf, nullptr, nullptr, PP2);
    bgemm_ln_k<2,2,false,true,2,false>
        <<<dim3(BNROWS/128), dim3(256), 0, stream>>>
        (t256_bf, emb_w2t, emb_b2, ln2_g, ln2_b, maskp, nullptr, x_hi, x_lo, 2*DD);

    // ---- ViG blocks ----
    for (int l = 0; l < LLAY; ++l) {
        const float* fc1b = fc1_b + (size_t)l*DD;
        const float* cb   = conv_b + (size_t)l*DD;
        const float* fc2b = fc2_b + (size_t)l*DD;
        const float* b1   = f1_b + (size_t)l*FFND;
        const float* b2   = f2_b + (size_t)l*DD;

        // h(split) = x(split) @ fc1(split) + b  -> SEPARATE buffers (x preserved)
        fc1mm_k<<<dim3(BNROWS/128), blk, 0, stream>>>
            (x_hi, x_lo, fc1_wthi + (size_t)l*DD*DD, fc1_wtlo + (size_t)l*DD*DD,
             fc1b, h_hi, h_lo, x2);
        dist_topk_gather_k<<<dim3(BB), dim3(1024), 0, stream>>>
            (h_hi, h_lo, maskp, x2, cat_bf);
        // x(split) <- conv+fc2+ffn(cat, x residual)
        conv_ffn_k<<<dim3(BNROWS/64), blk, 0, stream>>>
            (cat_bf, conv_wt + (size_t)l*DD*2*DD, cb,
             fc2_wt + (size_t)l*DD*DD, fc2b,
             ffn1_wt + (size_t)l*FFND*DD, b1,
             ffn2_wt + (size_t)l*DD*FFND, b2, maskp,
             x_hi, x_lo);
    }

    // ---- Pool + head (bf16 MFMA) ----
    pool_k<<<BB, 128, 0, stream>>>(x_hi, x_lo, maskp, g, g_bf);
    bgemm_k<ACT_LRELU,false,false,false,true,false>
        <<<dim3(BB/128, 512/128), blk, 0, stream>>>
        (g_bf, ow1t, ob1, nullptr, nullptr, nullptr, hid2_bf, nullptr, nullptr, BB, 512, DD);
    bgemm_k<ACT_NONE,false,false,true,false,false>
        <<<dim3(BB/128, 2048/128), blk, 0, stream>>>
        (hid2_bf, ow2t, ob2, nullptr, nullptr, out, nullptr, nullptr, nullptr, BB, 2048, 512);
}

// Round 19
// 291.436 us; speedup vs baseline: 1.4629x; 1.0212x over previous
//
#include <hip/hip_runtime.h>
#include <cstdint>

#define BB    256
#define NNODE 256
#define PP2   64
#define DD    128
#define LLAY  2
#define KNN   9
#define FFND  512
#define BNROWS (BB*NNODE)   // 65536

#define LRELU_(v) ((v) >= 0.f ? (v) : 0.01f*(v))

enum { ACT_NONE = 0, ACT_LRELU = 1 };

typedef short  short8_t  __attribute__((ext_vector_type(8)));
typedef float  f32x4     __attribute__((ext_vector_type(4)));
typedef unsigned short us4 __attribute__((ext_vector_type(4)));
typedef unsigned short us8 __attribute__((ext_vector_type(8)));

__device__ inline unsigned short f2bf(float x) {
    unsigned u = __float_as_uint(x);
    unsigned r = (u + 0x7FFFu + ((u >> 16) & 1u)) >> 16;
    return (unsigned short)r;
}
__device__ inline float bf2f(unsigned short h) {
    return __uint_as_float(((unsigned)h) << 16);
}

// async global->LDS, 16B per lane; LDS dest must be wave-uniform base.
__device__ inline void gload16(const void* src, void* dst) {
    __builtin_amdgcn_global_load_lds(
        (const __attribute__((address_space(1))) void*)src,
        (__attribute__((address_space(3))) void*)dst, 16, 0, 0);
}

// Stage a BK=64 bf16 tile (ROWS x 64 elems, 128B rows) from row-major global
// (element stride Kel, starting col k0) into LINEAR LDS via global_load_lds.
// Source address carries the inverse XOR swizzle; reads apply the same XOR.
template<int ROWS, int WAVES>
__device__ inline void stage64g(const unsigned short* __restrict__ g, size_t rowbase,
                                int Kel, int k0, unsigned short* lds, int w, int lane)
{
    constexpr int PER = (ROWS*128/1024) / WAVES;
    #pragma unroll
    for (int i = 0; i < PER; ++i) {
        const int inst = w + i*WAVES;                 // wave-uniform
        const unsigned o  = (unsigned)inst*1024u + (unsigned)lane*16u;
        const int      r  = (int)(o >> 7);
        const unsigned cb = o & 127u;
        const unsigned cs = cb ^ ((unsigned)(r & 7) << 4);
        gload16((const char*)(g + (rowbase + (size_t)r)*(size_t)Kel + k0) + cs,
                (char*)lds + (size_t)inst*1024u);
    }
}

// swizzled fragment read from a linear BK=64 tile
__device__ inline short8_t frag64(const unsigned short* lds, int r, int cb) {
    return *reinterpret_cast<const short8_t*>(
        (const char*)lds + (size_t)r*128 + (unsigned)(cb ^ ((r & 7) << 4)));
}

// swizzled 16B (8 cols) read from a BK=64 tile at column-byte cb (mult of 16)
__device__ inline us8 read8sw(const unsigned short* lds, int r, unsigned cb) {
    return *reinterpret_cast<const us8*>(
        (const char*)lds + (size_t)r*128 + (cb ^ ((unsigned)(r & 7) << 4)));
}

// 16-lane-group min (per DPP row); result in ALL lanes of each 16-group.
__device__ inline unsigned grp16_min_u32(unsigned v) {
    unsigned t;
    t = (unsigned)__builtin_amdgcn_update_dpp(-1, (int)v, 0xB1,  0xF, 0xF, false); v = t < v ? t : v; // quad_perm [1,0,3,2]
    t = (unsigned)__builtin_amdgcn_update_dpp(-1, (int)v, 0x4E,  0xF, 0xF, false); v = t < v ? t : v; // quad_perm [2,3,0,1]
    t = (unsigned)__builtin_amdgcn_update_dpp(-1, (int)v, 0x124, 0xF, 0xF, false); v = t < v ? t : v; // row_ror:4
    t = (unsigned)__builtin_amdgcn_update_dpp(-1, (int)v, 0x128, 0xF, 0xF, false); v = t < v ? t : v; // row_ror:8
    return v;
}

// 16-lane (DPP row) sum; result valid in lane 15 of each 16-lane row.
__device__ inline float dpp_rowsum16(float v) {
    float t;
    t = __uint_as_float((unsigned)__builtin_amdgcn_update_dpp(0, (int)__float_as_uint(v), 0x111, 0xF, 0xF, false)); v += t;
    t = __uint_as_float((unsigned)__builtin_amdgcn_update_dpp(0, (int)__float_as_uint(v), 0x112, 0xF, 0xF, false)); v += t;
    t = __uint_as_float((unsigned)__builtin_amdgcn_update_dpp(0, (int)__float_as_uint(v), 0x114, 0xF, 0xF, false)); v += t;
    t = __uint_as_float((unsigned)__builtin_amdgcn_update_dpp(0, (int)__float_as_uint(v), 0x118, 0xF, 0xF, false)); v += t;
    return v;
}

// counted-vmcnt barrier (T4): wait N outstanding VMEM, raw barrier, fence.
#define WAITB0  { asm volatile("s_waitcnt vmcnt(0)" ::: "memory");  __builtin_amdgcn_s_barrier(); asm volatile("" ::: "memory"); }
#define WAITB4  { asm volatile("s_waitcnt vmcnt(4)" ::: "memory");  __builtin_amdgcn_s_barrier(); asm volatile("" ::: "memory"); }
#define WAITB6  { asm volatile("s_waitcnt vmcnt(6)" ::: "memory");  __builtin_amdgcn_s_barrier(); asm volatile("" ::: "memory"); }
#define WAITBL4 { asm volatile("s_waitcnt vmcnt(4) lgkmcnt(0)" ::: "memory"); __builtin_amdgcn_s_barrier(); asm volatile("" ::: "memory"); }

// ---------------------------------------------------------------------------
// bf16 MFMA GEMM, BK=64, global_load_lds staging. (head only now)
// ---------------------------------------------------------------------------
template<int ACT, bool RES, bool MASK, bool OUTF, bool OUTB, bool OUTS>
__global__ __launch_bounds__(256)
void bgemm_k(const unsigned short* __restrict__ A,
             const unsigned short* __restrict__ W,
             const float* __restrict__ bias,
             const float* __restrict__ resp,
             const int* __restrict__ mask,
             float* __restrict__ Cf, unsigned short* __restrict__ Cb,
             unsigned short* Ohi, unsigned short* Olo,
             int M, int N, int K)
{
    __shared__ __align__(16) unsigned short As[128*64];
    __shared__ __align__(16) unsigned short Bs[128*64];

    const int tid  = threadIdx.x;
    const int lane = tid & 63;
    const int w    = tid >> 6;
    const int wr   = w >> 1, wc = w & 1;
    const int row0 = blockIdx.x * 128;
    const int col0 = blockIdx.y * 128;
    const int l15  = lane & 15;
    const int ko   = lane >> 4;

    f32x4 acc[4][4];
    #pragma unroll
    for (int m = 0; m < 4; ++m)
        #pragma unroll
        for (int n = 0; n < 4; ++n) acc[m][n] = (f32x4){0.f,0.f,0.f,0.f};

    for (int k0 = 0; k0 < K; k0 += 64) {
        stage64g<128,4>(A, (size_t)row0, K, k0, As, w, lane);
        stage64g<128,4>(W, (size_t)col0, K, k0, Bs, w, lane);
        __syncthreads();
        #pragma unroll
        for (int ks = 0; ks < 2; ++ks) {
            short8_t aF[4], bF[4];
            #pragma unroll
            for (int m = 0; m < 4; ++m)
                aF[m] = frag64(As, wr*64 + m*16 + l15, ks*64 + ko*16);
            #pragma unroll
            for (int n = 0; n < 4; ++n)
                bF[n] = frag64(Bs, wc*64 + n*16 + l15, ks*64 + ko*16);
            #pragma unroll
            for (int m = 0; m < 4; ++m)
                #pragma unroll
                for (int n = 0; n < 4; ++n)
                    acc[m][n] = __builtin_amdgcn_mfma_f32_16x16x32_bf16(aF[m], bF[n], acc[m][n], 0, 0, 0);
        }
        __syncthreads();
    }

    #pragma unroll
    for (int m = 0; m < 4; ++m) {
        const int rbase = row0 + wr*64 + m*16 + ko*4;
        #pragma unroll
        for (int n = 0; n < 4; ++n) {
            const int col = col0 + wc*64 + n*16 + l15;
            const float bv = bias[col];
            #pragma unroll
            for (int r = 0; r < 4; ++r) {
                const int row = rbase + r;
                float v = acc[m][n][r] + bv;
                if constexpr (ACT == ACT_LRELU) v = LRELU_(v);
                if constexpr (RES)  v += resp[(size_t)row*N + col];
                if constexpr (MASK) v *= (mask[row] != 0) ? 1.f : 0.f;
                if constexpr (OUTF) Cf[(size_t)row*N + col] = v;
                if constexpr (OUTB) Cb[(size_t)row*N + col] = f2bf(v);
                if constexpr (OUTS) {
                    unsigned short h = f2bf(v);
                    Ohi[(size_t)row*N + col] = h;
                    Olo[(size_t)row*N + col] = f2bf(v - bf2f(h));
                }
            }
        }
    }
}

// ---------------------------------------------------------------------------
// bf16 MFMA GEMM fused with full-row LayerNorm epilogue (BK=64).
// MODE 1: bf16 out. MODE 2: split hi/lo ONLY (no fp32).
// ---------------------------------------------------------------------------
template<int WR, int WC, bool DO_LRELU, bool MASKMUL, int MODE, bool AF32>
__global__ __launch_bounds__(WR*WC*64)
void bgemm_ln_k(const void* __restrict__ Ap,
                const unsigned short* __restrict__ W,
                const float* __restrict__ bias,
                const float* __restrict__ gam,
                const float* __restrict__ bet,
                const int* __restrict__ mask,
                void* __restrict__ outv,
                unsigned short* __restrict__ ohi, unsigned short* __restrict__ olo,
                int K)
{
    constexpr int BM = WR*64;
    constexpr int BN = WC*64;
    constexpr int THREADS = WR*WC*64;
    constexpr int WAVES = THREADS/64;
    __shared__ __align__(16) unsigned short As[BM*64];
    __shared__ __align__(16) unsigned short Bs[BN*64];
    __shared__ float red_s[WC][BM];
    __shared__ float red_q[WC][BM];
    __shared__ float mu_l[BM];
    __shared__ float rs_l[BM];

    const int tid  = threadIdx.x;
    const int lane = tid & 63;
    const int w    = tid >> 6;
    const int wr   = w / WC, wc = w % WC;
    const int row0 = blockIdx.x * BM;
    const int l15  = lane & 15;
    const int ko   = lane >> 4;

    f32x4 acc[4][4];
    #pragma unroll
    for (int m = 0; m < 4; ++m)
        #pragma unroll
        for (int n = 0; n < 4; ++n) acc[m][n] = (f32x4){0.f,0.f,0.f,0.f};

    for (int k0 = 0; k0 < K; k0 += 64) {
        if constexpr (AF32) {
            const float* Af = (const float*)Ap;
            constexpr int CH = (BM*8)/THREADS;    // 16B chunks per thread
            #pragma unroll
            for (int i = 0; i < CH; ++i) {
                const int q = i*THREADS + tid;
                const unsigned o  = (unsigned)q*16u;
                const int      r  = (int)(o >> 7);
                const unsigned cb = o & 127u;
                const unsigned cs = cb ^ ((unsigned)(r & 7) << 4);
                const float* src = Af + (size_t)(row0 + r)*K + k0 + (cs >> 1);
                const float4 f0 = *reinterpret_cast<const float4*>(src);
                const float4 f1 = *reinterpret_cast<const float4*>(src + 4);
                short8_t v;
                v[0]=(short)f2bf(f0.x); v[1]=(short)f2bf(f0.y); v[2]=(short)f2bf(f0.z); v[3]=(short)f2bf(f0.w);
                v[4]=(short)f2bf(f1.x); v[5]=(short)f2bf(f1.y); v[6]=(short)f2bf(f1.z); v[7]=(short)f2bf(f1.w);
                *reinterpret_cast<short8_t*>((char*)As + o) = v;
            }
        } else {
            stage64g<BM,WAVES>((const unsigned short*)Ap, (size_t)row0, K, k0, As, w, lane);
        }
        stage64g<BN,WAVES>(W, 0, K, k0, Bs, w, lane);
        __syncthreads();
        #pragma unroll
        for (int ks = 0; ks < 2; ++ks) {
            short8_t aF[4], bF[4];
            #pragma unroll
            for (int m = 0; m < 4; ++m)
                aF[m] = frag64(As, wr*64 + m*16 + l15, ks*64 + ko*16);
            #pragma unroll
            for (int n = 0; n < 4; ++n)
                bF[n] = frag64(Bs, wc*64 + n*16 + l15, ks*64 + ko*16);
            #pragma unroll
            for (int m = 0; m < 4; ++m)
                #pragma unroll
                for (int n = 0; n < 4; ++n)
                    acc[m][n] = __builtin_amdgcn_mfma_f32_16x16x32_bf16(aF[m], bF[n], acc[m][n], 0, 0, 0);
        }
        __syncthreads();
    }

    float bv[4];
    #pragma unroll
    for (int n = 0; n < 4; ++n) bv[n] = bias[wc*64 + n*16 + l15];
    #pragma unroll
    for (int m = 0; m < 4; ++m)
        #pragma unroll
        for (int n = 0; n < 4; ++n)
            #pragma unroll
            for (int r = 0; r < 4; ++r) acc[m][n][r] += bv[n];

    #pragma unroll
    for (int m = 0; m < 4; ++m) {
        #pragma unroll
        for (int r = 0; r < 4; ++r) {
            float s = acc[m][0][r] + acc[m][1][r] + acc[m][2][r] + acc[m][3][r];
            float q = acc[m][0][r]*acc[m][0][r] + acc[m][1][r]*acc[m][1][r]
                    + acc[m][2][r]*acc[m][2][r] + acc[m][3][r]*acc[m][3][r];
            s = dpp_rowsum16(s);
            q = dpp_rowsum16(q);
            if (l15 == 15) {
                int rl = wr*64 + m*16 + ko*4 + r;
                red_s[wc][rl] = s;
                red_q[wc][rl] = q;
            }
        }
    }
    __syncthreads();
    if (tid < BM) {
        float s = 0.f, q = 0.f;
        #pragma unroll
        for (int c2 = 0; c2 < WC; ++c2) { s += red_s[c2][tid]; q += red_q[c2][tid]; }
        float mu  = s * (1.0f/BN);
        float var = q * (1.0f/BN) - mu*mu;
        mu_l[tid] = mu;
        rs_l[tid] = rsqrtf(fmaxf(var, 0.f) + 1e-5f);
    }
    __syncthreads();

    float gm[4], bt[4];
    #pragma unroll
    for (int n = 0; n < 4; ++n) {
        int col = wc*64 + n*16 + l15;
        gm[n] = gam[col]; bt[n] = bet[col];
    }
    #pragma unroll
    for (int m = 0; m < 4; ++m) {
        #pragma unroll
        for (int r = 0; r < 4; ++r) {
            const int rl  = wr*64 + m*16 + ko*4 + r;
            const int row = row0 + rl;
            const float mu = mu_l[rl], rs = rs_l[rl];
            float mf = 1.f;
            if constexpr (MASKMUL) mf = (mask[row] != 0) ? 1.f : 0.f;
            #pragma unroll
            for (int n = 0; n < 4; ++n) {
                const int col = wc*64 + n*16 + l15;
                float y = (acc[m][n][r] - mu) * rs * gm[n] + bt[n];
                if constexpr (DO_LRELU) y = LRELU_(y);
                if constexpr (MASKMUL)  y *= mf;
                if constexpr (MODE == 1) {
                    ((unsigned short*)outv)[(size_t)row*BN + col] = f2bf(y);
                } else {
                    unsigned short h = f2bf(y);
                    ohi[(size_t)row*BN + col] = h;
                    olo[(size_t)row*BN + col] = f2bf(y - bf2f(h));
                }
            }
        }
    }
}

// ---------------------------------------------------------------------------
// fc1 split-bf16 MFMA GEMM, 3 phases, BK=64, fused rowsq(x2).
// ---------------------------------------------------------------------------
__global__ __launch_bounds__(256)
void fc1mm_k(const unsigned short* __restrict__ Ahi, const unsigned short* __restrict__ Alo,
             const unsigned short* __restrict__ Bhi, const unsigned short* __restrict__ Blo,
             const float* __restrict__ bias,
             unsigned short* __restrict__ Ohi, unsigned short* __restrict__ Olo,
             float* __restrict__ x2out)
{
    __shared__ __align__(16) unsigned short As[128*64];
    __shared__ __align__(16) unsigned short Bs[128*64];
    __shared__ float red_q[2][128];

    const int tid  = threadIdx.x;
    const int lane = tid & 63;
    const int w    = tid >> 6;
    const int wr   = w >> 1, wc = w & 1;
    const int row0 = blockIdx.x * 128;
    const int l15  = lane & 15;
    const int ko   = lane >> 4;

    f32x4 acc[4][4];
    #pragma unroll
    for (int m = 0; m < 4; ++m)
        #pragma unroll
        for (int n = 0; n < 4; ++n) acc[m][n] = (f32x4){0.f,0.f,0.f,0.f};

    for (int kk = 0; kk < 384; kk += 64) {
        const int p  = kk >> 7;        // 0,0,1,1,2,2
        const int kl = kk & 127;
        const unsigned short* Ap2 = (p == 1) ? Alo : Ahi;
        const unsigned short* Bp2 = (p == 2) ? Blo : Bhi;
        stage64g<128,4>(Ap2, (size_t)row0, DD, kl, As, w, lane);
        stage64g<128,4>(Bp2, 0, DD, kl, Bs, w, lane);
        __syncthreads();
        #pragma unroll
        for (int ks = 0; ks < 2; ++ks) {
            short8_t aF[4], bF[4];
            #pragma unroll
            for (int m = 0; m < 4; ++m)
                aF[m] = frag64(As, wr*64 + m*16 + l15, ks*64 + ko*16);
            #pragma unroll
            for (int n = 0; n < 4; ++n)
                bF[n] = frag64(Bs, wc*64 + n*16 + l15, ks*64 + ko*16);
            #pragma unroll
            for (int m = 0; m < 4; ++m)
                #pragma unroll
                for (int n = 0; n < 4; ++n)
                    acc[m][n] = __builtin_amdgcn_mfma_f32_16x16x32_bf16(aF[m], bF[n], acc[m][n], 0, 0, 0);
        }
        __syncthreads();
    }

    float qacc[4][4];
    #pragma unroll
    for (int m = 0; m < 4; ++m) {
        const int rbase = row0 + wr*64 + m*16 + ko*4;
        #pragma unroll
        for (int r = 0; r < 4; ++r) qacc[m][r] = 0.f;
        #pragma unroll
        for (int n = 0; n < 4; ++n) {
            const int col = wc*64 + n*16 + l15;
            const float bv = bias[col];
            #pragma unroll
            for (int r = 0; r < 4; ++r) {
                const int row = rbase + r;
                float v = acc[m][n][r] + bv;
                unsigned short h = f2bf(v);
                unsigned short l = f2bf(v - bf2f(h));
                Ohi[(size_t)row*DD + col] = h;
                Olo[(size_t)row*DD + col] = l;
                float vv = bf2f(h) + bf2f(l);
                qacc[m][r] += vv*vv;
            }
        }
    }
    #pragma unroll
    for (int m = 0; m < 4; ++m)
        #pragma unroll
        for (int r = 0; r < 4; ++r) {
            float q = dpp_rowsum16(qacc[m][r]);
            if (l15 == 15) red_q[wc][wr*64 + m*16 + ko*4 + r] = q;
        }
    __syncthreads();
    if (tid < 128) x2out[row0 + tid] = red_q[0][tid] + red_q[1][tid];
}

// ---------------------------------------------------------------------------
// Fused distance + top-9 + gather: ONE block per batch (1024 thr, 16 waves).
// ---------------------------------------------------------------------------
__global__ __launch_bounds__(1024)
void dist_topk_gather_k(const unsigned short* __restrict__ hhi,
                        const unsigned short* __restrict__ hlo,
                        const int* __restrict__ mask,
                        const float* __restrict__ x2,
                        unsigned short* __restrict__ cat)
{
    __shared__ __align__(16) unsigned short BsH[2][NNODE*64];   // 64KB
    __shared__ __align__(16) unsigned short BsL[2][NNODE*64];   // 64KB
    __shared__ unsigned char idx_s[NNODE*KNN];
    __shared__ unsigned char msk_s[NNODE];

    const int b    = blockIdx.x;
    const int tid  = threadIdx.x;
    const int lane = tid & 63;
    const int w    = tid >> 6;          // 0..15
    const int l15  = lane & 15;
    const int g    = lane >> 4;         // 0..3

    const unsigned short* Hhi = hhi + (size_t)b*NNODE*DD;
    const unsigned short* Hlo = hlo + (size_t)b*NNODE*DD;
    const float* x2b = x2 + b*NNODE;
    const int*   mkb = mask + b*NNODE;

    stage64g<NNODE,16>(Hhi, 0, DD, 0,  &BsH[0][0], w, lane);
    stage64g<NNODE,16>(Hhi, 0, DD, 64, &BsH[1][0], w, lane);
    stage64g<NNODE,16>(Hlo, 0, DD, 0,  &BsL[0][0], w, lane);
    stage64g<NNODE,16>(Hlo, 0, DD, 64, &BsL[1][0], w, lane);
    if (tid < NNODE) msk_s[tid] = (mkb[tid] != 0) ? 1 : 0;
    __syncthreads();

    const int arow = w*16 + l15;        // 0..255

    f32x4 acc[16];
    #pragma unroll
    for (int n = 0; n < 16; ++n) acc[n] = (f32x4){0.f,0.f,0.f,0.f};

    #pragma unroll
    for (int kt = 0; kt < 2; ++kt) {
        #pragma unroll
        for (int ks = 0; ks < 2; ++ks) {
            short8_t aH = frag64(&BsH[kt][0], arow, ks*64 + g*16);
            short8_t aL = frag64(&BsL[kt][0], arow, ks*64 + g*16);
            #pragma unroll
            for (int n = 0; n < 16; ++n) {
                int brow = n*16 + l15;
                short8_t bH = frag64(&BsH[kt][0], brow, ks*64 + g*16);
                short8_t bL = frag64(&BsL[kt][0], brow, ks*64 + g*16);
                acc[n] = __builtin_amdgcn_mfma_f32_16x16x32_bf16(aH, bH, acc[n], 0, 0, 0); // hi.hi
                acc[n] = __builtin_amdgcn_mfma_f32_16x16x32_bf16(aL, bH, acc[n], 0, 0, 0); // lo.hi
                acc[n] = __builtin_amdgcn_mfma_f32_16x16x32_bf16(aH, bL, acc[n], 0, 0, 0); // hi.lo
            }
        }
    }

    float x2c[16]; unsigned mk[16];
    #pragma unroll
    for (int n = 0; n < 16; ++n) {
        int col = n*16 + l15;
        x2c[n] = x2b[col];
        mk[n]  = (unsigned)msk_s[col];
    }

    #pragma unroll
    for (int r = 0; r < 4; ++r) {
        const int lrow = w*16 + g*4 + r;          // this wave's rows only
        const float x2r = x2b[lrow];
        unsigned key[16];
        #pragma unroll
        for (int n = 0; n < 16; ++n) {
            float v = x2r + x2c[n] - 2.0f*acc[n][r];
            if (!mk[n]) v = 1e10f;
            unsigned u = __float_as_uint(v);
            u = (u & 0x80000000u) ? ~u : (u | 0x80000000u);
            key[n] = (u & 0xFFFFFF00u) | (unsigned)(n*16 + l15);
        }
        for (int it = 0; it < KNN; ++it) {
            unsigned a0 = key[0]  < key[1]  ? key[0]  : key[1];
            unsigned a1 = key[2]  < key[3]  ? key[2]  : key[3];
            unsigned a2 = key[4]  < key[5]  ? key[4]  : key[5];
            unsigned a3 = key[6]  < key[7]  ? key[6]  : key[7];
            unsigned a4 = key[8]  < key[9]  ? key[8]  : key[9];
            unsigned a5 = key[10] < key[11] ? key[10] : key[11];
            unsigned a6 = key[12] < key[13] ? key[12] : key[13];
            unsigned a7 = key[14] < key[15] ? key[14] : key[15];
            unsigned b0 = a0 < a1 ? a0 : a1;
            unsigned b1 = a2 < a3 ? a2 : a3;
            unsigned b2 = a4 < a5 ? a4 : a5;
            unsigned b3 = a6 < a7 ? a6 : a7;
            unsigned c0 = b0 < b1 ? b0 : b1;
            unsigned c1 = b2 < b3 ? b2 : b3;
            unsigned lmin = c0 < c1 ? c0 : c1;
            unsigned gmin = grp16_min_u32(lmin);
            if (l15 == 0) idx_s[lrow*KNN + it] = (unsigned char)(gmin & 0xFFu);
            #pragma unroll
            for (int n = 0; n < 16; ++n)
                if (key[n] == gmin) key[n] = 0xFFFFFFFFu;
        }
    }
    // NO block barrier: gather touches only this wave's rows (same-wave DS order).

    const int gi = lane & 7;                       // granule 0..7 (8 cols)
    const unsigned cb = (unsigned)(gi * 16);       // byte col within tile
    #pragma unroll
    for (int kt = 0; kt < 2; ++kt) {
        #pragma unroll
        for (int p = 0; p < 2; ++p) {
            const int rl = w*16 + p*8 + (lane >> 3);   // this wave's row
            us8 h8 = read8sw(&BsH[kt][0], rl, cb);
            us8 l8 = read8sw(&BsL[kt][0], rl, cb);
            float hi[8], m[8];
            #pragma unroll
            for (int d = 0; d < 8; ++d) { hi[d] = bf2f(h8[d]) + bf2f(l8[d]); m[d] = -1e9f; }
            bool any = false;
            #pragma unroll
            for (int q = 0; q < KNN; ++q) {
                int j = idx_s[rl*KNN + q];
                if (msk_s[j]) {
                    any = true;
                    us8 a = read8sw(&BsH[kt][0], j, cb);
                    us8 o = read8sw(&BsL[kt][0], j, cb);
                    #pragma unroll
                    for (int d = 0; d < 8; ++d)
                        m[d] = fmaxf(m[d], bf2f(a[d]) + bf2f(o[d]) - hi[d]);
                }
            }
            us8 o1, o2;
            #pragma unroll
            for (int d = 0; d < 8; ++d) {
                o1[d] = f2bf(hi[d]);
                o2[d] = any ? f2bf(m[d]) : (unsigned short)0;
            }
            const size_t rowbase = (size_t)(b*NNODE + rl)*(2*DD);
            const int c0 = kt*64 + gi*8;
            *reinterpret_cast<us8*>(&cat[rowbase + c0])      = o1;
            *reinterpret_cast<us8*>(&cat[rowbase + DD + c0]) = o2;
        }
    }
}

// ---------------------------------------------------------------------------
// Fused conv + fc2 + FFN with ring-3 weight staging AND counted-vmcnt
// barriers (T4): stages issued AFTER each barrier (WAR-safe); each phase
// waits only its own tile (vmcnt(4)), never draining the queue. lgkmcnt(0)
// added only where freshly ds-written LDS (h2s/Xs) is consumed.
// ---------------------------------------------------------------------------
__global__ __launch_bounds__(256)
void conv_ffn_k(const unsigned short* __restrict__ cat,
                const unsigned short* __restrict__ Wc,   // [128][256]
                const float* __restrict__ cb,
                const unsigned short* __restrict__ W2c,  // [128][128] (fc2)
                const float* __restrict__ fb,
                const unsigned short* __restrict__ W1,   // [512][128] (ffn1)
                const float* __restrict__ b1,
                const unsigned short* __restrict__ W2f,  // [128][512] (ffn2)
                const float* __restrict__ b2,
                const int* __restrict__ mask,
                unsigned short* xhi,                     // in: x residual / out: new x
                unsigned short* xlo)
{
    __shared__ __align__(16) unsigned short Bs[3][128*64];   // 48KB ring
    __shared__ __align__(16) unsigned short h2s[2][64*64];   // 16KB
    __shared__ __align__(16) unsigned short Xs[2][64*64];    // 16KB; conv A-tiles alias

    const int tid  = threadIdx.x;
    const int lane = tid & 63;
    const int w    = tid >> 6;      // 0..3: wave col group
    const int row0 = blockIdx.x * 64;
    const int l15  = lane & 15;
    const int ko   = lane >> 4;

    // tile t -> weight source (t = 0..21); 4 VMEM instr per wave each
    auto issueB = [&](int t) {
        unsigned short* buf = &Bs[t % 3][0];
        if (t < 4)      stage64g<128,4>(Wc,  0, 256, t*64, buf, w, lane);
        else if (t < 6) stage64g<128,4>(W2c, 0, 128, (t-4)*64, buf, w, lane);
        else {
            int c = (t-6) >> 2, j = (t-6) & 3;
            if (j < 2) stage64g<128,4>(W1, (size_t)(c*128), DD, j*64, buf, w, lane);
            else       stage64g<128,4>(W2f, 0, FFND, c*128 + (j-2)*64, buf, w, lane);
        }
    };

    #define MM8(ATILE, BTILE, ACC)                                              \
        { _Pragma("unroll")                                                     \
          for (int ks = 0; ks < 2; ++ks) {                                      \
            short8_t aF[4], bF[2];                                              \
            _Pragma("unroll")                                                   \
            for (int m = 0; m < 4; ++m) aF[m] = frag64(ATILE, m*16 + l15, ks*64 + ko*16); \
            _Pragma("unroll")                                                   \
            for (int n = 0; n < 2; ++n) bF[n] = frag64(BTILE, w*32 + n*16 + l15, ks*64 + ko*16); \
            _Pragma("unroll")                                                   \
            for (int m = 0; m < 4; ++m)                                         \
              _Pragma("unroll")                                                 \
              for (int n = 0; n < 2; ++n)                                       \
                ACC[m][n] = __builtin_amdgcn_mfma_f32_16x16x32_bf16(aF[m], bF[n], ACC[m][n], 0, 0, 0); } }

    #define H2WRITE(ACC, BPTR, DST)                                             \
        { const int kt_ = w >> 1;                                               \
          _Pragma("unroll")                                                     \
          for (int n = 0; n < 2; ++n) {                                         \
            const int col_ = w*32 + n*16 + l15;                                 \
            const float bv_ = (BPTR)[col_];                                     \
            const unsigned bc_ = (unsigned)(((w & 1)*32 + n*16 + l15) * 2);     \
            _Pragma("unroll")                                                   \
            for (int m = 0; m < 4; ++m)                                         \
              _Pragma("unroll")                                                 \
              for (int r = 0; r < 4; ++r) {                                     \
                const int row_ = m*16 + ko*4 + r;                               \
                float v_ = LRELU_(ACC[m][n][r] + bv_);                          \
                *(unsigned short*)((char*)&(DST)[kt_][0] + row_*128             \
                    + (bc_ ^ ((unsigned)(row_ & 7) << 4))) = f2bf(v_); } } }

    // ---- prologue (issue order: Xs0, B0, Xs1, B1 -> 12 outstanding) ----
    stage64g<64,4>(cat, (size_t)row0, 256, 0,  &Xs[0][0], w, lane);
    issueB(0);
    stage64g<64,4>(cat, (size_t)row0, 256, 64, &Xs[1][0], w, lane);
    issueB(1);

    // ---- conv phases P0..P3 ----
    f32x4 accc[4][2];
    #pragma unroll
    for (int m = 0; m < 4; ++m)
        #pragma unroll
        for (int n = 0; n < 2; ++n) accc[m][n] = (f32x4){0.f,0.f,0.f,0.f};

    WAITB6;                                    // P0: need Xs0+B0 (Xs1+B1 = 6 out)
    issueB(2);
    MM8(&Xs[0][0], &Bs[0][0], accc);

    WAITB4;                                    // P1: need Xs1+B1 (B2 = 4 out)
    stage64g<64,4>(cat, (size_t)row0, 256, 128, &Xs[0][0], w, lane);
    issueB(3);
    MM8(&Xs[1][0], &Bs[1][0], accc);

    WAITB4;                                    // P2: need B2+cat2 (B3 = 4 out)
    stage64g<64,4>(cat, (size_t)row0, 256, 192, &Xs[1][0], w, lane);
    issueB(4);
    MM8(&Xs[0][0], &Bs[2][0], accc);

    WAITB4;                                    // P3: need B3+cat3 (B4 = 4 out)
    issueB(5);
    MM8(&Xs[1][0], &Bs[0][0], accc);
    H2WRITE(accc, cb, h2s);

    // ---- fc2 phases P4..P5 ----
    f32x4 accx[4][2];
    #pragma unroll
    for (int m = 0; m < 4; ++m)
        #pragma unroll
        for (int n = 0; n < 2; ++n) accx[m][n] = (f32x4){0.f,0.f,0.f,0.f};

    WAITBL4;                                   // P4: need B4 + h2s writes
    issueB(6);
    MM8(&h2s[0][0], &Bs[1][0], accx);

    WAITB4;                                    // P5: need B5 (B6 = 4 out)
    issueB(7);
    MM8(&h2s[1][0], &Bs[2][0], accx);
    // xn = accx + fb + residual(hi+lo); bf16 image -> Xs
    float xn[4][2][4];
    {
        const int kt = w >> 1;
        #pragma unroll
        for (int n = 0; n < 2; ++n) {
            const int col = w*32 + n*16 + l15;
            const float bv = fb[col];
            const unsigned bc = (unsigned)(((w & 1)*32 + n*16 + l15) * 2);
            #pragma unroll
            for (int m = 0; m < 4; ++m) {
                #pragma unroll
                for (int r = 0; r < 4; ++r) {
                    const int row = m*16 + ko*4 + r;
                    const size_t gix = (size_t)(row0 + row)*DD + col;
                    float res = bf2f(xhi[gix]) + bf2f(xlo[gix]);
                    float v = accx[m][n][r] + bv + res;
                    xn[m][n][r] = v;
                    *(unsigned short*)((char*)&Xs[kt][0] + row*128
                        + (bc ^ ((unsigned)(row & 7) << 4))) = f2bf(v);
                }
            }
        }
    }

    // ---- FFN chunks, phases P6..P21 ----
    f32x4 acc2[4][2];
    #pragma unroll
    for (int m = 0; m < 4; ++m)
        #pragma unroll
        for (int n = 0; n < 2; ++n) acc2[m][n] = (f32x4){0.f,0.f,0.f,0.f};

    #pragma unroll
    for (int c = 0; c < 4; ++c) {
        const int tb = 6 + c*4;
        f32x4 acc1[4][2];
        #pragma unroll
        for (int m = 0; m < 4; ++m)
            #pragma unroll
            for (int n = 0; n < 2; ++n) acc1[m][n] = (f32x4){0.f,0.f,0.f,0.f};

        // j0: need B_tb (+ Xs xn writes on first chunk)
        if (c == 0) { WAITBL4; } else { WAITB4; }
        if (tb+2 <= 21) issueB(tb+2);
        MM8(&Xs[0][0], &Bs[tb % 3][0], acc1);

        // j1: need B_{tb+1}
        WAITB4;
        if (tb+3 <= 21) issueB(tb+3);
        MM8(&Xs[1][0], &Bs[(tb+1) % 3][0], acc1);
        H2WRITE(acc1, b1 + c*128, h2s);

        // j2: need B_{tb+2} + h2s writes
        WAITBL4;
        if (tb+4 <= 21) issueB(tb+4);
        MM8(&h2s[0][0], &Bs[(tb+2) % 3][0], acc2);

        // j3: need B_{tb+3}; last phase (t=21) has nothing newer -> vmcnt(0)
        if (c == 3) { WAITB0; } else { WAITB4; }
        if (tb+5 <= 21) issueB(tb+5);
        MM8(&h2s[1][0], &Bs[(tb+3) % 3][0], acc2);
    }

    // ---- epilogue: x = acc2 + b2 + xn, masked; write split ----
    #pragma unroll
    for (int m = 0; m < 4; ++m) {
        const int rbase = row0 + m*16 + ko*4;
        #pragma unroll
        for (int n = 0; n < 2; ++n) {
            const int col = w*32 + n*16 + l15;
            const float bv = b2[col];
            #pragma unroll
            for (int r = 0; r < 4; ++r) {
                const int row = rbase + r;
                float v = acc2[m][n][r] + bv + xn[m][n][r];
                v *= (mask[row] != 0) ? 1.f : 0.f;
                unsigned short h = f2bf(v);
                xhi[(size_t)row*DD + col] = h;
                xlo[(size_t)row*DD + col] = f2bf(v - bf2f(h));
            }
        }
    }
    #undef MM8
    #undef H2WRITE
}

__global__ __launch_bounds__(128)
void pool_k(const unsigned short* __restrict__ xhi, const unsigned short* __restrict__ xlo,
            const int* __restrict__ mask,
            float* __restrict__ g, unsigned short* __restrict__ gbf)
{
    const int b = blockIdx.x, c = threadIdx.x;
    float s = 0.f; int cnt = 0;
    for (int n = 0; n < NNODE; ++n) {
        const size_t ix = ((size_t)b*NNODE + n)*DD + c;
        s += bf2f(xhi[ix]) + bf2f(xlo[ix]);
        cnt += (mask[b*NNODE + n] != 0) ? 1 : 0;
    }
    float v = s / fmaxf((float)cnt, 1.0f);
    g[b*DD + c] = v;
    gbf[b*DD + c] = f2bf(v);
}

// ---------------------------------------------------------------------------
// All weight transpose-casts in ONE kernel (compile-time job table).
// ---------------------------------------------------------------------------
__global__ __launch_bounds__(256)
void prep_all_k(const float* __restrict__ emb_w1, const float* __restrict__ emb_w2,
                const float* __restrict__ conv_w, const float* __restrict__ fc2_w,
                const float* __restrict__ f1_w,   const float* __restrict__ f2_w,
                const float* __restrict__ fc1_w,  const float* __restrict__ ow1,
                const float* __restrict__ ow2,
                unsigned short* __restrict__ emb_w1t, unsigned short* __restrict__ emb_w2t,
                unsigned short* __restrict__ conv_wt, unsigned short* __restrict__ fc2_wt,
                unsigned short* __restrict__ ffn1_wt, unsigned short* __restrict__ ffn2_wt,
                unsigned short* __restrict__ fc1_wthi, unsigned short* __restrict__ fc1_wtlo,
                unsigned short* __restrict__ ow1t, unsigned short* __restrict__ ow2t)
{
    __shared__ float tile[32][33];
    const int tx = threadIdx.x & 31, ty = threadIdx.x >> 5;

    int bid = blockIdx.x;
    const float* src = nullptr; unsigned short* dst = nullptr; unsigned short* dlo = nullptr;
    int K = 0, N = 0;
    do {
        if (bid < 16)  { src = emb_w1; dst = emb_w1t; K = 64;  N = 256; break; }  bid -= 16;
        if (bid < 32)  { src = emb_w2; dst = emb_w2t; K = 256; N = 128; break; }  bid -= 32;
        if (bid < 64)  { int l = bid >> 5; bid &= 31;
                         src = conv_w + (size_t)l*256*128; dst = conv_wt + (size_t)l*128*256;
                         K = 256; N = 128; break; }                               bid -= 64;
        if (bid < 32)  { int l = bid >> 4; bid &= 15;
                         src = fc2_w + (size_t)l*128*128; dst = fc2_wt + (size_t)l*128*128;
                         K = 128; N = 128; break; }                               bid -= 32;
        if (bid < 128) { int l = bid >> 6; bid &= 63;
                         src = f1_w + (size_t)l*128*512; dst = ffn1_wt + (size_t)l*512*128;
                         K = 128; N = 512; break; }                               bid -= 128;
        if (bid < 128) { int l = bid >> 6; bid &= 63;
                         src = f2_w + (size_t)l*512*128; dst = ffn2_wt + (size_t)l*128*512;
                         K = 512; N = 128; break; }                               bid -= 128;
        if (bid < 32)  { int l = bid >> 4; bid &= 15;
                         src = fc1_w + (size_t)l*128*128;
                         dst = fc1_wthi + (size_t)l*128*128; dlo = fc1_wtlo + (size_t)l*128*128;
                         K = 128; N = 128; break; }                               bid -= 32;
        if (bid < 64)  { src = ow1; dst = ow1t; K = 128; N = 512; break; }        bid -= 64;
        { src = ow2; dst = ow2t; K = 512; N = 2048; }
    } while (0);

    const int nbx = N / 32;
    const int bx = bid % nbx, by = bid / nbx;
    const int k0 = by*32, n0 = bx*32;

    #pragma unroll
    for (int i = ty; i < 32; i += 8)
        tile[i][tx] = src[(size_t)(k0+i)*N + n0+tx];
    __syncthreads();
    #pragma unroll
    for (int i = ty; i < 32; i += 8) {
        float v = tile[tx][i];
        unsigned short h = f2bf(v);
        dst[(size_t)(n0+i)*K + k0+tx] = h;
        if (dlo) dlo[(size_t)(n0+i)*K + k0+tx] = f2bf(v - bf2f(h));
    }
}

// ---------------------------------------------------------------------------
extern "C" void kernel_launch(void* const* d_in, const int* in_sizes, int n_in,
                              void* d_out, int out_size, void* d_ws, size_t ws_size,
                              hipStream_t stream)
{
    const float* nodes  = (const float*)d_in[0];
    const int*   maskp  = (const int*)  d_in[1];
    const float* emb_w1 = (const float*)d_in[2];
    const float* emb_b1 = (const float*)d_in[3];
    const float* ln1_g  = (const float*)d_in[4];
    const float* ln1_b  = (const float*)d_in[5];
    const float* emb_w2 = (const float*)d_in[6];
    const float* emb_b2 = (const float*)d_in[7];
    const float* ln2_g  = (const float*)d_in[8];
    const float* ln2_b  = (const float*)d_in[9];
    const float* fc1_w  = (const float*)d_in[10];
    const float* fc1_b  = (const float*)d_in[11];
    const float* conv_w = (const float*)d_in[12];
    const float* conv_b = (const float*)d_in[13];
    const float* fc2_w  = (const float*)d_in[14];
    const float* fc2_b  = (const float*)d_in[15];
    const float* f1_w   = (const float*)d_in[16];
    const float* f1_b   = (const float*)d_in[17];
    const float* f2_w   = (const float*)d_in[18];
    const float* f2_b   = (const float*)d_in[19];
    const float* ow1    = (const float*)d_in[20];
    const float* ob1    = (const float*)d_in[21];
    const float* ow2    = (const float*)d_in[22];
    const float* ob2    = (const float*)d_in[23];
    float* out = (float*)d_out;

    // ---- workspace layout ----
    char* base = (char*)d_ws;
    char*  H   = base + (size_t)BNROWS*DD*4;            // x_hi/x_lo (residual-carrying)
    char*  BIG = H + (size_t)BNROWS*DD*4;               // cat [0:33.5M] + h split [33.5:67.1M]
    float*          x2    = (float*)(BIG + (size_t)BNROWS*2*DD*4);
    float*          g     = (float*)(x2 + BNROWS);
    unsigned short* g_bf  = (unsigned short*)(g + BB*DD);
    unsigned short* hid2_bf = g_bf + BB*DD;
    unsigned short* wbuf  = hid2_bf + BB*FFND;

    unsigned short* x_hi   = (unsigned short*)H;
    unsigned short* x_lo   = x_hi + (size_t)BNROWS*DD;
    unsigned short* t256_bf= (unsigned short*)base;     // embed phase scratch
    unsigned short* cat_bf = (unsigned short*)BIG;
    unsigned short* h_hi   = (unsigned short*)(BIG + (size_t)BNROWS*DD*2);
    unsigned short* h_lo   = h_hi + (size_t)BNROWS*DD;

    unsigned short* emb_w1t  = wbuf;
    unsigned short* emb_w2t  = emb_w1t + 256*64;
    unsigned short* conv_wt  = emb_w2t + 128*256;
    unsigned short* fc2_wt   = conv_wt + 2*128*256;
    unsigned short* ffn1_wt  = fc2_wt  + 2*128*128;
    unsigned short* ffn2_wt  = ffn1_wt + 2*512*128;
    unsigned short* fc1_wthi = ffn2_wt + 2*128*512;
    unsigned short* fc1_wtlo = fc1_wthi + 2*128*128;
    unsigned short* ow1t     = fc1_wtlo + 2*128*128;
    unsigned short* ow2t     = ow1t + 512*128;

    const dim3 blk(256);

    // ---- all weight transpose-casts (one launch) ----
    prep_all_k<<<1520, blk, 0, stream>>>(
        emb_w1, emb_w2, conv_w, fc2_w, f1_w, f2_w, fc1_w, ow1, ow2,
        emb_w1t, emb_w2t, conv_wt, fc2_wt, ffn1_wt, ffn2_wt,
        fc1_wthi, fc1_wtlo, ow1t, ow2t);

    // ---- Embedding (GEMM + fused LN) ----
    bgemm_ln_k<2,4,true,false,1,true>
        <<<dim3(BNROWS/128), dim3(512), 0, stream>>>
        (nodes, emb_w1t, emb_b1, ln1_g, ln1_b, nullptr, t256_bf, nullptr, nullptr, PP2);
    bgemm_ln_k<2,2,false,true,2,false>
        <<<dim3(BNROWS/128), dim3(256), 0, stream>>>
        (t256_bf, emb_w2t, emb_b2, ln2_g, ln2_b, maskp, nullptr, x_hi, x_lo, 2*DD);

    // ---- ViG blocks ----
    for (int l = 0; l < LLAY; ++l) {
        const float* fc1b = fc1_b + (size_t)l*DD;
        const float* cb   = conv_b + (size_t)l*DD;
        const float* fc2b = fc2_b + (size_t)l*DD;
        const float* b1   = f1_b + (size_t)l*FFND;
        const float* b2   = f2_b + (size_t)l*DD;

        fc1mm_k<<<dim3(BNROWS/128), blk, 0, stream>>>
            (x_hi, x_lo, fc1_wthi + (size_t)l*DD*DD, fc1_wtlo + (size_t)l*DD*DD,
             fc1b, h_hi, h_lo, x2);
        dist_topk_gather_k<<<dim3(BB), dim3(1024), 0, stream>>>
            (h_hi, h_lo, maskp, x2, cat_bf);
        conv_ffn_k<<<dim3(BNROWS/64), blk, 0, stream>>>
            (cat_bf, conv_wt + (size_t)l*DD*2*DD, cb,
             fc2_wt + (size_t)l*DD*DD, fc2b,
             ffn1_wt + (size_t)l*FFND*DD, b1,
             ffn2_wt + (size_t)l*DD*FFND, b2, maskp,
             x_hi, x_lo);
    }

    // ---- Pool + head (bf16 MFMA) ----
    pool_k<<<BB, 128, 0, stream>>>(x_hi, x_lo, maskp, g, g_bf);
    bgemm_k<ACT_LRELU,false,false,false,true,false>
        <<<dim3(BB/128, 512/128), blk, 0, stream>>>
        (g_bf, ow1t, ob1, nullptr, nullptr, nullptr, hid2_bf, nullptr, nullptr, BB, 512, DD);
    bgemm_k<ACT_NONE,false,false,true,false,false>
        <<<dim3(BB/128, 2048/128), blk, 0, stream>>>
        (hid2_bf, ow2t, ob2, nullptr, nullptr, out, nullptr, nullptr, nullptr, BB, 2048, 512);
}